// Round 6
// baseline (3012.088 us; speedup 1.0000x reference)
//
#include <hip/hip_runtime.h>

#define SEQ 2048
#define DMODEL 1024
#define DINNER 2048
#define DSTATE 16
#define DTRANK 64
#define NLAYER 8
#define VOCAB 32000
#define NCHUNK 32
#define CLEN 64   // SEQ / NCHUNK
#define PROJ_NCH 16
#define PROJ_KC 128  // DINNER / PROJ_NCH

typedef float f32x4 __attribute__((ext_vector_type(4)));
typedef short bf16x8 __attribute__((ext_vector_type(8)));

__device__ __forceinline__ ushort f2bf(float f) {
  union { float f; unsigned u; } v; v.f = f;
  unsigned r = v.u + 0x7fffu + ((v.u >> 16) & 1u);
  return (ushort)(r >> 16);
}

__device__ __forceinline__ void lds_load16(const void* g, void* l) {
  __builtin_amdgcn_global_load_lds(
      (const __attribute__((address_space(1))) void*)g,
      (__attribute__((address_space(3))) void*)l, 16, 0, 0);
}

// ---------------- 8-phase counted-vmcnt MFMA GEMM (T2+T3+T4+T5) -------------
// C[M,N] = A[M,K] @ B[N,K]^T.  BN=256 fixed, BM template (256 or 128).
// Epilogue: per-wave LDS transpose (reusing Bs) -> float4 stores.
template<int BM, bool NTS>
__global__ __launch_bounds__(512, 2) void gemm8p_bt_bf16(
    const ushort* __restrict__ A, const ushort* __restrict__ B,
    float* __restrict__ C, int N, int K)
{
  constexpr int MFR = BM / 32;       // m-fragments per wave
  constexpr int MPP = MFR / 4;       // m-fragments per phase
  constexpr int ALOADS = BM / 128;   // global_load_lds per thread per A-half
  __shared__ __align__(16) ushort As[2 * BM * 64];
  __shared__ __align__(16) ushort Bs[2 * 256 * 64];
  const int tid = threadIdx.x;
  const int lane = tid & 63;
  const int wid = tid >> 6;
  const int wr = wid >> 2, wc = wid & 3;
  const int rr = lane & 15, kq = lane >> 4;

  unsigned nwg = gridDim.x * gridDim.y;
  unsigned lb = blockIdx.y * gridDim.x + blockIdx.x;
  if ((nwg & 7u) == 0u) { unsigned cpx = nwg >> 3; lb = (lb & 7u) * cpx + (lb >> 3); }
  const int bm = (int)(lb % gridDim.x) * BM;
  const int bn = (int)(lb / gridDim.x) * 256;

  const ushort* Abase = A + (size_t)bm * K;
  const ushort* Bbase = B + (size_t)bn * K;

  auto stageA = [&](int buf, int h, int kt) {
    constexpr int HR = BM / 2;
#pragma unroll
    for (int L = 0; L < ALOADS; ++L) {
      int f = L * 512 + tid;
      int rl = f >> 3, g = f & 7;
      int gg = g ^ (rl & 7);  // pre-swizzled source granule
      lds_load16(Abase + (size_t)(h * HR + rl) * K + kt * 64 + gg * 8,
                 (void*)(As + buf * (BM * 64) + (h * HR + rl) * 64 + g * 8));
    }
  };
  auto stageB = [&](int buf, int h, int kt) {
#pragma unroll
    for (int L = 0; L < 2; ++L) {
      int f = L * 512 + tid;
      int rl = f >> 3, g = f & 7;
      int gg = g ^ (rl & 7);
      lds_load16(Bbase + (size_t)(h * 128 + rl) * K + kt * 64 + gg * 8,
                 (void*)(Bs + buf * (256 * 64) + (h * 128 + rl) * 64 + g * 8));
    }
  };
  auto rdA = [&](int buf, int r, int kbyte) {
    int sw = kbyte ^ ((r & 7) << 4);
    return *(const bf16x8*)(As + buf * (BM * 64) + r * 64 + (sw >> 1));
  };
  auto rdB = [&](int buf, int r, int kbyte) {
    int sw = kbyte ^ ((r & 7) << 4);
    return *(const bf16x8*)(Bs + buf * (256 * 64) + r * 64 + (sw >> 1));
  };

  f32x4 acc[MFR][4];
#pragma unroll
  for (int m = 0; m < MFR; ++m)
#pragma unroll
    for (int n = 0; n < 4; ++n) acc[m][n] = (f32x4){0.f, 0.f, 0.f, 0.f};

  const int NT = K >> 6;
  stageA(0, 0, 0); stageA(0, 1, 0); stageB(0, 0, 0); stageB(0, 1, 0);

  for (int t = 0; t < NT; ++t) {
    const int cur = t & 1;
    const bool more = (t + 1 < NT);
    if (more) stageA(cur ^ 1, 0, t + 1);
    if (more) {
      if constexpr (BM == 256) asm volatile("s_waitcnt vmcnt(2)" ::: "memory");
      else                     asm volatile("s_waitcnt vmcnt(1)" ::: "memory");
    } else {
      asm volatile("s_waitcnt vmcnt(0)" ::: "memory");
    }
    __syncthreads();

    bf16x8 bfr[4][2];
#pragma unroll
    for (int n = 0; n < 4; ++n)
#pragma unroll
      for (int kk = 0; kk < 2; ++kk)
        bfr[n][kk] = rdB(cur, wc * 64 + n * 16 + rr, kk * 64 + kq * 16);

#pragma unroll
    for (int mq = 0; mq < 4; ++mq) {
      if (mq == 1 && more) stageA(cur ^ 1, 1, t + 1);
      if (mq == 2 && more) stageB(cur ^ 1, 0, t + 1);
      if (mq == 3 && more) stageB(cur ^ 1, 1, t + 1);
      bf16x8 af[MPP][2];
#pragma unroll
      for (int mf = 0; mf < MPP; ++mf)
#pragma unroll
        for (int kk = 0; kk < 2; ++kk)
          af[mf][kk] = rdA(cur, wr * (BM / 2) + (mq * MPP + mf) * 16 + rr, kk * 64 + kq * 16);
      __builtin_amdgcn_s_setprio(1);
#pragma unroll
      for (int kk = 0; kk < 2; ++kk)
#pragma unroll
        for (int mf = 0; mf < MPP; ++mf)
#pragma unroll
          for (int n = 0; n < 4; ++n)
            acc[mq * MPP + mf][n] = __builtin_amdgcn_mfma_f32_16x16x32_bf16(
                af[mf][kk], bfr[n][kk], acc[mq * MPP + mf][n], 0, 0, 0);
      __builtin_amdgcn_s_setprio(0);
    }
    __syncthreads();
  }

  // Epilogue: per-wave LDS transpose in Bs (16 rows x 64 cols f32, stride 68)
  __syncthreads();  // all waves done reading Bs[cur]
  float* ep = (float*)Bs + wid * (16 * 68);
  const int cg = bn + wc * 64;
#pragma unroll
  for (int m = 0; m < MFR; ++m) {
    const int r0g = bm + wr * (BM / 2) + m * 16;
#pragma unroll
    for (int n = 0; n < 4; ++n)
#pragma unroll
      for (int j = 0; j < 4; ++j)
        ep[(kq * 4 + j) * 68 + n * 16 + rr] = acc[m][n][j];
#pragma unroll
    for (int i = 0; i < 4; ++i) {
      int row = i * 4 + kq;
      f32x4 v = *(const f32x4*)&ep[row * 68 + rr * 4];
      f32x4* dst = (f32x4*)&C[(size_t)(r0g + row) * N + cg + rr * 4];
      if constexpr (NTS) __builtin_nontemporal_store(v, dst);
      else *dst = v;
    }
  }
}

// ---------------- bf16 MFMA GEMM (2-phase 128x128), keeps fused addsrc ------
__global__ __launch_bounds__(256) void gemm_bt_bf16(
    const ushort* __restrict__ A, const ushort* __restrict__ B,
    const float* __restrict__ addsrc, float* __restrict__ C,
    int M, int N, int K)
{
  __shared__ __align__(16) ushort As[128 * 64];
  __shared__ __align__(16) ushort Bs[128 * 64];
  const int tid = threadIdx.x;
  const int lane = tid & 63;
  const int wave = tid >> 6;
  const int wr = wave >> 1, wc = wave & 1;

  unsigned nwg = gridDim.x * gridDim.y;
  unsigned lb = blockIdx.y * gridDim.x + blockIdx.x;
  if ((nwg & 7u) == 0u) {
    unsigned cpx = nwg >> 3;
    lb = (lb & 7u) * cpx + (lb >> 3);
  }
  const int bm = (lb % gridDim.x) * 128;
  const int bn = (lb / gridDim.x) * 128;
  const int rr = lane & 15, kq = lane >> 4;

  f32x4 acc[4][4];
#pragma unroll
  for (int m = 0; m < 4; ++m)
#pragma unroll
    for (int n = 0; n < 4; ++n) acc[m][n] = (f32x4){0.f, 0.f, 0.f, 0.f};

  for (int kt = 0; kt < K; kt += 64) {
#pragma unroll
    for (int i = 0; i < 4; ++i) {
      int fb = i * 256 + tid;
      int row = fb >> 3, cb = fb & 7;
      lds_load16(A + (size_t)(bm + row) * K + kt + cb * 8, (void*)(As + (size_t)fb * 8));
      lds_load16(B + (size_t)(bn + row) * K + kt + cb * 8, (void*)(Bs + (size_t)fb * 8));
    }
    __syncthreads();
#pragma unroll
    for (int ks = 0; ks < 2; ++ks) {
      bf16x8 af[4], bfr[4];
      const int koff = ks * 32 + kq * 8;
#pragma unroll
      for (int m = 0; m < 4; ++m)
        af[m] = *(const bf16x8*)&As[(wr * 64 + m * 16 + rr) * 64 + koff];
#pragma unroll
      for (int n = 0; n < 4; ++n)
        bfr[n] = *(const bf16x8*)&Bs[(wc * 64 + n * 16 + rr) * 64 + koff];
#pragma unroll
      for (int m = 0; m < 4; ++m)
#pragma unroll
        for (int n = 0; n < 4; ++n)
          acc[m][n] = __builtin_amdgcn_mfma_f32_16x16x32_bf16(af[m], bfr[n], acc[m][n], 0, 0, 0);
    }
    __syncthreads();
  }
#pragma unroll
  for (int m = 0; m < 4; ++m) {
    const int r0 = bm + wr * 64 + m * 16 + kq * 4;
#pragma unroll
    for (int n = 0; n < 4; ++n) {
      const int cc = bn + wc * 64 + n * 16 + rr;
#pragma unroll
      for (int j = 0; j < 4; ++j) {
        size_t idx = (size_t)(r0 + j) * N + cc;
        float v = acc[m][n][j];
        if (addsrc) v += addsrc[idx];
        C[idx] = v;
      }
    }
  }
}

// ---------------- fused conv+SiLU + split-K projection GEMM -----------------
// Per block (bm, kc-chunk): u = silu(causal_conv(u0)) for [64 rows][128 chans],
// written to global u AND used as A-tile for Cp[chunk] = u @ Wbcdt^T.
__global__ __launch_bounds__(256) void convproj_f32(
    const float* __restrict__ resu0, const float* __restrict__ Wbcdt,
    const float* __restrict__ Wconv, float* __restrict__ u,
    float* __restrict__ Cp, int M)
{
  __shared__ float u0s[67][68];
  __shared__ float As[64][65];
  __shared__ float Ws[96][65];
  const int t = threadIdx.x;
  const int bm = blockIdx.x * 64;
  const int kc = blockIdx.y * PROJ_KC;
  const int ty = t >> 4, tx = t & 15;
  const int r0 = ty * 4, c0 = tx * 6;
  float acc[4][6] = {};

  for (int h = 0; h < 2; ++h) {
    const int cbase = kc + h * 64;
    // stage u0 rows bm-3..bm+63 (67) x 64 cols (float4)
    for (int i = t; i < 67 * 16; i += 256) {
      int r = i >> 4, c4 = (i & 15) * 4;
      int gr = bm - 3 + r;
      float4 v = (gr >= 0)
          ? *(const float4*)&resu0[(size_t)gr * (2 * DINNER) + DINNER + cbase + c4]
          : (float4){0.f, 0.f, 0.f, 0.f};
      *(float4*)&u0s[r][c4] = v;
    }
    // stage Ws 96 x 64 (scalar, keeps stride-65 padding)
    for (int i = t; i < 96 * 64; i += 256) {
      int r = i >> 6, c = i & 63;
      Ws[r][c] = Wbcdt[(size_t)r * DINNER + cbase + c];
    }
    __syncthreads();
    // conv + silu: each thread 4 rows x 4 cols
    {
      const int rr0 = (t >> 4) * 4;
      const int cc0 = (t & 15) * 4;
      float4 w0 = *(const float4*)&Wconv[(cbase + cc0 + 0) * 4];
      float4 w1 = *(const float4*)&Wconv[(cbase + cc0 + 1) * 4];
      float4 w2 = *(const float4*)&Wconv[(cbase + cc0 + 2) * 4];
      float4 w3 = *(const float4*)&Wconv[(cbase + cc0 + 3) * 4];
#pragma unroll
      for (int i = 0; i < 4; ++i) {
        int lr = rr0 + i;  // u0s rows lr..lr+3 = seq bm+lr-3 .. bm+lr
        float4 a0 = *(const float4*)&u0s[lr + 0][cc0];
        float4 a1 = *(const float4*)&u0s[lr + 1][cc0];
        float4 a2 = *(const float4*)&u0s[lr + 2][cc0];
        float4 a3 = *(const float4*)&u0s[lr + 3][cc0];
        float o0 = a0.x * w0.x + a1.x * w0.y + a2.x * w0.z + a3.x * w0.w;
        float o1 = a0.y * w1.x + a1.y * w1.y + a2.y * w1.z + a3.y * w1.w;
        float o2 = a0.z * w2.x + a1.z * w2.y + a2.z * w2.z + a3.z * w2.w;
        float o3 = a0.w * w3.x + a1.w * w3.y + a2.w * w3.z + a3.w * w3.w;
        o0 = o0 / (1.f + expf(-o0));
        o1 = o1 / (1.f + expf(-o1));
        o2 = o2 / (1.f + expf(-o2));
        o3 = o3 / (1.f + expf(-o3));
        As[lr][cc0 + 0] = o0;
        As[lr][cc0 + 1] = o1;
        As[lr][cc0 + 2] = o2;
        As[lr][cc0 + 3] = o3;
        float4 ov = {o0, o1, o2, o3};
        *(float4*)&u[(size_t)(bm + lr) * DINNER + cbase + cc0] = ov;
      }
    }
    __syncthreads();
#pragma unroll 4
    for (int kk = 0; kk < 64; ++kk) {
      float a0 = As[r0][kk], a1 = As[r0 + 1][kk], a2 = As[r0 + 2][kk], a3 = As[r0 + 3][kk];
      float w0 = Ws[c0][kk], w1 = Ws[c0 + 1][kk], w2 = Ws[c0 + 2][kk];
      float w3 = Ws[c0 + 3][kk], w4 = Ws[c0 + 4][kk], w5 = Ws[c0 + 5][kk];
      acc[0][0] += a0 * w0; acc[0][1] += a0 * w1; acc[0][2] += a0 * w2;
      acc[0][3] += a0 * w3; acc[0][4] += a0 * w4; acc[0][5] += a0 * w5;
      acc[1][0] += a1 * w0; acc[1][1] += a1 * w1; acc[1][2] += a1 * w2;
      acc[1][3] += a1 * w3; acc[1][4] += a1 * w4; acc[1][5] += a1 * w5;
      acc[2][0] += a2 * w0; acc[2][1] += a2 * w1; acc[2][2] += a2 * w2;
      acc[2][3] += a2 * w3; acc[2][4] += a2 * w4; acc[2][5] += a2 * w5;
      acc[3][0] += a3 * w0; acc[3][1] += a3 * w1; acc[3][2] += a3 * w2;
      acc[3][3] += a3 * w3; acc[3][4] += a3 * w4; acc[3][5] += a3 * w5;
    }
    __syncthreads();
  }
  float* cp = Cp + (size_t)blockIdx.y * M * 96;
#pragma unroll
  for (int i = 0; i < 4; ++i)
#pragma unroll
    for (int j = 0; j < 6; ++j)
      cp[(size_t)(bm + r0 + i) * 96 + c0 + j] = acc[i][j];
}

__global__ __launch_bounds__(256) void proj_reduce(
    const float* __restrict__ Cp, float* __restrict__ bcdt, int M)
{
  int idx = blockIdx.x * 256 + threadIdx.x;
  float s = 0.f;
#pragma unroll
  for (int c = 0; c < PROJ_NCH; ++c) s += Cp[(size_t)c * M * 96 + idx];
  bcdt[idx] = s;
}

// ---------------- embedding gather ------------------------------------------
__global__ __launch_bounds__(256) void gather_kernel(
    const int* __restrict__ ids, const float* __restrict__ embed, float* __restrict__ x)
{
  int row = blockIdx.x;
  int id = ids[row];
  ((float4*)x)[(size_t)row * (DMODEL / 4) + threadIdx.x] =
      ((const float4*)(embed + (size_t)id * DMODEL))[threadIdx.x];
}

// ---------------- RMSNorm (no scale) -> bf16 --------------------------------
__global__ __launch_bounds__(256) void rmsnorm_kernel(
    const float* __restrict__ x, ushort* __restrict__ xnb)
{
  int row = blockIdx.x;
  float4 v = ((const float4*)(x + (size_t)row * DMODEL))[threadIdx.x];
  float s = v.x * v.x + v.y * v.y + v.z * v.z + v.w * v.w;
#pragma unroll
  for (int o = 32; o > 0; o >>= 1) s += __shfl_down(s, o);
  __shared__ float ws[4];
  if ((threadIdx.x & 63) == 0) ws[threadIdx.x >> 6] = s;
  __syncthreads();
  float tot = ws[0] + ws[1] + ws[2] + ws[3];
  float sc = rsqrtf(tot * (1.0f / DMODEL) + 1e-6f);
  ushort4 o4 = {f2bf(v.x * sc), f2bf(v.y * sc), f2bf(v.z * sc), f2bf(v.w * sc)};
  ((ushort4*)xnb)[(size_t)row * (DMODEL / 4) + threadIdx.x] = o4;
}

// ---------------- chunk-parallel selective scan (dt fused in-kernel) --------
// dt[t][d] = softplus(bcdt[t][32:96] @ Wdt2[d][:]^T + bdt[d]) computed in LDS.
__global__ __launch_bounds__(256) void scan_pass1(
    const float* __restrict__ u, const float* __restrict__ bcdt,
    const float* __restrict__ Wdt2, const float* __restrict__ bdt,
    const float* __restrict__ logA,
    float* __restrict__ P, float* __restrict__ S)
{
  const int tid = threadIdx.x;
  const int n = tid & 15, dl = tid >> 4;
  const int dbase = blockIdx.x * 16;
  const int c = blockIdx.y;
  const int t0 = c * CLEN;
  const int d = dbase + dl;
  const float Aval = -expf(logA[d * DSTATE + n]);
  __shared__ float sdt[CLEN][16], su[CLEN][16], sB[CLEN][16];
  __shared__ float sDt[CLEN][65], sW2[16][65];
  {
    int tt = tid >> 2, j0 = (tid & 3) * 4;
    *(float4*)&su[tt][j0] = *(const float4*)&u[(size_t)(t0 + tt) * DINNER + dbase + j0];
    *(float4*)&sB[tt][j0] = *(const float4*)&bcdt[(size_t)(t0 + tt) * 96 + j0];
  }
  for (int i = tid; i < CLEN * 64; i += 256) {
    int r = i >> 6, cc = i & 63;
    sDt[r][cc] = bcdt[(size_t)(t0 + r) * 96 + 32 + cc];
  }
  for (int i = tid; i < 16 * 64; i += 256) {
    int r = i >> 6, cc = i & 63;
    sW2[r][cc] = Wdt2[(size_t)(dbase + r) * DTRANK + cc];
  }
  __syncthreads();
  {
    const int dd = tid & 15, tq = tid >> 4;
    const float bv = bdt[dbase + dd];
#pragma unroll
    for (int i = 0; i < 4; ++i) {
      int trow = tq * 4 + i;
      float a = bv;
#pragma unroll 8
      for (int k = 0; k < 64; ++k) a += sDt[trow][k] * sW2[dd][k];
      sdt[trow][dd] = (a > 20.f) ? a : log1pf(expf(a));
    }
  }
  __syncthreads();
  float h = 0.f, pr = 1.f;
#pragma unroll 8
  for (int i = 0; i < CLEN; ++i) {
    float dtv = sdt[i][dl], uv = su[i][dl], Bv = sB[i][n];
    float dtA = dtv * Aval;
    float rinv = __builtin_amdgcn_rcpf(1.f - 0.5f * dtA);
    float dA = (1.f + 0.5f * dtA) * rinv;
    float dBu = dtv * Bv * rinv * uv;
    h = dA * h + dBu;
    pr *= dA;
  }
  size_t idx = (size_t)c * (DINNER * DSTATE) + (size_t)d * DSTATE + n;
  P[idx] = pr;
  S[idx] = h;
}

__global__ __launch_bounds__(256) void scan_combine(
    const float* __restrict__ P, const float* __restrict__ S, float* __restrict__ Hinit)
{
  int idx = blockIdx.x * 256 + threadIdx.x;
  float H = 0.f;
#pragma unroll
  for (int c = 0; c < NCHUNK; ++c) {
    size_t o = (size_t)c * (DINNER * DSTATE) + idx;
    Hinit[o] = H;
    H = P[o] * H + S[o];
  }
}

__global__ __launch_bounds__(256) void scan_pass2(
    const float* __restrict__ u, const float* __restrict__ bcdt,
    const float* __restrict__ Wdt2, const float* __restrict__ bdt,
    const float* __restrict__ logA, const float* __restrict__ Dp,
    const float* __restrict__ Hinit, const float* __restrict__ resu0,
    ushort* __restrict__ y2b)
{
  const int tid = threadIdx.x;
  const int n = tid & 15, dl = tid >> 4;
  const int dbase = blockIdx.x * 16;
  const int c = blockIdx.y;
  const int t0 = c * CLEN;
  const int d = dbase + dl;
  const float Aval = -expf(logA[d * DSTATE + n]);
  const float Dpv = Dp[d];
  __shared__ float sdt[CLEN][16], su[CLEN][16], sB[CLEN][16], sC[CLEN][16], sres[CLEN][16];
  __shared__ float sDt[CLEN][65], sW2[16][65];
  {
    int tt = tid >> 2, j0 = (tid & 3) * 4;
    *(float4*)&su[tt][j0]   = *(const float4*)&u[(size_t)(t0 + tt) * DINNER + dbase + j0];
    *(float4*)&sB[tt][j0]   = *(const float4*)&bcdt[(size_t)(t0 + tt) * 96 + j0];
    *(float4*)&sC[tt][j0]   = *(const float4*)&bcdt[(size_t)(t0 + tt) * 96 + 16 + j0];
    *(float4*)&sres[tt][j0] = *(const float4*)&resu0[(size_t)(t0 + tt) * (2 * DINNER) + dbase + j0];
  }
  for (int i = tid; i < CLEN * 64; i += 256) {
    int r = i >> 6, cc = i & 63;
    sDt[r][cc] = bcdt[(size_t)(t0 + r) * 96 + 32 + cc];
  }
  for (int i = tid; i < 16 * 64; i += 256) {
    int r = i >> 6, cc = i & 63;
    sW2[r][cc] = Wdt2[(size_t)(dbase + r) * DTRANK + cc];
  }
  __syncthreads();
  {
    const int dd = tid & 15, tq = tid >> 4;
    const float bv = bdt[dbase + dd];
#pragma unroll
    for (int i = 0; i < 4; ++i) {
      int trow = tq * 4 + i;
      float a = bv;
#pragma unroll 8
      for (int k = 0; k < 64; ++k) a += sDt[trow][k] * sW2[dd][k];
      sdt[trow][dd] = (a > 20.f) ? a : log1pf(expf(a));
    }
  }
  __syncthreads();
  float h = Hinit[(size_t)c * (DINNER * DSTATE) + (size_t)d * DSTATE + n];
#pragma unroll 4
  for (int i = 0; i < CLEN; ++i) {
    float dtv = sdt[i][dl], uv = su[i][dl];
    float dtA = dtv * Aval;
    float rinv = __builtin_amdgcn_rcpf(1.f - 0.5f * dtA);
    float dA = (1.f + 0.5f * dtA) * rinv;
    float dBu = dtv * sB[i][n] * rinv * uv;
    h = dA * h + dBu;
    float p = h * sC[i][n];
    p += __shfl_xor(p, 1);
    p += __shfl_xor(p, 2);
    p += __shfl_xor(p, 4);
    p += __shfl_xor(p, 8);
    if (n == 0) {
      float rv = sres[i][dl];
      float yv = (p + uv * Dpv) * (rv / (1.f + expf(-rv)));
      y2b[(size_t)(t0 + i) * DINNER + d] = f2bf(yv);
    }
  }
}

// ---------------- f32 -> bf16 cast ------------------------------------------
__global__ __launch_bounds__(256) void cast_bf16_kernel(
    const float* __restrict__ in, ushort* __restrict__ out, size_t n4)
{
  size_t i = (size_t)blockIdx.x * 256 + threadIdx.x;
  if (i >= n4) return;
  float4 v = ((const float4*)in)[i];
  ushort4 o = {f2bf(v.x), f2bf(v.y), f2bf(v.z), f2bf(v.w)};
  ((ushort4*)out)[i] = o;
}

// ---------------- concat-cast Wres|Win -> bf16 [L][2*DINNER][DMODEL] --------
__global__ __launch_bounds__(256) void cast_cat2_kernel(
    const float* __restrict__ Wres, const float* __restrict__ Win, ushort* __restrict__ out)
{
  size_t i4 = (size_t)blockIdx.x * 256 + threadIdx.x;
  size_t e0 = i4 * 4;
  int k = (int)(e0 & (DMODEL - 1));
  int r = (int)((e0 >> 10) & (2 * DINNER - 1));
  int l = (int)(e0 >> 22);
  const float* src = (r < DINNER)
      ? &Wres[(((size_t)l * DINNER + r) << 10) + k]
      : &Win[(((size_t)l * DINNER + (r - DINNER)) << 10) + k];
  float4 v = *(const float4*)src;
  ushort4 o = {f2bf(v.x), f2bf(v.y), f2bf(v.z), f2bf(v.w)};
  ((ushort4*)out)[i4] = o;
}

// ---------------- concat WB|WC|Wdt1 -> [L][96][DINNER] ----------------------
__global__ __launch_bounds__(256) void concat_wbcdt_kernel(
    const float* __restrict__ WB, const float* __restrict__ WC,
    const float* __restrict__ Wdt1, float* __restrict__ out)
{
  size_t idx = (size_t)blockIdx.x * 256 + threadIdx.x;
  int k = idx & (DINNER - 1);
  size_t rl = idx >> 11;
  int row = (int)(rl % 96);
  int l = (int)(rl / 96);
  float v;
  if (row < 16)       v = WB[((size_t)l * DSTATE + row) * DINNER + k];
  else if (row < 32)  v = WC[((size_t)l * DSTATE + (row - 16)) * DINNER + k];
  else                v = Wdt1[((size_t)l * DTRANK + (row - 32)) * DINNER + k];
  out[idx] = v;
}

// ============================================================================
extern "C" void kernel_launch(void* const* d_in, const int* in_sizes, int n_in,
                              void* d_out, int out_size, void* d_ws, size_t ws_size,
                              hipStream_t stream) {
  (void)in_sizes; (void)n_in; (void)out_size;
  const int* token_ids = (const int*)d_in[0];
  const float* embed = (const float*)d_in[1];
  const float* Wres = (const float*)d_in[2];
  const float* Win = (const float*)d_in[3];
  const float* Wconv = (const float*)d_in[4];
  const float* WB = (const float*)d_in[5];
  const float* WC = (const float*)d_in[6];
  const float* Wdt1 = (const float*)d_in[7];
  const float* Wdt2 = (const float*)d_in[8];
  const float* bdt = (const float*)d_in[9];
  const float* logA = (const float*)d_in[10];
  const float* Dp = (const float*)d_in[11];
  const float* Wout = (const float*)d_in[12];
  float* out = (float*)d_out;

  char* w = (char*)d_ws;
  auto alloc = [&](size_t bytes) {
    char* p = w;
    w += (bytes + 255) & ~(size_t)255;
    return p;
  };
  ushort* eb    = (ushort*)alloc((size_t)VOCAB * DMODEL * 2);
  ushort* wcatb = (ushort*)alloc((size_t)NLAYER * 2 * DINNER * DMODEL * 2);
  ushort* woutb = (ushort*)alloc((size_t)NLAYER * DMODEL * DINNER * 2);
  float* wbcdt  = (float*)alloc((size_t)NLAYER * 96 * DINNER * 4);
  float* x      = (float*)alloc((size_t)SEQ * DMODEL * 4);
  ushort* xnb   = (ushort*)alloc((size_t)SEQ * DMODEL * 2);
  float* resu0  = (float*)alloc((size_t)SEQ * 2 * DINNER * 4);
  float* u      = (float*)alloc((size_t)SEQ * DINNER * 4);
  float* bcdt   = (float*)alloc((size_t)SEQ * 96 * 4);
  float* Cp     = (float*)alloc((size_t)PROJ_NCH * SEQ * 96 * 4);
  float* Pbuf   = (float*)alloc((size_t)NCHUNK * DINNER * DSTATE * 4);
  float* Sbuf   = (float*)alloc((size_t)NCHUNK * DINNER * DSTATE * 4);
  float* Hinit  = (float*)alloc((size_t)NCHUNK * DINNER * DSTATE * 4);
  ushort* y2b   = (ushort*)alloc((size_t)SEQ * DINNER * 2);
  ushort* xb    = (ushort*)alloc((size_t)SEQ * DMODEL * 2);
  if ((size_t)(w - (char*)d_ws) > ws_size) return;

  // weight preprocessing
  cast_bf16_kernel<<<VOCAB * DMODEL / 4 / 256, 256, 0, stream>>>(embed, eb, (size_t)VOCAB * DMODEL / 4);
  cast_cat2_kernel<<<NLAYER * 2 * DINNER * DMODEL / 4 / 256, 256, 0, stream>>>(Wres, Win, wcatb);
  cast_bf16_kernel<<<NLAYER * DMODEL * DINNER / 4 / 256, 256, 0, stream>>>(Wout, woutb, (size_t)NLAYER * DMODEL * DINNER / 4);
  concat_wbcdt_kernel<<<NLAYER * 96 * DINNER / 256, 256, 0, stream>>>(WB, WC, Wdt1, wbcdt);
  gather_kernel<<<SEQ, 256, 0, stream>>>(token_ids, embed, x);

  for (int i = 0; i < NLAYER; ++i) {
    const ushort* wcati = wcatb + (size_t)i * 2 * DINNER * DMODEL;
    const ushort* wouti = woutb + (size_t)i * DMODEL * DINNER;
    const float* wconvi = Wconv + (size_t)i * DINNER * 4;
    const float* wbcdti = wbcdt + (size_t)i * 96 * DINNER;
    const float* wdt2i = Wdt2 + (size_t)i * DINNER * DTRANK;
    const float* bdti = bdt + (size_t)i * DINNER;
    const float* logAi = logA + (size_t)i * DINNER * DSTATE;
    const float* Dpi = Dp + (size_t)i * DINNER;

    rmsnorm_kernel<<<SEQ, 256, 0, stream>>>(x, xnb);
    gemm8p_bt_bf16<128, false><<<dim3(SEQ / 128, 2 * DINNER / 256), 512, 0, stream>>>(
        xnb, wcati, resu0, 2 * DINNER, DMODEL);
    convproj_f32<<<dim3(SEQ / 64, PROJ_NCH), 256, 0, stream>>>(
        resu0, wbcdti, wconvi, u, Cp, SEQ);
    proj_reduce<<<SEQ * 96 / 256, 256, 0, stream>>>(Cp, bcdt, SEQ);
    dim3 gs(DINNER / 16, NCHUNK);
    scan_pass1<<<gs, 256, 0, stream>>>(u, bcdt, wdt2i, bdti, logAi, Pbuf, Sbuf);
    scan_combine<<<DINNER * DSTATE / 256, 256, 0, stream>>>(Pbuf, Sbuf, Hinit);
    scan_pass2<<<gs, 256, 0, stream>>>(u, bcdt, wdt2i, bdti, logAi, Dpi, Hinit, resu0, y2b);
    dim3 g2(SEQ / 128, DMODEL / 128);
    gemm_bt_bf16<<<g2, 256, 0, stream>>>(y2b, wouti, x, x, SEQ, DMODEL, DINNER);
  }
  cast_bf16_kernel<<<SEQ * DMODEL / 4 / 256, 256, 0, stream>>>(x, xb, (size_t)SEQ * DMODEL / 4);
  gemm8p_bt_bf16<256, true><<<dim3(SEQ / 256, VOCAB / 256), 512, 0, stream>>>(
      xb, eb, out, VOCAB, DMODEL);
}

// Round 7
// 2564.549 us; speedup vs baseline: 1.1745x; 1.1745x over previous
//
#include <hip/hip_runtime.h>

#define SEQ 2048
#define DMODEL 1024
#define DINNER 2048
#define DSTATE 16
#define DTRANK 64
#define NLAYER 8
#define VOCAB 32000
#define NCHUNK 32
#define CLEN 64   // SEQ / NCHUNK
#define PROJ_NCH 16
#define PROJ_KC 128  // DINNER / PROJ_NCH

typedef float f32x4 __attribute__((ext_vector_type(4)));
typedef short bf16x8 __attribute__((ext_vector_type(8)));

__device__ __forceinline__ ushort f2bf(float f) {
  union { float f; unsigned u; } v; v.f = f;
  unsigned r = v.u + 0x7fffu + ((v.u >> 16) & 1u);
  return (ushort)(r >> 16);
}

__device__ __forceinline__ void lds_load16(const void* g, void* l) {
  __builtin_amdgcn_global_load_lds(
      (const __attribute__((address_space(1))) void*)g,
      (__attribute__((address_space(3))) void*)l, 16, 0, 0);
}

// ---------------- counted-vmcnt MFMA GEMM, depth-1-tile prefetch ------------
// C[M,N] = A[M,K] @ B[N,K]^T.  BN=256 fixed, BM template (256 or 128).
// All stages for tile t+1 issued at top of iteration t; vmcnt(8/6) leaves them
// in flight across both barriers (T4). LDS XOR-swizzle on staging src + reads.
template<int BM, bool NTS>
__global__ __launch_bounds__(512, 2) void gemm8p_bt_bf16(
    const ushort* __restrict__ A, const ushort* __restrict__ B,
    float* __restrict__ C, int N, int K)
{
  constexpr int MFR = BM / 32;       // m-fragments per wave
  constexpr int MPP = MFR / 4;       // m-fragments per phase
  constexpr int ALOADS = BM / 128;   // global_load_lds per thread per A-half
  __shared__ __align__(16) ushort As[2 * BM * 64];
  __shared__ __align__(16) ushort Bs[2 * 256 * 64];
  const int tid = threadIdx.x;
  const int lane = tid & 63;
  const int wid = tid >> 6;
  const int wr = wid >> 2, wc = wid & 3;
  const int rr = lane & 15, kq = lane >> 4;

  unsigned nwg = gridDim.x * gridDim.y;
  unsigned lb = blockIdx.y * gridDim.x + blockIdx.x;
  if ((nwg & 7u) == 0u) { unsigned cpx = nwg >> 3; lb = (lb & 7u) * cpx + (lb >> 3); }
  const int bm = (int)(lb % gridDim.x) * BM;
  const int bn = (int)(lb / gridDim.x) * 256;

  const ushort* Abase = A + (size_t)bm * K;
  const ushort* Bbase = B + (size_t)bn * K;

  auto stageA = [&](int buf, int h, int kt) {
    constexpr int HR = BM / 2;
#pragma unroll
    for (int L = 0; L < ALOADS; ++L) {
      int f = L * 512 + tid;
      int rl = f >> 3, g = f & 7;
      int gg = g ^ (rl & 7);  // pre-swizzled source granule
      lds_load16(Abase + (size_t)(h * HR + rl) * K + kt * 64 + gg * 8,
                 (void*)(As + buf * (BM * 64) + (h * HR + rl) * 64 + g * 8));
    }
  };
  auto stageB = [&](int buf, int h, int kt) {
#pragma unroll
    for (int L = 0; L < 2; ++L) {
      int f = L * 512 + tid;
      int rl = f >> 3, g = f & 7;
      int gg = g ^ (rl & 7);
      lds_load16(Bbase + (size_t)(h * 128 + rl) * K + kt * 64 + gg * 8,
                 (void*)(Bs + buf * (256 * 64) + (h * 128 + rl) * 64 + g * 8));
    }
  };
  auto rdA = [&](int buf, int r, int kbyte) {
    int sw = kbyte ^ ((r & 7) << 4);
    return *(const bf16x8*)(As + buf * (BM * 64) + r * 64 + (sw >> 1));
  };
  auto rdB = [&](int buf, int r, int kbyte) {
    int sw = kbyte ^ ((r & 7) << 4);
    return *(const bf16x8*)(Bs + buf * (256 * 64) + r * 64 + (sw >> 1));
  };

  f32x4 acc[MFR][4];
#pragma unroll
  for (int m = 0; m < MFR; ++m)
#pragma unroll
    for (int n = 0; n < 4; ++n) acc[m][n] = (f32x4){0.f, 0.f, 0.f, 0.f};

  const int NT = K >> 6;
  stageA(0, 0, 0); stageA(0, 1, 0); stageB(0, 0, 0); stageB(0, 1, 0);

  for (int t = 0; t < NT; ++t) {
    const int cur = t & 1;
    if (t + 1 < NT) {
      // issue ALL of tile t+1's stages now -> full-tile prefetch depth
      stageA(cur ^ 1, 0, t + 1);
      stageA(cur ^ 1, 1, t + 1);
      stageB(cur ^ 1, 0, t + 1);
      stageB(cur ^ 1, 1, t + 1);
      // wait for tile t's loads only; t+1's (8 or 6) stay in flight
      if constexpr (BM == 256) asm volatile("s_waitcnt vmcnt(8)" ::: "memory");
      else                     asm volatile("s_waitcnt vmcnt(6)" ::: "memory");
    } else {
      asm volatile("s_waitcnt vmcnt(0)" ::: "memory");
    }
    __syncthreads();

    bf16x8 bfr[4][2];
#pragma unroll
    for (int n = 0; n < 4; ++n)
#pragma unroll
      for (int kk = 0; kk < 2; ++kk)
        bfr[n][kk] = rdB(cur, wc * 64 + n * 16 + rr, kk * 64 + kq * 16);

#pragma unroll
    for (int mq = 0; mq < 4; ++mq) {
      bf16x8 af[MPP][2];
#pragma unroll
      for (int mf = 0; mf < MPP; ++mf)
#pragma unroll
        for (int kk = 0; kk < 2; ++kk)
          af[mf][kk] = rdA(cur, wr * (BM / 2) + (mq * MPP + mf) * 16 + rr, kk * 64 + kq * 16);
      __builtin_amdgcn_s_setprio(1);
#pragma unroll
      for (int kk = 0; kk < 2; ++kk)
#pragma unroll
        for (int mf = 0; mf < MPP; ++mf)
#pragma unroll
          for (int n = 0; n < 4; ++n)
            acc[mq * MPP + mf][n] = __builtin_amdgcn_mfma_f32_16x16x32_bf16(
                af[mf][kk], bfr[n][kk], acc[mq * MPP + mf][n], 0, 0, 0);
      __builtin_amdgcn_s_setprio(0);
    }
    __syncthreads();
  }

  // Epilogue: per-wave LDS transpose in Bs (16 rows x 64 cols f32, stride 68)
  __syncthreads();
  float* ep = (float*)Bs + wid * (16 * 68);
  const int cg = bn + wc * 64;
#pragma unroll
  for (int m = 0; m < MFR; ++m) {
    const int r0g = bm + wr * (BM / 2) + m * 16;
#pragma unroll
    for (int n = 0; n < 4; ++n)
#pragma unroll
      for (int j = 0; j < 4; ++j)
        ep[(kq * 4 + j) * 68 + n * 16 + rr] = acc[m][n][j];
#pragma unroll
    for (int i = 0; i < 4; ++i) {
      int row = i * 4 + kq;
      f32x4 v = *(const f32x4*)&ep[row * 68 + rr * 4];
      f32x4* dst = (f32x4*)&C[(size_t)(r0g + row) * N + cg + rr * 4];
      if constexpr (NTS) __builtin_nontemporal_store(v, dst);
      else *dst = v;
    }
  }
}

// ---------------- bf16 MFMA GEMM (2-phase 128x128), keeps fused addsrc ------
__global__ __launch_bounds__(256) void gemm_bt_bf16(
    const ushort* __restrict__ A, const ushort* __restrict__ B,
    const float* __restrict__ addsrc, float* __restrict__ C,
    int M, int N, int K)
{
  __shared__ __align__(16) ushort As[128 * 64];
  __shared__ __align__(16) ushort Bs[128 * 64];
  const int tid = threadIdx.x;
  const int lane = tid & 63;
  const int wave = tid >> 6;
  const int wr = wave >> 1, wc = wave & 1;

  unsigned nwg = gridDim.x * gridDim.y;
  unsigned lb = blockIdx.y * gridDim.x + blockIdx.x;
  if ((nwg & 7u) == 0u) {
    unsigned cpx = nwg >> 3;
    lb = (lb & 7u) * cpx + (lb >> 3);
  }
  const int bm = (lb % gridDim.x) * 128;
  const int bn = (lb / gridDim.x) * 128;
  const int rr = lane & 15, kq = lane >> 4;

  f32x4 acc[4][4];
#pragma unroll
  for (int m = 0; m < 4; ++m)
#pragma unroll
    for (int n = 0; n < 4; ++n) acc[m][n] = (f32x4){0.f, 0.f, 0.f, 0.f};

  for (int kt = 0; kt < K; kt += 64) {
#pragma unroll
    for (int i = 0; i < 4; ++i) {
      int fb = i * 256 + tid;
      int row = fb >> 3, cb = fb & 7;
      lds_load16(A + (size_t)(bm + row) * K + kt + cb * 8, (void*)(As + (size_t)fb * 8));
      lds_load16(B + (size_t)(bn + row) * K + kt + cb * 8, (void*)(Bs + (size_t)fb * 8));
    }
    __syncthreads();
#pragma unroll
    for (int ks = 0; ks < 2; ++ks) {
      bf16x8 af[4], bfr[4];
      const int koff = ks * 32 + kq * 8;
#pragma unroll
      for (int m = 0; m < 4; ++m)
        af[m] = *(const bf16x8*)&As[(wr * 64 + m * 16 + rr) * 64 + koff];
#pragma unroll
      for (int n = 0; n < 4; ++n)
        bfr[n] = *(const bf16x8*)&Bs[(wc * 64 + n * 16 + rr) * 64 + koff];
#pragma unroll
      for (int m = 0; m < 4; ++m)
#pragma unroll
        for (int n = 0; n < 4; ++n)
          acc[m][n] = __builtin_amdgcn_mfma_f32_16x16x32_bf16(af[m], bfr[n], acc[m][n], 0, 0, 0);
    }
    __syncthreads();
  }
#pragma unroll
  for (int m = 0; m < 4; ++m) {
    const int r0 = bm + wr * 64 + m * 16 + kq * 4;
#pragma unroll
    for (int n = 0; n < 4; ++n) {
      const int cc = bn + wc * 64 + n * 16 + rr;
#pragma unroll
      for (int j = 0; j < 4; ++j) {
        size_t idx = (size_t)(r0 + j) * N + cc;
        float v = acc[m][n][j];
        if (addsrc) v += addsrc[idx];
        C[idx] = v;
      }
    }
  }
}

// ---------------- split-K f32 projection GEMM: Cp[ch] = A@W^T chunk ---------
__global__ __launch_bounds__(256) void projgemm_f32(
    const float* __restrict__ A, const float* __restrict__ W,
    float* __restrict__ Cp, int M)
{
  __shared__ float As[64][65];
  __shared__ float Ws[96][65];
  const int t = threadIdx.x;
  const int bm = blockIdx.x * 64;
  const int kc = blockIdx.y * PROJ_KC;
  const int ty = t >> 4, tx = t & 15;
  const int r0 = ty * 4, c0 = tx * 6;
  float acc[4][6] = {};
  for (int kt = 0; kt < PROJ_KC; kt += 64) {
#pragma unroll
    for (int i = 0; i < 4; ++i) {
      int e4 = i * 256 + t;
      int r = e4 >> 4, c4 = (e4 & 15) * 4;
      *(float4*)&As[r][c4] = *(const float4*)&A[(size_t)(bm + r) * DINNER + kc + kt + c4];
    }
#pragma unroll
    for (int i = 0; i < 6; ++i) {
      int e4 = i * 256 + t;
      int r = e4 >> 4, c4 = (e4 & 15) * 4;
      *(float4*)&Ws[r][c4] = *(const float4*)&W[(size_t)r * DINNER + kc + kt + c4];
    }
    __syncthreads();
#pragma unroll 4
    for (int kk = 0; kk < 64; ++kk) {
      float a0 = As[r0][kk], a1 = As[r0 + 1][kk], a2 = As[r0 + 2][kk], a3 = As[r0 + 3][kk];
      float w0 = Ws[c0][kk], w1 = Ws[c0 + 1][kk], w2 = Ws[c0 + 2][kk];
      float w3 = Ws[c0 + 3][kk], w4 = Ws[c0 + 4][kk], w5 = Ws[c0 + 5][kk];
      acc[0][0] += a0 * w0; acc[0][1] += a0 * w1; acc[0][2] += a0 * w2;
      acc[0][3] += a0 * w3; acc[0][4] += a0 * w4; acc[0][5] += a0 * w5;
      acc[1][0] += a1 * w0; acc[1][1] += a1 * w1; acc[1][2] += a1 * w2;
      acc[1][3] += a1 * w3; acc[1][4] += a1 * w4; acc[1][5] += a1 * w5;
      acc[2][0] += a2 * w0; acc[2][1] += a2 * w1; acc[2][2] += a2 * w2;
      acc[2][3] += a2 * w3; acc[2][4] += a2 * w4; acc[2][5] += a2 * w5;
      acc[3][0] += a3 * w0; acc[3][1] += a3 * w1; acc[3][2] += a3 * w2;
      acc[3][3] += a3 * w3; acc[3][4] += a3 * w4; acc[3][5] += a3 * w5;
    }
    __syncthreads();
  }
  float* cp = Cp + (size_t)blockIdx.y * M * 96;
#pragma unroll
  for (int i = 0; i < 4; ++i)
#pragma unroll
    for (int j = 0; j < 6; ++j)
      cp[(size_t)(bm + r0 + i) * 96 + c0 + j] = acc[i][j];
}

__global__ __launch_bounds__(256) void proj_reduce(
    const float* __restrict__ Cp, float* __restrict__ bcdt, int M)
{
  int idx = blockIdx.x * 256 + threadIdx.x;
  float s = 0.f;
#pragma unroll
  for (int c = 0; c < PROJ_NCH; ++c) s += Cp[(size_t)c * M * 96 + idx];
  bcdt[idx] = s;
}

// ---------------- f32 small GEMM: C[M,N] = A[M,K(lda)] @ W[N,K(ldw)]^T ------
__global__ __launch_bounds__(256) void smallgemm_f32(
    const float* __restrict__ A, int lda,
    const float* __restrict__ W, int ldw,
    float* __restrict__ C, int ldc,
    const float* __restrict__ bias,
    int M, int N, int K, int act)
{
  __shared__ float As[64][65];
  __shared__ float Ws[64][65];
  const int t = threadIdx.x;
  const int bm = blockIdx.x * 64, bn = blockIdx.y * 64;
  const int r0 = (t >> 4) * 4;
  const int c0 = (t & 15) * 4;
  float acc[4][4] = {};

  for (int kt = 0; kt < K; kt += 64) {
#pragma unroll
    for (int i = 0; i < 16; ++i) {
      int idx = i * 256 + t;
      int r = idx >> 6, c = idx & 63;
      As[r][c] = A[(size_t)(bm + r) * lda + kt + c];
      int wrow = bn + r;
      Ws[r][c] = (wrow < N) ? W[(size_t)wrow * ldw + kt + c] : 0.f;
    }
    __syncthreads();
#pragma unroll 8
    for (int kk = 0; kk < 64; ++kk) {
      float a0 = As[r0][kk], a1 = As[r0 + 1][kk], a2 = As[r0 + 2][kk], a3 = As[r0 + 3][kk];
      float w0 = Ws[c0][kk], w1 = Ws[c0 + 1][kk], w2 = Ws[c0 + 2][kk], w3 = Ws[c0 + 3][kk];
      acc[0][0] += a0 * w0; acc[0][1] += a0 * w1; acc[0][2] += a0 * w2; acc[0][3] += a0 * w3;
      acc[1][0] += a1 * w0; acc[1][1] += a1 * w1; acc[1][2] += a1 * w2; acc[1][3] += a1 * w3;
      acc[2][0] += a2 * w0; acc[2][1] += a2 * w1; acc[2][2] += a2 * w2; acc[2][3] += a2 * w3;
      acc[3][0] += a3 * w0; acc[3][1] += a3 * w1; acc[3][2] += a3 * w2; acc[3][3] += a3 * w3;
    }
    __syncthreads();
  }
#pragma unroll
  for (int i = 0; i < 4; ++i)
#pragma unroll
    for (int j = 0; j < 4; ++j) {
      int cc = bn + c0 + j;
      if (cc < N) {
        float v = acc[i][j];
        if (bias) v += bias[cc];
        if (act == 1) v = (v > 20.f) ? v : log1pf(expf(v));
        C[(size_t)(bm + r0 + i) * ldc + cc] = v;
      }
    }
}

// ---------------- embedding gather ------------------------------------------
__global__ __launch_bounds__(256) void gather_kernel(
    const int* __restrict__ ids, const float* __restrict__ embed, float* __restrict__ x)
{
  int row = blockIdx.x;
  int id = ids[row];
  ((float4*)x)[(size_t)row * (DMODEL / 4) + threadIdx.x] =
      ((const float4*)(embed + (size_t)id * DMODEL))[threadIdx.x];
}

// ---------------- RMSNorm (no scale) -> bf16 --------------------------------
__global__ __launch_bounds__(256) void rmsnorm_kernel(
    const float* __restrict__ x, ushort* __restrict__ xnb)
{
  int row = blockIdx.x;
  float4 v = ((const float4*)(x + (size_t)row * DMODEL))[threadIdx.x];
  float s = v.x * v.x + v.y * v.y + v.z * v.z + v.w * v.w;
#pragma unroll
  for (int o = 32; o > 0; o >>= 1) s += __shfl_down(s, o);
  __shared__ float ws[4];
  if ((threadIdx.x & 63) == 0) ws[threadIdx.x >> 6] = s;
  __syncthreads();
  float tot = ws[0] + ws[1] + ws[2] + ws[3];
  float sc = rsqrtf(tot * (1.0f / DMODEL) + 1e-6f);
  ushort4 o4 = {f2bf(v.x * sc), f2bf(v.y * sc), f2bf(v.z * sc), f2bf(v.w * sc)};
  ((ushort4*)xnb)[(size_t)row * (DMODEL / 4) + threadIdx.x] = o4;
}

// ---------------- causal depthwise conv (K=4) + SiLU ------------------------
__global__ __launch_bounds__(256) void conv_silu_kernel(
    const float* __restrict__ u0, int ld, const float* __restrict__ Wconv,
    float* __restrict__ u)
{
  int idx = blockIdx.x * 256 + threadIdx.x;
  int d4 = idx & (DINNER / 4 - 1);
  int l = idx >> 9;
  int d0 = d4 * 4;
  float wt[4][4];
#pragma unroll
  for (int j = 0; j < 4; ++j) {
    float4 tv = *(const float4*)&Wconv[(d0 + j) * 4];
    wt[j][0] = tv.x; wt[j][1] = tv.y; wt[j][2] = tv.z; wt[j][3] = tv.w;
  }
  float a[4] = {0.f, 0.f, 0.f, 0.f};
#pragma unroll
  for (int k = 0; k < 4; ++k) {
    int ls = l - 3 + k;
    if (ls >= 0) {
      float4 uv = *(const float4*)&u0[(size_t)ls * ld + d0];
      a[0] += uv.x * wt[0][k];
      a[1] += uv.y * wt[1][k];
      a[2] += uv.z * wt[2][k];
      a[3] += uv.w * wt[3][k];
    }
  }
  float4 r;
  r.x = a[0] / (1.f + expf(-a[0]));
  r.y = a[1] / (1.f + expf(-a[1]));
  r.z = a[2] / (1.f + expf(-a[2]));
  r.w = a[3] / (1.f + expf(-a[3]));
  *(float4*)&u[(size_t)l * DINNER + d0] = r;
}

// ---------------- chunk-parallel selective scan -----------------------------
__global__ __launch_bounds__(256) void scan_pass1(
    const float* __restrict__ dt, const float* __restrict__ u,
    const float* __restrict__ bcdt, const float* __restrict__ logA,
    float* __restrict__ P, float* __restrict__ S)
{
  const int tid = threadIdx.x;
  const int n = tid & 15, dl = tid >> 4;
  const int dbase = blockIdx.x * 16;
  const int c = blockIdx.y;
  const int t0 = c * CLEN;
  const int d = dbase + dl;
  const float Aval = -expf(logA[d * DSTATE + n]);
  __shared__ float sdt[CLEN][16], su[CLEN][16], sB[CLEN][16];
  {
    int tt = tid >> 2, j0 = (tid & 3) * 4;
    *(float4*)&sdt[tt][j0] = *(const float4*)&dt[(size_t)(t0 + tt) * DINNER + dbase + j0];
    *(float4*)&su[tt][j0]  = *(const float4*)&u[(size_t)(t0 + tt) * DINNER + dbase + j0];
    *(float4*)&sB[tt][j0]  = *(const float4*)&bcdt[(size_t)(t0 + tt) * 96 + j0];
  }
  __syncthreads();
  float h = 0.f, pr = 1.f;
#pragma unroll 8
  for (int i = 0; i < CLEN; ++i) {
    float dtv = sdt[i][dl], uv = su[i][dl], Bv = sB[i][n];
    float dtA = dtv * Aval;
    float rinv = __builtin_amdgcn_rcpf(1.f - 0.5f * dtA);
    float dA = (1.f + 0.5f * dtA) * rinv;
    float dBu = dtv * Bv * rinv * uv;
    h = dA * h + dBu;
    pr *= dA;
  }
  size_t idx = (size_t)c * (DINNER * DSTATE) + (size_t)d * DSTATE + n;
  P[idx] = pr;
  S[idx] = h;
}

__global__ __launch_bounds__(256) void scan_combine(
    const float* __restrict__ P, const float* __restrict__ S, float* __restrict__ Hinit)
{
  int idx = blockIdx.x * 256 + threadIdx.x;
  float H = 0.f;
#pragma unroll
  for (int c = 0; c < NCHUNK; ++c) {
    size_t o = (size_t)c * (DINNER * DSTATE) + idx;
    Hinit[o] = H;
    H = P[o] * H + S[o];
  }
}

__global__ __launch_bounds__(256) void scan_pass2(
    const float* __restrict__ dt, const float* __restrict__ u,
    const float* __restrict__ bcdt, const float* __restrict__ logA,
    const float* __restrict__ Dp, const float* __restrict__ Hinit,
    const float* __restrict__ resu0, ushort* __restrict__ y2b)
{
  const int tid = threadIdx.x;
  const int n = tid & 15, dl = tid >> 4;
  const int dbase = blockIdx.x * 16;
  const int c = blockIdx.y;
  const int t0 = c * CLEN;
  const int d = dbase + dl;
  const float Aval = -expf(logA[d * DSTATE + n]);
  const float Dpv = Dp[d];
  __shared__ float sdt[CLEN][16], su[CLEN][16], sB[CLEN][16], sC[CLEN][16], sres[CLEN][16];
  {
    int tt = tid >> 2, j0 = (tid & 3) * 4;
    *(float4*)&sdt[tt][j0]  = *(const float4*)&dt[(size_t)(t0 + tt) * DINNER + dbase + j0];
    *(float4*)&su[tt][j0]   = *(const float4*)&u[(size_t)(t0 + tt) * DINNER + dbase + j0];
    *(float4*)&sB[tt][j0]   = *(const float4*)&bcdt[(size_t)(t0 + tt) * 96 + j0];
    *(float4*)&sC[tt][j0]   = *(const float4*)&bcdt[(size_t)(t0 + tt) * 96 + 16 + j0];
    *(float4*)&sres[tt][j0] = *(const float4*)&resu0[(size_t)(t0 + tt) * (2 * DINNER) + dbase + j0];
  }
  __syncthreads();
  float h = Hinit[(size_t)c * (DINNER * DSTATE) + (size_t)d * DSTATE + n];
#pragma unroll 4
  for (int i = 0; i < CLEN; ++i) {
    float dtv = sdt[i][dl], uv = su[i][dl];
    float dtA = dtv * Aval;
    float rinv = __builtin_amdgcn_rcpf(1.f - 0.5f * dtA);
    float dA = (1.f + 0.5f * dtA) * rinv;
    float dBu = dtv * sB[i][n] * rinv * uv;
    h = dA * h + dBu;
    float p = h * sC[i][n];
    p += __shfl_xor(p, 1);
    p += __shfl_xor(p, 2);
    p += __shfl_xor(p, 4);
    p += __shfl_xor(p, 8);
    if (n == 0) {
      float rv = sres[i][dl];
      float yv = (p + uv * Dpv) * (rv / (1.f + expf(-rv)));
      y2b[(size_t)(t0 + i) * DINNER + d] = f2bf(yv);
    }
  }
}

// ---------------- f32 -> bf16 cast ------------------------------------------
__global__ __launch_bounds__(256) void cast_bf16_kernel(
    const float* __restrict__ in, ushort* __restrict__ out, size_t n4)
{
  size_t i = (size_t)blockIdx.x * 256 + threadIdx.x;
  if (i >= n4) return;
  float4 v = ((const float4*)in)[i];
  ushort4 o = {f2bf(v.x), f2bf(v.y), f2bf(v.z), f2bf(v.w)};
  ((ushort4*)out)[i] = o;
}

// ---------------- concat-cast Wres|Win -> bf16 [L][2*DINNER][DMODEL] --------
__global__ __launch_bounds__(256) void cast_cat2_kernel(
    const float* __restrict__ Wres, const float* __restrict__ Win, ushort* __restrict__ out)
{
  size_t i4 = (size_t)blockIdx.x * 256 + threadIdx.x;
  size_t e0 = i4 * 4;
  int k = (int)(e0 & (DMODEL - 1));
  int r = (int)((e0 >> 10) & (2 * DINNER - 1));
  int l = (int)(e0 >> 22);
  const float* src = (r < DINNER)
      ? &Wres[(((size_t)l * DINNER + r) << 10) + k]
      : &Win[(((size_t)l * DINNER + (r - DINNER)) << 10) + k];
  float4 v = *(const float4*)src;
  ushort4 o = {f2bf(v.x), f2bf(v.y), f2bf(v.z), f2bf(v.w)};
  ((ushort4*)out)[i4] = o;
}

// ---------------- concat WB|WC|Wdt1 -> [L][96][DINNER] ----------------------
__global__ __launch_bounds__(256) void concat_wbcdt_kernel(
    const float* __restrict__ WB, const float* __restrict__ WC,
    const float* __restrict__ Wdt1, float* __restrict__ out)
{
  size_t idx = (size_t)blockIdx.x * 256 + threadIdx.x;
  int k = idx & (DINNER - 1);
  size_t rl = idx >> 11;
  int row = (int)(rl % 96);
  int l = (int)(rl / 96);
  float v;
  if (row < 16)       v = WB[((size_t)l * DSTATE + row) * DINNER + k];
  else if (row < 32)  v = WC[((size_t)l * DSTATE + (row - 16)) * DINNER + k];
  else                v = Wdt1[((size_t)l * DTRANK + (row - 32)) * DINNER + k];
  out[idx] = v;
}

// ============================================================================
extern "C" void kernel_launch(void* const* d_in, const int* in_sizes, int n_in,
                              void* d_out, int out_size, void* d_ws, size_t ws_size,
                              hipStream_t stream) {
  (void)in_sizes; (void)n_in; (void)out_size;
  const int* token_ids = (const int*)d_in[0];
  const float* embed = (const float*)d_in[1];
  const float* Wres = (const float*)d_in[2];
  const float* Win = (const float*)d_in[3];
  const float* Wconv = (const float*)d_in[4];
  const float* WB = (const float*)d_in[5];
  const float* WC = (const float*)d_in[6];
  const float* Wdt1 = (const float*)d_in[7];
  const float* Wdt2 = (const float*)d_in[8];
  const float* bdt = (const float*)d_in[9];
  const float* logA = (const float*)d_in[10];
  const float* Dp = (const float*)d_in[11];
  const float* Wout = (const float*)d_in[12];
  float* out = (float*)d_out;

  char* w = (char*)d_ws;
  auto alloc = [&](size_t bytes) {
    char* p = w;
    w += (bytes + 255) & ~(size_t)255;
    return p;
  };
  ushort* eb    = (ushort*)alloc((size_t)VOCAB * DMODEL * 2);
  ushort* wcatb = (ushort*)alloc((size_t)NLAYER * 2 * DINNER * DMODEL * 2);
  ushort* woutb = (ushort*)alloc((size_t)NLAYER * DMODEL * DINNER * 2);
  float* wbcdt  = (float*)alloc((size_t)NLAYER * 96 * DINNER * 4);
  float* x      = (float*)alloc((size_t)SEQ * DMODEL * 4);
  ushort* xnb   = (ushort*)alloc((size_t)SEQ * DMODEL * 2);
  float* resu0  = (float*)alloc((size_t)SEQ * 2 * DINNER * 4);
  float* u      = (float*)alloc((size_t)SEQ * DINNER * 4);
  float* bcdt   = (float*)alloc((size_t)SEQ * 96 * 4);
  float* dt     = (float*)alloc((size_t)SEQ * DINNER * 4);
  float* Cp     = (float*)alloc((size_t)PROJ_NCH * SEQ * 96 * 4);
  float* Pbuf   = (float*)alloc((size_t)NCHUNK * DINNER * DSTATE * 4);
  float* Sbuf   = (float*)alloc((size_t)NCHUNK * DINNER * DSTATE * 4);
  float* Hinit  = (float*)alloc((size_t)NCHUNK * DINNER * DSTATE * 4);
  ushort* y2b   = (ushort*)alloc((size_t)SEQ * DINNER * 2);
  ushort* xb    = (ushort*)alloc((size_t)SEQ * DMODEL * 2);
  if ((size_t)(w - (char*)d_ws) > ws_size) return;

  // weight preprocessing
  cast_bf16_kernel<<<VOCAB * DMODEL / 4 / 256, 256, 0, stream>>>(embed, eb, (size_t)VOCAB * DMODEL / 4);
  cast_cat2_kernel<<<NLAYER * 2 * DINNER * DMODEL / 4 / 256, 256, 0, stream>>>(Wres, Win, wcatb);
  cast_bf16_kernel<<<NLAYER * DMODEL * DINNER / 4 / 256, 256, 0, stream>>>(Wout, woutb, (size_t)NLAYER * DMODEL * DINNER / 4);
  concat_wbcdt_kernel<<<NLAYER * 96 * DINNER / 256, 256, 0, stream>>>(WB, WC, Wdt1, wbcdt);
  gather_kernel<<<SEQ, 256, 0, stream>>>(token_ids, embed, x);

  for (int i = 0; i < NLAYER; ++i) {
    const ushort* wcati = wcatb + (size_t)i * 2 * DINNER * DMODEL;
    const ushort* wouti = woutb + (size_t)i * DMODEL * DINNER;
    const float* wconvi = Wconv + (size_t)i * DINNER * 4;
    const float* wbcdti = wbcdt + (size_t)i * 96 * DINNER;
    const float* wdt2i = Wdt2 + (size_t)i * DINNER * DTRANK;
    const float* bdti = bdt + (size_t)i * DINNER;
    const float* logAi = logA + (size_t)i * DINNER * DSTATE;
    const float* Dpi = Dp + (size_t)i * DINNER;

    rmsnorm_kernel<<<SEQ, 256, 0, stream>>>(x, xnb);
    gemm8p_bt_bf16<128, false><<<dim3(SEQ / 128, 2 * DINNER / 256), 512, 0, stream>>>(
        xnb, wcati, resu0, 2 * DINNER, DMODEL);
    conv_silu_kernel<<<SEQ * DINNER / 4 / 256, 256, 0, stream>>>(resu0 + DINNER, 2 * DINNER, wconvi, u);
    projgemm_f32<<<dim3(SEQ / 64, PROJ_NCH), 256, 0, stream>>>(u, wbcdti, Cp, SEQ);
    proj_reduce<<<SEQ * 96 / 256, 256, 0, stream>>>(Cp, bcdt, SEQ);
    smallgemm_f32<<<dim3(SEQ / 64, DINNER / 64), 256, 0, stream>>>(
        bcdt + 32, 96, wdt2i, DTRANK, dt, DINNER, bdti, SEQ, DINNER, DTRANK, 1);
    dim3 gs(DINNER / 16, NCHUNK);
    scan_pass1<<<gs, 256, 0, stream>>>(dt, u, bcdt, logAi, Pbuf, Sbuf);
    scan_combine<<<DINNER * DSTATE / 256, 256, 0, stream>>>(Pbuf, Sbuf, Hinit);
    scan_pass2<<<gs, 256, 0, stream>>>(dt, u, bcdt, logAi, Dpi, Hinit, resu0, y2b);
    dim3 g2(SEQ / 128, DMODEL / 128);
    gemm_bt_bf16<<<g2, 256, 0, stream>>>(y2b, wouti, x, x, SEQ, DMODEL, DINNER);
  }
  cast_bf16_kernel<<<SEQ * DMODEL / 4 / 256, 256, 0, stream>>>(x, xb, (size_t)SEQ * DMODEL / 4);
  gemm8p_bt_bf16<256, true><<<dim3(SEQ / 256, VOCAB / 256), 512, 0, stream>>>(
      xb, eb, out, VOCAB, DMODEL);
}

// Round 9
// 2307.867 us; speedup vs baseline: 1.3051x; 1.1112x over previous
//
#include <hip/hip_runtime.h>

#define SEQ 2048
#define DMODEL 1024
#define DINNER 2048
#define DSTATE 16
#define DTRANK 64
#define NLAYER 8
#define VOCAB 32000
#define NCHUNK 32
#define CLEN 64   // SEQ / NCHUNK
#define PROJ_NCH 16
#define PROJ_KC 128  // DINNER / PROJ_NCH

typedef float f32x4 __attribute__((ext_vector_type(4)));
typedef short bf16x8 __attribute__((ext_vector_type(8)));

__device__ __forceinline__ ushort f2bf(float f) {
  union { float f; unsigned u; } v; v.f = f;
  unsigned r = v.u + 0x7fffu + ((v.u >> 16) & 1u);
  return (ushort)(r >> 16);
}

__device__ __forceinline__ void lds_load16(const void* g, void* l) {
  __builtin_amdgcn_global_load_lds(
      (const __attribute__((address_space(1))) void*)g,
      (__attribute__((address_space(3))) void*)l, 16, 0, 0);
}

// ---------------- counted-vmcnt MFMA GEMM (proven R3 schedule) --------------
// C[M,N] = A[M,K] @ B[N,K]^T.  BN=256 fixed, BM template (256 or 128).
// Waves read fixed (A-half, B-half) pairs -> ALL of tile t must be landed
// before first read: vmcnt(2)/(1) leaves only A0(t+1) in flight. Stages for
// t+1 staggered at mq boundaries. LDS XOR-swizzle src+read (involution).
template<int BM, bool NTS>
__global__ __launch_bounds__(512, 2) void gemm8p_bt_bf16(
    const ushort* __restrict__ A, const ushort* __restrict__ B,
    float* __restrict__ C, int N, int K)
{
  constexpr int MFR = BM / 32;       // m-fragments per wave
  constexpr int MPP = MFR / 4;       // m-fragments per phase
  constexpr int ALOADS = BM / 128;   // global_load_lds per thread per A-half
  __shared__ __align__(16) ushort As[2 * BM * 64];
  __shared__ __align__(16) ushort Bs[2 * 256 * 64];
  const int tid = threadIdx.x;
  const int lane = tid & 63;
  const int wid = tid >> 6;
  const int wr = wid >> 2, wc = wid & 3;
  const int rr = lane & 15, kq = lane >> 4;

  unsigned nwg = gridDim.x * gridDim.y;
  unsigned lb = blockIdx.y * gridDim.x + blockIdx.x;
  if ((nwg & 7u) == 0u) { unsigned cpx = nwg >> 3; lb = (lb & 7u) * cpx + (lb >> 3); }
  const int bm = (int)(lb % gridDim.x) * BM;
  const int bn = (int)(lb / gridDim.x) * 256;

  const ushort* Abase = A + (size_t)bm * K;
  const ushort* Bbase = B + (size_t)bn * K;

  auto stageA = [&](int buf, int h, int kt) {
    constexpr int HR = BM / 2;
#pragma unroll
    for (int L = 0; L < ALOADS; ++L) {
      int f = L * 512 + tid;
      int rl = f >> 3, g = f & 7;
      int gg = g ^ (rl & 7);  // pre-swizzled source granule
      lds_load16(Abase + (size_t)(h * HR + rl) * K + kt * 64 + gg * 8,
                 (void*)(As + buf * (BM * 64) + (h * HR + rl) * 64 + g * 8));
    }
  };
  auto stageB = [&](int buf, int h, int kt) {
#pragma unroll
    for (int L = 0; L < 2; ++L) {
      int f = L * 512 + tid;
      int rl = f >> 3, g = f & 7;
      int gg = g ^ (rl & 7);
      lds_load16(Bbase + (size_t)(h * 128 + rl) * K + kt * 64 + gg * 8,
                 (void*)(Bs + buf * (256 * 64) + (h * 128 + rl) * 64 + g * 8));
    }
  };
  auto rdA = [&](int buf, int r, int kbyte) {
    int sw = kbyte ^ ((r & 7) << 4);
    return *(const bf16x8*)(As + buf * (BM * 64) + r * 64 + (sw >> 1));
  };
  auto rdB = [&](int buf, int r, int kbyte) {
    int sw = kbyte ^ ((r & 7) << 4);
    return *(const bf16x8*)(Bs + buf * (256 * 64) + r * 64 + (sw >> 1));
  };

  f32x4 acc[MFR][4];
#pragma unroll
  for (int m = 0; m < MFR; ++m)
#pragma unroll
    for (int n = 0; n < 4; ++n) acc[m][n] = (f32x4){0.f, 0.f, 0.f, 0.f};

  const int NT = K >> 6;
  stageA(0, 0, 0); stageA(0, 1, 0); stageB(0, 0, 0); stageB(0, 1, 0);

  for (int t = 0; t < NT; ++t) {
    const int cur = t & 1;
    const bool more = (t + 1 < NT);
    if (more) stageA(cur ^ 1, 0, t + 1);
    if (more) {
      // ALL of tile t landed; only A0(t+1) in flight
      if constexpr (BM == 256) asm volatile("s_waitcnt vmcnt(2)" ::: "memory");
      else                     asm volatile("s_waitcnt vmcnt(1)" ::: "memory");
    } else {
      asm volatile("s_waitcnt vmcnt(0)" ::: "memory");
    }
    __syncthreads();

    bf16x8 bfr[4][2];
#pragma unroll
    for (int n = 0; n < 4; ++n)
#pragma unroll
      for (int kk = 0; kk < 2; ++kk)
        bfr[n][kk] = rdB(cur, wc * 64 + n * 16 + rr, kk * 64 + kq * 16);

#pragma unroll
    for (int mq = 0; mq < 4; ++mq) {
      if (mq == 1 && more) stageA(cur ^ 1, 1, t + 1);
      if (mq == 2 && more) stageB(cur ^ 1, 0, t + 1);
      if (mq == 3 && more) stageB(cur ^ 1, 1, t + 1);
      bf16x8 af[MPP][2];
#pragma unroll
      for (int mf = 0; mf < MPP; ++mf)
#pragma unroll
        for (int kk = 0; kk < 2; ++kk)
          af[mf][kk] = rdA(cur, wr * (BM / 2) + (mq * MPP + mf) * 16 + rr, kk * 64 + kq * 16);
      __builtin_amdgcn_s_setprio(1);
#pragma unroll
      for (int kk = 0; kk < 2; ++kk)
#pragma unroll
        for (int mf = 0; mf < MPP; ++mf)
#pragma unroll
          for (int n = 0; n < 4; ++n)
            acc[mq * MPP + mf][n] = __builtin_amdgcn_mfma_f32_16x16x32_bf16(
                af[mf][kk], bfr[n][kk], acc[mq * MPP + mf][n], 0, 0, 0);
      __builtin_amdgcn_s_setprio(0);
    }
    __syncthreads();
  }

  // Epilogue: per-wave LDS transpose in Bs (16 rows x 64 cols f32, stride 68).
  // Loop's trailing barrier already fenced all Bs reads; regions are per-wave.
  float* ep = (float*)Bs + wid * (16 * 68);
  const int cg = bn + wc * 64;
#pragma unroll
  for (int m = 0; m < MFR; ++m) {
    const int r0g = bm + wr * (BM / 2) + m * 16;
#pragma unroll
    for (int n = 0; n < 4; ++n)
#pragma unroll
      for (int j = 0; j < 4; ++j)
        ep[(kq * 4 + j) * 68 + n * 16 + rr] = acc[m][n][j];
#pragma unroll
    for (int i = 0; i < 4; ++i) {
      int row = i * 4 + kq;
      f32x4 v = *(const f32x4*)&ep[row * 68 + rr * 4];
      f32x4* dst = (f32x4*)&C[(size_t)(r0g + row) * N + cg + rr * 4];
      if constexpr (NTS) __builtin_nontemporal_store(v, dst);
      else *dst = v;
    }
  }
}

// ---------------- split-K bf16 MFMA GEMM (2-phase 128x128) ------------------
// Chunk z = blockIdx.z over K/2; writes partials Cp[z][M][N].
__global__ __launch_bounds__(256) void gemm_btk_bf16(
    const ushort* __restrict__ A, const ushort* __restrict__ B,
    float* __restrict__ Cp, int M, int N, int K)
{
  __shared__ __align__(16) ushort As[128 * 64];
  __shared__ __align__(16) ushort Bs[128 * 64];
  const int tid = threadIdx.x;
  const int lane = tid & 63;
  const int wave = tid >> 6;
  const int wr = wave >> 1, wc = wave & 1;
  const int KC = K >> 1;
  const int k0 = blockIdx.z * KC;

  unsigned nwg = gridDim.x * gridDim.y;
  unsigned lb = blockIdx.y * gridDim.x + blockIdx.x;
  if ((nwg & 7u) == 0u) {
    unsigned cpx = nwg >> 3;
    lb = (lb & 7u) * cpx + (lb >> 3);
  }
  const int bm = (lb % gridDim.x) * 128;
  const int bn = (lb / gridDim.x) * 128;
  const int rr = lane & 15, kq = lane >> 4;

  f32x4 acc[4][4];
#pragma unroll
  for (int m = 0; m < 4; ++m)
#pragma unroll
    for (int n = 0; n < 4; ++n) acc[m][n] = (f32x4){0.f, 0.f, 0.f, 0.f};

  for (int kt = 0; kt < KC; kt += 64) {
#pragma unroll
    for (int i = 0; i < 4; ++i) {
      int fb = i * 256 + tid;
      int row = fb >> 3, cb = fb & 7;
      lds_load16(A + (size_t)(bm + row) * K + k0 + kt + cb * 8, (void*)(As + (size_t)fb * 8));
      lds_load16(B + (size_t)(bn + row) * K + k0 + kt + cb * 8, (void*)(Bs + (size_t)fb * 8));
    }
    __syncthreads();
#pragma unroll
    for (int ks = 0; ks < 2; ++ks) {
      bf16x8 af[4], bfr[4];
      const int koff = ks * 32 + kq * 8;
#pragma unroll
      for (int m = 0; m < 4; ++m)
        af[m] = *(const bf16x8*)&As[(wr * 64 + m * 16 + rr) * 64 + koff];
#pragma unroll
      for (int n = 0; n < 4; ++n)
        bfr[n] = *(const bf16x8*)&Bs[(wc * 64 + n * 16 + rr) * 64 + koff];
#pragma unroll
      for (int m = 0; m < 4; ++m)
#pragma unroll
        for (int n = 0; n < 4; ++n)
          acc[m][n] = __builtin_amdgcn_mfma_f32_16x16x32_bf16(af[m], bfr[n], acc[m][n], 0, 0, 0);
    }
    __syncthreads();
  }
  float* C = Cp + (size_t)blockIdx.z * M * N;
#pragma unroll
  for (int m = 0; m < 4; ++m) {
    const int r0 = bm + wr * 64 + m * 16 + kq * 4;
#pragma unroll
    for (int n = 0; n < 4; ++n) {
      const int cc = bn + wc * 64 + n * 16 + rr;
#pragma unroll
      for (int j = 0; j < 4; ++j)
        C[(size_t)(r0 + j) * N + cc] = acc[m][n][j];
    }
  }
}

// x += P0 + P1 (residual update for split-K gemm2)
__global__ __launch_bounds__(256) void add3_kernel(
    const float* __restrict__ P0, const float* __restrict__ P1, float* __restrict__ x)
{
  size_t i = (size_t)blockIdx.x * 256 + threadIdx.x;
  float4 a = ((const float4*)P0)[i];
  float4 b = ((const float4*)P1)[i];
  float4 c = ((float4*)x)[i];
  c.x += a.x + b.x; c.y += a.y + b.y; c.z += a.z + b.z; c.w += a.w + b.w;
  ((float4*)x)[i] = c;
}

// ---------------- split-K f32 projection GEMM: Cp[ch] = A@W^T chunk ---------
__global__ __launch_bounds__(256) void projgemm_f32(
    const float* __restrict__ A, const float* __restrict__ W,
    float* __restrict__ Cp, int M)
{
  __shared__ float As[64][65];
  __shared__ float Ws[96][65];
  const int t = threadIdx.x;
  const int bm = blockIdx.x * 64;
  const int kc = blockIdx.y * PROJ_KC;
  const int ty = t >> 4, tx = t & 15;
  const int r0 = ty * 4, c0 = tx * 6;
  float acc[4][6] = {};
  for (int kt = 0; kt < PROJ_KC; kt += 64) {
#pragma unroll
    for (int i = 0; i < 4; ++i) {
      int e4 = i * 256 + t;
      int r = e4 >> 4, c4 = (e4 & 15) * 4;
      *(float4*)&As[r][c4] = *(const float4*)&A[(size_t)(bm + r) * DINNER + kc + kt + c4];
    }
#pragma unroll
    for (int i = 0; i < 6; ++i) {
      int e4 = i * 256 + t;
      int r = e4 >> 4, c4 = (e4 & 15) * 4;
      *(float4*)&Ws[r][c4] = *(const float4*)&W[(size_t)r * DINNER + kc + kt + c4];
    }
    __syncthreads();
#pragma unroll 4
    for (int kk = 0; kk < 64; ++kk) {
      float a0 = As[r0][kk], a1 = As[r0 + 1][kk], a2 = As[r0 + 2][kk], a3 = As[r0 + 3][kk];
      float w0 = Ws[c0][kk], w1 = Ws[c0 + 1][kk], w2 = Ws[c0 + 2][kk];
      float w3 = Ws[c0 + 3][kk], w4 = Ws[c0 + 4][kk], w5 = Ws[c0 + 5][kk];
      acc[0][0] += a0 * w0; acc[0][1] += a0 * w1; acc[0][2] += a0 * w2;
      acc[0][3] += a0 * w3; acc[0][4] += a0 * w4; acc[0][5] += a0 * w5;
      acc[1][0] += a1 * w0; acc[1][1] += a1 * w1; acc[1][2] += a1 * w2;
      acc[1][3] += a1 * w3; acc[1][4] += a1 * w4; acc[1][5] += a1 * w5;
      acc[2][0] += a2 * w0; acc[2][1] += a2 * w1; acc[2][2] += a2 * w2;
      acc[2][3] += a2 * w3; acc[2][4] += a2 * w4; acc[2][5] += a2 * w5;
      acc[3][0] += a3 * w0; acc[3][1] += a3 * w1; acc[3][2] += a3 * w2;
      acc[3][3] += a3 * w3; acc[3][4] += a3 * w4; acc[3][5] += a3 * w5;
    }
    __syncthreads();
  }
  float* cp = Cp + (size_t)blockIdx.y * M * 96;
#pragma unroll
  for (int i = 0; i < 4; ++i)
#pragma unroll
    for (int j = 0; j < 6; ++j)
      cp[(size_t)(bm + r0 + i) * 96 + c0 + j] = acc[i][j];
}

__global__ __launch_bounds__(256) void proj_reduce(
    const float* __restrict__ Cp, float* __restrict__ bcdt, int M)
{
  int idx = blockIdx.x * 256 + threadIdx.x;
  float s = 0.f;
#pragma unroll
  for (int c = 0; c < PROJ_NCH; ++c) s += Cp[(size_t)c * M * 96 + idx];
  bcdt[idx] = s;
}

// ---------------- f32 small GEMM: C[M,N] = A[M,K(lda)] @ W[N,K(ldw)]^T ------
__global__ __launch_bounds__(256) void smallgemm_f32(
    const float* __restrict__ A, int lda,
    const float* __restrict__ W, int ldw,
    float* __restrict__ C, int ldc,
    const float* __restrict__ bias,
    int M, int N, int K, int act)
{
  __shared__ float As[64][65];
  __shared__ float Ws[64][65];
  const int t = threadIdx.x;
  const int bm = blockIdx.x * 64, bn = blockIdx.y * 64;
  const int r0 = (t >> 4) * 4;
  const int c0 = (t & 15) * 4;
  float acc[4][4] = {};

  for (int kt = 0; kt < K; kt += 64) {
#pragma unroll
    for (int i = 0; i < 16; ++i) {
      int idx = i * 256 + t;
      int r = idx >> 6, c = idx & 63;
      As[r][c] = A[(size_t)(bm + r) * lda + kt + c];
      int wrow = bn + r;
      Ws[r][c] = (wrow < N) ? W[(size_t)wrow * ldw + kt + c] : 0.f;
    }
    __syncthreads();
#pragma unroll 8
    for (int kk = 0; kk < 64; ++kk) {
      float a0 = As[r0][kk], a1 = As[r0 + 1][kk], a2 = As[r0 + 2][kk], a3 = As[r0 + 3][kk];
      float w0 = Ws[c0][kk], w1 = Ws[c0 + 1][kk], w2 = Ws[c0 + 2][kk], w3 = Ws[c0 + 3][kk];
      acc[0][0] += a0 * w0; acc[0][1] += a0 * w1; acc[0][2] += a0 * w2; acc[0][3] += a0 * w3;
      acc[1][0] += a1 * w0; acc[1][1] += a1 * w1; acc[1][2] += a1 * w2; acc[1][3] += a1 * w3;
      acc[2][0] += a2 * w0; acc[2][1] += a2 * w1; acc[2][2] += a2 * w2; acc[2][3] += a2 * w3;
      acc[3][0] += a3 * w0; acc[3][1] += a3 * w1; acc[3][2] += a3 * w2; acc[3][3] += a3 * w3;
    }
    __syncthreads();
  }
#pragma unroll
  for (int i = 0; i < 4; ++i)
#pragma unroll
    for (int j = 0; j < 4; ++j) {
      int cc = bn + c0 + j;
      if (cc < N) {
        float v = acc[i][j];
        if (bias) v += bias[cc];
        if (act == 1) v = (v > 20.f) ? v : log1pf(expf(v));
        C[(size_t)(bm + r0 + i) * ldc + cc] = v;
      }
    }
}

// ---------------- embedding gather ------------------------------------------
__global__ __launch_bounds__(256) void gather_kernel(
    const int* __restrict__ ids, const float* __restrict__ embed, float* __restrict__ x)
{
  int row = blockIdx.x;
  int id = ids[row];
  ((float4*)x)[(size_t)row * (DMODEL / 4) + threadIdx.x] =
      ((const float4*)(embed + (size_t)id * DMODEL))[threadIdx.x];
}

// ---------------- RMSNorm (no scale) -> bf16 --------------------------------
__global__ __launch_bounds__(256) void rmsnorm_kernel(
    const float* __restrict__ x, ushort* __restrict__ xnb)
{
  int row = blockIdx.x;
  float4 v = ((const float4*)(x + (size_t)row * DMODEL))[threadIdx.x];
  float s = v.x * v.x + v.y * v.y + v.z * v.z + v.w * v.w;
#pragma unroll
  for (int o = 32; o > 0; o >>= 1) s += __shfl_down(s, o);
  __shared__ float ws[4];
  if ((threadIdx.x & 63) == 0) ws[threadIdx.x >> 6] = s;
  __syncthreads();
  float tot = ws[0] + ws[1] + ws[2] + ws[3];
  float sc = rsqrtf(tot * (1.0f / DMODEL) + 1e-6f);
  ushort4 o4 = {f2bf(v.x * sc), f2bf(v.y * sc), f2bf(v.z * sc), f2bf(v.w * sc)};
  ((ushort4*)xnb)[(size_t)row * (DMODEL / 4) + threadIdx.x] = o4;
}

// ---------------- causal depthwise conv (K=4) + SiLU ------------------------
__global__ __launch_bounds__(256) void conv_silu_kernel(
    const float* __restrict__ u0, int ld, const float* __restrict__ Wconv,
    float* __restrict__ u)
{
  int idx = blockIdx.x * 256 + threadIdx.x;
  int d4 = idx & (DINNER / 4 - 1);
  int l = idx >> 9;
  int d0 = d4 * 4;
  float wt[4][4];
#pragma unroll
  for (int j = 0; j < 4; ++j) {
    float4 tv = *(const float4*)&Wconv[(d0 + j) * 4];
    wt[j][0] = tv.x; wt[j][1] = tv.y; wt[j][2] = tv.z; wt[j][3] = tv.w;
  }
  float a[4] = {0.f, 0.f, 0.f, 0.f};
#pragma unroll
  for (int k = 0; k < 4; ++k) {
    int ls = l - 3 + k;
    if (ls >= 0) {
      float4 uv = *(const float4*)&u0[(size_t)ls * ld + d0];
      a[0] += uv.x * wt[0][k];
      a[1] += uv.y * wt[1][k];
      a[2] += uv.z * wt[2][k];
      a[3] += uv.w * wt[3][k];
    }
  }
  float4 r;
  r.x = a[0] / (1.f + expf(-a[0]));
  r.y = a[1] / (1.f + expf(-a[1]));
  r.z = a[2] / (1.f + expf(-a[2]));
  r.w = a[3] / (1.f + expf(-a[3]));
  *(float4*)&u[(size_t)l * DINNER + d0] = r;
}

// ---------------- chunk-parallel selective scan -----------------------------
__global__ __launch_bounds__(256) void scan_pass1(
    const float* __restrict__ dt, const float* __restrict__ u,
    const float* __restrict__ bcdt, const float* __restrict__ logA,
    float* __restrict__ P, float* __restrict__ S)
{
  const int tid = threadIdx.x;
  const int n = tid & 15, dl = tid >> 4;
  const int dbase = blockIdx.x * 16;
  const int c = blockIdx.y;
  const int t0 = c * CLEN;
  const int d = dbase + dl;
  const float Aval = -expf(logA[d * DSTATE + n]);
  __shared__ float sdt[CLEN][16], su[CLEN][16], sB[CLEN][16];
  {
    int tt = tid >> 2, j0 = (tid & 3) * 4;
    *(float4*)&sdt[tt][j0] = *(const float4*)&dt[(size_t)(t0 + tt) * DINNER + dbase + j0];
    *(float4*)&su[tt][j0]  = *(const float4*)&u[(size_t)(t0 + tt) * DINNER + dbase + j0];
    *(float4*)&sB[tt][j0]  = *(const float4*)&bcdt[(size_t)(t0 + tt) * 96 + j0];
  }
  __syncthreads();
  float h = 0.f, pr = 1.f;
#pragma unroll 8
  for (int i = 0; i < CLEN; ++i) {
    float dtv = sdt[i][dl], uv = su[i][dl], Bv = sB[i][n];
    float dtA = dtv * Aval;
    float rinv = __builtin_amdgcn_rcpf(1.f - 0.5f * dtA);
    float dA = (1.f + 0.5f * dtA) * rinv;
    float dBu = dtv * Bv * rinv * uv;
    h = dA * h + dBu;
    pr *= dA;
  }
  size_t idx = (size_t)c * (DINNER * DSTATE) + (size_t)d * DSTATE + n;
  P[idx] = pr;
  S[idx] = h;
}

// pass2: chunk-prefix from P,S computed in-kernel (combine fused); reduce over
// states; fuse y*silu(res) -> bf16
__global__ __launch_bounds__(256) void scan_pass2(
    const float* __restrict__ dt, const float* __restrict__ u,
    const float* __restrict__ bcdt, const float* __restrict__ logA,
    const float* __restrict__ Dp, const float* __restrict__ P,
    const float* __restrict__ S, const float* __restrict__ resu0,
    ushort* __restrict__ y2b)
{
  const int tid = threadIdx.x;
  const int n = tid & 15, dl = tid >> 4;
  const int dbase = blockIdx.x * 16;
  const int c = blockIdx.y;
  const int t0 = c * CLEN;
  const int d = dbase + dl;
  const float Aval = -expf(logA[d * DSTATE + n]);
  const float Dpv = Dp[d];
  __shared__ float sdt[CLEN][16], su[CLEN][16], sB[CLEN][16], sC[CLEN][16], sres[CLEN][16];
  {
    int tt = tid >> 2, j0 = (tid & 3) * 4;
    *(float4*)&sdt[tt][j0]  = *(const float4*)&dt[(size_t)(t0 + tt) * DINNER + dbase + j0];
    *(float4*)&su[tt][j0]   = *(const float4*)&u[(size_t)(t0 + tt) * DINNER + dbase + j0];
    *(float4*)&sB[tt][j0]   = *(const float4*)&bcdt[(size_t)(t0 + tt) * 96 + j0];
    *(float4*)&sC[tt][j0]   = *(const float4*)&bcdt[(size_t)(t0 + tt) * 96 + 16 + j0];
    *(float4*)&sres[tt][j0] = *(const float4*)&resu0[(size_t)(t0 + tt) * (2 * DINNER) + dbase + j0];
  }
  // chunk-entry state: prefix over previous chunks (fused scan_combine)
  float h = 0.f;
  {
    const size_t base = (size_t)d * DSTATE + n;
#pragma unroll 4
    for (int cc = 0; cc < c; ++cc) {
      size_t o = (size_t)cc * (DINNER * DSTATE) + base;
      h = P[o] * h + S[o];
    }
  }
  __syncthreads();
#pragma unroll 4
  for (int i = 0; i < CLEN; ++i) {
    float dtv = sdt[i][dl], uv = su[i][dl];
    float dtA = dtv * Aval;
    float rinv = __builtin_amdgcn_rcpf(1.f - 0.5f * dtA);
    float dA = (1.f + 0.5f * dtA) * rinv;
    float dBu = dtv * sB[i][n] * rinv * uv;
    h = dA * h + dBu;
    float p = h * sC[i][n];
    p += __shfl_xor(p, 1);
    p += __shfl_xor(p, 2);
    p += __shfl_xor(p, 4);
    p += __shfl_xor(p, 8);
    if (n == 0) {
      float rv = sres[i][dl];
      float yv = (p + uv * Dpv) * (rv / (1.f + expf(-rv)));
      y2b[(size_t)(t0 + i) * DINNER + d] = f2bf(yv);
    }
  }
}

// ---------------- f32 -> bf16 cast ------------------------------------------
__global__ __launch_bounds__(256) void cast_bf16_kernel(
    const float* __restrict__ in, ushort* __restrict__ out, size_t n4)
{
  size_t i = (size_t)blockIdx.x * 256 + threadIdx.x;
  if (i >= n4) return;
  float4 v = ((const float4*)in)[i];
  ushort4 o = {f2bf(v.x), f2bf(v.y), f2bf(v.z), f2bf(v.w)};
  ((ushort4*)out)[i] = o;
}

// ---------------- concat-cast Wres|Win -> bf16 [L][2*DINNER][DMODEL] --------
__global__ __launch_bounds__(256) void cast_cat2_kernel(
    const float* __restrict__ Wres, const float* __restrict__ Win, ushort* __restrict__ out)
{
  size_t i4 = (size_t)blockIdx.x * 256 + threadIdx.x;
  size_t e0 = i4 * 4;
  int k = (int)(e0 & (DMODEL - 1));
  int r = (int)((e0 >> 10) & (2 * DINNER - 1));
  int l = (int)(e0 >> 22);
  const float* src = (r < DINNER)
      ? &Wres[(((size_t)l * DINNER + r) << 10) + k]
      : &Win[(((size_t)l * DINNER + (r - DINNER)) << 10) + k];
  float4 v = *(const float4*)src;
  ushort4 o = {f2bf(v.x), f2bf(v.y), f2bf(v.z), f2bf(v.w)};
  ((ushort4*)out)[i4] = o;
}

// ---------------- concat WB|WC|Wdt1 -> [L][96][DINNER] ----------------------
__global__ __launch_bounds__(256) void concat_wbcdt_kernel(
    const float* __restrict__ WB, const float* __restrict__ WC,
    const float* __restrict__ Wdt1, float* __restrict__ out)
{
  size_t idx = (size_t)blockIdx.x * 256 + threadIdx.x;
  int k = idx & (DINNER - 1);
  size_t rl = idx >> 11;
  int row = (int)(rl % 96);
  int l = (int)(rl / 96);
  float v;
  if (row < 16)       v = WB[((size_t)l * DSTATE + row) * DINNER + k];
  else if (row < 32)  v = WC[((size_t)l * DSTATE + (row - 16)) * DINNER + k];
  else                v = Wdt1[((size_t)l * DTRANK + (row - 32)) * DINNER + k];
  out[idx] = v;
}

// ============================================================================
extern "C" void kernel_launch(void* const* d_in, const int* in_sizes, int n_in,
                              void* d_out, int out_size, void* d_ws, size_t ws_size,
                              hipStream_t stream) {
  (void)in_sizes; (void)n_in; (void)out_size;
  const int* token_ids = (const int*)d_in[0];
  const float* embed = (const float*)d_in[1];
  const float* Wres = (const float*)d_in[2];
  const float* Win = (const float*)d_in[3];
  const float* Wconv = (const float*)d_in[4];
  const float* WB = (const float*)d_in[5];
  const float* WC = (const float*)d_in[6];
  const float* Wdt1 = (const float*)d_in[7];
  const float* Wdt2 = (const float*)d_in[8];
  const float* bdt = (const float*)d_in[9];
  const float* logA = (const float*)d_in[10];
  const float* Dp = (const float*)d_in[11];
  const float* Wout = (const float*)d_in[12];
  float* out = (float*)d_out;

  char* w = (char*)d_ws;
  auto alloc = [&](size_t bytes) {
    char* p = w;
    w += (bytes + 255) & ~(size_t)255;
    return p;
  };
  ushort* eb    = (ushort*)alloc((size_t)VOCAB * DMODEL * 2);
  ushort* wcatb = (ushort*)alloc((size_t)NLAYER * 2 * DINNER * DMODEL * 2);
  ushort* woutb = (ushort*)alloc((size_t)NLAYER * DMODEL * DINNER * 2);
  float* wbcdt  = (float*)alloc((size_t)NLAYER * 96 * DINNER * 4);
  float* x      = (float*)alloc((size_t)SEQ * DMODEL * 4);
  ushort* xnb   = (ushort*)alloc((size_t)SEQ * DMODEL * 2);
  float* resu0  = (float*)alloc((size_t)SEQ * 2 * DINNER * 4);
  float* u      = (float*)alloc((size_t)SEQ * DINNER * 4);
  float* bcdt   = (float*)alloc((size_t)SEQ * 96 * 4);
  float* dt     = (float*)alloc((size_t)SEQ * DINNER * 4);
  float* Cp     = (float*)alloc((size_t)PROJ_NCH * SEQ * 96 * 4);
  float* Cp2    = (float*)alloc((size_t)2 * SEQ * DMODEL * 4);
  float* Pbuf   = (float*)alloc((size_t)NCHUNK * DINNER * DSTATE * 4);
  float* Sbuf   = (float*)alloc((size_t)NCHUNK * DINNER * DSTATE * 4);
  ushort* y2b   = (ushort*)alloc((size_t)SEQ * DINNER * 2);
  ushort* xb    = (ushort*)alloc((size_t)SEQ * DMODEL * 2);
  if ((size_t)(w - (char*)d_ws) > ws_size) return;

  // weight preprocessing
  cast_bf16_kernel<<<VOCAB * DMODEL / 4 / 256, 256, 0, stream>>>(embed, eb, (size_t)VOCAB * DMODEL / 4);
  cast_cat2_kernel<<<NLAYER * 2 * DINNER * DMODEL / 4 / 256, 256, 0, stream>>>(Wres, Win, wcatb);
  cast_bf16_kernel<<<NLAYER * DMODEL * DINNER / 4 / 256, 256, 0, stream>>>(Wout, woutb, (size_t)NLAYER * DMODEL * DINNER / 4);
  concat_wbcdt_kernel<<<NLAYER * 96 * DINNER / 256, 256, 0, stream>>>(WB, WC, Wdt1, wbcdt);
  gather_kernel<<<SEQ, 256, 0, stream>>>(token_ids, embed, x);

  for (int i = 0; i < NLAYER; ++i) {
    const ushort* wcati = wcatb + (size_t)i * 2 * DINNER * DMODEL;
    const ushort* wouti = woutb + (size_t)i * DMODEL * DINNER;
    const float* wconvi = Wconv + (size_t)i * DINNER * 4;
    const float* wbcdti = wbcdt + (size_t)i * 96 * DINNER;
    const float* wdt2i = Wdt2 + (size_t)i * DINNER * DTRANK;
    const float* bdti = bdt + (size_t)i * DINNER;
    const float* logAi = logA + (size_t)i * DINNER * DSTATE;
    const float* Dpi = Dp + (size_t)i * DINNER;

    rmsnorm_kernel<<<SEQ, 256, 0, stream>>>(x, xnb);
    gemm8p_bt_bf16<128, false><<<dim3(SEQ / 128, 2 * DINNER / 256), 512, 0, stream>>>(
        xnb, wcati, resu0, 2 * DINNER, DMODEL);
    conv_silu_kernel<<<SEQ * DINNER / 4 / 256, 256, 0, stream>>>(resu0 + DINNER, 2 * DINNER, wconvi, u);
    projgemm_f32<<<dim3(SEQ / 64, PROJ_NCH), 256, 0, stream>>>(u, wbcdti, Cp, SEQ);
    proj_reduce<<<SEQ * 96 / 256, 256, 0, stream>>>(Cp, bcdt, SEQ);
    smallgemm_f32<<<dim3(SEQ / 64, DINNER / 64), 256, 0, stream>>>(
        bcdt + 32, 96, wdt2i, DTRANK, dt, DINNER, bdti, SEQ, DINNER, DTRANK, 1);
    dim3 gs(DINNER / 16, NCHUNK);
    scan_pass1<<<gs, 256, 0, stream>>>(dt, u, bcdt, logAi, Pbuf, Sbuf);
    scan_pass2<<<gs, 256, 0, stream>>>(dt, u, bcdt, logAi, Dpi, Pbuf, Sbuf, resu0, y2b);
    gemm_btk_bf16<<<dim3(SEQ / 128, DMODEL / 128, 2), 256, 0, stream>>>(
        y2b, wouti, Cp2, SEQ, DMODEL, DINNER);
    add3_kernel<<<SEQ * DMODEL / 4 / 256, 256, 0, stream>>>(
        Cp2, Cp2 + (size_t)SEQ * DMODEL, x);
  }
  cast_bf16_kernel<<<SEQ * DMODEL / 4 / 256, 256, 0, stream>>>(x, xb, (size_t)SEQ * DMODEL / 4);
  gemm8p_bt_bf16<256, true><<<dim3(SEQ / 256, VOCAB / 256), 512, 0, stream>>>(
      xb, eb, out, VOCAB, DMODEL);
}

// Round 10
// 2267.919 us; speedup vs baseline: 1.3281x; 1.0176x over previous
//
#include <hip/hip_runtime.h>

#define SEQ 2048
#define DMODEL 1024
#define DINNER 2048
#define DSTATE 16
#define DTRANK 64
#define NLAYER 8
#define VOCAB 32000
#define NCHUNK 32
#define CLEN 64   // SEQ / NCHUNK
#define PROJ_NCH 16
#define PROJ_KC 128  // DINNER / PROJ_NCH

typedef float f32x4 __attribute__((ext_vector_type(4)));
typedef short bf16x8 __attribute__((ext_vector_type(8)));

__device__ __forceinline__ ushort f2bf(float f) {
  union { float f; unsigned u; } v; v.f = f;
  unsigned r = v.u + 0x7fffu + ((v.u >> 16) & 1u);
  return (ushort)(r >> 16);
}

__device__ __forceinline__ void lds_load16(const void* g, void* l) {
  __builtin_amdgcn_global_load_lds(
      (const __attribute__((address_space(1))) void*)g,
      (__attribute__((address_space(3))) void*)l, 16, 0, 0);
}

// ---------------- 128x128 2-blocks/CU MFMA GEMM ------------------------------
// C[M,N] = A[M,K] @ B[N,K]^T. 256 thr (4 waves, 2x2), 64KB LDS dbuf ->
// 2 blocks/CU: one block's K-loop hides the other's vmcnt stalls + epilogue.
// Full-tile prefetch: all 8 loads of t+1 issued at top, vmcnt(8) = tile t
// landed. XOR-swizzle staging src + reads (involution). XCD block swizzle.
template<bool NTS>
__global__ __launch_bounds__(256, 2) void gemm2p_bt_bf16(
    const ushort* __restrict__ A, const ushort* __restrict__ B,
    float* __restrict__ C, int N, int K)
{
  __shared__ __align__(16) ushort As[2 * 128 * 64];
  __shared__ __align__(16) ushort Bs[2 * 128 * 64];
  const int tid = threadIdx.x;
  const int lane = tid & 63;
  const int wave = tid >> 6;
  const int wr = wave >> 1, wc = wave & 1;
  const int rr = lane & 15, kq = lane >> 4;

  unsigned nwg = gridDim.x * gridDim.y;
  unsigned lb = blockIdx.y * gridDim.x + blockIdx.x;
  if ((nwg & 7u) == 0u) { unsigned cpx = nwg >> 3; lb = (lb & 7u) * cpx + (lb >> 3); }
  const int bm = (int)(lb % gridDim.x) * 128;
  const int bn = (int)(lb / gridDim.x) * 128;

  const ushort* Abase = A + (size_t)bm * K;
  const ushort* Bbase = B + (size_t)bn * K;

  auto stage = [&](int buf, int kt) {
#pragma unroll
    for (int i = 0; i < 4; ++i) {
      int f = i * 256 + tid;           // 0..1023 over 128 rows x 8 granules
      int rl = f >> 3, g = f & 7;
      int gg = g ^ (rl & 7);           // pre-swizzled source granule
      lds_load16(Abase + (size_t)rl * K + kt * 64 + gg * 8,
                 (void*)(As + buf * 8192 + rl * 64 + g * 8));
      lds_load16(Bbase + (size_t)rl * K + kt * 64 + gg * 8,
                 (void*)(Bs + buf * 8192 + rl * 64 + g * 8));
    }
  };
  auto rdA = [&](int buf, int r, int kbyte) {
    int sw = kbyte ^ ((r & 7) << 4);
    return *(const bf16x8*)(As + buf * 8192 + r * 64 + (sw >> 1));
  };
  auto rdB = [&](int buf, int r, int kbyte) {
    int sw = kbyte ^ ((r & 7) << 4);
    return *(const bf16x8*)(Bs + buf * 8192 + r * 64 + (sw >> 1));
  };

  f32x4 acc[4][4];
#pragma unroll
  for (int m = 0; m < 4; ++m)
#pragma unroll
    for (int n = 0; n < 4; ++n) acc[m][n] = (f32x4){0.f, 0.f, 0.f, 0.f};

  const int NT = K >> 6;
  stage(0, 0);

  for (int t = 0; t < NT; ++t) {
    const int cur = t & 1;
    if (t + 1 < NT) {
      stage(cur ^ 1, t + 1);                       // 8 loads of tile t+1
      asm volatile("s_waitcnt vmcnt(8)" ::: "memory");  // tile t landed
    } else {
      asm volatile("s_waitcnt vmcnt(0)" ::: "memory");
    }
    __syncthreads();
#pragma unroll
    for (int ks = 0; ks < 2; ++ks) {
      const int kbyte = ks * 64 + kq * 16;
      bf16x8 af[4], bfr[4];
#pragma unroll
      for (int m = 0; m < 4; ++m)
        af[m] = rdA(cur, wr * 64 + m * 16 + rr, kbyte);
#pragma unroll
      for (int n = 0; n < 4; ++n)
        bfr[n] = rdB(cur, wc * 64 + n * 16 + rr, kbyte);
      __builtin_amdgcn_s_setprio(1);
#pragma unroll
      for (int m = 0; m < 4; ++m)
#pragma unroll
        for (int n = 0; n < 4; ++n)
          acc[m][n] = __builtin_amdgcn_mfma_f32_16x16x32_bf16(af[m], bfr[n], acc[m][n], 0, 0, 0);
      __builtin_amdgcn_s_setprio(0);
    }
    __syncthreads();
  }

  // Epilogue: per-wave LDS transpose (16 rows x 64 cols f32, stride 68) in Bs
  float* ep = (float*)Bs + wave * (16 * 68);
  const int cg = bn + wc * 64;
#pragma unroll
  for (int m = 0; m < 4; ++m) {
    const int r0g = bm + wr * 64 + m * 16;
#pragma unroll
    for (int n = 0; n < 4; ++n)
#pragma unroll
      for (int j = 0; j < 4; ++j)
        ep[(kq * 4 + j) * 68 + n * 16 + rr] = acc[m][n][j];
#pragma unroll
    for (int i = 0; i < 4; ++i) {
      int row = i * 4 + kq;
      f32x4 v = *(const f32x4*)&ep[row * 68 + rr * 4];
      f32x4* dst = (f32x4*)&C[(size_t)(r0g + row) * N + cg + rr * 4];
      if constexpr (NTS) __builtin_nontemporal_store(v, dst);
      else *dst = v;
    }
  }
}

// ---------------- split-K bf16 MFMA GEMM (2-phase 128x128) ------------------
__global__ __launch_bounds__(256) void gemm_btk_bf16(
    const ushort* __restrict__ A, const ushort* __restrict__ B,
    float* __restrict__ Cp, int M, int N, int K)
{
  __shared__ __align__(16) ushort As[128 * 64];
  __shared__ __align__(16) ushort Bs[128 * 64];
  const int tid = threadIdx.x;
  const int lane = tid & 63;
  const int wave = tid >> 6;
  const int wr = wave >> 1, wc = wave & 1;
  const int KC = K >> 1;
  const int k0 = blockIdx.z * KC;

  unsigned nwg = gridDim.x * gridDim.y;
  unsigned lb = blockIdx.y * gridDim.x + blockIdx.x;
  if ((nwg & 7u) == 0u) {
    unsigned cpx = nwg >> 3;
    lb = (lb & 7u) * cpx + (lb >> 3);
  }
  const int bm = (lb % gridDim.x) * 128;
  const int bn = (lb / gridDim.x) * 128;
  const int rr = lane & 15, kq = lane >> 4;

  f32x4 acc[4][4];
#pragma unroll
  for (int m = 0; m < 4; ++m)
#pragma unroll
    for (int n = 0; n < 4; ++n) acc[m][n] = (f32x4){0.f, 0.f, 0.f, 0.f};

  for (int kt = 0; kt < KC; kt += 64) {
#pragma unroll
    for (int i = 0; i < 4; ++i) {
      int fb = i * 256 + tid;
      int row = fb >> 3, cb = fb & 7;
      lds_load16(A + (size_t)(bm + row) * K + k0 + kt + cb * 8, (void*)(As + (size_t)fb * 8));
      lds_load16(B + (size_t)(bn + row) * K + k0 + kt + cb * 8, (void*)(Bs + (size_t)fb * 8));
    }
    __syncthreads();
#pragma unroll
    for (int ks = 0; ks < 2; ++ks) {
      bf16x8 af[4], bfr[4];
      const int koff = ks * 32 + kq * 8;
#pragma unroll
      for (int m = 0; m < 4; ++m)
        af[m] = *(const bf16x8*)&As[(wr * 64 + m * 16 + rr) * 64 + koff];
#pragma unroll
      for (int n = 0; n < 4; ++n)
        bfr[n] = *(const bf16x8*)&Bs[(wc * 64 + n * 16 + rr) * 64 + koff];
#pragma unroll
      for (int m = 0; m < 4; ++m)
#pragma unroll
        for (int n = 0; n < 4; ++n)
          acc[m][n] = __builtin_amdgcn_mfma_f32_16x16x32_bf16(af[m], bfr[n], acc[m][n], 0, 0, 0);
    }
    __syncthreads();
  }
  float* C = Cp + (size_t)blockIdx.z * M * N;
#pragma unroll
  for (int m = 0; m < 4; ++m) {
    const int r0 = bm + wr * 64 + m * 16 + kq * 4;
#pragma unroll
    for (int n = 0; n < 4; ++n) {
      const int cc = bn + wc * 64 + n * 16 + rr;
#pragma unroll
      for (int j = 0; j < 4; ++j)
        C[(size_t)(r0 + j) * N + cc] = acc[m][n][j];
    }
  }
}

// ---------------- x += P0 + P1, then RMSNorm(x)->bf16 (or plain cast) -------
// One block per row (1024 floats = 256 thr x 4).
__global__ __launch_bounds__(256) void add3_rms_kernel(
    const float* __restrict__ P0, const float* __restrict__ P1,
    float* __restrict__ x, ushort* __restrict__ dst, int donorm)
{
  size_t o = (size_t)blockIdx.x * (DMODEL / 4) + threadIdx.x;
  float4 a = ((const float4*)P0)[o];
  float4 b = ((const float4*)P1)[o];
  float4 c = ((float4*)x)[o];
  c.x += a.x + b.x; c.y += a.y + b.y; c.z += a.z + b.z; c.w += a.w + b.w;
  ((float4*)x)[o] = c;
  float sc = 1.f;
  if (donorm) {
    float s = c.x * c.x + c.y * c.y + c.z * c.z + c.w * c.w;
#pragma unroll
    for (int off = 32; off > 0; off >>= 1) s += __shfl_down(s, off);
    __shared__ float ws[4];
    if ((threadIdx.x & 63) == 0) ws[threadIdx.x >> 6] = s;
    __syncthreads();
    float tot = ws[0] + ws[1] + ws[2] + ws[3];
    sc = rsqrtf(tot * (1.0f / DMODEL) + 1e-6f);
  }
  ushort4 o4 = {f2bf(c.x * sc), f2bf(c.y * sc), f2bf(c.z * sc), f2bf(c.w * sc)};
  ((ushort4*)dst)[o] = o4;
}

// ---------------- embedding gather + RMSNorm -> x (f32) and xnb (bf16) ------
__global__ __launch_bounds__(256) void gather_rms_kernel(
    const int* __restrict__ ids, const float* __restrict__ embed,
    float* __restrict__ x, ushort* __restrict__ xnb)
{
  int row = blockIdx.x;
  int id = ids[row];
  float4 v = ((const float4*)(embed + (size_t)id * DMODEL))[threadIdx.x];
  size_t o = (size_t)row * (DMODEL / 4) + threadIdx.x;
  ((float4*)x)[o] = v;
  float s = v.x * v.x + v.y * v.y + v.z * v.z + v.w * v.w;
#pragma unroll
  for (int off = 32; off > 0; off >>= 1) s += __shfl_down(s, off);
  __shared__ float ws[4];
  if ((threadIdx.x & 63) == 0) ws[threadIdx.x >> 6] = s;
  __syncthreads();
  float tot = ws[0] + ws[1] + ws[2] + ws[3];
  float sc = rsqrtf(tot * (1.0f / DMODEL) + 1e-6f);
  ushort4 o4 = {f2bf(v.x * sc), f2bf(v.y * sc), f2bf(v.z * sc), f2bf(v.w * sc)};
  ((ushort4*)xnb)[o] = o4;
}

// ---------------- split-K f32 projection GEMM: Cp[ch] = A@W^T chunk ---------
__global__ __launch_bounds__(256) void projgemm_f32(
    const float* __restrict__ A, const float* __restrict__ W,
    float* __restrict__ Cp, int M)
{
  __shared__ float As[64][65];
  __shared__ float Ws[96][65];
  const int t = threadIdx.x;
  const int bm = blockIdx.x * 64;
  const int kc = blockIdx.y * PROJ_KC;
  const int ty = t >> 4, tx = t & 15;
  const int r0 = ty * 4, c0 = tx * 6;
  float acc[4][6] = {};
  for (int kt = 0; kt < PROJ_KC; kt += 64) {
#pragma unroll
    for (int i = 0; i < 4; ++i) {
      int e4 = i * 256 + t;
      int r = e4 >> 4, c4 = (e4 & 15) * 4;
      *(float4*)&As[r][c4] = *(const float4*)&A[(size_t)(bm + r) * DINNER + kc + kt + c4];
    }
#pragma unroll
    for (int i = 0; i < 6; ++i) {
      int e4 = i * 256 + t;
      int r = e4 >> 4, c4 = (e4 & 15) * 4;
      *(float4*)&Ws[r][c4] = *(const float4*)&W[(size_t)r * DINNER + kc + kt + c4];
    }
    __syncthreads();
#pragma unroll 4
    for (int kk = 0; kk < 64; ++kk) {
      float a0 = As[r0][kk], a1 = As[r0 + 1][kk], a2 = As[r0 + 2][kk], a3 = As[r0 + 3][kk];
      float w0 = Ws[c0][kk], w1 = Ws[c0 + 1][kk], w2 = Ws[c0 + 2][kk];
      float w3 = Ws[c0 + 3][kk], w4 = Ws[c0 + 4][kk], w5 = Ws[c0 + 5][kk];
      acc[0][0] += a0 * w0; acc[0][1] += a0 * w1; acc[0][2] += a0 * w2;
      acc[0][3] += a0 * w3; acc[0][4] += a0 * w4; acc[0][5] += a0 * w5;
      acc[1][0] += a1 * w0; acc[1][1] += a1 * w1; acc[1][2] += a1 * w2;
      acc[1][3] += a1 * w3; acc[1][4] += a1 * w4; acc[1][5] += a1 * w5;
      acc[2][0] += a2 * w0; acc[2][1] += a2 * w1; acc[2][2] += a2 * w2;
      acc[2][3] += a2 * w3; acc[2][4] += a2 * w4; acc[2][5] += a2 * w5;
      acc[3][0] += a3 * w0; acc[3][1] += a3 * w1; acc[3][2] += a3 * w2;
      acc[3][3] += a3 * w3; acc[3][4] += a3 * w4; acc[3][5] += a3 * w5;
    }
    __syncthreads();
  }
  float* cp = Cp + (size_t)blockIdx.y * M * 96;
#pragma unroll
  for (int i = 0; i < 4; ++i)
#pragma unroll
    for (int j = 0; j < 6; ++j)
      cp[(size_t)(bm + r0 + i) * 96 + c0 + j] = acc[i][j];
}

__global__ __launch_bounds__(256) void proj_reduce(
    const float* __restrict__ Cp, float* __restrict__ bcdt, int M)
{
  int idx = blockIdx.x * 256 + threadIdx.x;
  float s = 0.f;
#pragma unroll
  for (int c = 0; c < PROJ_NCH; ++c) s += Cp[(size_t)c * M * 96 + idx];
  bcdt[idx] = s;
}

// ---------------- f32 small GEMM: C[M,N] = A[M,K(lda)] @ W[N,K(ldw)]^T ------
__global__ __launch_bounds__(256) void smallgemm_f32(
    const float* __restrict__ A, int lda,
    const float* __restrict__ W, int ldw,
    float* __restrict__ C, int ldc,
    const float* __restrict__ bias,
    int M, int N, int K, int act)
{
  __shared__ float As[64][65];
  __shared__ float Ws[64][65];
  const int t = threadIdx.x;
  const int bm = blockIdx.x * 64, bn = blockIdx.y * 64;
  const int r0 = (t >> 4) * 4;
  const int c0 = (t & 15) * 4;
  float acc[4][4] = {};

  for (int kt = 0; kt < K; kt += 64) {
#pragma unroll
    for (int i = 0; i < 16; ++i) {
      int idx = i * 256 + t;
      int r = idx >> 6, c = idx & 63;
      As[r][c] = A[(size_t)(bm + r) * lda + kt + c];
      int wrow = bn + r;
      Ws[r][c] = (wrow < N) ? W[(size_t)wrow * ldw + kt + c] : 0.f;
    }
    __syncthreads();
#pragma unroll 8
    for (int kk = 0; kk < 64; ++kk) {
      float a0 = As[r0][kk], a1 = As[r0 + 1][kk], a2 = As[r0 + 2][kk], a3 = As[r0 + 3][kk];
      float w0 = Ws[c0][kk], w1 = Ws[c0 + 1][kk], w2 = Ws[c0 + 2][kk], w3 = Ws[c0 + 3][kk];
      acc[0][0] += a0 * w0; acc[0][1] += a0 * w1; acc[0][2] += a0 * w2; acc[0][3] += a0 * w3;
      acc[1][0] += a1 * w0; acc[1][1] += a1 * w1; acc[1][2] += a1 * w2; acc[1][3] += a1 * w3;
      acc[2][0] += a2 * w0; acc[2][1] += a2 * w1; acc[2][2] += a2 * w2; acc[2][3] += a2 * w3;
      acc[3][0] += a3 * w0; acc[3][1] += a3 * w1; acc[3][2] += a3 * w2; acc[3][3] += a3 * w3;
    }
    __syncthreads();
  }
#pragma unroll
  for (int i = 0; i < 4; ++i)
#pragma unroll
    for (int j = 0; j < 4; ++j) {
      int cc = bn + c0 + j;
      if (cc < N) {
        float v = acc[i][j];
        if (bias) v += bias[cc];
        if (act == 1) v = (v > 20.f) ? v : log1pf(expf(v));
        C[(size_t)(bm + r0 + i) * ldc + cc] = v;
      }
    }
}

// ---------------- causal depthwise conv (K=4) + SiLU ------------------------
__global__ __launch_bounds__(256) void conv_silu_kernel(
    const float* __restrict__ u0, int ld, const float* __restrict__ Wconv,
    float* __restrict__ u)
{
  int idx = blockIdx.x * 256 + threadIdx.x;
  int d4 = idx & (DINNER / 4 - 1);
  int l = idx >> 9;
  int d0 = d4 * 4;
  float wt[4][4];
#pragma unroll
  for (int j = 0; j < 4; ++j) {
    float4 tv = *(const float4*)&Wconv[(d0 + j) * 4];
    wt[j][0] = tv.x; wt[j][1] = tv.y; wt[j][2] = tv.z; wt[j][3] = tv.w;
  }
  float a[4] = {0.f, 0.f, 0.f, 0.f};
#pragma unroll
  for (int k = 0; k < 4; ++k) {
    int ls = l - 3 + k;
    if (ls >= 0) {
      float4 uv = *(const float4*)&u0[(size_t)ls * ld + d0];
      a[0] += uv.x * wt[0][k];
      a[1] += uv.y * wt[1][k];
      a[2] += uv.z * wt[2][k];
      a[3] += uv.w * wt[3][k];
    }
  }
  float4 r;
  r.x = a[0] / (1.f + expf(-a[0]));
  r.y = a[1] / (1.f + expf(-a[1]));
  r.z = a[2] / (1.f + expf(-a[2]));
  r.w = a[3] / (1.f + expf(-a[3]));
  *(float4*)&u[(size_t)l * DINNER + d0] = r;
}

// ---------------- chunk-parallel selective scan -----------------------------
__global__ __launch_bounds__(256) void scan_pass1(
    const float* __restrict__ dt, const float* __restrict__ u,
    const float* __restrict__ bcdt, const float* __restrict__ logA,
    float* __restrict__ P, float* __restrict__ S)
{
  const int tid = threadIdx.x;
  const int n = tid & 15, dl = tid >> 4;
  const int dbase = blockIdx.x * 16;
  const int c = blockIdx.y;
  const int t0 = c * CLEN;
  const int d = dbase + dl;
  const float Aval = -expf(logA[d * DSTATE + n]);
  __shared__ float sdt[CLEN][16], su[CLEN][16], sB[CLEN][16];
  {
    int tt = tid >> 2, j0 = (tid & 3) * 4;
    *(float4*)&sdt[tt][j0] = *(const float4*)&dt[(size_t)(t0 + tt) * DINNER + dbase + j0];
    *(float4*)&su[tt][j0]  = *(const float4*)&u[(size_t)(t0 + tt) * DINNER + dbase + j0];
    *(float4*)&sB[tt][j0]  = *(const float4*)&bcdt[(size_t)(t0 + tt) * 96 + j0];
  }
  __syncthreads();
  float h = 0.f, pr = 1.f;
#pragma unroll 8
  for (int i = 0; i < CLEN; ++i) {
    float dtv = sdt[i][dl], uv = su[i][dl], Bv = sB[i][n];
    float dtA = dtv * Aval;
    float rinv = __builtin_amdgcn_rcpf(1.f - 0.5f * dtA);
    float dA = (1.f + 0.5f * dtA) * rinv;
    float dBu = dtv * Bv * rinv * uv;
    h = dA * h + dBu;
    pr *= dA;
  }
  size_t idx = (size_t)c * (DINNER * DSTATE) + (size_t)d * DSTATE + n;
  P[idx] = pr;
  S[idx] = h;
}

// pass2: chunk-prefix from P,S computed in-kernel; reduce over states;
// fuse y*silu(res) -> bf16
__global__ __launch_bounds__(256) void scan_pass2(
    const float* __restrict__ dt, const float* __restrict__ u,
    const float* __restrict__ bcdt, const float* __restrict__ logA,
    const float* __restrict__ Dp, const float* __restrict__ P,
    const float* __restrict__ S, const float* __restrict__ resu0,
    ushort* __restrict__ y2b)
{
  const int tid = threadIdx.x;
  const int n = tid & 15, dl = tid >> 4;
  const int dbase = blockIdx.x * 16;
  const int c = blockIdx.y;
  const int t0 = c * CLEN;
  const int d = dbase + dl;
  const float Aval = -expf(logA[d * DSTATE + n]);
  const float Dpv = Dp[d];
  __shared__ float sdt[CLEN][16], su[CLEN][16], sB[CLEN][16], sC[CLEN][16], sres[CLEN][16];
  {
    int tt = tid >> 2, j0 = (tid & 3) * 4;
    *(float4*)&sdt[tt][j0]  = *(const float4*)&dt[(size_t)(t0 + tt) * DINNER + dbase + j0];
    *(float4*)&su[tt][j0]   = *(const float4*)&u[(size_t)(t0 + tt) * DINNER + dbase + j0];
    *(float4*)&sB[tt][j0]   = *(const float4*)&bcdt[(size_t)(t0 + tt) * 96 + j0];
    *(float4*)&sC[tt][j0]   = *(const float4*)&bcdt[(size_t)(t0 + tt) * 96 + 16 + j0];
    *(float4*)&sres[tt][j0] = *(const float4*)&resu0[(size_t)(t0 + tt) * (2 * DINNER) + dbase + j0];
  }
  float h = 0.f;
  {
    const size_t base = (size_t)d * DSTATE + n;
#pragma unroll 4
    for (int cc = 0; cc < c; ++cc) {
      size_t o = (size_t)cc * (DINNER * DSTATE) + base;
      h = P[o] * h + S[o];
    }
  }
  __syncthreads();
#pragma unroll 4
  for (int i = 0; i < CLEN; ++i) {
    float dtv = sdt[i][dl], uv = su[i][dl];
    float dtA = dtv * Aval;
    float rinv = __builtin_amdgcn_rcpf(1.f - 0.5f * dtA);
    float dA = (1.f + 0.5f * dtA) * rinv;
    float dBu = dtv * sB[i][n] * rinv * uv;
    h = dA * h + dBu;
    float p = h * sC[i][n];
    p += __shfl_xor(p, 1);
    p += __shfl_xor(p, 2);
    p += __shfl_xor(p, 4);
    p += __shfl_xor(p, 8);
    if (n == 0) {
      float rv = sres[i][dl];
      float yv = (p + uv * Dpv) * (rv / (1.f + expf(-rv)));
      y2b[(size_t)(t0 + i) * DINNER + d] = f2bf(yv);
    }
  }
}

// ---------------- f32 -> bf16 cast ------------------------------------------
__global__ __launch_bounds__(256) void cast_bf16_kernel(
    const float* __restrict__ in, ushort* __restrict__ out, size_t n4)
{
  size_t i = (size_t)blockIdx.x * 256 + threadIdx.x;
  if (i >= n4) return;
  float4 v = ((const float4*)in)[i];
  ushort4 o = {f2bf(v.x), f2bf(v.y), f2bf(v.z), f2bf(v.w)};
  ((ushort4*)out)[i] = o;
}

// ---------------- concat-cast Wres|Win -> bf16 [L][2*DINNER][DMODEL] --------
__global__ __launch_bounds__(256) void cast_cat2_kernel(
    const float* __restrict__ Wres, const float* __restrict__ Win, ushort* __restrict__ out)
{
  size_t i4 = (size_t)blockIdx.x * 256 + threadIdx.x;
  size_t e0 = i4 * 4;
  int k = (int)(e0 & (DMODEL - 1));
  int r = (int)((e0 >> 10) & (2 * DINNER - 1));
  int l = (int)(e0 >> 22);
  const float* src = (r < DINNER)
      ? &Wres[(((size_t)l * DINNER + r) << 10) + k]
      : &Win[(((size_t)l * DINNER + (r - DINNER)) << 10) + k];
  float4 v = *(const float4*)src;
  ushort4 o = {f2bf(v.x), f2bf(v.y), f2bf(v.z), f2bf(v.w)};
  ((ushort4*)out)[i4] = o;
}

// ---------------- concat WB|WC|Wdt1 -> [L][96][DINNER] ----------------------
__global__ __launch_bounds__(256) void concat_wbcdt_kernel(
    const float* __restrict__ WB, const float* __restrict__ WC,
    const float* __restrict__ Wdt1, float* __restrict__ out)
{
  size_t idx = (size_t)blockIdx.x * 256 + threadIdx.x;
  int k = idx & (DINNER - 1);
  size_t rl = idx >> 11;
  int row = (int)(rl % 96);
  int l = (int)(rl / 96);
  float v;
  if (row < 16)       v = WB[((size_t)l * DSTATE + row) * DINNER + k];
  else if (row < 32)  v = WC[((size_t)l * DSTATE + (row - 16)) * DINNER + k];
  else                v = Wdt1[((size_t)l * DTRANK + (row - 32)) * DINNER + k];
  out[idx] = v;
}

// ============================================================================
extern "C" void kernel_launch(void* const* d_in, const int* in_sizes, int n_in,
                              void* d_out, int out_size, void* d_ws, size_t ws_size,
                              hipStream_t stream) {
  (void)in_sizes; (void)n_in; (void)out_size;
  const int* token_ids = (const int*)d_in[0];
  const float* embed = (const float*)d_in[1];
  const float* Wres = (const float*)d_in[2];
  const float* Win = (const float*)d_in[3];
  const float* Wconv = (const float*)d_in[4];
  const float* WB = (const float*)d_in[5];
  const float* WC = (const float*)d_in[6];
  const float* Wdt1 = (const float*)d_in[7];
  const float* Wdt2 = (const float*)d_in[8];
  const float* bdt = (const float*)d_in[9];
  const float* logA = (const float*)d_in[10];
  const float* Dp = (const float*)d_in[11];
  const float* Wout = (const float*)d_in[12];
  float* out = (float*)d_out;

  char* w = (char*)d_ws;
  auto alloc = [&](size_t bytes) {
    char* p = w;
    w += (bytes + 255) & ~(size_t)255;
    return p;
  };
  ushort* eb    = (ushort*)alloc((size_t)VOCAB * DMODEL * 2);
  ushort* wcatb = (ushort*)alloc((size_t)NLAYER * 2 * DINNER * DMODEL * 2);
  ushort* woutb = (ushort*)alloc((size_t)NLAYER * DMODEL * DINNER * 2);
  float* wbcdt  = (float*)alloc((size_t)NLAYER * 96 * DINNER * 4);
  float* x      = (float*)alloc((size_t)SEQ * DMODEL * 4);
  ushort* xnb   = (ushort*)alloc((size_t)SEQ * DMODEL * 2);
  float* resu0  = (float*)alloc((size_t)SEQ * 2 * DINNER * 4);
  float* u      = (float*)alloc((size_t)SEQ * DINNER * 4);
  float* bcdt   = (float*)alloc((size_t)SEQ * 96 * 4);
  float* dt     = (float*)alloc((size_t)SEQ * DINNER * 4);
  float* Cp     = (float*)alloc((size_t)PROJ_NCH * SEQ * 96 * 4);
  float* Cp2    = (float*)alloc((size_t)2 * SEQ * DMODEL * 4);
  float* Pbuf   = (float*)alloc((size_t)NCHUNK * DINNER * DSTATE * 4);
  float* Sbuf   = (float*)alloc((size_t)NCHUNK * DINNER * DSTATE * 4);
  ushort* y2b   = (ushort*)alloc((size_t)SEQ * DINNER * 2);
  ushort* xb    = (ushort*)alloc((size_t)SEQ * DMODEL * 2);
  if ((size_t)(w - (char*)d_ws) > ws_size) return;

  // weight preprocessing
  cast_bf16_kernel<<<VOCAB * DMODEL / 4 / 256, 256, 0, stream>>>(embed, eb, (size_t)VOCAB * DMODEL / 4);
  cast_cat2_kernel<<<NLAYER * 2 * DINNER * DMODEL / 4 / 256, 256, 0, stream>>>(Wres, Win, wcatb);
  cast_bf16_kernel<<<NLAYER * DMODEL * DINNER / 4 / 256, 256, 0, stream>>>(Wout, woutb, (size_t)NLAYER * DMODEL * DINNER / 4);
  concat_wbcdt_kernel<<<NLAYER * 96 * DINNER / 256, 256, 0, stream>>>(WB, WC, Wdt1, wbcdt);
  gather_rms_kernel<<<SEQ, 256, 0, stream>>>(token_ids, embed, x, xnb);

  for (int i = 0; i < NLAYER; ++i) {
    const ushort* wcati = wcatb + (size_t)i * 2 * DINNER * DMODEL;
    const ushort* wouti = woutb + (size_t)i * DMODEL * DINNER;
    const float* wconvi = Wconv + (size_t)i * DINNER * 4;
    const float* wbcdti = wbcdt + (size_t)i * 96 * DINNER;
    const float* wdt2i = Wdt2 + (size_t)i * DINNER * DTRANK;
    const float* bdti = bdt + (size_t)i * DINNER;
    const float* logAi = logA + (size_t)i * DINNER * DSTATE;
    const float* Dpi = Dp + (size_t)i * DINNER;

    // gemm1: 2048 x 4096 x 1024, grid (16,32) = 512 blocks, 2/CU
    gemm2p_bt_bf16<false><<<dim3(SEQ / 128, 2 * DINNER / 128), 256, 0, stream>>>(
        xnb, wcati, resu0, 2 * DINNER, DMODEL);
    conv_silu_kernel<<<SEQ * DINNER / 4 / 256, 256, 0, stream>>>(resu0 + DINNER, 2 * DINNER, wconvi, u);
    projgemm_f32<<<dim3(SEQ / 64, PROJ_NCH), 256, 0, stream>>>(u, wbcdti, Cp, SEQ);
    proj_reduce<<<SEQ * 96 / 256, 256, 0, stream>>>(Cp, bcdt, SEQ);
    smallgemm_f32<<<dim3(SEQ / 64, DINNER / 64), 256, 0, stream>>>(
        bcdt + 32, 96, wdt2i, DTRANK, dt, DINNER, bdti, SEQ, DINNER, DTRANK, 1);
    dim3 gs(DINNER / 16, NCHUNK);
    scan_pass1<<<gs, 256, 0, stream>>>(dt, u, bcdt, logAi, Pbuf, Sbuf);
    scan_pass2<<<gs, 256, 0, stream>>>(dt, u, bcdt, logAi, Dpi, Pbuf, Sbuf, resu0, y2b);
    gemm_btk_bf16<<<dim3(SEQ / 128, DMODEL / 128, 2), 256, 0, stream>>>(
        y2b, wouti, Cp2, SEQ, DMODEL, DINNER);
    // residual add + (RMSNorm->xnb for next layer | plain bf16 cast for logits)
    add3_rms_kernel<<<SEQ, 256, 0, stream>>>(
        Cp2, Cp2 + (size_t)SEQ * DMODEL, x,
        (i < NLAYER - 1) ? xnb : xb, (i < NLAYER - 1) ? 1 : 0);
  }
  // logits: 2048 x 32000 x 1024, grid (16,250) = 4000 blocks, 2/CU
  gemm2p_bt_bf16<true><<<dim3(SEQ / 128, VOCAB / 128), 256, 0, stream>>>(
      xb, eb, out, VOCAB, DMODEL);
}

// Round 11
// 2227.930 us; speedup vs baseline: 1.3520x; 1.0179x over previous
//
#include <hip/hip_runtime.h>

#define SEQ 2048
#define DMODEL 1024
#define DINNER 2048
#define DSTATE 16
#define DTRANK 64
#define NLAYER 8
#define VOCAB 32000
#define NCHUNK 32
#define CLEN 64   // SEQ / NCHUNK
#define PROJ_NCH 16
#define PROJ_KC 128  // DINNER / PROJ_NCH

typedef float f32x4 __attribute__((ext_vector_type(4)));
typedef short bf16x8 __attribute__((ext_vector_type(8)));

__device__ __forceinline__ ushort f2bf(float f) {
  union { float f; unsigned u; } v; v.f = f;
  unsigned r = v.u + 0x7fffu + ((v.u >> 16) & 1u);
  return (ushort)(r >> 16);
}

__device__ __forceinline__ void lds_load16(const void* g, void* l) {
  __builtin_amdgcn_global_load_lds(
      (const __attribute__((address_space(1))) void*)g,
      (__attribute__((address_space(3))) void*)l, 16, 0, 0);
}

// ---------------- 256x256 counted-vmcnt MFMA GEMM (proven 199us @ logits) ---
// C[M,N] = A[M,K] @ B[N,K]^T. 512 thr (8 waves 2x4), 128KB LDS dbuf.
// Stages staggered at mq boundaries; vmcnt(2) = all of tile t landed, A0(t+1)
// in flight. XOR-swizzle staging src + reads. LDS-transpose float4 epilogue.
template<int BM, bool NTS>
__global__ __launch_bounds__(512, 2) void gemm8p_bt_bf16(
    const ushort* __restrict__ A, const ushort* __restrict__ B,
    float* __restrict__ C, int N, int K)
{
  constexpr int MFR = BM / 32;
  constexpr int MPP = MFR / 4;
  constexpr int ALOADS = BM / 128;
  __shared__ __align__(16) ushort As[2 * BM * 64];
  __shared__ __align__(16) ushort Bs[2 * 256 * 64];
  const int tid = threadIdx.x;
  const int lane = tid & 63;
  const int wid = tid >> 6;
  const int wr = wid >> 2, wc = wid & 3;
  const int rr = lane & 15, kq = lane >> 4;

  unsigned nwg = gridDim.x * gridDim.y;
  unsigned lb = blockIdx.y * gridDim.x + blockIdx.x;
  if ((nwg & 7u) == 0u) { unsigned cpx = nwg >> 3; lb = (lb & 7u) * cpx + (lb >> 3); }
  const int bm = (int)(lb % gridDim.x) * BM;
  const int bn = (int)(lb / gridDim.x) * 256;

  const ushort* Abase = A + (size_t)bm * K;
  const ushort* Bbase = B + (size_t)bn * K;

  auto stageA = [&](int buf, int h, int kt) {
    constexpr int HR = BM / 2;
#pragma unroll
    for (int L = 0; L < ALOADS; ++L) {
      int f = L * 512 + tid;
      int rl = f >> 3, g = f & 7;
      int gg = g ^ (rl & 7);
      lds_load16(Abase + (size_t)(h * HR + rl) * K + kt * 64 + gg * 8,
                 (void*)(As + buf * (BM * 64) + (h * HR + rl) * 64 + g * 8));
    }
  };
  auto stageB = [&](int buf, int h, int kt) {
#pragma unroll
    for (int L = 0; L < 2; ++L) {
      int f = L * 512 + tid;
      int rl = f >> 3, g = f & 7;
      int gg = g ^ (rl & 7);
      lds_load16(Bbase + (size_t)(h * 128 + rl) * K + kt * 64 + gg * 8,
                 (void*)(Bs + buf * (256 * 64) + (h * 128 + rl) * 64 + g * 8));
    }
  };
  auto rdA = [&](int buf, int r, int kbyte) {
    int sw = kbyte ^ ((r & 7) << 4);
    return *(const bf16x8*)(As + buf * (BM * 64) + r * 64 + (sw >> 1));
  };
  auto rdB = [&](int buf, int r, int kbyte) {
    int sw = kbyte ^ ((r & 7) << 4);
    return *(const bf16x8*)(Bs + buf * (256 * 64) + r * 64 + (sw >> 1));
  };

  f32x4 acc[MFR][4];
#pragma unroll
  for (int m = 0; m < MFR; ++m)
#pragma unroll
    for (int n = 0; n < 4; ++n) acc[m][n] = (f32x4){0.f, 0.f, 0.f, 0.f};

  const int NT = K >> 6;
  stageA(0, 0, 0); stageA(0, 1, 0); stageB(0, 0, 0); stageB(0, 1, 0);

  for (int t = 0; t < NT; ++t) {
    const int cur = t & 1;
    const bool more = (t + 1 < NT);
    if (more) stageA(cur ^ 1, 0, t + 1);
    if (more) {
      if constexpr (BM == 256) asm volatile("s_waitcnt vmcnt(2)" ::: "memory");
      else                     asm volatile("s_waitcnt vmcnt(1)" ::: "memory");
    } else {
      asm volatile("s_waitcnt vmcnt(0)" ::: "memory");
    }
    __syncthreads();

    bf16x8 bfr[4][2];
#pragma unroll
    for (int n = 0; n < 4; ++n)
#pragma unroll
      for (int kk = 0; kk < 2; ++kk)
        bfr[n][kk] = rdB(cur, wc * 64 + n * 16 + rr, kk * 64 + kq * 16);

#pragma unroll
    for (int mq = 0; mq < 4; ++mq) {
      if (mq == 1 && more) stageA(cur ^ 1, 1, t + 1);
      if (mq == 2 && more) stageB(cur ^ 1, 0, t + 1);
      if (mq == 3 && more) stageB(cur ^ 1, 1, t + 1);
      bf16x8 af[MPP][2];
#pragma unroll
      for (int mf = 0; mf < MPP; ++mf)
#pragma unroll
        for (int kk = 0; kk < 2; ++kk)
          af[mf][kk] = rdA(cur, wr * (BM / 2) + (mq * MPP + mf) * 16 + rr, kk * 64 + kq * 16);
      __builtin_amdgcn_s_setprio(1);
#pragma unroll
      for (int kk = 0; kk < 2; ++kk)
#pragma unroll
        for (int mf = 0; mf < MPP; ++mf)
#pragma unroll
          for (int n = 0; n < 4; ++n)
            acc[mq * MPP + mf][n] = __builtin_amdgcn_mfma_f32_16x16x32_bf16(
                af[mf][kk], bfr[n][kk], acc[mq * MPP + mf][n], 0, 0, 0);
      __builtin_amdgcn_s_setprio(0);
    }
    __syncthreads();
  }

  // Epilogue: per-wave LDS transpose in Bs (16 rows x 64 cols f32, stride 68)
  float* ep = (float*)Bs + wid * (16 * 68);
  const int cg = bn + wc * 64;
#pragma unroll
  for (int m = 0; m < MFR; ++m) {
    const int r0g = bm + wr * (BM / 2) + m * 16;
#pragma unroll
    for (int n = 0; n < 4; ++n)
#pragma unroll
      for (int j = 0; j < 4; ++j)
        ep[(kq * 4 + j) * 68 + n * 16 + rr] = acc[m][n][j];
#pragma unroll
    for (int i = 0; i < 4; ++i) {
      int row = i * 4 + kq;
      f32x4 v = *(const f32x4*)&ep[row * 68 + rr * 4];
      f32x4* dst = (f32x4*)&C[(size_t)(r0g + row) * N + cg + rr * 4];
      if constexpr (NTS) __builtin_nontemporal_store(v, dst);
      else *dst = v;
    }
  }
}

// ---------------- 128x128 2-blocks/CU MFMA GEMM (layer gemm1) ---------------
template<bool NTS>
__global__ __launch_bounds__(256, 2) void gemm2p_bt_bf16(
    const ushort* __restrict__ A, const ushort* __restrict__ B,
    float* __restrict__ C, int N, int K)
{
  __shared__ __align__(16) ushort As[2 * 128 * 64];
  __shared__ __align__(16) ushort Bs[2 * 128 * 64];
  const int tid = threadIdx.x;
  const int lane = tid & 63;
  const int wave = tid >> 6;
  const int wr = wave >> 1, wc = wave & 1;
  const int rr = lane & 15, kq = lane >> 4;

  unsigned nwg = gridDim.x * gridDim.y;
  unsigned lb = blockIdx.y * gridDim.x + blockIdx.x;
  if ((nwg & 7u) == 0u) { unsigned cpx = nwg >> 3; lb = (lb & 7u) * cpx + (lb >> 3); }
  const int bm = (int)(lb % gridDim.x) * 128;
  const int bn = (int)(lb / gridDim.x) * 128;

  const ushort* Abase = A + (size_t)bm * K;
  const ushort* Bbase = B + (size_t)bn * K;

  auto stage = [&](int buf, int kt) {
#pragma unroll
    for (int i = 0; i < 4; ++i) {
      int f = i * 256 + tid;
      int rl = f >> 3, g = f & 7;
      int gg = g ^ (rl & 7);
      lds_load16(Abase + (size_t)rl * K + kt * 64 + gg * 8,
                 (void*)(As + buf * 8192 + rl * 64 + g * 8));
      lds_load16(Bbase + (size_t)rl * K + kt * 64 + gg * 8,
                 (void*)(Bs + buf * 8192 + rl * 64 + g * 8));
    }
  };
  auto rdA = [&](int buf, int r, int kbyte) {
    int sw = kbyte ^ ((r & 7) << 4);
    return *(const bf16x8*)(As + buf * 8192 + r * 64 + (sw >> 1));
  };
  auto rdB = [&](int buf, int r, int kbyte) {
    int sw = kbyte ^ ((r & 7) << 4);
    return *(const bf16x8*)(Bs + buf * 8192 + r * 64 + (sw >> 1));
  };

  f32x4 acc[4][4];
#pragma unroll
  for (int m = 0; m < 4; ++m)
#pragma unroll
    for (int n = 0; n < 4; ++n) acc[m][n] = (f32x4){0.f, 0.f, 0.f, 0.f};

  const int NT = K >> 6;
  stage(0, 0);

  for (int t = 0; t < NT; ++t) {
    const int cur = t & 1;
    if (t + 1 < NT) {
      stage(cur ^ 1, t + 1);
      asm volatile("s_waitcnt vmcnt(8)" ::: "memory");
    } else {
      asm volatile("s_waitcnt vmcnt(0)" ::: "memory");
    }
    __syncthreads();
#pragma unroll
    for (int ks = 0; ks < 2; ++ks) {
      const int kbyte = ks * 64 + kq * 16;
      bf16x8 af[4], bfr[4];
#pragma unroll
      for (int m = 0; m < 4; ++m)
        af[m] = rdA(cur, wr * 64 + m * 16 + rr, kbyte);
#pragma unroll
      for (int n = 0; n < 4; ++n)
        bfr[n] = rdB(cur, wc * 64 + n * 16 + rr, kbyte);
      __builtin_amdgcn_s_setprio(1);
#pragma unroll
      for (int m = 0; m < 4; ++m)
#pragma unroll
        for (int n = 0; n < 4; ++n)
          acc[m][n] = __builtin_amdgcn_mfma_f32_16x16x32_bf16(af[m], bfr[n], acc[m][n], 0, 0, 0);
      __builtin_amdgcn_s_setprio(0);
    }
    __syncthreads();
  }

  float* ep = (float*)Bs + wave * (16 * 68);
  const int cg = bn + wc * 64;
#pragma unroll
  for (int m = 0; m < 4; ++m) {
    const int r0g = bm + wr * 64 + m * 16;
#pragma unroll
    for (int n = 0; n < 4; ++n)
#pragma unroll
      for (int j = 0; j < 4; ++j)
        ep[(kq * 4 + j) * 68 + n * 16 + rr] = acc[m][n][j];
#pragma unroll
    for (int i = 0; i < 4; ++i) {
      int row = i * 4 + kq;
      f32x4 v = *(const f32x4*)&ep[row * 68 + rr * 4];
      f32x4* dst = (f32x4*)&C[(size_t)(r0g + row) * N + cg + rr * 4];
      if constexpr (NTS) __builtin_nontemporal_store(v, dst);
      else *dst = v;
    }
  }
}

// ---------------- split-K bf16 MFMA GEMM (2-phase 128x128) ------------------
__global__ __launch_bounds__(256) void gemm_btk_bf16(
    const ushort* __restrict__ A, const ushort* __restrict__ B,
    float* __restrict__ Cp, int M, int N, int K)
{
  __shared__ __align__(16) ushort As[128 * 64];
  __shared__ __align__(16) ushort Bs[128 * 64];
  const int tid = threadIdx.x;
  const int lane = tid & 63;
  const int wave = tid >> 6;
  const int wr = wave >> 1, wc = wave & 1;
  const int KC = K >> 1;
  const int k0 = blockIdx.z * KC;

  unsigned nwg = gridDim.x * gridDim.y;
  unsigned lb = blockIdx.y * gridDim.x + blockIdx.x;
  if ((nwg & 7u) == 0u) {
    unsigned cpx = nwg >> 3;
    lb = (lb & 7u) * cpx + (lb >> 3);
  }
  const int bm = (lb % gridDim.x) * 128;
  const int bn = (lb / gridDim.x) * 128;
  const int rr = lane & 15, kq = lane >> 4;

  f32x4 acc[4][4];
#pragma unroll
  for (int m = 0; m < 4; ++m)
#pragma unroll
    for (int n = 0; n < 4; ++n) acc[m][n] = (f32x4){0.f, 0.f, 0.f, 0.f};

  for (int kt = 0; kt < KC; kt += 64) {
#pragma unroll
    for (int i = 0; i < 4; ++i) {
      int fb = i * 256 + tid;
      int row = fb >> 3, cb = fb & 7;
      lds_load16(A + (size_t)(bm + row) * K + k0 + kt + cb * 8, (void*)(As + (size_t)fb * 8));
      lds_load16(B + (size_t)(bn + row) * K + k0 + kt + cb * 8, (void*)(Bs + (size_t)fb * 8));
    }
    __syncthreads();
#pragma unroll
    for (int ks = 0; ks < 2; ++ks) {
      bf16x8 af[4], bfr[4];
      const int koff = ks * 32 + kq * 8;
#pragma unroll
      for (int m = 0; m < 4; ++m)
        af[m] = *(const bf16x8*)&As[(wr * 64 + m * 16 + rr) * 64 + koff];
#pragma unroll
      for (int n = 0; n < 4; ++n)
        bfr[n] = *(const bf16x8*)&Bs[(wc * 64 + n * 16 + rr) * 64 + koff];
#pragma unroll
      for (int m = 0; m < 4; ++m)
#pragma unroll
        for (int n = 0; n < 4; ++n)
          acc[m][n] = __builtin_amdgcn_mfma_f32_16x16x32_bf16(af[m], bfr[n], acc[m][n], 0, 0, 0);
    }
    __syncthreads();
  }
  float* C = Cp + (size_t)blockIdx.z * M * N;
#pragma unroll
  for (int m = 0; m < 4; ++m) {
    const int r0 = bm + wr * 64 + m * 16 + kq * 4;
#pragma unroll
    for (int n = 0; n < 4; ++n) {
      const int cc = bn + wc * 64 + n * 16 + rr;
#pragma unroll
      for (int j = 0; j < 4; ++j)
        C[(size_t)(r0 + j) * N + cc] = acc[m][n][j];
    }
  }
}

// ---------------- x += P0 + P1, then RMSNorm(x)->bf16 (or plain cast) -------
__global__ __launch_bounds__(256) void add3_rms_kernel(
    const float* __restrict__ P0, const float* __restrict__ P1,
    float* __restrict__ x, ushort* __restrict__ dst, int donorm)
{
  size_t o = (size_t)blockIdx.x * (DMODEL / 4) + threadIdx.x;
  float4 a = ((const float4*)P0)[o];
  float4 b = ((const float4*)P1)[o];
  float4 c = ((float4*)x)[o];
  c.x += a.x + b.x; c.y += a.y + b.y; c.z += a.z + b.z; c.w += a.w + b.w;
  ((float4*)x)[o] = c;
  float sc = 1.f;
  if (donorm) {
    float s = c.x * c.x + c.y * c.y + c.z * c.z + c.w * c.w;
#pragma unroll
    for (int off = 32; off > 0; off >>= 1) s += __shfl_down(s, off);
    __shared__ float ws[4];
    if ((threadIdx.x & 63) == 0) ws[threadIdx.x >> 6] = s;
    __syncthreads();
    float tot = ws[0] + ws[1] + ws[2] + ws[3];
    sc = rsqrtf(tot * (1.0f / DMODEL) + 1e-6f);
  }
  ushort4 o4 = {f2bf(c.x * sc), f2bf(c.y * sc), f2bf(c.z * sc), f2bf(c.w * sc)};
  ((ushort4*)dst)[o] = o4;
}

// ---------------- embedding gather + RMSNorm -> x (f32) and xnb (bf16) ------
__global__ __launch_bounds__(256) void gather_rms_kernel(
    const int* __restrict__ ids, const float* __restrict__ embed,
    float* __restrict__ x, ushort* __restrict__ xnb)
{
  int row = blockIdx.x;
  int id = ids[row];
  float4 v = ((const float4*)(embed + (size_t)id * DMODEL))[threadIdx.x];
  size_t o = (size_t)row * (DMODEL / 4) + threadIdx.x;
  ((float4*)x)[o] = v;
  float s = v.x * v.x + v.y * v.y + v.z * v.z + v.w * v.w;
#pragma unroll
  for (int off = 32; off > 0; off >>= 1) s += __shfl_down(s, off);
  __shared__ float ws[4];
  if ((threadIdx.x & 63) == 0) ws[threadIdx.x >> 6] = s;
  __syncthreads();
  float tot = ws[0] + ws[1] + ws[2] + ws[3];
  float sc = rsqrtf(tot * (1.0f / DMODEL) + 1e-6f);
  ushort4 o4 = {f2bf(v.x * sc), f2bf(v.y * sc), f2bf(v.z * sc), f2bf(v.w * sc)};
  ((ushort4*)xnb)[o] = o4;
}

// ---------------- split-K f32 projection GEMM: Cp[ch] = A@W^T chunk ---------
__global__ __launch_bounds__(256) void projgemm_f32(
    const float* __restrict__ A, const float* __restrict__ W,
    float* __restrict__ Cp, int M)
{
  __shared__ float As[64][65];
  __shared__ float Ws[96][65];
  const int t = threadIdx.x;
  const int bm = blockIdx.x * 64;
  const int kc = blockIdx.y * PROJ_KC;
  const int ty = t >> 4, tx = t & 15;
  const int r0 = ty * 4, c0 = tx * 6;
  float acc[4][6] = {};
  for (int kt = 0; kt < PROJ_KC; kt += 64) {
#pragma unroll
    for (int i = 0; i < 4; ++i) {
      int e4 = i * 256 + t;
      int r = e4 >> 4, c4 = (e4 & 15) * 4;
      *(float4*)&As[r][c4] = *(const float4*)&A[(size_t)(bm + r) * DINNER + kc + kt + c4];
    }
#pragma unroll
    for (int i = 0; i < 6; ++i) {
      int e4 = i * 256 + t;
      int r = e4 >> 4, c4 = (e4 & 15) * 4;
      *(float4*)&Ws[r][c4] = *(const float4*)&W[(size_t)r * DINNER + kc + kt + c4];
    }
    __syncthreads();
#pragma unroll 4
    for (int kk = 0; kk < 64; ++kk) {
      float a0 = As[r0][kk], a1 = As[r0 + 1][kk], a2 = As[r0 + 2][kk], a3 = As[r0 + 3][kk];
      float w0 = Ws[c0][kk], w1 = Ws[c0 + 1][kk], w2 = Ws[c0 + 2][kk];
      float w3 = Ws[c0 + 3][kk], w4 = Ws[c0 + 4][kk], w5 = Ws[c0 + 5][kk];
      acc[0][0] += a0 * w0; acc[0][1] += a0 * w1; acc[0][2] += a0 * w2;
      acc[0][3] += a0 * w3; acc[0][4] += a0 * w4; acc[0][5] += a0 * w5;
      acc[1][0] += a1 * w0; acc[1][1] += a1 * w1; acc[1][2] += a1 * w2;
      acc[1][3] += a1 * w3; acc[1][4] += a1 * w4; acc[1][5] += a1 * w5;
      acc[2][0] += a2 * w0; acc[2][1] += a2 * w1; acc[2][2] += a2 * w2;
      acc[2][3] += a2 * w3; acc[2][4] += a2 * w4; acc[2][5] += a2 * w5;
      acc[3][0] += a3 * w0; acc[3][1] += a3 * w1; acc[3][2] += a3 * w2;
      acc[3][3] += a3 * w3; acc[3][4] += a3 * w4; acc[3][5] += a3 * w5;
    }
    __syncthreads();
  }
  float* cp = Cp + (size_t)blockIdx.y * M * 96;
#pragma unroll
  for (int i = 0; i < 4; ++i)
#pragma unroll
    for (int j = 0; j < 6; ++j)
      cp[(size_t)(bm + r0 + i) * 96 + c0 + j] = acc[i][j];
}

__global__ __launch_bounds__(256) void proj_reduce(
    const float* __restrict__ Cp, float* __restrict__ bcdt, int M)
{
  int idx = blockIdx.x * 256 + threadIdx.x;
  float s = 0.f;
#pragma unroll
  for (int c = 0; c < PROJ_NCH; ++c) s += Cp[(size_t)c * M * 96 + idx];
  bcdt[idx] = s;
}

// ---------------- f32 small GEMM: C[M,N] = A[M,K(lda)] @ W[N,K(ldw)]^T ------
__global__ __launch_bounds__(256) void smallgemm_f32(
    const float* __restrict__ A, int lda,
    const float* __restrict__ W, int ldw,
    float* __restrict__ C, int ldc,
    const float* __restrict__ bias,
    int M, int N, int K, int act)
{
  __shared__ float As[64][65];
  __shared__ float Ws[64][65];
  const int t = threadIdx.x;
  const int bm = blockIdx.x * 64, bn = blockIdx.y * 64;
  const int r0 = (t >> 4) * 4;
  const int c0 = (t & 15) * 4;
  float acc[4][4] = {};

  for (int kt = 0; kt < K; kt += 64) {
#pragma unroll
    for (int i = 0; i < 16; ++i) {
      int idx = i * 256 + t;
      int r = idx >> 6, c = idx & 63;
      As[r][c] = A[(size_t)(bm + r) * lda + kt + c];
      int wrow = bn + r;
      Ws[r][c] = (wrow < N) ? W[(size_t)wrow * ldw + kt + c] : 0.f;
    }
    __syncthreads();
#pragma unroll 8
    for (int kk = 0; kk < 64; ++kk) {
      float a0 = As[r0][kk], a1 = As[r0 + 1][kk], a2 = As[r0 + 2][kk], a3 = As[r0 + 3][kk];
      float w0 = Ws[c0][kk], w1 = Ws[c0 + 1][kk], w2 = Ws[c0 + 2][kk], w3 = Ws[c0 + 3][kk];
      acc[0][0] += a0 * w0; acc[0][1] += a0 * w1; acc[0][2] += a0 * w2; acc[0][3] += a0 * w3;
      acc[1][0] += a1 * w0; acc[1][1] += a1 * w1; acc[1][2] += a1 * w2; acc[1][3] += a1 * w3;
      acc[2][0] += a2 * w0; acc[2][1] += a2 * w1; acc[2][2] += a2 * w2; acc[2][3] += a2 * w3;
      acc[3][0] += a3 * w0; acc[3][1] += a3 * w1; acc[3][2] += a3 * w2; acc[3][3] += a3 * w3;
    }
    __syncthreads();
  }
#pragma unroll
  for (int i = 0; i < 4; ++i)
#pragma unroll
    for (int j = 0; j < 4; ++j) {
      int cc = bn + c0 + j;
      if (cc < N) {
        float v = acc[i][j];
        if (bias) v += bias[cc];
        if (act == 1) v = (v > 20.f) ? v : log1pf(expf(v));
        C[(size_t)(bm + r0 + i) * ldc + cc] = v;
      }
    }
}

// ---------------- causal depthwise conv (K=4) + SiLU ------------------------
__global__ __launch_bounds__(256) void conv_silu_kernel(
    const float* __restrict__ u0, int ld, const float* __restrict__ Wconv,
    float* __restrict__ u)
{
  int idx = blockIdx.x * 256 + threadIdx.x;
  int d4 = idx & (DINNER / 4 - 1);
  int l = idx >> 9;
  int d0 = d4 * 4;
  float wt[4][4];
#pragma unroll
  for (int j = 0; j < 4; ++j) {
    float4 tv = *(const float4*)&Wconv[(d0 + j) * 4];
    wt[j][0] = tv.x; wt[j][1] = tv.y; wt[j][2] = tv.z; wt[j][3] = tv.w;
  }
  float a[4] = {0.f, 0.f, 0.f, 0.f};
#pragma unroll
  for (int k = 0; k < 4; ++k) {
    int ls = l - 3 + k;
    if (ls >= 0) {
      float4 uv = *(const float4*)&u0[(size_t)ls * ld + d0];
      a[0] += uv.x * wt[0][k];
      a[1] += uv.y * wt[1][k];
      a[2] += uv.z * wt[2][k];
      a[3] += uv.w * wt[3][k];
    }
  }
  float4 r;
  r.x = a[0] / (1.f + expf(-a[0]));
  r.y = a[1] / (1.f + expf(-a[1]));
  r.z = a[2] / (1.f + expf(-a[2]));
  r.w = a[3] / (1.f + expf(-a[3]));
  *(float4*)&u[(size_t)l * DINNER + d0] = r;
}

// ---------------- chunk-parallel selective scan -----------------------------
__global__ __launch_bounds__(256) void scan_pass1(
    const float* __restrict__ dt, const float* __restrict__ u,
    const float* __restrict__ bcdt, const float* __restrict__ logA,
    float* __restrict__ P, float* __restrict__ S)
{
  const int tid = threadIdx.x;
  const int n = tid & 15, dl = tid >> 4;
  const int dbase = blockIdx.x * 16;
  const int c = blockIdx.y;
  const int t0 = c * CLEN;
  const int d = dbase + dl;
  const float Aval = -expf(logA[d * DSTATE + n]);
  __shared__ float sdt[CLEN][16], su[CLEN][16], sB[CLEN][16];
  {
    int tt = tid >> 2, j0 = (tid & 3) * 4;
    *(float4*)&sdt[tt][j0] = *(const float4*)&dt[(size_t)(t0 + tt) * DINNER + dbase + j0];
    *(float4*)&su[tt][j0]  = *(const float4*)&u[(size_t)(t0 + tt) * DINNER + dbase + j0];
    *(float4*)&sB[tt][j0]  = *(const float4*)&bcdt[(size_t)(t0 + tt) * 96 + j0];
  }
  __syncthreads();
  float h = 0.f, pr = 1.f;
#pragma unroll 8
  for (int i = 0; i < CLEN; ++i) {
    float dtv = sdt[i][dl], uv = su[i][dl], Bv = sB[i][n];
    float dtA = dtv * Aval;
    float rinv = __builtin_amdgcn_rcpf(1.f - 0.5f * dtA);
    float dA = (1.f + 0.5f * dtA) * rinv;
    float dBu = dtv * Bv * rinv * uv;
    h = dA * h + dBu;
    pr *= dA;
  }
  size_t idx = (size_t)c * (DINNER * DSTATE) + (size_t)d * DSTATE + n;
  P[idx] = pr;
  S[idx] = h;
}

// pass2: chunk-prefix from P,S computed in-kernel; reduce over states;
// fuse y*silu(res) -> bf16
__global__ __launch_bounds__(256) void scan_pass2(
    const float* __restrict__ dt, const float* __restrict__ u,
    const float* __restrict__ bcdt, const float* __restrict__ logA,
    const float* __restrict__ Dp, const float* __restrict__ P,
    const float* __restrict__ S, const float* __restrict__ resu0,
    ushort* __restrict__ y2b)
{
  const int tid = threadIdx.x;
  const int n = tid & 15, dl = tid >> 4;
  const int dbase = blockIdx.x * 16;
  const int c = blockIdx.y;
  const int t0 = c * CLEN;
  const int d = dbase + dl;
  const float Aval = -expf(logA[d * DSTATE + n]);
  const float Dpv = Dp[d];
  __shared__ float sdt[CLEN][16], su[CLEN][16], sB[CLEN][16], sC[CLEN][16], sres[CLEN][16];
  {
    int tt = tid >> 2, j0 = (tid & 3) * 4;
    *(float4*)&sdt[tt][j0]  = *(const float4*)&dt[(size_t)(t0 + tt) * DINNER + dbase + j0];
    *(float4*)&su[tt][j0]   = *(const float4*)&u[(size_t)(t0 + tt) * DINNER + dbase + j0];
    *(float4*)&sB[tt][j0]   = *(const float4*)&bcdt[(size_t)(t0 + tt) * 96 + j0];
    *(float4*)&sC[tt][j0]   = *(const float4*)&bcdt[(size_t)(t0 + tt) * 96 + 16 + j0];
    *(float4*)&sres[tt][j0] = *(const float4*)&resu0[(size_t)(t0 + tt) * (2 * DINNER) + dbase + j0];
  }
  float h = 0.f;
  {
    const size_t base = (size_t)d * DSTATE + n;
#pragma unroll 4
    for (int cc = 0; cc < c; ++cc) {
      size_t o = (size_t)cc * (DINNER * DSTATE) + base;
      h = P[o] * h + S[o];
    }
  }
  __syncthreads();
#pragma unroll 4
  for (int i = 0; i < CLEN; ++i) {
    float dtv = sdt[i][dl], uv = su[i][dl];
    float dtA = dtv * Aval;
    float rinv = __builtin_amdgcn_rcpf(1.f - 0.5f * dtA);
    float dA = (1.f + 0.5f * dtA) * rinv;
    float dBu = dtv * sB[i][n] * rinv * uv;
    h = dA * h + dBu;
    float p = h * sC[i][n];
    p += __shfl_xor(p, 1);
    p += __shfl_xor(p, 2);
    p += __shfl_xor(p, 4);
    p += __shfl_xor(p, 8);
    if (n == 0) {
      float rv = sres[i][dl];
      float yv = (p + uv * Dpv) * (rv / (1.f + expf(-rv)));
      y2b[(size_t)(t0 + i) * DINNER + d] = f2bf(yv);
    }
  }
}

// ---------------- f32 -> bf16 cast ------------------------------------------
__global__ __launch_bounds__(256) void cast_bf16_kernel(
    const float* __restrict__ in, ushort* __restrict__ out, size_t n4)
{
  size_t i = (size_t)blockIdx.x * 256 + threadIdx.x;
  if (i >= n4) return;
  float4 v = ((const float4*)in)[i];
  ushort4 o = {f2bf(v.x), f2bf(v.y), f2bf(v.z), f2bf(v.w)};
  ((ushort4*)out)[i] = o;
}

// ---------------- concat-cast Wres|Win -> bf16 [L][2*DINNER][DMODEL] --------
__global__ __launch_bounds__(256) void cast_cat2_kernel(
    const float* __restrict__ Wres, const float* __restrict__ Win, ushort* __restrict__ out)
{
  size_t i4 = (size_t)blockIdx.x * 256 + threadIdx.x;
  size_t e0 = i4 * 4;
  int k = (int)(e0 & (DMODEL - 1));
  int r = (int)((e0 >> 10) & (2 * DINNER - 1));
  int l = (int)(e0 >> 22);
  const float* src = (r < DINNER)
      ? &Wres[(((size_t)l * DINNER + r) << 10) + k]
      : &Win[(((size_t)l * DINNER + (r - DINNER)) << 10) + k];
  float4 v = *(const float4*)src;
  ushort4 o = {f2bf(v.x), f2bf(v.y), f2bf(v.z), f2bf(v.w)};
  ((ushort4*)out)[i4] = o;
}

// ---------------- concat WB|WC|Wdt1 -> [L][96][DINNER] ----------------------
__global__ __launch_bounds__(256) void concat_wbcdt_kernel(
    const float* __restrict__ WB, const float* __restrict__ WC,
    const float* __restrict__ Wdt1, float* __restrict__ out)
{
  size_t idx = (size_t)blockIdx.x * 256 + threadIdx.x;
  int k = idx & (DINNER - 1);
  size_t rl = idx >> 11;
  int row = (int)(rl % 96);
  int l = (int)(rl / 96);
  float v;
  if (row < 16)       v = WB[((size_t)l * DSTATE + row) * DINNER + k];
  else if (row < 32)  v = WC[((size_t)l * DSTATE + (row - 16)) * DINNER + k];
  else                v = Wdt1[((size_t)l * DTRANK + (row - 32)) * DINNER + k];
  out[idx] = v;
}

// ============================================================================
extern "C" void kernel_launch(void* const* d_in, const int* in_sizes, int n_in,
                              void* d_out, int out_size, void* d_ws, size_t ws_size,
                              hipStream_t stream) {
  (void)in_sizes; (void)n_in; (void)out_size;
  const int* token_ids = (const int*)d_in[0];
  const float* embed = (const float*)d_in[1];
  const float* Wres = (const float*)d_in[2];
  const float* Win = (const float*)d_in[3];
  const float* Wconv = (const float*)d_in[4];
  const float* WB = (const float*)d_in[5];
  const float* WC = (const float*)d_in[6];
  const float* Wdt1 = (const float*)d_in[7];
  const float* Wdt2 = (const float*)d_in[8];
  const float* bdt = (const float*)d_in[9];
  const float* logA = (const float*)d_in[10];
  const float* Dp = (const float*)d_in[11];
  const float* Wout = (const float*)d_in[12];
  float* out = (float*)d_out;

  char* w = (char*)d_ws;
  auto alloc = [&](size_t bytes) {
    char* p = w;
    w += (bytes + 255) & ~(size_t)255;
    return p;
  };
  ushort* eb    = (ushort*)alloc((size_t)VOCAB * DMODEL * 2);
  ushort* wcatb = (ushort*)alloc((size_t)NLAYER * 2 * DINNER * DMODEL * 2);
  ushort* woutb = (ushort*)alloc((size_t)NLAYER * DMODEL * DINNER * 2);
  float* wbcdt  = (float*)alloc((size_t)NLAYER * 96 * DINNER * 4);
  float* x      = (float*)alloc((size_t)SEQ * DMODEL * 4);
  ushort* xnb   = (ushort*)alloc((size_t)SEQ * DMODEL * 2);
  float* resu0  = (float*)alloc((size_t)SEQ * 2 * DINNER * 4);
  float* u      = (float*)alloc((size_t)SEQ * DINNER * 4);
  float* bcdt   = (float*)alloc((size_t)SEQ * 96 * 4);
  float* dt     = (float*)alloc((size_t)SEQ * DINNER * 4);
  float* Cp     = (float*)alloc((size_t)PROJ_NCH * SEQ * 96 * 4);
  float* Cp2    = (float*)alloc((size_t)2 * SEQ * DMODEL * 4);
  float* Pbuf   = (float*)alloc((size_t)NCHUNK * DINNER * DSTATE * 4);
  float* Sbuf   = (float*)alloc((size_t)NCHUNK * DINNER * DSTATE * 4);
  ushort* y2b   = (ushort*)alloc((size_t)SEQ * DINNER * 2);
  ushort* xb    = (ushort*)alloc((size_t)SEQ * DMODEL * 2);
  if ((size_t)(w - (char*)d_ws) > ws_size) return;

  // weight preprocessing
  cast_bf16_kernel<<<VOCAB * DMODEL / 4 / 256, 256, 0, stream>>>(embed, eb, (size_t)VOCAB * DMODEL / 4);
  cast_cat2_kernel<<<NLAYER * 2 * DINNER * DMODEL / 4 / 256, 256, 0, stream>>>(Wres, Win, wcatb);
  cast_bf16_kernel<<<NLAYER * DMODEL * DINNER / 4 / 256, 256, 0, stream>>>(Wout, woutb, (size_t)NLAYER * DMODEL * DINNER / 4);
  concat_wbcdt_kernel<<<NLAYER * 96 * DINNER / 256, 256, 0, stream>>>(WB, WC, Wdt1, wbcdt);
  gather_rms_kernel<<<SEQ, 256, 0, stream>>>(token_ids, embed, x, xnb);

  for (int i = 0; i < NLAYER; ++i) {
    const ushort* wcati = wcatb + (size_t)i * 2 * DINNER * DMODEL;
    const ushort* wouti = woutb + (size_t)i * DMODEL * DINNER;
    const float* wconvi = Wconv + (size_t)i * DINNER * 4;
    const float* wbcdti = wbcdt + (size_t)i * 96 * DINNER;
    const float* wdt2i = Wdt2 + (size_t)i * DINNER * DTRANK;
    const float* bdti = bdt + (size_t)i * DINNER;
    const float* logAi = logA + (size_t)i * DINNER * DSTATE;
    const float* Dpi = Dp + (size_t)i * DINNER;

    // gemm1: 2048 x 4096 x 1024, grid (16,32) = 512 blocks, 2/CU
    gemm2p_bt_bf16<false><<<dim3(SEQ / 128, 2 * DINNER / 128), 256, 0, stream>>>(
        xnb, wcati, resu0, 2 * DINNER, DMODEL);
    conv_silu_kernel<<<SEQ * DINNER / 4 / 256, 256, 0, stream>>>(resu0 + DINNER, 2 * DINNER, wconvi, u);
    projgemm_f32<<<dim3(SEQ / 64, PROJ_NCH), 256, 0, stream>>>(u, wbcdti, Cp, SEQ);
    proj_reduce<<<SEQ * 96 / 256, 256, 0, stream>>>(Cp, bcdt, SEQ);
    smallgemm_f32<<<dim3(SEQ / 64, DINNER / 64), 256, 0, stream>>>(
        bcdt + 32, 96, wdt2i, DTRANK, dt, DINNER, bdti, SEQ, DINNER, DTRANK, 1);
    dim3 gs(DINNER / 16, NCHUNK);
    scan_pass1<<<gs, 256, 0, stream>>>(dt, u, bcdt, logAi, Pbuf, Sbuf);
    scan_pass2<<<gs, 256, 0, stream>>>(dt, u, bcdt, logAi, Dpi, Pbuf, Sbuf, resu0, y2b);
    gemm_btk_bf16<<<dim3(SEQ / 128, DMODEL / 128, 2), 256, 0, stream>>>(
        y2b, wouti, Cp2, SEQ, DMODEL, DINNER);
    add3_rms_kernel<<<SEQ, 256, 0, stream>>>(
        Cp2, Cp2 + (size_t)SEQ * DMODEL, x,
        (i < NLAYER - 1) ? xnb : xb, (i < NLAYER - 1) ? 1 : 0);
  }
  // logits: 2048 x 32000 x 1024, grid (8,125) = 1000 blocks, 256x256 tile
  gemm8p_bt_bf16<256, true><<<dim3(SEQ / 256, VOCAB / 256), 512, 0, stream>>>(
      xb, eb, out, VOCAB, DMODEL);
}

// Round 12
// 2204.142 us; speedup vs baseline: 1.3666x; 1.0108x over previous
//
#include <hip/hip_runtime.h>

#define SEQ 2048
#define DMODEL 1024
#define DINNER 2048
#define DSTATE 16
#define DTRANK 64
#define NLAYER 8
#define VOCAB 32000
#define NCHUNK 32
#define CLEN 64   // SEQ / NCHUNK
#define PROJ_NCH 16
#define PROJ_KC 128  // DINNER / PROJ_NCH

typedef float f32x4 __attribute__((ext_vector_type(4)));
typedef short bf16x8 __attribute__((ext_vector_type(8)));

__device__ __forceinline__ ushort f2bf(float f) {
  union { float f; unsigned u; } v; v.f = f;
  unsigned r = v.u + 0x7fffu + ((v.u >> 16) & 1u);
  return (ushort)(r >> 16);
}
__device__ __forceinline__ float bf2f(ushort b) {
  union { unsigned u; float f; } v; v.u = ((unsigned)b) << 16;
  return v.f;
}

__device__ __forceinline__ void lds_load16(const void* g, void* l) {
  __builtin_amdgcn_global_load_lds(
      (const __attribute__((address_space(1))) void*)g,
      (__attribute__((address_space(3))) void*)l, 16, 0, 0);
}

// ---------------- 256x256 counted-vmcnt MFMA GEMM (proven ~199us logits) ----
template<int BM, bool NTS>
__global__ __launch_bounds__(512, 2) void gemm8p_bt_bf16(
    const ushort* __restrict__ A, const ushort* __restrict__ B,
    float* __restrict__ C, int N, int K)
{
  constexpr int MFR = BM / 32;
  constexpr int MPP = MFR / 4;
  constexpr int ALOADS = BM / 128;
  __shared__ __align__(16) ushort As[2 * BM * 64];
  __shared__ __align__(16) ushort Bs[2 * 256 * 64];
  const int tid = threadIdx.x;
  const int lane = tid & 63;
  const int wid = tid >> 6;
  const int wr = wid >> 2, wc = wid & 3;
  const int rr = lane & 15, kq = lane >> 4;

  unsigned nwg = gridDim.x * gridDim.y;
  unsigned lb = blockIdx.y * gridDim.x + blockIdx.x;
  if ((nwg & 7u) == 0u) { unsigned cpx = nwg >> 3; lb = (lb & 7u) * cpx + (lb >> 3); }
  const int bm = (int)(lb % gridDim.x) * BM;
  const int bn = (int)(lb / gridDim.x) * 256;

  const ushort* Abase = A + (size_t)bm * K;
  const ushort* Bbase = B + (size_t)bn * K;

  auto stageA = [&](int buf, int h, int kt) {
    constexpr int HR = BM / 2;
#pragma unroll
    for (int L = 0; L < ALOADS; ++L) {
      int f = L * 512 + tid;
      int rl = f >> 3, g = f & 7;
      int gg = g ^ (rl & 7);
      lds_load16(Abase + (size_t)(h * HR + rl) * K + kt * 64 + gg * 8,
                 (void*)(As + buf * (BM * 64) + (h * HR + rl) * 64 + g * 8));
    }
  };
  auto stageB = [&](int buf, int h, int kt) {
#pragma unroll
    for (int L = 0; L < 2; ++L) {
      int f = L * 512 + tid;
      int rl = f >> 3, g = f & 7;
      int gg = g ^ (rl & 7);
      lds_load16(Bbase + (size_t)(h * 128 + rl) * K + kt * 64 + gg * 8,
                 (void*)(Bs + buf * (256 * 64) + (h * 128 + rl) * 64 + g * 8));
    }
  };
  auto rdA = [&](int buf, int r, int kbyte) {
    int sw = kbyte ^ ((r & 7) << 4);
    return *(const bf16x8*)(As + buf * (BM * 64) + r * 64 + (sw >> 1));
  };
  auto rdB = [&](int buf, int r, int kbyte) {
    int sw = kbyte ^ ((r & 7) << 4);
    return *(const bf16x8*)(Bs + buf * (256 * 64) + r * 64 + (sw >> 1));
  };

  f32x4 acc[MFR][4];
#pragma unroll
  for (int m = 0; m < MFR; ++m)
#pragma unroll
    for (int n = 0; n < 4; ++n) acc[m][n] = (f32x4){0.f, 0.f, 0.f, 0.f};

  const int NT = K >> 6;
  stageA(0, 0, 0); stageA(0, 1, 0); stageB(0, 0, 0); stageB(0, 1, 0);

  for (int t = 0; t < NT; ++t) {
    const int cur = t & 1;
    const bool more = (t + 1 < NT);
    if (more) stageA(cur ^ 1, 0, t + 1);
    if (more) {
      if constexpr (BM == 256) asm volatile("s_waitcnt vmcnt(2)" ::: "memory");
      else                     asm volatile("s_waitcnt vmcnt(1)" ::: "memory");
    } else {
      asm volatile("s_waitcnt vmcnt(0)" ::: "memory");
    }
    __syncthreads();

    bf16x8 bfr[4][2];
#pragma unroll
    for (int n = 0; n < 4; ++n)
#pragma unroll
      for (int kk = 0; kk < 2; ++kk)
        bfr[n][kk] = rdB(cur, wc * 64 + n * 16 + rr, kk * 64 + kq * 16);

#pragma unroll
    for (int mq = 0; mq < 4; ++mq) {
      if (mq == 1 && more) stageA(cur ^ 1, 1, t + 1);
      if (mq == 2 && more) stageB(cur ^ 1, 0, t + 1);
      if (mq == 3 && more) stageB(cur ^ 1, 1, t + 1);
      bf16x8 af[MPP][2];
#pragma unroll
      for (int mf = 0; mf < MPP; ++mf)
#pragma unroll
        for (int kk = 0; kk < 2; ++kk)
          af[mf][kk] = rdA(cur, wr * (BM / 2) + (mq * MPP + mf) * 16 + rr, kk * 64 + kq * 16);
      __builtin_amdgcn_s_setprio(1);
#pragma unroll
      for (int kk = 0; kk < 2; ++kk)
#pragma unroll
        for (int mf = 0; mf < MPP; ++mf)
#pragma unroll
          for (int n = 0; n < 4; ++n)
            acc[mq * MPP + mf][n] = __builtin_amdgcn_mfma_f32_16x16x32_bf16(
                af[mf][kk], bfr[n][kk], acc[mq * MPP + mf][n], 0, 0, 0);
      __builtin_amdgcn_s_setprio(0);
    }
    __syncthreads();
  }

  float* ep = (float*)Bs + wid * (16 * 68);
  const int cg = bn + wc * 64;
#pragma unroll
  for (int m = 0; m < MFR; ++m) {
    const int r0g = bm + wr * (BM / 2) + m * 16;
#pragma unroll
    for (int n = 0; n < 4; ++n)
#pragma unroll
      for (int j = 0; j < 4; ++j)
        ep[(kq * 4 + j) * 68 + n * 16 + rr] = acc[m][n][j];
#pragma unroll
    for (int i = 0; i < 4; ++i) {
      int row = i * 4 + kq;
      f32x4 v = *(const f32x4*)&ep[row * 68 + rr * 4];
      f32x4* dst = (f32x4*)&C[(size_t)(r0g + row) * N + cg + rr * 4];
      if constexpr (NTS) __builtin_nontemporal_store(v, dst);
      else *dst = v;
    }
  }
}

// ---------------- 128x128 2-blocks/CU MFMA GEMM (layer gemm1) ---------------
template<bool NTS>
__global__ __launch_bounds__(256, 2) void gemm2p_bt_bf16(
    const ushort* __restrict__ A, const ushort* __restrict__ B,
    float* __restrict__ C, int N, int K)
{
  __shared__ __align__(16) ushort As[2 * 128 * 64];
  __shared__ __align__(16) ushort Bs[2 * 128 * 64];
  const int tid = threadIdx.x;
  const int lane = tid & 63;
  const int wave = tid >> 6;
  const int wr = wave >> 1, wc = wave & 1;
  const int rr = lane & 15, kq = lane >> 4;

  unsigned nwg = gridDim.x * gridDim.y;
  unsigned lb = blockIdx.y * gridDim.x + blockIdx.x;
  if ((nwg & 7u) == 0u) { unsigned cpx = nwg >> 3; lb = (lb & 7u) * cpx + (lb >> 3); }
  const int bm = (int)(lb % gridDim.x) * 128;
  const int bn = (int)(lb / gridDim.x) * 128;

  const ushort* Abase = A + (size_t)bm * K;
  const ushort* Bbase = B + (size_t)bn * K;

  auto stage = [&](int buf, int kt) {
#pragma unroll
    for (int i = 0; i < 4; ++i) {
      int f = i * 256 + tid;
      int rl = f >> 3, g = f & 7;
      int gg = g ^ (rl & 7);
      lds_load16(Abase + (size_t)rl * K + kt * 64 + gg * 8,
                 (void*)(As + buf * 8192 + rl * 64 + g * 8));
      lds_load16(Bbase + (size_t)rl * K + kt * 64 + gg * 8,
                 (void*)(Bs + buf * 8192 + rl * 64 + g * 8));
    }
  };
  auto rdA = [&](int buf, int r, int kbyte) {
    int sw = kbyte ^ ((r & 7) << 4);
    return *(const bf16x8*)(As + buf * 8192 + r * 64 + (sw >> 1));
  };
  auto rdB = [&](int buf, int r, int kbyte) {
    int sw = kbyte ^ ((r & 7) << 4);
    return *(const bf16x8*)(Bs + buf * 8192 + r * 64 + (sw >> 1));
  };

  f32x4 acc[4][4];
#pragma unroll
  for (int m = 0; m < 4; ++m)
#pragma unroll
    for (int n = 0; n < 4; ++n) acc[m][n] = (f32x4){0.f, 0.f, 0.f, 0.f};

  const int NT = K >> 6;
  stage(0, 0);

  for (int t = 0; t < NT; ++t) {
    const int cur = t & 1;
    if (t + 1 < NT) {
      stage(cur ^ 1, t + 1);
      asm volatile("s_waitcnt vmcnt(8)" ::: "memory");
    } else {
      asm volatile("s_waitcnt vmcnt(0)" ::: "memory");
    }
    __syncthreads();
#pragma unroll
    for (int ks = 0; ks < 2; ++ks) {
      const int kbyte = ks * 64 + kq * 16;
      bf16x8 af[4], bfr[4];
#pragma unroll
      for (int m = 0; m < 4; ++m)
        af[m] = rdA(cur, wr * 64 + m * 16 + rr, kbyte);
#pragma unroll
      for (int n = 0; n < 4; ++n)
        bfr[n] = rdB(cur, wc * 64 + n * 16 + rr, kbyte);
      __builtin_amdgcn_s_setprio(1);
#pragma unroll
      for (int m = 0; m < 4; ++m)
#pragma unroll
        for (int n = 0; n < 4; ++n)
          acc[m][n] = __builtin_amdgcn_mfma_f32_16x16x32_bf16(af[m], bfr[n], acc[m][n], 0, 0, 0);
      __builtin_amdgcn_s_setprio(0);
    }
    __syncthreads();
  }

  float* ep = (float*)Bs + wave * (16 * 68);
  const int cg = bn + wc * 64;
#pragma unroll
  for (int m = 0; m < 4; ++m) {
    const int r0g = bm + wr * 64 + m * 16;
#pragma unroll
    for (int n = 0; n < 4; ++n)
#pragma unroll
      for (int j = 0; j < 4; ++j)
        ep[(kq * 4 + j) * 68 + n * 16 + rr] = acc[m][n][j];
#pragma unroll
    for (int i = 0; i < 4; ++i) {
      int row = i * 4 + kq;
      f32x4 v = *(const f32x4*)&ep[row * 68 + rr * 4];
      f32x4* dst = (f32x4*)&C[(size_t)(r0g + row) * N + cg + rr * 4];
      if constexpr (NTS) __builtin_nontemporal_store(v, dst);
      else *dst = v;
    }
  }
}

// ---------------- split-K bf16 MFMA GEMM (2-phase 128x128) ------------------
__global__ __launch_bounds__(256) void gemm_btk_bf16(
    const ushort* __restrict__ A, const ushort* __restrict__ B,
    float* __restrict__ Cp, int M, int N, int K)
{
  __shared__ __align__(16) ushort As[128 * 64];
  __shared__ __align__(16) ushort Bs[128 * 64];
  const int tid = threadIdx.x;
  const int lane = tid & 63;
  const int wave = tid >> 6;
  const int wr = wave >> 1, wc = wave & 1;
  const int KC = K >> 1;
  const int k0 = blockIdx.z * KC;

  unsigned nwg = gridDim.x * gridDim.y;
  unsigned lb = blockIdx.y * gridDim.x + blockIdx.x;
  if ((nwg & 7u) == 0u) {
    unsigned cpx = nwg >> 3;
    lb = (lb & 7u) * cpx + (lb >> 3);
  }
  const int bm = (lb % gridDim.x) * 128;
  const int bn = (lb / gridDim.x) * 128;
  const int rr = lane & 15, kq = lane >> 4;

  f32x4 acc[4][4];
#pragma unroll
  for (int m = 0; m < 4; ++m)
#pragma unroll
    for (int n = 0; n < 4; ++n) acc[m][n] = (f32x4){0.f, 0.f, 0.f, 0.f};

  for (int kt = 0; kt < KC; kt += 64) {
#pragma unroll
    for (int i = 0; i < 4; ++i) {
      int fb = i * 256 + tid;
      int row = fb >> 3, cb = fb & 7;
      lds_load16(A + (size_t)(bm + row) * K + k0 + kt + cb * 8, (void*)(As + (size_t)fb * 8));
      lds_load16(B + (size_t)(bn + row) * K + k0 + kt + cb * 8, (void*)(Bs + (size_t)fb * 8));
    }
    __syncthreads();
#pragma unroll
    for (int ks = 0; ks < 2; ++ks) {
      bf16x8 af[4], bfr[4];
      const int koff = ks * 32 + kq * 8;
#pragma unroll
      for (int m = 0; m < 4; ++m)
        af[m] = *(const bf16x8*)&As[(wr * 64 + m * 16 + rr) * 64 + koff];
#pragma unroll
      for (int n = 0; n < 4; ++n)
        bfr[n] = *(const bf16x8*)&Bs[(wc * 64 + n * 16 + rr) * 64 + koff];
#pragma unroll
      for (int m = 0; m < 4; ++m)
#pragma unroll
        for (int n = 0; n < 4; ++n)
          acc[m][n] = __builtin_amdgcn_mfma_f32_16x16x32_bf16(af[m], bfr[n], acc[m][n], 0, 0, 0);
    }
    __syncthreads();
  }
  float* C = Cp + (size_t)blockIdx.z * M * N;
#pragma unroll
  for (int m = 0; m < 4; ++m) {
    const int r0 = bm + wr * 64 + m * 16 + kq * 4;
#pragma unroll
    for (int n = 0; n < 4; ++n) {
      const int cc = bn + wc * 64 + n * 16 + rr;
#pragma unroll
      for (int j = 0; j < 4; ++j)
        C[(size_t)(r0 + j) * N + cc] = acc[m][n][j];
    }
  }
}

// ---------------- x += P0 + P1, then RMSNorm(x)->bf16 (or plain cast) -------
__global__ __launch_bounds__(256) void add3_rms_kernel(
    const float* __restrict__ P0, const float* __restrict__ P1,
    float* __restrict__ x, ushort* __restrict__ dst, int donorm)
{
  size_t o = (size_t)blockIdx.x * (DMODEL / 4) + threadIdx.x;
  float4 a = ((const float4*)P0)[o];
  float4 b = ((const float4*)P1)[o];
  float4 c = ((float4*)x)[o];
  c.x += a.x + b.x; c.y += a.y + b.y; c.z += a.z + b.z; c.w += a.w + b.w;
  ((float4*)x)[o] = c;
  float sc = 1.f;
  if (donorm) {
    float s = c.x * c.x + c.y * c.y + c.z * c.z + c.w * c.w;
#pragma unroll
    for (int off = 32; off > 0; off >>= 1) s += __shfl_down(s, off);
    __shared__ float ws[4];
    if ((threadIdx.x & 63) == 0) ws[threadIdx.x >> 6] = s;
    __syncthreads();
    float tot = ws[0] + ws[1] + ws[2] + ws[3];
    sc = rsqrtf(tot * (1.0f / DMODEL) + 1e-6f);
  }
  ushort4 o4 = {f2bf(c.x * sc), f2bf(c.y * sc), f2bf(c.z * sc), f2bf(c.w * sc)};
  ((ushort4*)dst)[o] = o4;
}

// ---------------- embedding gather + RMSNorm -> x (f32) and xnb (bf16) ------
__global__ __launch_bounds__(256) void gather_rms_kernel(
    const int* __restrict__ ids, const float* __restrict__ embed,
    float* __restrict__ x, ushort* __restrict__ xnb)
{
  int row = blockIdx.x;
  int id = ids[row];
  float4 v = ((const float4*)(embed + (size_t)id * DMODEL))[threadIdx.x];
  size_t o = (size_t)row * (DMODEL / 4) + threadIdx.x;
  ((float4*)x)[o] = v;
  float s = v.x * v.x + v.y * v.y + v.z * v.z + v.w * v.w;
#pragma unroll
  for (int off = 32; off > 0; off >>= 1) s += __shfl_down(s, off);
  __shared__ float ws[4];
  if ((threadIdx.x & 63) == 0) ws[threadIdx.x >> 6] = s;
  __syncthreads();
  float tot = ws[0] + ws[1] + ws[2] + ws[3];
  float sc = rsqrtf(tot * (1.0f / DMODEL) + 1e-6f);
  ushort4 o4 = {f2bf(v.x * sc), f2bf(v.y * sc), f2bf(v.z * sc), f2bf(v.w * sc)};
  ((ushort4*)xnb)[o] = o4;
}

// ---------------- split-K f32 projection GEMM (bf16 u input) ----------------
__global__ __launch_bounds__(256) void projgemm_f32(
    const ushort* __restrict__ A, const float* __restrict__ W,
    float* __restrict__ Cp, int M)
{
  __shared__ float As[64][65];
  __shared__ float Ws[96][65];
  const int t = threadIdx.x;
  const int bm = blockIdx.x * 64;
  const int kc = blockIdx.y * PROJ_KC;
  const int ty = t >> 4, tx = t & 15;
  const int r0 = ty * 4, c0 = tx * 6;
  float acc[4][6] = {};
  for (int kt = 0; kt < PROJ_KC; kt += 64) {
#pragma unroll
    for (int i = 0; i < 4; ++i) {
      int e4 = i * 256 + t;
      int r = e4 >> 4, c4 = (e4 & 15) * 4;
      ushort4 raw = *(const ushort4*)&A[(size_t)(bm + r) * DINNER + kc + kt + c4];
      As[r][c4 + 0] = bf2f(raw.x);
      As[r][c4 + 1] = bf2f(raw.y);
      As[r][c4 + 2] = bf2f(raw.z);
      As[r][c4 + 3] = bf2f(raw.w);
    }
#pragma unroll
    for (int i = 0; i < 6; ++i) {
      int e4 = i * 256 + t;
      int r = e4 >> 4, c4 = (e4 & 15) * 4;
      *(float4*)&Ws[r][c4] = *(const float4*)&W[(size_t)r * DINNER + kc + kt + c4];
    }
    __syncthreads();
#pragma unroll 4
    for (int kk = 0; kk < 64; ++kk) {
      float a0 = As[r0][kk], a1 = As[r0 + 1][kk], a2 = As[r0 + 2][kk], a3 = As[r0 + 3][kk];
      float w0 = Ws[c0][kk], w1 = Ws[c0 + 1][kk], w2 = Ws[c0 + 2][kk];
      float w3 = Ws[c0 + 3][kk], w4 = Ws[c0 + 4][kk], w5 = Ws[c0 + 5][kk];
      acc[0][0] += a0 * w0; acc[0][1] += a0 * w1; acc[0][2] += a0 * w2;
      acc[0][3] += a0 * w3; acc[0][4] += a0 * w4; acc[0][5] += a0 * w5;
      acc[1][0] += a1 * w0; acc[1][1] += a1 * w1; acc[1][2] += a1 * w2;
      acc[1][3] += a1 * w3; acc[1][4] += a1 * w4; acc[1][5] += a1 * w5;
      acc[2][0] += a2 * w0; acc[2][1] += a2 * w1; acc[2][2] += a2 * w2;
      acc[2][3] += a2 * w3; acc[2][4] += a2 * w4; acc[2][5] += a2 * w5;
      acc[3][0] += a3 * w0; acc[3][1] += a3 * w1; acc[3][2] += a3 * w2;
      acc[3][3] += a3 * w3; acc[3][4] += a3 * w4; acc[3][5] += a3 * w5;
    }
    __syncthreads();
  }
  float* cp = Cp + (size_t)blockIdx.y * M * 96;
#pragma unroll
  for (int i = 0; i < 4; ++i)
#pragma unroll
    for (int j = 0; j < 6; ++j)
      cp[(size_t)(bm + r0 + i) * 96 + c0 + j] = acc[i][j];
}

__global__ __launch_bounds__(256) void proj_reduce(
    const float* __restrict__ Cp, float* __restrict__ bcdt, int M)
{
  int idx = blockIdx.x * 256 + threadIdx.x;
  float s = 0.f;
#pragma unroll
  for (int c = 0; c < PROJ_NCH; ++c) s += Cp[(size_t)c * M * 96 + idx];
  bcdt[idx] = s;
}

// ---------------- f32 small GEMM -> bf16 out (dt path only) -----------------
__global__ __launch_bounds__(256) void smallgemm_f32(
    const float* __restrict__ A, int lda,
    const float* __restrict__ W, int ldw,
    ushort* __restrict__ C, int ldc,
    const float* __restrict__ bias,
    int M, int N, int K, int act)
{
  __shared__ float As[64][65];
  __shared__ float Ws[64][65];
  const int t = threadIdx.x;
  const int bm = blockIdx.x * 64, bn = blockIdx.y * 64;
  const int r0 = (t >> 4) * 4;
  const int c0 = (t & 15) * 4;
  float acc[4][4] = {};

  for (int kt = 0; kt < K; kt += 64) {
#pragma unroll
    for (int i = 0; i < 16; ++i) {
      int idx = i * 256 + t;
      int r = idx >> 6, c = idx & 63;
      As[r][c] = A[(size_t)(bm + r) * lda + kt + c];
      int wrow = bn + r;
      Ws[r][c] = (wrow < N) ? W[(size_t)wrow * ldw + kt + c] : 0.f;
    }
    __syncthreads();
#pragma unroll 8
    for (int kk = 0; kk < 64; ++kk) {
      float a0 = As[r0][kk], a1 = As[r0 + 1][kk], a2 = As[r0 + 2][kk], a3 = As[r0 + 3][kk];
      float w0 = Ws[c0][kk], w1 = Ws[c0 + 1][kk], w2 = Ws[c0 + 2][kk], w3 = Ws[c0 + 3][kk];
      acc[0][0] += a0 * w0; acc[0][1] += a0 * w1; acc[0][2] += a0 * w2; acc[0][3] += a0 * w3;
      acc[1][0] += a1 * w0; acc[1][1] += a1 * w1; acc[1][2] += a1 * w2; acc[1][3] += a1 * w3;
      acc[2][0] += a2 * w0; acc[2][1] += a2 * w1; acc[2][2] += a2 * w2; acc[2][3] += a2 * w3;
      acc[3][0] += a3 * w0; acc[3][1] += a3 * w1; acc[3][2] += a3 * w2; acc[3][3] += a3 * w3;
    }
    __syncthreads();
  }
#pragma unroll
  for (int i = 0; i < 4; ++i)
#pragma unroll
    for (int j = 0; j < 4; ++j) {
      int cc = bn + c0 + j;
      if (cc < N) {
        float v = acc[i][j];
        if (bias) v += bias[cc];
        if (act == 1) v = (v > 20.f) ? v : log1pf(expf(v));
        C[(size_t)(bm + r0 + i) * ldc + cc] = f2bf(v);
      }
    }
}

// ---------------- causal depthwise conv (K=4) + SiLU -> bf16 u --------------
__global__ __launch_bounds__(256) void conv_silu_kernel(
    const float* __restrict__ u0, int ld, const float* __restrict__ Wconv,
    ushort* __restrict__ u)
{
  int idx = blockIdx.x * 256 + threadIdx.x;
  int d4 = idx & (DINNER / 4 - 1);
  int l = idx >> 9;
  int d0 = d4 * 4;
  float wt[4][4];
#pragma unroll
  for (int j = 0; j < 4; ++j) {
    float4 tv = *(const float4*)&Wconv[(d0 + j) * 4];
    wt[j][0] = tv.x; wt[j][1] = tv.y; wt[j][2] = tv.z; wt[j][3] = tv.w;
  }
  float a[4] = {0.f, 0.f, 0.f, 0.f};
#pragma unroll
  for (int k = 0; k < 4; ++k) {
    int ls = l - 3 + k;
    if (ls >= 0) {
      float4 uv = *(const float4*)&u0[(size_t)ls * ld + d0];
      a[0] += uv.x * wt[0][k];
      a[1] += uv.y * wt[1][k];
      a[2] += uv.z * wt[2][k];
      a[3] += uv.w * wt[3][k];
    }
  }
  float s0 = a[0] / (1.f + expf(-a[0]));
  float s1 = a[1] / (1.f + expf(-a[1]));
  float s2 = a[2] / (1.f + expf(-a[2]));
  float s3 = a[3] / (1.f + expf(-a[3]));
  ushort4 o = {f2bf(s0), f2bf(s1), f2bf(s2), f2bf(s3)};
  *(ushort4*)&u[(size_t)l * DINNER + d0] = o;
}

// ---------------- chunk-parallel selective scan (bf16 dt/u inputs) ----------
__global__ __launch_bounds__(256) void scan_pass1(
    const ushort* __restrict__ dt, const ushort* __restrict__ u,
    const float* __restrict__ bcdt, const float* __restrict__ logA,
    float* __restrict__ P, float* __restrict__ S)
{
  const int tid = threadIdx.x;
  const int n = tid & 15, dl = tid >> 4;
  const int dbase = blockIdx.x * 16;
  const int c = blockIdx.y;
  const int t0 = c * CLEN;
  const int d = dbase + dl;
  const float Aval = -expf(logA[d * DSTATE + n]);
  __shared__ float sdt[CLEN][16], su[CLEN][16], sB[CLEN][16];
  {
    int tt = tid >> 2, j0 = (tid & 3) * 4;
    ushort4 rd = *(const ushort4*)&dt[(size_t)(t0 + tt) * DINNER + dbase + j0];
    ushort4 ru = *(const ushort4*)&u[(size_t)(t0 + tt) * DINNER + dbase + j0];
    sdt[tt][j0 + 0] = bf2f(rd.x); sdt[tt][j0 + 1] = bf2f(rd.y);
    sdt[tt][j0 + 2] = bf2f(rd.z); sdt[tt][j0 + 3] = bf2f(rd.w);
    su[tt][j0 + 0] = bf2f(ru.x); su[tt][j0 + 1] = bf2f(ru.y);
    su[tt][j0 + 2] = bf2f(ru.z); su[tt][j0 + 3] = bf2f(ru.w);
    *(float4*)&sB[tt][j0] = *(const float4*)&bcdt[(size_t)(t0 + tt) * 96 + j0];
  }
  __syncthreads();
  float h = 0.f, pr = 1.f;
#pragma unroll 8
  for (int i = 0; i < CLEN; ++i) {
    float dtv = sdt[i][dl], uv = su[i][dl], Bv = sB[i][n];
    float dtA = dtv * Aval;
    float rinv = __builtin_amdgcn_rcpf(1.f - 0.5f * dtA);
    float dA = (1.f + 0.5f * dtA) * rinv;
    float dBu = dtv * Bv * rinv * uv;
    h = dA * h + dBu;
    pr *= dA;
  }
  size_t idx = (size_t)c * (DINNER * DSTATE) + (size_t)d * DSTATE + n;
  P[idx] = pr;
  S[idx] = h;
}

__global__ __launch_bounds__(256) void scan_pass2(
    const ushort* __restrict__ dt, const ushort* __restrict__ u,
    const float* __restrict__ bcdt, const float* __restrict__ logA,
    const float* __restrict__ Dp, const float* __restrict__ P,
    const float* __restrict__ S, const float* __restrict__ resu0,
    ushort* __restrict__ y2b)
{
  const int tid = threadIdx.x;
  const int n = tid & 15, dl = tid >> 4;
  const int dbase = blockIdx.x * 16;
  const int c = blockIdx.y;
  const int t0 = c * CLEN;
  const int d = dbase + dl;
  const float Aval = -expf(logA[d * DSTATE + n]);
  const float Dpv = Dp[d];
  __shared__ float sdt[CLEN][16], su[CLEN][16], sB[CLEN][16], sC[CLEN][16], sres[CLEN][16];
  {
    int tt = tid >> 2, j0 = (tid & 3) * 4;
    ushort4 rd = *(const ushort4*)&dt[(size_t)(t0 + tt) * DINNER + dbase + j0];
    ushort4 ru = *(const ushort4*)&u[(size_t)(t0 + tt) * DINNER + dbase + j0];
    sdt[tt][j0 + 0] = bf2f(rd.x); sdt[tt][j0 + 1] = bf2f(rd.y);
    sdt[tt][j0 + 2] = bf2f(rd.z); sdt[tt][j0 + 3] = bf2f(rd.w);
    su[tt][j0 + 0] = bf2f(ru.x); su[tt][j0 + 1] = bf2f(ru.y);
    su[tt][j0 + 2] = bf2f(ru.z); su[tt][j0 + 3] = bf2f(ru.w);
    *(float4*)&sB[tt][j0]   = *(const float4*)&bcdt[(size_t)(t0 + tt) * 96 + j0];
    *(float4*)&sC[tt][j0]   = *(const float4*)&bcdt[(size_t)(t0 + tt) * 96 + 16 + j0];
    *(float4*)&sres[tt][j0] = *(const float4*)&resu0[(size_t)(t0 + tt) * (2 * DINNER) + dbase + j0];
  }
  float h = 0.f;
  {
    const size_t base = (size_t)d * DSTATE + n;
#pragma unroll 4
    for (int cc = 0; cc < c; ++cc) {
      size_t o = (size_t)cc * (DINNER * DSTATE) + base;
      h = P[o] * h + S[o];
    }
  }
  __syncthreads();
#pragma unroll 4
  for (int i = 0; i < CLEN; ++i) {
    float dtv = sdt[i][dl], uv = su[i][dl];
    float dtA = dtv * Aval;
    float rinv = __builtin_amdgcn_rcpf(1.f - 0.5f * dtA);
    float dA = (1.f + 0.5f * dtA) * rinv;
    float dBu = dtv * sB[i][n] * rinv * uv;
    h = dA * h + dBu;
    float p = h * sC[i][n];
    p += __shfl_xor(p, 1);
    p += __shfl_xor(p, 2);
    p += __shfl_xor(p, 4);
    p += __shfl_xor(p, 8);
    if (n == 0) {
      float rv = sres[i][dl];
      float yv = (p + uv * Dpv) * (rv / (1.f + expf(-rv)));
      y2b[(size_t)(t0 + i) * DINNER + d] = f2bf(yv);
    }
  }
}

// ---------------- f32 -> bf16 cast ------------------------------------------
__global__ __launch_bounds__(256) void cast_bf16_kernel(
    const float* __restrict__ in, ushort* __restrict__ out, size_t n4)
{
  size_t i = (size_t)blockIdx.x * 256 + threadIdx.x;
  if (i >= n4) return;
  float4 v = ((const float4*)in)[i];
  ushort4 o = {f2bf(v.x), f2bf(v.y), f2bf(v.z), f2bf(v.w)};
  ((ushort4*)out)[i] = o;
}

// ---------------- concat-cast Wres|Win -> bf16 [L][2*DINNER][DMODEL] --------
__global__ __launch_bounds__(256) void cast_cat2_kernel(
    const float* __restrict__ Wres, const float* __restrict__ Win, ushort* __restrict__ out)
{
  size_t i4 = (size_t)blockIdx.x * 256 + threadIdx.x;
  size_t e0 = i4 * 4;
  int k = (int)(e0 & (DMODEL - 1));
  int r = (int)((e0 >> 10) & (2 * DINNER - 1));
  int l = (int)(e0 >> 22);
  const float* src = (r < DINNER)
      ? &Wres[(((size_t)l * DINNER + r) << 10) + k]
      : &Win[(((size_t)l * DINNER + (r - DINNER)) << 10) + k];
  float4 v = *(const float4*)src;
  ushort4 o = {f2bf(v.x), f2bf(v.y), f2bf(v.z), f2bf(v.w)};
  ((ushort4*)out)[i4] = o;
}

// ---------------- concat WB|WC|Wdt1 -> [L][96][DINNER] ----------------------
__global__ __launch_bounds__(256) void concat_wbcdt_kernel(
    const float* __restrict__ WB, const float* __restrict__ WC,
    const float* __restrict__ Wdt1, float* __restrict__ out)
{
  size_t idx = (size_t)blockIdx.x * 256 + threadIdx.x;
  int k = idx & (DINNER - 1);
  size_t rl = idx >> 11;
  int row = (int)(rl % 96);
  int l = (int)(rl / 96);
  float v;
  if (row < 16)       v = WB[((size_t)l * DSTATE + row) * DINNER + k];
  else if (row < 32)  v = WC[((size_t)l * DSTATE + (row - 16)) * DINNER + k];
  else                v = Wdt1[((size_t)l * DTRANK + (row - 32)) * DINNER + k];
  out[idx] = v;
}

// ============================================================================
extern "C" void kernel_launch(void* const* d_in, const int* in_sizes, int n_in,
                              void* d_out, int out_size, void* d_ws, size_t ws_size,
                              hipStream_t stream) {
  (void)in_sizes; (void)n_in; (void)out_size;
  const int* token_ids = (const int*)d_in[0];
  const float* embed = (const float*)d_in[1];
  const float* Wres = (const float*)d_in[2];
  const float* Win = (const float*)d_in[3];
  const float* Wconv = (const float*)d_in[4];
  const float* WB = (const float*)d_in[5];
  const float* WC = (const float*)d_in[6];
  const float* Wdt1 = (const float*)d_in[7];
  const float* Wdt2 = (const float*)d_in[8];
  const float* bdt = (const float*)d_in[9];
  const float* logA = (const float*)d_in[10];
  const float* Dp = (const float*)d_in[11];
  const float* Wout = (const float*)d_in[12];
  float* out = (float*)d_out;

  char* w = (char*)d_ws;
  auto alloc = [&](size_t bytes) {
    char* p = w;
    w += (bytes + 255) & ~(size_t)255;
    return p;
  };
  ushort* eb    = (ushort*)alloc((size_t)VOCAB * DMODEL * 2);
  ushort* wcatb = (ushort*)alloc((size_t)NLAYER * 2 * DINNER * DMODEL * 2);
  ushort* woutb = (ushort*)alloc((size_t)NLAYER * DMODEL * DINNER * 2);
  float* wbcdt  = (float*)alloc((size_t)NLAYER * 96 * DINNER * 4);
  float* x      = (float*)alloc((size_t)SEQ * DMODEL * 4);
  ushort* xnb   = (ushort*)alloc((size_t)SEQ * DMODEL * 2);
  float* resu0  = (float*)alloc((size_t)SEQ * 2 * DINNER * 4);
  ushort* u     = (ushort*)alloc((size_t)SEQ * DINNER * 2);
  float* bcdt   = (float*)alloc((size_t)SEQ * 96 * 4);
  ushort* dt    = (ushort*)alloc((size_t)SEQ * DINNER * 2);
  float* Cp     = (float*)alloc((size_t)PROJ_NCH * SEQ * 96 * 4);
  float* Cp2    = (float*)alloc((size_t)2 * SEQ * DMODEL * 4);
  float* Pbuf   = (float*)alloc((size_t)NCHUNK * DINNER * DSTATE * 4);
  float* Sbuf   = (float*)alloc((size_t)NCHUNK * DINNER * DSTATE * 4);
  ushort* y2b   = (ushort*)alloc((size_t)SEQ * DINNER * 2);
  ushort* xb    = (ushort*)alloc((size_t)SEQ * DMODEL * 2);
  if ((size_t)(w - (char*)d_ws) > ws_size) return;

  // weight preprocessing
  cast_bf16_kernel<<<VOCAB * DMODEL / 4 / 256, 256, 0, stream>>>(embed, eb, (size_t)VOCAB * DMODEL / 4);
  cast_cat2_kernel<<<NLAYER * 2 * DINNER * DMODEL / 4 / 256, 256, 0, stream>>>(Wres, Win, wcatb);
  cast_bf16_kernel<<<NLAYER * DMODEL * DINNER / 4 / 256, 256, 0, stream>>>(Wout, woutb, (size_t)NLAYER * DMODEL * DINNER / 4);
  concat_wbcdt_kernel<<<NLAYER * 96 * DINNER / 256, 256, 0, stream>>>(WB, WC, Wdt1, wbcdt);
  gather_rms_kernel<<<SEQ, 256, 0, stream>>>(token_ids, embed, x, xnb);

  for (int i = 0; i < NLAYER; ++i) {
    const ushort* wcati = wcatb + (size_t)i * 2 * DINNER * DMODEL;
    const ushort* wouti = woutb + (size_t)i * DMODEL * DINNER;
    const float* wconvi = Wconv + (size_t)i * DINNER * 4;
    const float* wbcdti = wbcdt + (size_t)i * 96 * DINNER;
    const float* wdt2i = Wdt2 + (size_t)i * DINNER * DTRANK;
    const float* bdti = bdt + (size_t)i * DINNER;
    const float* logAi = logA + (size_t)i * DINNER * DSTATE;
    const float* Dpi = Dp + (size_t)i * DINNER;

    gemm2p_bt_bf16<false><<<dim3(SEQ / 128, 2 * DINNER / 128), 256, 0, stream>>>(
        xnb, wcati, resu0, 2 * DINNER, DMODEL);
    conv_silu_kernel<<<SEQ * DINNER / 4 / 256, 256, 0, stream>>>(resu0 + DINNER, 2 * DINNER, wconvi, u);
    projgemm_f32<<<dim3(SEQ / 64, PROJ_NCH), 256, 0, stream>>>(u, wbcdti, Cp, SEQ);
    proj_reduce<<<SEQ * 96 / 256, 256, 0, stream>>>(Cp, bcdt, SEQ);
    smallgemm_f32<<<dim3(SEQ / 64, DINNER / 64), 256, 0, stream>>>(
        bcdt + 32, 96, wdt2i, DTRANK, dt, DINNER, bdti, SEQ, DINNER, DTRANK, 1);
    dim3 gs(DINNER / 16, NCHUNK);
    scan_pass1<<<gs, 256, 0, stream>>>(dt, u, bcdt, logAi, Pbuf, Sbuf);
    scan_pass2<<<gs, 256, 0, stream>>>(dt, u, bcdt, logAi, Dpi, Pbuf, Sbuf, resu0, y2b);
    gemm_btk_bf16<<<dim3(SEQ / 128, DMODEL / 128, 2), 256, 0, stream>>>(
        y2b, wouti, Cp2, SEQ, DMODEL, DINNER);
    add3_rms_kernel<<<SEQ, 256, 0, stream>>>(
        Cp2, Cp2 + (size_t)SEQ * DMODEL, x,
        (i < NLAYER - 1) ? xnb : xb, (i < NLAYER - 1) ? 1 : 0);
  }
  gemm8p_bt_bf16<256, true><<<dim3(SEQ / 256, VOCAB / 256), 512, 0, stream>>>(
      xb, eb, out, VOCAB, DMODEL);
}

// Round 13
// 2198.182 us; speedup vs baseline: 1.3703x; 1.0027x over previous
//
#include <hip/hip_runtime.h>

#define SEQ 2048
#define DMODEL 1024
#define DINNER 2048
#define DSTATE 16
#define DTRANK 64
#define NLAYER 8
#define VOCAB 32000
#define NCHUNK 32
#define CLEN 64   // SEQ / NCHUNK
#define PROJ_NCH 16
#define PROJ_KC 128  // DINNER / PROJ_NCH

typedef float f32x4 __attribute__((ext_vector_type(4)));
typedef short bf16x8 __attribute__((ext_vector_type(8)));

__device__ __forceinline__ ushort f2bf(float f) {
  union { float f; unsigned u; } v; v.f = f;
  unsigned r = v.u + 0x7fffu + ((v.u >> 16) & 1u);
  return (ushort)(r >> 16);
}
__device__ __forceinline__ float bf2f(ushort b) {
  union { unsigned u; float f; } v; v.u = ((unsigned)b) << 16;
  return v.f;
}

__device__ __forceinline__ void lds_load16(const void* g, void* l) {
  __builtin_amdgcn_global_load_lds(
      (const __attribute__((address_space(1))) void*)g,
      (__attribute__((address_space(3))) void*)l, 16, 0, 0);
}

// ---------------- 256x256 counted-vmcnt MFMA GEMM (proven ~197us logits) ----
template<int BM, bool NTS>
__global__ __launch_bounds__(512, 2) void gemm8p_bt_bf16(
    const ushort* __restrict__ A, const ushort* __restrict__ B,
    float* __restrict__ C, int N, int K)
{
  constexpr int MFR = BM / 32;
  constexpr int MPP = MFR / 4;
  constexpr int ALOADS = BM / 128;
  __shared__ __align__(16) ushort As[2 * BM * 64];
  __shared__ __align__(16) ushort Bs[2 * 256 * 64];
  const int tid = threadIdx.x;
  const int lane = tid & 63;
  const int wid = tid >> 6;
  const int wr = wid >> 2, wc = wid & 3;
  const int rr = lane & 15, kq = lane >> 4;

  unsigned nwg = gridDim.x * gridDim.y;
  unsigned lb = blockIdx.y * gridDim.x + blockIdx.x;
  if ((nwg & 7u) == 0u) { unsigned cpx = nwg >> 3; lb = (lb & 7u) * cpx + (lb >> 3); }
  const int bm = (int)(lb % gridDim.x) * BM;
  const int bn = (int)(lb / gridDim.x) * 256;

  const ushort* Abase = A + (size_t)bm * K;
  const ushort* Bbase = B + (size_t)bn * K;

  auto stageA = [&](int buf, int h, int kt) {
    constexpr int HR = BM / 2;
#pragma unroll
    for (int L = 0; L < ALOADS; ++L) {
      int f = L * 512 + tid;
      int rl = f >> 3, g = f & 7;
      int gg = g ^ (rl & 7);
      lds_load16(Abase + (size_t)(h * HR + rl) * K + kt * 64 + gg * 8,
                 (void*)(As + buf * (BM * 64) + (h * HR + rl) * 64 + g * 8));
    }
  };
  auto stageB = [&](int buf, int h, int kt) {
#pragma unroll
    for (int L = 0; L < 2; ++L) {
      int f = L * 512 + tid;
      int rl = f >> 3, g = f & 7;
      int gg = g ^ (rl & 7);
      lds_load16(Bbase + (size_t)(h * 128 + rl) * K + kt * 64 + gg * 8,
                 (void*)(Bs + buf * (256 * 64) + (h * 128 + rl) * 64 + g * 8));
    }
  };
  auto rdA = [&](int buf, int r, int kbyte) {
    int sw = kbyte ^ ((r & 7) << 4);
    return *(const bf16x8*)(As + buf * (BM * 64) + r * 64 + (sw >> 1));
  };
  auto rdB = [&](int buf, int r, int kbyte) {
    int sw = kbyte ^ ((r & 7) << 4);
    return *(const bf16x8*)(Bs + buf * (256 * 64) + r * 64 + (sw >> 1));
  };

  f32x4 acc[MFR][4];
#pragma unroll
  for (int m = 0; m < MFR; ++m)
#pragma unroll
    for (int n = 0; n < 4; ++n) acc[m][n] = (f32x4){0.f, 0.f, 0.f, 0.f};

  const int NT = K >> 6;
  stageA(0, 0, 0); stageA(0, 1, 0); stageB(0, 0, 0); stageB(0, 1, 0);

  for (int t = 0; t < NT; ++t) {
    const int cur = t & 1;
    const bool more = (t + 1 < NT);
    if (more) stageA(cur ^ 1, 0, t + 1);
    if (more) {
      if constexpr (BM == 256) asm volatile("s_waitcnt vmcnt(2)" ::: "memory");
      else                     asm volatile("s_waitcnt vmcnt(1)" ::: "memory");
    } else {
      asm volatile("s_waitcnt vmcnt(0)" ::: "memory");
    }
    __syncthreads();

    bf16x8 bfr[4][2];
#pragma unroll
    for (int n = 0; n < 4; ++n)
#pragma unroll
      for (int kk = 0; kk < 2; ++kk)
        bfr[n][kk] = rdB(cur, wc * 64 + n * 16 + rr, kk * 64 + kq * 16);

#pragma unroll
    for (int mq = 0; mq < 4; ++mq) {
      if (mq == 1 && more) stageA(cur ^ 1, 1, t + 1);
      if (mq == 2 && more) stageB(cur ^ 1, 0, t + 1);
      if (mq == 3 && more) stageB(cur ^ 1, 1, t + 1);
      bf16x8 af[MPP][2];
#pragma unroll
      for (int mf = 0; mf < MPP; ++mf)
#pragma unroll
        for (int kk = 0; kk < 2; ++kk)
          af[mf][kk] = rdA(cur, wr * (BM / 2) + (mq * MPP + mf) * 16 + rr, kk * 64 + kq * 16);
      __builtin_amdgcn_s_setprio(1);
#pragma unroll
      for (int kk = 0; kk < 2; ++kk)
#pragma unroll
        for (int mf = 0; mf < MPP; ++mf)
#pragma unroll
          for (int n = 0; n < 4; ++n)
            acc[mq * MPP + mf][n] = __builtin_amdgcn_mfma_f32_16x16x32_bf16(
                af[mf][kk], bfr[n][kk], acc[mq * MPP + mf][n], 0, 0, 0);
      __builtin_amdgcn_s_setprio(0);
    }
    __syncthreads();
  }

  float* ep = (float*)Bs + wid * (16 * 68);
  const int cg = bn + wc * 64;
#pragma unroll
  for (int m = 0; m < MFR; ++m) {
    const int r0g = bm + wr * (BM / 2) + m * 16;
#pragma unroll
    for (int n = 0; n < 4; ++n)
#pragma unroll
      for (int j = 0; j < 4; ++j)
        ep[(kq * 4 + j) * 68 + n * 16 + rr] = acc[m][n][j];
#pragma unroll
    for (int i = 0; i < 4; ++i) {
      int row = i * 4 + kq;
      f32x4 v = *(const f32x4*)&ep[row * 68 + rr * 4];
      f32x4* dst = (f32x4*)&C[(size_t)(r0g + row) * N + cg + rr * 4];
      if constexpr (NTS) __builtin_nontemporal_store(v, dst);
      else *dst = v;
    }
  }
}

// ---------------- 128x128 2-blocks/CU MFMA GEMM (layer gemm1) ---------------
// OUTBF: epilogue converts to bf16 (ushort4 stores) — used for resu0.
template<bool OUTBF>
__global__ __launch_bounds__(256, 2) void gemm2p_bt_bf16(
    const ushort* __restrict__ A, const ushort* __restrict__ B,
    void* __restrict__ Cv, int N, int K)
{
  __shared__ __align__(16) ushort As[2 * 128 * 64];
  __shared__ __align__(16) ushort Bs[2 * 128 * 64];
  const int tid = threadIdx.x;
  const int lane = tid & 63;
  const int wave = tid >> 6;
  const int wr = wave >> 1, wc = wave & 1;
  const int rr = lane & 15, kq = lane >> 4;

  unsigned nwg = gridDim.x * gridDim.y;
  unsigned lb = blockIdx.y * gridDim.x + blockIdx.x;
  if ((nwg & 7u) == 0u) { unsigned cpx = nwg >> 3; lb = (lb & 7u) * cpx + (lb >> 3); }
  const int bm = (int)(lb % gridDim.x) * 128;
  const int bn = (int)(lb / gridDim.x) * 128;

  const ushort* Abase = A + (size_t)bm * K;
  const ushort* Bbase = B + (size_t)bn * K;

  auto stage = [&](int buf, int kt) {
#pragma unroll
    for (int i = 0; i < 4; ++i) {
      int f = i * 256 + tid;
      int rl = f >> 3, g = f & 7;
      int gg = g ^ (rl & 7);
      lds_load16(Abase + (size_t)rl * K + kt * 64 + gg * 8,
                 (void*)(As + buf * 8192 + rl * 64 + g * 8));
      lds_load16(Bbase + (size_t)rl * K + kt * 64 + gg * 8,
                 (void*)(Bs + buf * 8192 + rl * 64 + g * 8));
    }
  };
  auto rdA = [&](int buf, int r, int kbyte) {
    int sw = kbyte ^ ((r & 7) << 4);
    return *(const bf16x8*)(As + buf * 8192 + r * 64 + (sw >> 1));
  };
  auto rdB = [&](int buf, int r, int kbyte) {
    int sw = kbyte ^ ((r & 7) << 4);
    return *(const bf16x8*)(Bs + buf * 8192 + r * 64 + (sw >> 1));
  };

  f32x4 acc[4][4];
#pragma unroll
  for (int m = 0; m < 4; ++m)
#pragma unroll
    for (int n = 0; n < 4; ++n) acc[m][n] = (f32x4){0.f, 0.f, 0.f, 0.f};

  const int NT = K >> 6;
  stage(0, 0);

  for (int t = 0; t < NT; ++t) {
    const int cur = t & 1;
    if (t + 1 < NT) {
      stage(cur ^ 1, t + 1);
      asm volatile("s_waitcnt vmcnt(8)" ::: "memory");
    } else {
      asm volatile("s_waitcnt vmcnt(0)" ::: "memory");
    }
    __syncthreads();
#pragma unroll
    for (int ks = 0; ks < 2; ++ks) {
      const int kbyte = ks * 64 + kq * 16;
      bf16x8 af[4], bfr[4];
#pragma unroll
      for (int m = 0; m < 4; ++m)
        af[m] = rdA(cur, wr * 64 + m * 16 + rr, kbyte);
#pragma unroll
      for (int n = 0; n < 4; ++n)
        bfr[n] = rdB(cur, wc * 64 + n * 16 + rr, kbyte);
      __builtin_amdgcn_s_setprio(1);
#pragma unroll
      for (int m = 0; m < 4; ++m)
#pragma unroll
        for (int n = 0; n < 4; ++n)
          acc[m][n] = __builtin_amdgcn_mfma_f32_16x16x32_bf16(af[m], bfr[n], acc[m][n], 0, 0, 0);
      __builtin_amdgcn_s_setprio(0);
    }
    __syncthreads();
  }

  float* ep = (float*)Bs + wave * (16 * 68);
  const int cg = bn + wc * 64;
#pragma unroll
  for (int m = 0; m < 4; ++m) {
    const int r0g = bm + wr * 64 + m * 16;
#pragma unroll
    for (int n = 0; n < 4; ++n)
#pragma unroll
      for (int j = 0; j < 4; ++j)
        ep[(kq * 4 + j) * 68 + n * 16 + rr] = acc[m][n][j];
#pragma unroll
    for (int i = 0; i < 4; ++i) {
      int row = i * 4 + kq;
      f32x4 v = *(const f32x4*)&ep[row * 68 + rr * 4];
      if constexpr (OUTBF) {
        ushort* C = (ushort*)Cv;
        ushort4 o = {f2bf(v.x), f2bf(v.y), f2bf(v.z), f2bf(v.w)};
        *(ushort4*)&C[(size_t)(r0g + row) * N + cg + rr * 4] = o;
      } else {
        float* C = (float*)Cv;
        *(f32x4*)&C[(size_t)(r0g + row) * N + cg + rr * 4] = v;
      }
    }
  }
}

// ---------------- split-K bf16 MFMA GEMM (2-phase 128x128) ------------------
__global__ __launch_bounds__(256) void gemm_btk_bf16(
    const ushort* __restrict__ A, const ushort* __restrict__ B,
    float* __restrict__ Cp, int M, int N, int K)
{
  __shared__ __align__(16) ushort As[128 * 64];
  __shared__ __align__(16) ushort Bs[128 * 64];
  const int tid = threadIdx.x;
  const int lane = tid & 63;
  const int wave = tid >> 6;
  const int wr = wave >> 1, wc = wave & 1;
  const int KC = K >> 1;
  const int k0 = blockIdx.z * KC;

  unsigned nwg = gridDim.x * gridDim.y;
  unsigned lb = blockIdx.y * gridDim.x + blockIdx.x;
  if ((nwg & 7u) == 0u) {
    unsigned cpx = nwg >> 3;
    lb = (lb & 7u) * cpx + (lb >> 3);
  }
  const int bm = (lb % gridDim.x) * 128;
  const int bn = (lb / gridDim.x) * 128;
  const int rr = lane & 15, kq = lane >> 4;

  f32x4 acc[4][4];
#pragma unroll
  for (int m = 0; m < 4; ++m)
#pragma unroll
    for (int n = 0; n < 4; ++n) acc[m][n] = (f32x4){0.f, 0.f, 0.f, 0.f};

  for (int kt = 0; kt < KC; kt += 64) {
#pragma unroll
    for (int i = 0; i < 4; ++i) {
      int fb = i * 256 + tid;
      int row = fb >> 3, cb = fb & 7;
      lds_load16(A + (size_t)(bm + row) * K + k0 + kt + cb * 8, (void*)(As + (size_t)fb * 8));
      lds_load16(B + (size_t)(bn + row) * K + k0 + kt + cb * 8, (void*)(Bs + (size_t)fb * 8));
    }
    __syncthreads();
#pragma unroll
    for (int ks = 0; ks < 2; ++ks) {
      bf16x8 af[4], bfr[4];
      const int koff = ks * 32 + kq * 8;
#pragma unroll
      for (int m = 0; m < 4; ++m)
        af[m] = *(const bf16x8*)&As[(wr * 64 + m * 16 + rr) * 64 + koff];
#pragma unroll
      for (int n = 0; n < 4; ++n)
        bfr[n] = *(const bf16x8*)&Bs[(wc * 64 + n * 16 + rr) * 64 + koff];
#pragma unroll
      for (int m = 0; m < 4; ++m)
#pragma unroll
        for (int n = 0; n < 4; ++n)
          acc[m][n] = __builtin_amdgcn_mfma_f32_16x16x32_bf16(af[m], bfr[n], acc[m][n], 0, 0, 0);
    }
    __syncthreads();
  }
  float* C = Cp + (size_t)blockIdx.z * M * N;
#pragma unroll
  for (int m = 0; m < 4; ++m) {
    const int r0 = bm + wr * 64 + m * 16 + kq * 4;
#pragma unroll
    for (int n = 0; n < 4; ++n) {
      const int cc = bn + wc * 64 + n * 16 + rr;
#pragma unroll
      for (int j = 0; j < 4; ++j)
        C[(size_t)(r0 + j) * N + cc] = acc[m][n][j];
    }
  }
}

// ---------------- x += P0 + P1, then RMSNorm(x)->bf16 (or plain cast) -------
__global__ __launch_bounds__(256) void add3_rms_kernel(
    const float* __restrict__ P0, const float* __restrict__ P1,
    float* __restrict__ x, ushort* __restrict__ dst, int donorm)
{
  size_t o = (size_t)blockIdx.x * (DMODEL / 4) + threadIdx.x;
  float4 a = ((const float4*)P0)[o];
  float4 b = ((const float4*)P1)[o];
  float4 c = ((float4*)x)[o];
  c.x += a.x + b.x; c.y += a.y + b.y; c.z += a.z + b.z; c.w += a.w + b.w;
  ((float4*)x)[o] = c;
  float sc = 1.f;
  if (donorm) {
    float s = c.x * c.x + c.y * c.y + c.z * c.z + c.w * c.w;
#pragma unroll
    for (int off = 32; off > 0; off >>= 1) s += __shfl_down(s, off);
    __shared__ float ws[4];
    if ((threadIdx.x & 63) == 0) ws[threadIdx.x >> 6] = s;
    __syncthreads();
    float tot = ws[0] + ws[1] + ws[2] + ws[3];
    sc = rsqrtf(tot * (1.0f / DMODEL) + 1e-6f);
  }
  ushort4 o4 = {f2bf(c.x * sc), f2bf(c.y * sc), f2bf(c.z * sc), f2bf(c.w * sc)};
  ((ushort4*)dst)[o] = o4;
}

// ---------------- embedding gather + RMSNorm -> x (f32) and xnb (bf16) ------
__global__ __launch_bounds__(256) void gather_rms_kernel(
    const int* __restrict__ ids, const float* __restrict__ embed,
    float* __restrict__ x, ushort* __restrict__ xnb)
{
  int row = blockIdx.x;
  int id = ids[row];
  float4 v = ((const float4*)(embed + (size_t)id * DMODEL))[threadIdx.x];
  size_t o = (size_t)row * (DMODEL / 4) + threadIdx.x;
  ((float4*)x)[o] = v;
  float s = v.x * v.x + v.y * v.y + v.z * v.z + v.w * v.w;
#pragma unroll
  for (int off = 32; off > 0; off >>= 1) s += __shfl_down(s, off);
  __shared__ float ws[4];
  if ((threadIdx.x & 63) == 0) ws[threadIdx.x >> 6] = s;
  __syncthreads();
  float tot = ws[0] + ws[1] + ws[2] + ws[3];
  float sc = rsqrtf(tot * (1.0f / DMODEL) + 1e-6f);
  ushort4 o4 = {f2bf(v.x * sc), f2bf(v.y * sc), f2bf(v.z * sc), f2bf(v.w * sc)};
  ((ushort4*)xnb)[o] = o4;
}

// ---------------- split-K f32 projection GEMM (bf16 u input) ----------------
__global__ __launch_bounds__(256) void projgemm_f32(
    const ushort* __restrict__ A, const float* __restrict__ W,
    float* __restrict__ Cp, int M)
{
  __shared__ float As[64][65];
  __shared__ float Ws[96][65];
  const int t = threadIdx.x;
  const int bm = blockIdx.x * 64;
  const int kc = blockIdx.y * PROJ_KC;
  const int ty = t >> 4, tx = t & 15;
  const int r0 = ty * 4, c0 = tx * 6;
  float acc[4][6] = {};
  for (int kt = 0; kt < PROJ_KC; kt += 64) {
#pragma unroll
    for (int i = 0; i < 4; ++i) {
      int e4 = i * 256 + t;
      int r = e4 >> 4, c4 = (e4 & 15) * 4;
      ushort4 raw = *(const ushort4*)&A[(size_t)(bm + r) * DINNER + kc + kt + c4];
      As[r][c4 + 0] = bf2f(raw.x);
      As[r][c4 + 1] = bf2f(raw.y);
      As[r][c4 + 2] = bf2f(raw.z);
      As[r][c4 + 3] = bf2f(raw.w);
    }
#pragma unroll
    for (int i = 0; i < 6; ++i) {
      int e4 = i * 256 + t;
      int r = e4 >> 4, c4 = (e4 & 15) * 4;
      *(float4*)&Ws[r][c4] = *(const float4*)&W[(size_t)r * DINNER + kc + kt + c4];
    }
    __syncthreads();
#pragma unroll 4
    for (int kk = 0; kk < 64; ++kk) {
      float a0 = As[r0][kk], a1 = As[r0 + 1][kk], a2 = As[r0 + 2][kk], a3 = As[r0 + 3][kk];
      float w0 = Ws[c0][kk], w1 = Ws[c0 + 1][kk], w2 = Ws[c0 + 2][kk];
      float w3 = Ws[c0 + 3][kk], w4 = Ws[c0 + 4][kk], w5 = Ws[c0 + 5][kk];
      acc[0][0] += a0 * w0; acc[0][1] += a0 * w1; acc[0][2] += a0 * w2;
      acc[0][3] += a0 * w3; acc[0][4] += a0 * w4; acc[0][5] += a0 * w5;
      acc[1][0] += a1 * w0; acc[1][1] += a1 * w1; acc[1][2] += a1 * w2;
      acc[1][3] += a1 * w3; acc[1][4] += a1 * w4; acc[1][5] += a1 * w5;
      acc[2][0] += a2 * w0; acc[2][1] += a2 * w1; acc[2][2] += a2 * w2;
      acc[2][3] += a2 * w3; acc[2][4] += a2 * w4; acc[2][5] += a2 * w5;
      acc[3][0] += a3 * w0; acc[3][1] += a3 * w1; acc[3][2] += a3 * w2;
      acc[3][3] += a3 * w3; acc[3][4] += a3 * w4; acc[3][5] += a3 * w5;
    }
    __syncthreads();
  }
  float* cp = Cp + (size_t)blockIdx.y * M * 96;
#pragma unroll
  for (int i = 0; i < 4; ++i)
#pragma unroll
    for (int j = 0; j < 6; ++j)
      cp[(size_t)(bm + r0 + i) * 96 + c0 + j] = acc[i][j];
}

__global__ __launch_bounds__(256) void proj_reduce(
    const float* __restrict__ Cp, float* __restrict__ bcdt, int M)
{
  int idx = blockIdx.x * 256 + threadIdx.x;
  float s = 0.f;
#pragma unroll
  for (int c = 0; c < PROJ_NCH; ++c) s += Cp[(size_t)c * M * 96 + idx];
  bcdt[idx] = s;
}

// ---------------- f32 small GEMM -> bf16 out (dt path only) -----------------
__global__ __launch_bounds__(256) void smallgemm_f32(
    const float* __restrict__ A, int lda,
    const float* __restrict__ W, int ldw,
    ushort* __restrict__ C, int ldc,
    const float* __restrict__ bias,
    int M, int N, int K, int act)
{
  __shared__ float As[64][65];
  __shared__ float Ws[64][65];
  const int t = threadIdx.x;
  const int bm = blockIdx.x * 64, bn = blockIdx.y * 64;
  const int r0 = (t >> 4) * 4;
  const int c0 = (t & 15) * 4;
  float acc[4][4] = {};

  for (int kt = 0; kt < K; kt += 64) {
#pragma unroll
    for (int i = 0; i < 16; ++i) {
      int idx = i * 256 + t;
      int r = idx >> 6, c = idx & 63;
      As[r][c] = A[(size_t)(bm + r) * lda + kt + c];
      int wrow = bn + r;
      Ws[r][c] = (wrow < N) ? W[(size_t)wrow * ldw + kt + c] : 0.f;
    }
    __syncthreads();
#pragma unroll 8
    for (int kk = 0; kk < 64; ++kk) {
      float a0 = As[r0][kk], a1 = As[r0 + 1][kk], a2 = As[r0 + 2][kk], a3 = As[r0 + 3][kk];
      float w0 = Ws[c0][kk], w1 = Ws[c0 + 1][kk], w2 = Ws[c0 + 2][kk], w3 = Ws[c0 + 3][kk];
      acc[0][0] += a0 * w0; acc[0][1] += a0 * w1; acc[0][2] += a0 * w2; acc[0][3] += a0 * w3;
      acc[1][0] += a1 * w0; acc[1][1] += a1 * w1; acc[1][2] += a1 * w2; acc[1][3] += a1 * w3;
      acc[2][0] += a2 * w0; acc[2][1] += a2 * w1; acc[2][2] += a2 * w2; acc[2][3] += a2 * w3;
      acc[3][0] += a3 * w0; acc[3][1] += a3 * w1; acc[3][2] += a3 * w2; acc[3][3] += a3 * w3;
    }
    __syncthreads();
  }
#pragma unroll
  for (int i = 0; i < 4; ++i)
#pragma unroll
    for (int j = 0; j < 4; ++j) {
      int cc = bn + c0 + j;
      if (cc < N) {
        float v = acc[i][j];
        if (bias) v += bias[cc];
        if (act == 1) v = (v > 20.f) ? v : log1pf(expf(v));
        C[(size_t)(bm + r0 + i) * ldc + cc] = f2bf(v);
      }
    }
}

// ---------------- causal depthwise conv (K=4) + SiLU (bf16 in/out) ----------
__global__ __launch_bounds__(256) void conv_silu_kernel(
    const ushort* __restrict__ u0, int ld, const float* __restrict__ Wconv,
    ushort* __restrict__ u)
{
  int idx = blockIdx.x * 256 + threadIdx.x;
  int d4 = idx & (DINNER / 4 - 1);
  int l = idx >> 9;
  int d0 = d4 * 4;
  float wt[4][4];
#pragma unroll
  for (int j = 0; j < 4; ++j) {
    float4 tv = *(const float4*)&Wconv[(d0 + j) * 4];
    wt[j][0] = tv.x; wt[j][1] = tv.y; wt[j][2] = tv.z; wt[j][3] = tv.w;
  }
  float a[4] = {0.f, 0.f, 0.f, 0.f};
#pragma unroll
  for (int k = 0; k < 4; ++k) {
    int ls = l - 3 + k;
    if (ls >= 0) {
      ushort4 uv = *(const ushort4*)&u0[(size_t)ls * ld + d0];
      a[0] += bf2f(uv.x) * wt[0][k];
      a[1] += bf2f(uv.y) * wt[1][k];
      a[2] += bf2f(uv.z) * wt[2][k];
      a[3] += bf2f(uv.w) * wt[3][k];
    }
  }
  float s0 = a[0] / (1.f + expf(-a[0]));
  float s1 = a[1] / (1.f + expf(-a[1]));
  float s2 = a[2] / (1.f + expf(-a[2]));
  float s3 = a[3] / (1.f + expf(-a[3]));
  ushort4 o = {f2bf(s0), f2bf(s1), f2bf(s2), f2bf(s3)};
  *(ushort4*)&u[(size_t)l * DINNER + d0] = o;
}

// ---------------- chunk-parallel selective scan (bf16 dt/u inputs) ----------
__global__ __launch_bounds__(256) void scan_pass1(
    const ushort* __restrict__ dt, const ushort* __restrict__ u,
    const float* __restrict__ bcdt, const float* __restrict__ logA,
    float* __restrict__ P, float* __restrict__ S)
{
  const int tid = threadIdx.x;
  const int n = tid & 15, dl = tid >> 4;
  const int dbase = blockIdx.x * 16;
  const int c = blockIdx.y;
  const int t0 = c * CLEN;
  const int d = dbase + dl;
  const float Aval = -expf(logA[d * DSTATE + n]);
  __shared__ float sdt[CLEN][16], su[CLEN][16], sB[CLEN][16];
  {
    int tt = tid >> 2, j0 = (tid & 3) * 4;
    ushort4 rd = *(const ushort4*)&dt[(size_t)(t0 + tt) * DINNER + dbase + j0];
    ushort4 ru = *(const ushort4*)&u[(size_t)(t0 + tt) * DINNER + dbase + j0];
    sdt[tt][j0 + 0] = bf2f(rd.x); sdt[tt][j0 + 1] = bf2f(rd.y);
    sdt[tt][j0 + 2] = bf2f(rd.z); sdt[tt][j0 + 3] = bf2f(rd.w);
    su[tt][j0 + 0] = bf2f(ru.x); su[tt][j0 + 1] = bf2f(ru.y);
    su[tt][j0 + 2] = bf2f(ru.z); su[tt][j0 + 3] = bf2f(ru.w);
    *(float4*)&sB[tt][j0] = *(const float4*)&bcdt[(size_t)(t0 + tt) * 96 + j0];
  }
  __syncthreads();
  float h = 0.f, pr = 1.f;
#pragma unroll 8
  for (int i = 0; i < CLEN; ++i) {
    float dtv = sdt[i][dl], uv = su[i][dl], Bv = sB[i][n];
    float dtA = dtv * Aval;
    float rinv = __builtin_amdgcn_rcpf(1.f - 0.5f * dtA);
    float dA = (1.f + 0.5f * dtA) * rinv;
    float dBu = dtv * Bv * rinv * uv;
    h = dA * h + dBu;
    pr *= dA;
  }
  size_t idx = (size_t)c * (DINNER * DSTATE) + (size_t)d * DSTATE + n;
  P[idx] = pr;
  S[idx] = h;
}

__global__ __launch_bounds__(256) void scan_pass2(
    const ushort* __restrict__ dt, const ushort* __restrict__ u,
    const float* __restrict__ bcdt, const float* __restrict__ logA,
    const float* __restrict__ Dp, const float* __restrict__ P,
    const float* __restrict__ S, const ushort* __restrict__ resu0,
    ushort* __restrict__ y2b)
{
  const int tid = threadIdx.x;
  const int n = tid & 15, dl = tid >> 4;
  const int dbase = blockIdx.x * 16;
  const int c = blockIdx.y;
  const int t0 = c * CLEN;
  const int d = dbase + dl;
  const float Aval = -expf(logA[d * DSTATE + n]);
  const float Dpv = Dp[d];
  __shared__ float sdt[CLEN][16], su[CLEN][16], sB[CLEN][16], sC[CLEN][16], sres[CLEN][16];
  {
    int tt = tid >> 2, j0 = (tid & 3) * 4;
    ushort4 rd = *(const ushort4*)&dt[(size_t)(t0 + tt) * DINNER + dbase + j0];
    ushort4 ru = *(const ushort4*)&u[(size_t)(t0 + tt) * DINNER + dbase + j0];
    ushort4 rr4 = *(const ushort4*)&resu0[(size_t)(t0 + tt) * (2 * DINNER) + dbase + j0];
    sdt[tt][j0 + 0] = bf2f(rd.x); sdt[tt][j0 + 1] = bf2f(rd.y);
    sdt[tt][j0 + 2] = bf2f(rd.z); sdt[tt][j0 + 3] = bf2f(rd.w);
    su[tt][j0 + 0] = bf2f(ru.x); su[tt][j0 + 1] = bf2f(ru.y);
    su[tt][j0 + 2] = bf2f(ru.z); su[tt][j0 + 3] = bf2f(ru.w);
    sres[tt][j0 + 0] = bf2f(rr4.x); sres[tt][j0 + 1] = bf2f(rr4.y);
    sres[tt][j0 + 2] = bf2f(rr4.z); sres[tt][j0 + 3] = bf2f(rr4.w);
    *(float4*)&sB[tt][j0] = *(const float4*)&bcdt[(size_t)(t0 + tt) * 96 + j0];
    *(float4*)&sC[tt][j0] = *(const float4*)&bcdt[(size_t)(t0 + tt) * 96 + 16 + j0];
  }
  float h = 0.f;
  {
    const size_t base = (size_t)d * DSTATE + n;
#pragma unroll 4
    for (int cc = 0; cc < c; ++cc) {
      size_t o = (size_t)cc * (DINNER * DSTATE) + base;
      h = P[o] * h + S[o];
    }
  }
  __syncthreads();
#pragma unroll 4
  for (int i = 0; i < CLEN; ++i) {
    float dtv = sdt[i][dl], uv = su[i][dl];
    float dtA = dtv * Aval;
    float rinv = __builtin_amdgcn_rcpf(1.f - 0.5f * dtA);
    float dA = (1.f + 0.5f * dtA) * rinv;
    float dBu = dtv * sB[i][n] * rinv * uv;
    h = dA * h + dBu;
    float p = h * sC[i][n];
    p += __shfl_xor(p, 1);
    p += __shfl_xor(p, 2);
    p += __shfl_xor(p, 4);
    p += __shfl_xor(p, 8);
    if (n == 0) {
      float rv = sres[i][dl];
      float yv = (p + uv * Dpv) * (rv / (1.f + expf(-rv)));
      y2b[(size_t)(t0 + i) * DINNER + d] = f2bf(yv);
    }
  }
}

// ---------------- f32 -> bf16 cast ------------------------------------------
__global__ __launch_bounds__(256) void cast_bf16_kernel(
    const float* __restrict__ in, ushort* __restrict__ out, size_t n4)
{
  size_t i = (size_t)blockIdx.x * 256 + threadIdx.x;
  if (i >= n4) return;
  float4 v = ((const float4*)in)[i];
  ushort4 o = {f2bf(v.x), f2bf(v.y), f2bf(v.z), f2bf(v.w)};
  ((ushort4*)out)[i] = o;
}

// ---------------- concat-cast Wres|Win -> bf16 [L][2*DINNER][DMODEL] --------
__global__ __launch_bounds__(256) void cast_cat2_kernel(
    const float* __restrict__ Wres, const float* __restrict__ Win, ushort* __restrict__ out)
{
  size_t i4 = (size_t)blockIdx.x * 256 + threadIdx.x;
  size_t e0 = i4 * 4;
  int k = (int)(e0 & (DMODEL - 1));
  int r = (int)((e0 >> 10) & (2 * DINNER - 1));
  int l = (int)(e0 >> 22);
  const float* src = (r < DINNER)
      ? &Wres[(((size_t)l * DINNER + r) << 10) + k]
      : &Win[(((size_t)l * DINNER + (r - DINNER)) << 10) + k];
  float4 v = *(const float4*)src;
  ushort4 o = {f2bf(v.x), f2bf(v.y), f2bf(v.z), f2bf(v.w)};
  ((ushort4*)out)[i4] = o;
}

// ---------------- concat WB|WC|Wdt1 -> [L][96][DINNER] ----------------------
__global__ __launch_bounds__(256) void concat_wbcdt_kernel(
    const float* __restrict__ WB, const float* __restrict__ WC,
    const float* __restrict__ Wdt1, float* __restrict__ out)
{
  size_t idx = (size_t)blockIdx.x * 256 + threadIdx.x;
  int k = idx & (DINNER - 1);
  size_t rl = idx >> 11;
  int row = (int)(rl % 96);
  int l = (int)(rl / 96);
  float v;
  if (row < 16)       v = WB[((size_t)l * DSTATE + row) * DINNER + k];
  else if (row < 32)  v = WC[((size_t)l * DSTATE + (row - 16)) * DINNER + k];
  else                v = Wdt1[((size_t)l * DTRANK + (row - 32)) * DINNER + k];
  out[idx] = v;
}

// ============================================================================
extern "C" void kernel_launch(void* const* d_in, const int* in_sizes, int n_in,
                              void* d_out, int out_size, void* d_ws, size_t ws_size,
                              hipStream_t stream) {
  (void)in_sizes; (void)n_in; (void)out_size;
  const int* token_ids = (const int*)d_in[0];
  const float* embed = (const float*)d_in[1];
  const float* Wres = (const float*)d_in[2];
  const float* Win = (const float*)d_in[3];
  const float* Wconv = (const float*)d_in[4];
  const float* WB = (const float*)d_in[5];
  const float* WC = (const float*)d_in[6];
  const float* Wdt1 = (const float*)d_in[7];
  const float* Wdt2 = (const float*)d_in[8];
  const float* bdt = (const float*)d_in[9];
  const float* logA = (const float*)d_in[10];
  const float* Dp = (const float*)d_in[11];
  const float* Wout = (const float*)d_in[12];
  float* out = (float*)d_out;

  char* w = (char*)d_ws;
  auto alloc = [&](size_t bytes) {
    char* p = w;
    w += (bytes + 255) & ~(size_t)255;
    return p;
  };
  ushort* eb    = (ushort*)alloc((size_t)VOCAB * DMODEL * 2);
  ushort* wcatb = (ushort*)alloc((size_t)NLAYER * 2 * DINNER * DMODEL * 2);
  ushort* woutb = (ushort*)alloc((size_t)NLAYER * DMODEL * DINNER * 2);
  float* wbcdt  = (float*)alloc((size_t)NLAYER * 96 * DINNER * 4);
  float* x      = (float*)alloc((size_t)SEQ * DMODEL * 4);
  ushort* xnb   = (ushort*)alloc((size_t)SEQ * DMODEL * 2);
  ushort* resu0 = (ushort*)alloc((size_t)SEQ * 2 * DINNER * 2);
  ushort* u     = (ushort*)alloc((size_t)SEQ * DINNER * 2);
  float* bcdt   = (float*)alloc((size_t)SEQ * 96 * 4);
  ushort* dt    = (ushort*)alloc((size_t)SEQ * DINNER * 2);
  float* Cp     = (float*)alloc((size_t)PROJ_NCH * SEQ * 96 * 4);
  float* Cp2    = (float*)alloc((size_t)2 * SEQ * DMODEL * 4);
  float* Pbuf   = (float*)alloc((size_t)NCHUNK * DINNER * DSTATE * 4);
  float* Sbuf   = (float*)alloc((size_t)NCHUNK * DINNER * DSTATE * 4);
  ushort* y2b   = (ushort*)alloc((size_t)SEQ * DINNER * 2);
  ushort* xb    = (ushort*)alloc((size_t)SEQ * DMODEL * 2);
  if ((size_t)(w - (char*)d_ws) > ws_size) return;

  // weight preprocessing
  cast_bf16_kernel<<<VOCAB * DMODEL / 4 / 256, 256, 0, stream>>>(embed, eb, (size_t)VOCAB * DMODEL / 4);
  cast_cat2_kernel<<<NLAYER * 2 * DINNER * DMODEL / 4 / 256, 256, 0, stream>>>(Wres, Win, wcatb);
  cast_bf16_kernel<<<NLAYER * DMODEL * DINNER / 4 / 256, 256, 0, stream>>>(Wout, woutb, (size_t)NLAYER * DMODEL * DINNER / 4);
  concat_wbcdt_kernel<<<NLAYER * 96 * DINNER / 256, 256, 0, stream>>>(WB, WC, Wdt1, wbcdt);
  gather_rms_kernel<<<SEQ, 256, 0, stream>>>(token_ids, embed, x, xnb);

  for (int i = 0; i < NLAYER; ++i) {
    const ushort* wcati = wcatb + (size_t)i * 2 * DINNER * DMODEL;
    const ushort* wouti = woutb + (size_t)i * DMODEL * DINNER;
    const float* wconvi = Wconv + (size_t)i * DINNER * 4;
    const float* wbcdti = wbcdt + (size_t)i * 96 * DINNER;
    const float* wdt2i = Wdt2 + (size_t)i * DINNER * DTRANK;
    const float* bdti = bdt + (size_t)i * DINNER;
    const float* logAi = logA + (size_t)i * DINNER * DSTATE;
    const float* Dpi = Dp + (size_t)i * DINNER;

    gemm2p_bt_bf16<true><<<dim3(SEQ / 128, 2 * DINNER / 128), 256, 0, stream>>>(
        xnb, wcati, resu0, 2 * DINNER, DMODEL);
    conv_silu_kernel<<<SEQ * DINNER / 4 / 256, 256, 0, stream>>>(resu0 + DINNER, 2 * DINNER, wconvi, u);
    projgemm_f32<<<dim3(SEQ / 64, PROJ_NCH), 256, 0, stream>>>(u, wbcdti, Cp, SEQ);
    proj_reduce<<<SEQ * 96 / 256, 256, 0, stream>>>(Cp, bcdt, SEQ);
    smallgemm_f32<<<dim3(SEQ / 64, DINNER / 64), 256, 0, stream>>>(
        bcdt + 32, 96, wdt2i, DTRANK, dt, DINNER, bdti, SEQ, DINNER, DTRANK, 1);
    dim3 gs(DINNER / 16, NCHUNK);
    scan_pass1<<<gs, 256, 0, stream>>>(dt, u, bcdt, logAi, Pbuf, Sbuf);
    scan_pass2<<<gs, 256, 0, stream>>>(dt, u, bcdt, logAi, Dpi, Pbuf, Sbuf, resu0, y2b);
    gemm_btk_bf16<<<dim3(SEQ / 128, DMODEL / 128, 2), 256, 0, stream>>>(
        y2b, wouti, Cp2, SEQ, DMODEL, DINNER);
    add3_rms_kernel<<<SEQ, 256, 0, stream>>>(
        Cp2, Cp2 + (size_t)SEQ * DMODEL, x,
        (i < NLAYER - 1) ? xnb : xb, (i < NLAYER - 1) ? 1 : 0);
  }
  gemm8p_bt_bf16<256, true><<<dim3(SEQ / 256, VOCAB / 256), 512, 0, stream>>>(
      xb, eb, out, VOCAB, DMODEL);
}

// Round 14
// 2114.814 us; speedup vs baseline: 1.4243x; 1.0394x over previous
//
#include <hip/hip_runtime.h>

#define SEQ 2048
#define DMODEL 1024
#define DINNER 2048
#define DSTATE 16
#define DTRANK 64
#define NLAYER 8
#define VOCAB 32000
#define NCHUNK 32
#define CLEN 64   // SEQ / NCHUNK
#define PZ 16     // split-K chunks for the projection GEMM

typedef float f32x4 __attribute__((ext_vector_type(4)));
typedef short bf16x8 __attribute__((ext_vector_type(8)));

__device__ __forceinline__ ushort f2bf(float f) {
  union { float f; unsigned u; } v; v.f = f;
  unsigned r = v.u + 0x7fffu + ((v.u >> 16) & 1u);
  return (ushort)(r >> 16);
}
__device__ __forceinline__ float bf2f(ushort b) {
  union { unsigned u; float f; } v; v.u = ((unsigned)b) << 16;
  return v.f;
}

__device__ __forceinline__ void lds_load16(const void* g, void* l) {
  __builtin_amdgcn_global_load_lds(
      (const __attribute__((address_space(1))) void*)g,
      (__attribute__((address_space(3))) void*)l, 16, 0, 0);
}

// ---------------- 256x256 counted-vmcnt MFMA GEMM (proven ~197us logits) ----
template<int BM, bool NTS>
__global__ __launch_bounds__(512, 2) void gemm8p_bt_bf16(
    const ushort* __restrict__ A, const ushort* __restrict__ B,
    float* __restrict__ C, int N, int K)
{
  constexpr int MFR = BM / 32;
  constexpr int MPP = MFR / 4;
  constexpr int ALOADS = BM / 128;
  __shared__ __align__(16) ushort As[2 * BM * 64];
  __shared__ __align__(16) ushort Bs[2 * 256 * 64];
  const int tid = threadIdx.x;
  const int lane = tid & 63;
  const int wid = tid >> 6;
  const int wr = wid >> 2, wc = wid & 3;
  const int rr = lane & 15, kq = lane >> 4;

  unsigned nwg = gridDim.x * gridDim.y;
  unsigned lb = blockIdx.y * gridDim.x + blockIdx.x;
  if ((nwg & 7u) == 0u) { unsigned cpx = nwg >> 3; lb = (lb & 7u) * cpx + (lb >> 3); }
  const int bm = (int)(lb % gridDim.x) * BM;
  const int bn = (int)(lb / gridDim.x) * 256;

  const ushort* Abase = A + (size_t)bm * K;
  const ushort* Bbase = B + (size_t)bn * K;

  auto stageA = [&](int buf, int h, int kt) {
    constexpr int HR = BM / 2;
#pragma unroll
    for (int L = 0; L < ALOADS; ++L) {
      int f = L * 512 + tid;
      int rl = f >> 3, g = f & 7;
      int gg = g ^ (rl & 7);
      lds_load16(Abase + (size_t)(h * HR + rl) * K + kt * 64 + gg * 8,
                 (void*)(As + buf * (BM * 64) + (h * HR + rl) * 64 + g * 8));
    }
  };
  auto stageB = [&](int buf, int h, int kt) {
#pragma unroll
    for (int L = 0; L < 2; ++L) {
      int f = L * 512 + tid;
      int rl = f >> 3, g = f & 7;
      int gg = g ^ (rl & 7);
      lds_load16(Bbase + (size_t)(h * 128 + rl) * K + kt * 64 + gg * 8,
                 (void*)(Bs + buf * (256 * 64) + (h * 128 + rl) * 64 + g * 8));
    }
  };
  auto rdA = [&](int buf, int r, int kbyte) {
    int sw = kbyte ^ ((r & 7) << 4);
    return *(const bf16x8*)(As + buf * (BM * 64) + r * 64 + (sw >> 1));
  };
  auto rdB = [&](int buf, int r, int kbyte) {
    int sw = kbyte ^ ((r & 7) << 4);
    return *(const bf16x8*)(Bs + buf * (256 * 64) + r * 64 + (sw >> 1));
  };

  f32x4 acc[MFR][4];
#pragma unroll
  for (int m = 0; m < MFR; ++m)
#pragma unroll
    for (int n = 0; n < 4; ++n) acc[m][n] = (f32x4){0.f, 0.f, 0.f, 0.f};

  const int NT = K >> 6;
  stageA(0, 0, 0); stageA(0, 1, 0); stageB(0, 0, 0); stageB(0, 1, 0);

  for (int t = 0; t < NT; ++t) {
    const int cur = t & 1;
    const bool more = (t + 1 < NT);
    if (more) stageA(cur ^ 1, 0, t + 1);
    if (more) {
      if constexpr (BM == 256) asm volatile("s_waitcnt vmcnt(2)" ::: "memory");
      else                     asm volatile("s_waitcnt vmcnt(1)" ::: "memory");
    } else {
      asm volatile("s_waitcnt vmcnt(0)" ::: "memory");
    }
    __syncthreads();

    bf16x8 bfr[4][2];
#pragma unroll
    for (int n = 0; n < 4; ++n)
#pragma unroll
      for (int kk = 0; kk < 2; ++kk)
        bfr[n][kk] = rdB(cur, wc * 64 + n * 16 + rr, kk * 64 + kq * 16);

#pragma unroll
    for (int mq = 0; mq < 4; ++mq) {
      if (mq == 1 && more) stageA(cur ^ 1, 1, t + 1);
      if (mq == 2 && more) stageB(cur ^ 1, 0, t + 1);
      if (mq == 3 && more) stageB(cur ^ 1, 1, t + 1);
      bf16x8 af[MPP][2];
#pragma unroll
      for (int mf = 0; mf < MPP; ++mf)
#pragma unroll
        for (int kk = 0; kk < 2; ++kk)
          af[mf][kk] = rdA(cur, wr * (BM / 2) + (mq * MPP + mf) * 16 + rr, kk * 64 + kq * 16);
      __builtin_amdgcn_s_setprio(1);
#pragma unroll
      for (int kk = 0; kk < 2; ++kk)
#pragma unroll
        for (int mf = 0; mf < MPP; ++mf)
#pragma unroll
          for (int n = 0; n < 4; ++n)
            acc[mq * MPP + mf][n] = __builtin_amdgcn_mfma_f32_16x16x32_bf16(
                af[mf][kk], bfr[n][kk], acc[mq * MPP + mf][n], 0, 0, 0);
      __builtin_amdgcn_s_setprio(0);
    }
    __syncthreads();
  }

  float* ep = (float*)Bs + wid * (16 * 68);
  const int cg = bn + wc * 64;
#pragma unroll
  for (int m = 0; m < MFR; ++m) {
    const int r0g = bm + wr * (BM / 2) + m * 16;
#pragma unroll
    for (int n = 0; n < 4; ++n)
#pragma unroll
      for (int j = 0; j < 4; ++j)
        ep[(kq * 4 + j) * 68 + n * 16 + rr] = acc[m][n][j];
#pragma unroll
    for (int i = 0; i < 4; ++i) {
      int row = i * 4 + kq;
      f32x4 v = *(const f32x4*)&ep[row * 68 + rr * 4];
      f32x4* dst = (f32x4*)&C[(size_t)(r0g + row) * N + cg + rr * 4];
      if constexpr (NTS) __builtin_nontemporal_store(v, dst);
      else *dst = v;
    }
  }
}

// ---------------- 128x128 2-blocks/CU MFMA GEMM (layer gemm1) ---------------
// OUTBF: epilogue converts to bf16 (ushort4 stores) — used for resu0.
template<bool OUTBF>
__global__ __launch_bounds__(256, 2) void gemm2p_bt_bf16(
    const ushort* __restrict__ A, const ushort* __restrict__ B,
    void* __restrict__ Cv, int N, int K)
{
  __shared__ __align__(16) ushort As[2 * 128 * 64];
  __shared__ __align__(16) ushort Bs[2 * 128 * 64];
  const int tid = threadIdx.x;
  const int lane = tid & 63;
  const int wave = tid >> 6;
  const int wr = wave >> 1, wc = wave & 1;
  const int rr = lane & 15, kq = lane >> 4;

  unsigned nwg = gridDim.x * gridDim.y;
  unsigned lb = blockIdx.y * gridDim.x + blockIdx.x;
  if ((nwg & 7u) == 0u) { unsigned cpx = nwg >> 3; lb = (lb & 7u) * cpx + (lb >> 3); }
  const int bm = (int)(lb % gridDim.x) * 128;
  const int bn = (int)(lb / gridDim.x) * 128;

  const ushort* Abase = A + (size_t)bm * K;
  const ushort* Bbase = B + (size_t)bn * K;

  auto stage = [&](int buf, int kt) {
#pragma unroll
    for (int i = 0; i < 4; ++i) {
      int f = i * 256 + tid;
      int rl = f >> 3, g = f & 7;
      int gg = g ^ (rl & 7);
      lds_load16(Abase + (size_t)rl * K + kt * 64 + gg * 8,
                 (void*)(As + buf * 8192 + rl * 64 + g * 8));
      lds_load16(Bbase + (size_t)rl * K + kt * 64 + gg * 8,
                 (void*)(Bs + buf * 8192 + rl * 64 + g * 8));
    }
  };
  auto rdA = [&](int buf, int r, int kbyte) {
    int sw = kbyte ^ ((r & 7) << 4);
    return *(const bf16x8*)(As + buf * 8192 + r * 64 + (sw >> 1));
  };
  auto rdB = [&](int buf, int r, int kbyte) {
    int sw = kbyte ^ ((r & 7) << 4);
    return *(const bf16x8*)(Bs + buf * 8192 + r * 64 + (sw >> 1));
  };

  f32x4 acc[4][4];
#pragma unroll
  for (int m = 0; m < 4; ++m)
#pragma unroll
    for (int n = 0; n < 4; ++n) acc[m][n] = (f32x4){0.f, 0.f, 0.f, 0.f};

  const int NT = K >> 6;
  stage(0, 0);

  for (int t = 0; t < NT; ++t) {
    const int cur = t & 1;
    if (t + 1 < NT) {
      stage(cur ^ 1, t + 1);
      asm volatile("s_waitcnt vmcnt(8)" ::: "memory");
    } else {
      asm volatile("s_waitcnt vmcnt(0)" ::: "memory");
    }
    __syncthreads();
#pragma unroll
    for (int ks = 0; ks < 2; ++ks) {
      const int kbyte = ks * 64 + kq * 16;
      bf16x8 af[4], bfr[4];
#pragma unroll
      for (int m = 0; m < 4; ++m)
        af[m] = rdA(cur, wr * 64 + m * 16 + rr, kbyte);
#pragma unroll
      for (int n = 0; n < 4; ++n)
        bfr[n] = rdB(cur, wc * 64 + n * 16 + rr, kbyte);
      __builtin_amdgcn_s_setprio(1);
#pragma unroll
      for (int m = 0; m < 4; ++m)
#pragma unroll
        for (int n = 0; n < 4; ++n)
          acc[m][n] = __builtin_amdgcn_mfma_f32_16x16x32_bf16(af[m], bfr[n], acc[m][n], 0, 0, 0);
      __builtin_amdgcn_s_setprio(0);
    }
    __syncthreads();
  }

  float* ep = (float*)Bs + wave * (16 * 68);
  const int cg = bn + wc * 64;
#pragma unroll
  for (int m = 0; m < 4; ++m) {
    const int r0g = bm + wr * 64 + m * 16;
#pragma unroll
    for (int n = 0; n < 4; ++n)
#pragma unroll
      for (int j = 0; j < 4; ++j)
        ep[(kq * 4 + j) * 68 + n * 16 + rr] = acc[m][n][j];
#pragma unroll
    for (int i = 0; i < 4; ++i) {
      int row = i * 4 + kq;
      f32x4 v = *(const f32x4*)&ep[row * 68 + rr * 4];
      if constexpr (OUTBF) {
        ushort* C = (ushort*)Cv;
        ushort4 o = {f2bf(v.x), f2bf(v.y), f2bf(v.z), f2bf(v.w)};
        *(ushort4*)&C[(size_t)(r0g + row) * N + cg + rr * 4] = o;
      } else {
        float* C = (float*)Cv;
        *(f32x4*)&C[(size_t)(r0g + row) * N + cg + rr * 4] = v;
      }
    }
  }
}

// ---------------- split-K bf16 MFMA GEMM (2-phase 128x128) ------------------
// K chunk count = gridDim.z; writes partials Cp[z][M][N].
__global__ __launch_bounds__(256) void gemm_btk_bf16(
    const ushort* __restrict__ A, const ushort* __restrict__ B,
    float* __restrict__ Cp, int M, int N, int K)
{
  __shared__ __align__(16) ushort As[128 * 64];
  __shared__ __align__(16) ushort Bs[128 * 64];
  const int tid = threadIdx.x;
  const int lane = tid & 63;
  const int wave = tid >> 6;
  const int wr = wave >> 1, wc = wave & 1;
  const int KC = K / gridDim.z;
  const int k0 = blockIdx.z * KC;

  unsigned nwg = gridDim.x * gridDim.y;
  unsigned lb = blockIdx.y * gridDim.x + blockIdx.x;
  if ((nwg & 7u) == 0u) {
    unsigned cpx = nwg >> 3;
    lb = (lb & 7u) * cpx + (lb >> 3);
  }
  const int bm = (lb % gridDim.x) * 128;
  const int bn = (lb / gridDim.x) * 128;
  const int rr = lane & 15, kq = lane >> 4;

  f32x4 acc[4][4];
#pragma unroll
  for (int m = 0; m < 4; ++m)
#pragma unroll
    for (int n = 0; n < 4; ++n) acc[m][n] = (f32x4){0.f, 0.f, 0.f, 0.f};

  for (int kt = 0; kt < KC; kt += 64) {
#pragma unroll
    for (int i = 0; i < 4; ++i) {
      int fb = i * 256 + tid;
      int row = fb >> 3, cb = fb & 7;
      lds_load16(A + (size_t)(bm + row) * K + k0 + kt + cb * 8, (void*)(As + (size_t)fb * 8));
      lds_load16(B + (size_t)(bn + row) * K + k0 + kt + cb * 8, (void*)(Bs + (size_t)fb * 8));
    }
    __syncthreads();
#pragma unroll
    for (int ks = 0; ks < 2; ++ks) {
      bf16x8 af[4], bfr[4];
      const int koff = ks * 32 + kq * 8;
#pragma unroll
      for (int m = 0; m < 4; ++m)
        af[m] = *(const bf16x8*)&As[(wr * 64 + m * 16 + rr) * 64 + koff];
#pragma unroll
      for (int n = 0; n < 4; ++n)
        bfr[n] = *(const bf16x8*)&Bs[(wc * 64 + n * 16 + rr) * 64 + koff];
#pragma unroll
      for (int m = 0; m < 4; ++m)
#pragma unroll
        for (int n = 0; n < 4; ++n)
          acc[m][n] = __builtin_amdgcn_mfma_f32_16x16x32_bf16(af[m], bfr[n], acc[m][n], 0, 0, 0);
    }
    __syncthreads();
  }
  float* C = Cp + (size_t)blockIdx.z * M * N;
#pragma unroll
  for (int m = 0; m < 4; ++m) {
    const int r0 = bm + wr * 64 + m * 16 + kq * 4;
#pragma unroll
    for (int n = 0; n < 4; ++n) {
      const int cc = bn + wc * 64 + n * 16 + rr;
#pragma unroll
      for (int j = 0; j < 4; ++j)
        C[(size_t)(r0 + j) * N + cc] = acc[m][n][j];
    }
  }
}

// ---------------- x += P0 + P1, then RMSNorm(x)->bf16 (or plain cast) -------
__global__ __launch_bounds__(256) void add3_rms_kernel(
    const float* __restrict__ P0, const float* __restrict__ P1,
    float* __restrict__ x, ushort* __restrict__ dst, int donorm)
{
  size_t o = (size_t)blockIdx.x * (DMODEL / 4) + threadIdx.x;
  float4 a = ((const float4*)P0)[o];
  float4 b = ((const float4*)P1)[o];
  float4 c = ((float4*)x)[o];
  c.x += a.x + b.x; c.y += a.y + b.y; c.z += a.z + b.z; c.w += a.w + b.w;
  ((float4*)x)[o] = c;
  float sc = 1.f;
  if (donorm) {
    float s = c.x * c.x + c.y * c.y + c.z * c.z + c.w * c.w;
#pragma unroll
    for (int off = 32; off > 0; off >>= 1) s += __shfl_down(s, off);
    __shared__ float ws[4];
    if ((threadIdx.x & 63) == 0) ws[threadIdx.x >> 6] = s;
    __syncthreads();
    float tot = ws[0] + ws[1] + ws[2] + ws[3];
    sc = rsqrtf(tot * (1.0f / DMODEL) + 1e-6f);
  }
  ushort4 o4 = {f2bf(c.x * sc), f2bf(c.y * sc), f2bf(c.z * sc), f2bf(c.w * sc)};
  ((ushort4*)dst)[o] = o4;
}

// ---------------- embedding gather + RMSNorm -> x (f32) and xnb (bf16) ------
__global__ __launch_bounds__(256) void gather_rms_kernel(
    const int* __restrict__ ids, const float* __restrict__ embed,
    float* __restrict__ x, ushort* __restrict__ xnb)
{
  int row = blockIdx.x;
  int id = ids[row];
  float4 v = ((const float4*)(embed + (size_t)id * DMODEL))[threadIdx.x];
  size_t o = (size_t)row * (DMODEL / 4) + threadIdx.x;
  ((float4*)x)[o] = v;
  float s = v.x * v.x + v.y * v.y + v.z * v.z + v.w * v.w;
#pragma unroll
  for (int off = 32; off > 0; off >>= 1) s += __shfl_down(s, off);
  __shared__ float ws[4];
  if ((threadIdx.x & 63) == 0) ws[threadIdx.x >> 6] = s;
  __syncthreads();
  float tot = ws[0] + ws[1] + ws[2] + ws[3];
  float sc = rsqrtf(tot * (1.0f / DMODEL) + 1e-6f);
  ushort4 o4 = {f2bf(v.x * sc), f2bf(v.y * sc), f2bf(v.z * sc), f2bf(v.w * sc)};
  ((ushort4*)xnb)[o] = o4;
}

// ---------------- proj reduce: bcdt[M][96] = sum_z Cp[z][M][128][:96] -------
__global__ __launch_bounds__(256) void proj_reduce(
    const float* __restrict__ Cp, float* __restrict__ bcdt, int M)
{
  int idx = blockIdx.x * 256 + threadIdx.x;  // over M*96
  int row = idx / 96, col = idx - row * 96;
  float s = 0.f;
#pragma unroll
  for (int c = 0; c < PZ; ++c) s += Cp[(size_t)c * M * 128 + (size_t)row * 128 + col];
  bcdt[idx] = s;
}

// ---------------- f32 small GEMM -> bf16 out (dt path only) -----------------
__global__ __launch_bounds__(256) void smallgemm_f32(
    const float* __restrict__ A, int lda,
    const float* __restrict__ W, int ldw,
    ushort* __restrict__ C, int ldc,
    const float* __restrict__ bias,
    int M, int N, int K, int act)
{
  __shared__ float As[64][65];
  __shared__ float Ws[64][65];
  const int t = threadIdx.x;
  const int bm = blockIdx.x * 64, bn = blockIdx.y * 64;
  const int r0 = (t >> 4) * 4;
  const int c0 = (t & 15) * 4;
  float acc[4][4] = {};

  for (int kt = 0; kt < K; kt += 64) {
#pragma unroll
    for (int i = 0; i < 16; ++i) {
      int idx = i * 256 + t;
      int r = idx >> 6, c = idx & 63;
      As[r][c] = A[(size_t)(bm + r) * lda + kt + c];
      int wrow = bn + r;
      Ws[r][c] = (wrow < N) ? W[(size_t)wrow * ldw + kt + c] : 0.f;
    }
    __syncthreads();
#pragma unroll 8
    for (int kk = 0; kk < 64; ++kk) {
      float a0 = As[r0][kk], a1 = As[r0 + 1][kk], a2 = As[r0 + 2][kk], a3 = As[r0 + 3][kk];
      float w0 = Ws[c0][kk], w1 = Ws[c0 + 1][kk], w2 = Ws[c0 + 2][kk], w3 = Ws[c0 + 3][kk];
      acc[0][0] += a0 * w0; acc[0][1] += a0 * w1; acc[0][2] += a0 * w2; acc[0][3] += a0 * w3;
      acc[1][0] += a1 * w0; acc[1][1] += a1 * w1; acc[1][2] += a1 * w2; acc[1][3] += a1 * w3;
      acc[2][0] += a2 * w0; acc[2][1] += a2 * w1; acc[2][2] += a2 * w2; acc[2][3] += a2 * w3;
      acc[3][0] += a3 * w0; acc[3][1] += a3 * w1; acc[3][2] += a3 * w2; acc[3][3] += a3 * w3;
    }
    __syncthreads();
  }
#pragma unroll
  for (int i = 0; i < 4; ++i)
#pragma unroll
    for (int j = 0; j < 4; ++j) {
      int cc = bn + c0 + j;
      if (cc < N) {
        float v = acc[i][j];
        if (bias) v += bias[cc];
        if (act == 1) v = (v > 20.f) ? v : log1pf(expf(v));
        C[(size_t)(bm + r0 + i) * ldc + cc] = f2bf(v);
      }
    }
}

// ---------------- causal depthwise conv (K=4) + SiLU (bf16 in/out) ----------
__global__ __launch_bounds__(256) void conv_silu_kernel(
    const ushort* __restrict__ u0, int ld, const float* __restrict__ Wconv,
    ushort* __restrict__ u)
{
  int idx = blockIdx.x * 256 + threadIdx.x;
  int d4 = idx & (DINNER / 4 - 1);
  int l = idx >> 9;
  int d0 = d4 * 4;
  float wt[4][4];
#pragma unroll
  for (int j = 0; j < 4; ++j) {
    float4 tv = *(const float4*)&Wconv[(d0 + j) * 4];
    wt[j][0] = tv.x; wt[j][1] = tv.y; wt[j][2] = tv.z; wt[j][3] = tv.w;
  }
  float a[4] = {0.f, 0.f, 0.f, 0.f};
#pragma unroll
  for (int k = 0; k < 4; ++k) {
    int ls = l - 3 + k;
    if (ls >= 0) {
      ushort4 uv = *(const ushort4*)&u0[(size_t)ls * ld + d0];
      a[0] += bf2f(uv.x) * wt[0][k];
      a[1] += bf2f(uv.y) * wt[1][k];
      a[2] += bf2f(uv.z) * wt[2][k];
      a[3] += bf2f(uv.w) * wt[3][k];
    }
  }
  float s0 = a[0] / (1.f + expf(-a[0]));
  float s1 = a[1] / (1.f + expf(-a[1]));
  float s2 = a[2] / (1.f + expf(-a[2]));
  float s3 = a[3] / (1.f + expf(-a[3]));
  ushort4 o = {f2bf(s0), f2bf(s1), f2bf(s2), f2bf(s3)};
  *(ushort4*)&u[(size_t)l * DINNER + d0] = o;
}

// ---------------- chunk-parallel selective scan (bf16 dt/u inputs) ----------
__global__ __launch_bounds__(256) void scan_pass1(
    const ushort* __restrict__ dt, const ushort* __restrict__ u,
    const float* __restrict__ bcdt, const float* __restrict__ logA,
    float* __restrict__ P, float* __restrict__ S)
{
  const int tid = threadIdx.x;
  const int n = tid & 15, dl = tid >> 4;
  const int dbase = blockIdx.x * 16;
  const int c = blockIdx.y;
  const int t0 = c * CLEN;
  const int d = dbase + dl;
  const float Aval = -expf(logA[d * DSTATE + n]);
  __shared__ float sdt[CLEN][16], su[CLEN][16], sB[CLEN][16];
  {
    int tt = tid >> 2, j0 = (tid & 3) * 4;
    ushort4 rd = *(const ushort4*)&dt[(size_t)(t0 + tt) * DINNER + dbase + j0];
    ushort4 ru = *(const ushort4*)&u[(size_t)(t0 + tt) * DINNER + dbase + j0];
    sdt[tt][j0 + 0] = bf2f(rd.x); sdt[tt][j0 + 1] = bf2f(rd.y);
    sdt[tt][j0 + 2] = bf2f(rd.z); sdt[tt][j0 + 3] = bf2f(rd.w);
    su[tt][j0 + 0] = bf2f(ru.x); su[tt][j0 + 1] = bf2f(ru.y);
    su[tt][j0 + 2] = bf2f(ru.z); su[tt][j0 + 3] = bf2f(ru.w);
    *(float4*)&sB[tt][j0] = *(const float4*)&bcdt[(size_t)(t0 + tt) * 96 + j0];
  }
  __syncthreads();
  float h = 0.f, pr = 1.f;
#pragma unroll 8
  for (int i = 0; i < CLEN; ++i) {
    float dtv = sdt[i][dl], uv = su[i][dl], Bv = sB[i][n];
    float dtA = dtv * Aval;
    float rinv = __builtin_amdgcn_rcpf(1.f - 0.5f * dtA);
    float dA = (1.f + 0.5f * dtA) * rinv;
    float dBu = dtv * Bv * rinv * uv;
    h = dA * h + dBu;
    pr *= dA;
  }
  size_t idx = (size_t)c * (DINNER * DSTATE) + (size_t)d * DSTATE + n;
  P[idx] = pr;
  S[idx] = h;
}

__global__ __launch_bounds__(256) void scan_pass2(
    const ushort* __restrict__ dt, const ushort* __restrict__ u,
    const float* __restrict__ bcdt, const float* __restrict__ logA,
    const float* __restrict__ Dp, const float* __restrict__ P,
    const float* __restrict__ S, const ushort* __restrict__ resu0,
    ushort* __restrict__ y2b)
{
  const int tid = threadIdx.x;
  const int n = tid & 15, dl = tid >> 4;
  const int dbase = blockIdx.x * 16;
  const int c = blockIdx.y;
  const int t0 = c * CLEN;
  const int d = dbase + dl;
  const float Aval = -expf(logA[d * DSTATE + n]);
  const float Dpv = Dp[d];
  __shared__ float sdt[CLEN][16], su[CLEN][16], sB[CLEN][16], sC[CLEN][16], sres[CLEN][16];
  {
    int tt = tid >> 2, j0 = (tid & 3) * 4;
    ushort4 rd = *(const ushort4*)&dt[(size_t)(t0 + tt) * DINNER + dbase + j0];
    ushort4 ru = *(const ushort4*)&u[(size_t)(t0 + tt) * DINNER + dbase + j0];
    ushort4 rr4 = *(const ushort4*)&resu0[(size_t)(t0 + tt) * (2 * DINNER) + dbase + j0];
    sdt[tt][j0 + 0] = bf2f(rd.x); sdt[tt][j0 + 1] = bf2f(rd.y);
    sdt[tt][j0 + 2] = bf2f(rd.z); sdt[tt][j0 + 3] = bf2f(rd.w);
    su[tt][j0 + 0] = bf2f(ru.x); su[tt][j0 + 1] = bf2f(ru.y);
    su[tt][j0 + 2] = bf2f(ru.z); su[tt][j0 + 3] = bf2f(ru.w);
    sres[tt][j0 + 0] = bf2f(rr4.x); sres[tt][j0 + 1] = bf2f(rr4.y);
    sres[tt][j0 + 2] = bf2f(rr4.z); sres[tt][j0 + 3] = bf2f(rr4.w);
    *(float4*)&sB[tt][j0] = *(const float4*)&bcdt[(size_t)(t0 + tt) * 96 + j0];
    *(float4*)&sC[tt][j0] = *(const float4*)&bcdt[(size_t)(t0 + tt) * 96 + 16 + j0];
  }
  float h = 0.f;
  {
    const size_t base = (size_t)d * DSTATE + n;
#pragma unroll 4
    for (int cc = 0; cc < c; ++cc) {
      size_t o = (size_t)cc * (DINNER * DSTATE) + base;
      h = P[o] * h + S[o];
    }
  }
  __syncthreads();
#pragma unroll 4
  for (int i = 0; i < CLEN; ++i) {
    float dtv = sdt[i][dl], uv = su[i][dl];
    float dtA = dtv * Aval;
    float rinv = __builtin_amdgcn_rcpf(1.f - 0.5f * dtA);
    float dA = (1.f + 0.5f * dtA) * rinv;
    float dBu = dtv * sB[i][n] * rinv * uv;
    h = dA * h + dBu;
    float p = h * sC[i][n];
    p += __shfl_xor(p, 1);
    p += __shfl_xor(p, 2);
    p += __shfl_xor(p, 4);
    p += __shfl_xor(p, 8);
    if (n == 0) {
      float rv = sres[i][dl];
      float yv = (p + uv * Dpv) * (rv / (1.f + expf(-rv)));
      y2b[(size_t)(t0 + i) * DINNER + d] = f2bf(yv);
    }
  }
}

// ---------------- f32 -> bf16 cast ------------------------------------------
__global__ __launch_bounds__(256) void cast_bf16_kernel(
    const float* __restrict__ in, ushort* __restrict__ out, size_t n4)
{
  size_t i = (size_t)blockIdx.x * 256 + threadIdx.x;
  if (i >= n4) return;
  float4 v = ((const float4*)in)[i];
  ushort4 o = {f2bf(v.x), f2bf(v.y), f2bf(v.z), f2bf(v.w)};
  ((ushort4*)out)[i] = o;
}

// ---------------- concat-cast Wres|Win -> bf16 [L][2*DINNER][DMODEL] --------
__global__ __launch_bounds__(256) void cast_cat2_kernel(
    const float* __restrict__ Wres, const float* __restrict__ Win, ushort* __restrict__ out)
{
  size_t i4 = (size_t)blockIdx.x * 256 + threadIdx.x;
  size_t e0 = i4 * 4;
  int k = (int)(e0 & (DMODEL - 1));
  int r = (int)((e0 >> 10) & (2 * DINNER - 1));
  int l = (int)(e0 >> 22);
  const float* src = (r < DINNER)
      ? &Wres[(((size_t)l * DINNER + r) << 10) + k]
      : &Win[(((size_t)l * DINNER + (r - DINNER)) << 10) + k];
  float4 v = *(const float4*)src;
  ushort4 o = {f2bf(v.x), f2bf(v.y), f2bf(v.z), f2bf(v.w)};
  ((ushort4*)out)[i4] = o;
}

// ---------------- concat-cast WB|WC|Wdt1 -> bf16 [L][128][DINNER] (pad 0) ---
__global__ __launch_bounds__(256) void concat_wbcdt_bf16_kernel(
    const float* __restrict__ WB, const float* __restrict__ WC,
    const float* __restrict__ Wdt1, ushort* __restrict__ out)
{
  size_t i4 = (size_t)blockIdx.x * 256 + threadIdx.x;  // over L*128*DINNER/4
  int k4 = (int)(i4 & (DINNER / 4 - 1));
  int row = (int)((i4 >> 9) & 127);
  int l = (int)(i4 >> 16);
  int k = k4 * 4;
  float4 v = {0.f, 0.f, 0.f, 0.f};
  if (row < 16)       v = *(const float4*)&WB[((size_t)l * DSTATE + row) * DINNER + k];
  else if (row < 32)  v = *(const float4*)&WC[((size_t)l * DSTATE + (row - 16)) * DINNER + k];
  else if (row < 96)  v = *(const float4*)&Wdt1[((size_t)l * DTRANK + (row - 32)) * DINNER + k];
  ushort4 o = {f2bf(v.x), f2bf(v.y), f2bf(v.z), f2bf(v.w)};
  ((ushort4*)out)[i4] = o;
}

// ============================================================================
extern "C" void kernel_launch(void* const* d_in, const int* in_sizes, int n_in,
                              void* d_out, int out_size, void* d_ws, size_t ws_size,
                              hipStream_t stream) {
  (void)in_sizes; (void)n_in; (void)out_size;
  const int* token_ids = (const int*)d_in[0];
  const float* embed = (const float*)d_in[1];
  const float* Wres = (const float*)d_in[2];
  const float* Win = (const float*)d_in[3];
  const float* Wconv = (const float*)d_in[4];
  const float* WB = (const float*)d_in[5];
  const float* WC = (const float*)d_in[6];
  const float* Wdt1 = (const float*)d_in[7];
  const float* Wdt2 = (const float*)d_in[8];
  const float* bdt = (const float*)d_in[9];
  const float* logA = (const float*)d_in[10];
  const float* Dp = (const float*)d_in[11];
  const float* Wout = (const float*)d_in[12];
  float* out = (float*)d_out;

  char* w = (char*)d_ws;
  auto alloc = [&](size_t bytes) {
    char* p = w;
    w += (bytes + 255) & ~(size_t)255;
    return p;
  };
  ushort* eb     = (ushort*)alloc((size_t)VOCAB * DMODEL * 2);
  ushort* wcatb  = (ushort*)alloc((size_t)NLAYER * 2 * DINNER * DMODEL * 2);
  ushort* woutb  = (ushort*)alloc((size_t)NLAYER * DMODEL * DINNER * 2);
  ushort* wbcdtb = (ushort*)alloc((size_t)NLAYER * 128 * DINNER * 2);
  float* x       = (float*)alloc((size_t)SEQ * DMODEL * 4);
  ushort* xnb    = (ushort*)alloc((size_t)SEQ * DMODEL * 2);
  ushort* resu0  = (ushort*)alloc((size_t)SEQ * 2 * DINNER * 2);
  ushort* u      = (ushort*)alloc((size_t)SEQ * DINNER * 2);
  float* bcdt    = (float*)alloc((size_t)SEQ * 96 * 4);
  ushort* dt     = (ushort*)alloc((size_t)SEQ * DINNER * 2);
  float* Cp      = (float*)alloc((size_t)PZ * SEQ * 128 * 4);
  float* Cp2     = (float*)alloc((size_t)2 * SEQ * DMODEL * 4);
  float* Pbuf    = (float*)alloc((size_t)NCHUNK * DINNER * DSTATE * 4);
  float* Sbuf    = (float*)alloc((size_t)NCHUNK * DINNER * DSTATE * 4);
  ushort* y2b    = (ushort*)alloc((size_t)SEQ * DINNER * 2);
  ushort* xb     = (ushort*)alloc((size_t)SEQ * DMODEL * 2);
  if ((size_t)(w - (char*)d_ws) > ws_size) return;

  // weight preprocessing
  cast_bf16_kernel<<<VOCAB * DMODEL / 4 / 256, 256, 0, stream>>>(embed, eb, (size_t)VOCAB * DMODEL / 4);
  cast_cat2_kernel<<<NLAYER * 2 * DINNER * DMODEL / 4 / 256, 256, 0, stream>>>(Wres, Win, wcatb);
  cast_bf16_kernel<<<NLAYER * DMODEL * DINNER / 4 / 256, 256, 0, stream>>>(Wout, woutb, (size_t)NLAYER * DMODEL * DINNER / 4);
  concat_wbcdt_bf16_kernel<<<NLAYER * 128 * DINNER / 4 / 256, 256, 0, stream>>>(WB, WC, Wdt1, wbcdtb);
  gather_rms_kernel<<<SEQ, 256, 0, stream>>>(token_ids, embed, x, xnb);

  for (int i = 0; i < NLAYER; ++i) {
    const ushort* wcati = wcatb + (size_t)i * 2 * DINNER * DMODEL;
    const ushort* wouti = woutb + (size_t)i * DMODEL * DINNER;
    const float* wconvi = Wconv + (size_t)i * DINNER * 4;
    const ushort* wbcdtbi = wbcdtb + (size_t)i * 128 * DINNER;
    const float* wdt2i = Wdt2 + (size_t)i * DINNER * DTRANK;
    const float* bdti = bdt + (size_t)i * DINNER;
    const float* logAi = logA + (size_t)i * DINNER * DSTATE;
    const float* Dpi = Dp + (size_t)i * DINNER;

    gemm2p_bt_bf16<true><<<dim3(SEQ / 128, 2 * DINNER / 128), 256, 0, stream>>>(
        xnb, wcati, resu0, 2 * DINNER, DMODEL);
    conv_silu_kernel<<<SEQ * DINNER / 4 / 256, 256, 0, stream>>>(resu0 + DINNER, 2 * DINNER, wconvi, u);
    // MFMA projection: bcdt partials = u @ wbcdtb^T, grid (16,1,PZ)=256 blocks
    gemm_btk_bf16<<<dim3(SEQ / 128, 1, PZ), 256, 0, stream>>>(
        u, wbcdtbi, Cp, SEQ, 128, DINNER);
    proj_reduce<<<SEQ * 96 / 256, 256, 0, stream>>>(Cp, bcdt, SEQ);
    smallgemm_f32<<<dim3(SEQ / 64, DINNER / 64), 256, 0, stream>>>(
        bcdt + 32, 96, wdt2i, DTRANK, dt, DINNER, bdti, SEQ, DINNER, DTRANK, 1);
    dim3 gs(DINNER / 16, NCHUNK);
    scan_pass1<<<gs, 256, 0, stream>>>(dt, u, bcdt, logAi, Pbuf, Sbuf);
    scan_pass2<<<gs, 256, 0, stream>>>(dt, u, bcdt, logAi, Dpi, Pbuf, Sbuf, resu0, y2b);
    gemm_btk_bf16<<<dim3(SEQ / 128, DMODEL / 128, 2), 256, 0, stream>>>(
        y2b, wouti, Cp2, SEQ, DMODEL, DINNER);
    add3_rms_kernel<<<SEQ, 256, 0, stream>>>(
        Cp2, Cp2 + (size_t)SEQ * DMODEL, x,
        (i < NLAYER - 1) ? xnb : xb, (i < NLAYER - 1) ? 1 : 0);
  }
  gemm8p_bt_bf16<256, true><<<dim3(SEQ / 256, VOCAB / 256), 512, 0, stream>>>(
      xb, eb, out, VOCAB, DMODEL);
}

// Round 15
// 1996.065 us; speedup vs baseline: 1.5090x; 1.0595x over previous
//
#include <hip/hip_runtime.h>

#define SEQ 2048
#define DMODEL 1024
#define DINNER 2048
#define DSTATE 16
#define DTRANK 64
#define NLAYER 8
#define VOCAB 32000
#define NCHUNK 32
#define CLEN 64   // SEQ / NCHUNK
#define PZ 16     // split-K chunks for the projection GEMM

typedef float f32x4 __attribute__((ext_vector_type(4)));
typedef short bf16x8 __attribute__((ext_vector_type(8)));

__device__ __forceinline__ ushort f2bf(float f) {
  union { float f; unsigned u; } v; v.f = f;
  unsigned r = v.u + 0x7fffu + ((v.u >> 16) & 1u);
  return (ushort)(r >> 16);
}
__device__ __forceinline__ float bf2f(ushort b) {
  union { unsigned u; float f; } v; v.u = ((unsigned)b) << 16;
  return v.f;
}

__device__ __forceinline__ void lds_load16(const void* g, void* l) {
  __builtin_amdgcn_global_load_lds(
      (const __attribute__((address_space(1))) void*)g,
      (__attribute__((address_space(3))) void*)l, 16, 0, 0);
}

// ---------------- 256x256 counted-vmcnt MFMA GEMM (proven ~197us logits) ----
template<int BM, bool NTS>
__global__ __launch_bounds__(512, 2) void gemm8p_bt_bf16(
    const ushort* __restrict__ A, const ushort* __restrict__ B,
    float* __restrict__ C, int N, int K)
{
  constexpr int MFR = BM / 32;
  constexpr int MPP = MFR / 4;
  constexpr int ALOADS = BM / 128;
  __shared__ __align__(16) ushort As[2 * BM * 64];
  __shared__ __align__(16) ushort Bs[2 * 256 * 64];
  const int tid = threadIdx.x;
  const int lane = tid & 63;
  const int wid = tid >> 6;
  const int wr = wid >> 2, wc = wid & 3;
  const int rr = lane & 15, kq = lane >> 4;

  unsigned nwg = gridDim.x * gridDim.y;
  unsigned lb = blockIdx.y * gridDim.x + blockIdx.x;
  if ((nwg & 7u) == 0u) { unsigned cpx = nwg >> 3; lb = (lb & 7u) * cpx + (lb >> 3); }
  const int bm = (int)(lb % gridDim.x) * BM;
  const int bn = (int)(lb / gridDim.x) * 256;

  const ushort* Abase = A + (size_t)bm * K;
  const ushort* Bbase = B + (size_t)bn * K;

  auto stageA = [&](int buf, int h, int kt) {
    constexpr int HR = BM / 2;
#pragma unroll
    for (int L = 0; L < ALOADS; ++L) {
      int f = L * 512 + tid;
      int rl = f >> 3, g = f & 7;
      int gg = g ^ (rl & 7);
      lds_load16(Abase + (size_t)(h * HR + rl) * K + kt * 64 + gg * 8,
                 (void*)(As + buf * (BM * 64) + (h * HR + rl) * 64 + g * 8));
    }
  };
  auto stageB = [&](int buf, int h, int kt) {
#pragma unroll
    for (int L = 0; L < 2; ++L) {
      int f = L * 512 + tid;
      int rl = f >> 3, g = f & 7;
      int gg = g ^ (rl & 7);
      lds_load16(Bbase + (size_t)(h * 128 + rl) * K + kt * 64 + gg * 8,
                 (void*)(Bs + buf * (256 * 64) + (h * 128 + rl) * 64 + g * 8));
    }
  };
  auto rdA = [&](int buf, int r, int kbyte) {
    int sw = kbyte ^ ((r & 7) << 4);
    return *(const bf16x8*)(As + buf * (BM * 64) + r * 64 + (sw >> 1));
  };
  auto rdB = [&](int buf, int r, int kbyte) {
    int sw = kbyte ^ ((r & 7) << 4);
    return *(const bf16x8*)(Bs + buf * (256 * 64) + r * 64 + (sw >> 1));
  };

  f32x4 acc[MFR][4];
#pragma unroll
  for (int m = 0; m < MFR; ++m)
#pragma unroll
    for (int n = 0; n < 4; ++n) acc[m][n] = (f32x4){0.f, 0.f, 0.f, 0.f};

  const int NT = K >> 6;
  stageA(0, 0, 0); stageA(0, 1, 0); stageB(0, 0, 0); stageB(0, 1, 0);

  for (int t = 0; t < NT; ++t) {
    const int cur = t & 1;
    const bool more = (t + 1 < NT);
    if (more) stageA(cur ^ 1, 0, t + 1);
    if (more) {
      if constexpr (BM == 256) asm volatile("s_waitcnt vmcnt(2)" ::: "memory");
      else                     asm volatile("s_waitcnt vmcnt(1)" ::: "memory");
    } else {
      asm volatile("s_waitcnt vmcnt(0)" ::: "memory");
    }
    __syncthreads();

    bf16x8 bfr[4][2];
#pragma unroll
    for (int n = 0; n < 4; ++n)
#pragma unroll
      for (int kk = 0; kk < 2; ++kk)
        bfr[n][kk] = rdB(cur, wc * 64 + n * 16 + rr, kk * 64 + kq * 16);

#pragma unroll
    for (int mq = 0; mq < 4; ++mq) {
      if (mq == 1 && more) stageA(cur ^ 1, 1, t + 1);
      if (mq == 2 && more) stageB(cur ^ 1, 0, t + 1);
      if (mq == 3 && more) stageB(cur ^ 1, 1, t + 1);
      bf16x8 af[MPP][2];
#pragma unroll
      for (int mf = 0; mf < MPP; ++mf)
#pragma unroll
        for (int kk = 0; kk < 2; ++kk)
          af[mf][kk] = rdA(cur, wr * (BM / 2) + (mq * MPP + mf) * 16 + rr, kk * 64 + kq * 16);
      __builtin_amdgcn_s_setprio(1);
#pragma unroll
      for (int kk = 0; kk < 2; ++kk)
#pragma unroll
        for (int mf = 0; mf < MPP; ++mf)
#pragma unroll
          for (int n = 0; n < 4; ++n)
            acc[mq * MPP + mf][n] = __builtin_amdgcn_mfma_f32_16x16x32_bf16(
                af[mf][kk], bfr[n][kk], acc[mq * MPP + mf][n], 0, 0, 0);
      __builtin_amdgcn_s_setprio(0);
    }
    __syncthreads();
  }

  float* ep = (float*)Bs + wid * (16 * 68);
  const int cg = bn + wc * 64;
#pragma unroll
  for (int m = 0; m < MFR; ++m) {
    const int r0g = bm + wr * (BM / 2) + m * 16;
#pragma unroll
    for (int n = 0; n < 4; ++n)
#pragma unroll
      for (int j = 0; j < 4; ++j)
        ep[(kq * 4 + j) * 68 + n * 16 + rr] = acc[m][n][j];
#pragma unroll
    for (int i = 0; i < 4; ++i) {
      int row = i * 4 + kq;
      f32x4 v = *(const f32x4*)&ep[row * 68 + rr * 4];
      f32x4* dst = (f32x4*)&C[(size_t)(r0g + row) * N + cg + rr * 4];
      if constexpr (NTS) __builtin_nontemporal_store(v, dst);
      else *dst = v;
    }
  }
}

// ---------------- 128x128 2-blocks/CU MFMA GEMM (layer gemm1) ---------------
// OUTBF: epilogue converts to bf16 (ushort4 stores) — used for resu0.
template<bool OUTBF>
__global__ __launch_bounds__(256, 2) void gemm2p_bt_bf16(
    const ushort* __restrict__ A, const ushort* __restrict__ B,
    void* __restrict__ Cv, int N, int K)
{
  __shared__ __align__(16) ushort As[2 * 128 * 64];
  __shared__ __align__(16) ushort Bs[2 * 128 * 64];
  const int tid = threadIdx.x;
  const int lane = tid & 63;
  const int wave = tid >> 6;
  const int wr = wave >> 1, wc = wave & 1;
  const int rr = lane & 15, kq = lane >> 4;

  unsigned nwg = gridDim.x * gridDim.y;
  unsigned lb = blockIdx.y * gridDim.x + blockIdx.x;
  if ((nwg & 7u) == 0u) { unsigned cpx = nwg >> 3; lb = (lb & 7u) * cpx + (lb >> 3); }
  const int bm = (int)(lb % gridDim.x) * 128;
  const int bn = (int)(lb / gridDim.x) * 128;

  const ushort* Abase = A + (size_t)bm * K;
  const ushort* Bbase = B + (size_t)bn * K;

  auto stage = [&](int buf, int kt) {
#pragma unroll
    for (int i = 0; i < 4; ++i) {
      int f = i * 256 + tid;
      int rl = f >> 3, g = f & 7;
      int gg = g ^ (rl & 7);
      lds_load16(Abase + (size_t)rl * K + kt * 64 + gg * 8,
                 (void*)(As + buf * 8192 + rl * 64 + g * 8));
      lds_load16(Bbase + (size_t)rl * K + kt * 64 + gg * 8,
                 (void*)(Bs + buf * 8192 + rl * 64 + g * 8));
    }
  };
  auto rdA = [&](int buf, int r, int kbyte) {
    int sw = kbyte ^ ((r & 7) << 4);
    return *(const bf16x8*)(As + buf * 8192 + r * 64 + (sw >> 1));
  };
  auto rdB = [&](int buf, int r, int kbyte) {
    int sw = kbyte ^ ((r & 7) << 4);
    return *(const bf16x8*)(Bs + buf * 8192 + r * 64 + (sw >> 1));
  };

  f32x4 acc[4][4];
#pragma unroll
  for (int m = 0; m < 4; ++m)
#pragma unroll
    for (int n = 0; n < 4; ++n) acc[m][n] = (f32x4){0.f, 0.f, 0.f, 0.f};

  const int NT = K >> 6;
  stage(0, 0);

  for (int t = 0; t < NT; ++t) {
    const int cur = t & 1;
    if (t + 1 < NT) {
      stage(cur ^ 1, t + 1);
      asm volatile("s_waitcnt vmcnt(8)" ::: "memory");
    } else {
      asm volatile("s_waitcnt vmcnt(0)" ::: "memory");
    }
    __syncthreads();
#pragma unroll
    for (int ks = 0; ks < 2; ++ks) {
      const int kbyte = ks * 64 + kq * 16;
      bf16x8 af[4], bfr[4];
#pragma unroll
      for (int m = 0; m < 4; ++m)
        af[m] = rdA(cur, wr * 64 + m * 16 + rr, kbyte);
#pragma unroll
      for (int n = 0; n < 4; ++n)
        bfr[n] = rdB(cur, wc * 64 + n * 16 + rr, kbyte);
      __builtin_amdgcn_s_setprio(1);
#pragma unroll
      for (int m = 0; m < 4; ++m)
#pragma unroll
        for (int n = 0; n < 4; ++n)
          acc[m][n] = __builtin_amdgcn_mfma_f32_16x16x32_bf16(af[m], bfr[n], acc[m][n], 0, 0, 0);
      __builtin_amdgcn_s_setprio(0);
    }
    __syncthreads();
  }

  float* ep = (float*)Bs + wave * (16 * 68);
  const int cg = bn + wc * 64;
#pragma unroll
  for (int m = 0; m < 4; ++m) {
    const int r0g = bm + wr * 64 + m * 16;
#pragma unroll
    for (int n = 0; n < 4; ++n)
#pragma unroll
      for (int j = 0; j < 4; ++j)
        ep[(kq * 4 + j) * 68 + n * 16 + rr] = acc[m][n][j];
#pragma unroll
    for (int i = 0; i < 4; ++i) {
      int row = i * 4 + kq;
      f32x4 v = *(const f32x4*)&ep[row * 68 + rr * 4];
      if constexpr (OUTBF) {
        ushort* C = (ushort*)Cv;
        ushort4 o = {f2bf(v.x), f2bf(v.y), f2bf(v.z), f2bf(v.w)};
        *(ushort4*)&C[(size_t)(r0g + row) * N + cg + rr * 4] = o;
      } else {
        float* C = (float*)Cv;
        *(f32x4*)&C[(size_t)(r0g + row) * N + cg + rr * 4] = v;
      }
    }
  }
}

// ---------------- split-K bf16 MFMA GEMM (2-phase 128x128) ------------------
// K chunk count = gridDim.z; writes partials Cp[z][M][N].
__global__ __launch_bounds__(256) void gemm_btk_bf16(
    const ushort* __restrict__ A, const ushort* __restrict__ B,
    float* __restrict__ Cp, int M, int N, int K)
{
  __shared__ __align__(16) ushort As[128 * 64];
  __shared__ __align__(16) ushort Bs[128 * 64];
  const int tid = threadIdx.x;
  const int lane = tid & 63;
  const int wave = tid >> 6;
  const int wr = wave >> 1, wc = wave & 1;
  const int KC = K / gridDim.z;
  const int k0 = blockIdx.z * KC;

  unsigned nwg = gridDim.x * gridDim.y;
  unsigned lb = blockIdx.y * gridDim.x + blockIdx.x;
  if ((nwg & 7u) == 0u) {
    unsigned cpx = nwg >> 3;
    lb = (lb & 7u) * cpx + (lb >> 3);
  }
  const int bm = (lb % gridDim.x) * 128;
  const int bn = (lb / gridDim.x) * 128;
  const int rr = lane & 15, kq = lane >> 4;

  f32x4 acc[4][4];
#pragma unroll
  for (int m = 0; m < 4; ++m)
#pragma unroll
    for (int n = 0; n < 4; ++n) acc[m][n] = (f32x4){0.f, 0.f, 0.f, 0.f};

  for (int kt = 0; kt < KC; kt += 64) {
#pragma unroll
    for (int i = 0; i < 4; ++i) {
      int fb = i * 256 + tid;
      int row = fb >> 3, cb = fb & 7;
      lds_load16(A + (size_t)(bm + row) * K + k0 + kt + cb * 8, (void*)(As + (size_t)fb * 8));
      lds_load16(B + (size_t)(bn + row) * K + k0 + kt + cb * 8, (void*)(Bs + (size_t)fb * 8));
    }
    __syncthreads();
#pragma unroll
    for (int ks = 0; ks < 2; ++ks) {
      bf16x8 af[4], bfr[4];
      const int koff = ks * 32 + kq * 8;
#pragma unroll
      for (int m = 0; m < 4; ++m)
        af[m] = *(const bf16x8*)&As[(wr * 64 + m * 16 + rr) * 64 + koff];
#pragma unroll
      for (int n = 0; n < 4; ++n)
        bfr[n] = *(const bf16x8*)&Bs[(wc * 64 + n * 16 + rr) * 64 + koff];
#pragma unroll
      for (int m = 0; m < 4; ++m)
#pragma unroll
        for (int n = 0; n < 4; ++n)
          acc[m][n] = __builtin_amdgcn_mfma_f32_16x16x32_bf16(af[m], bfr[n], acc[m][n], 0, 0, 0);
    }
    __syncthreads();
  }
  float* C = Cp + (size_t)blockIdx.z * M * N;
#pragma unroll
  for (int m = 0; m < 4; ++m) {
    const int r0 = bm + wr * 64 + m * 16 + kq * 4;
#pragma unroll
    for (int n = 0; n < 4; ++n) {
      const int cc = bn + wc * 64 + n * 16 + rr;
#pragma unroll
      for (int j = 0; j < 4; ++j)
        C[(size_t)(r0 + j) * N + cc] = acc[m][n][j];
    }
  }
}

// ---------------- dt GEMM: dt = softplus(dtin @ Wdt2^T + bdt) -> bf16 -------
// K = 64 (single staged tile). 128x128 tile, 256 thr, MFMA + fused epilogue.
__global__ __launch_bounds__(256) void gemm_dt_bf16(
    const ushort* __restrict__ A, const ushort* __restrict__ W,
    const float* __restrict__ bias, ushort* __restrict__ dt)
{
  __shared__ __align__(16) ushort As[128 * 64];
  __shared__ __align__(16) ushort Bs[128 * 64];
  __shared__ float eps[4 * 16 * 68];
  const int tid = threadIdx.x;
  const int lane = tid & 63;
  const int wave = tid >> 6;
  const int wr = wave >> 1, wc = wave & 1;
  const int rr = lane & 15, kq = lane >> 4;
  const int bm = blockIdx.x * 128;
  const int bn = blockIdx.y * 128;

#pragma unroll
  for (int i = 0; i < 4; ++i) {
    int f = i * 256 + tid;
    int rl = f >> 3, g = f & 7;
    lds_load16(A + (size_t)(bm + rl) * DTRANK + g * 8, (void*)(As + (size_t)f * 8));
    lds_load16(W + (size_t)(bn + rl) * DTRANK + g * 8, (void*)(Bs + (size_t)f * 8));
  }
  asm volatile("s_waitcnt vmcnt(0)" ::: "memory");
  __syncthreads();

  f32x4 acc[4][4];
#pragma unroll
  for (int m = 0; m < 4; ++m)
#pragma unroll
    for (int n = 0; n < 4; ++n) acc[m][n] = (f32x4){0.f, 0.f, 0.f, 0.f};

#pragma unroll
  for (int ks = 0; ks < 2; ++ks) {
    bf16x8 af[4], bfr[4];
    const int koff = ks * 32 + kq * 8;
#pragma unroll
    for (int m = 0; m < 4; ++m)
      af[m] = *(const bf16x8*)&As[(wr * 64 + m * 16 + rr) * 64 + koff];
#pragma unroll
    for (int n = 0; n < 4; ++n)
      bfr[n] = *(const bf16x8*)&Bs[(wc * 64 + n * 16 + rr) * 64 + koff];
#pragma unroll
    for (int m = 0; m < 4; ++m)
#pragma unroll
      for (int n = 0; n < 4; ++n)
        acc[m][n] = __builtin_amdgcn_mfma_f32_16x16x32_bf16(af[m], bfr[n], acc[m][n], 0, 0, 0);
  }
  __syncthreads();

  // epilogue: transpose in LDS, add bias, softplus, bf16 store
  float* ep = eps + wave * (16 * 68);
  const int cgb = bn + wc * 64 + rr * 4;
  float4 b4 = *(const float4*)&bias[cgb];
#pragma unroll
  for (int m = 0; m < 4; ++m) {
    const int r0g = bm + wr * 64 + m * 16;
#pragma unroll
    for (int n = 0; n < 4; ++n)
#pragma unroll
      for (int j = 0; j < 4; ++j)
        ep[(kq * 4 + j) * 68 + n * 16 + rr] = acc[m][n][j];
#pragma unroll
    for (int i = 0; i < 4; ++i) {
      int row = i * 4 + kq;
      f32x4 v = *(const f32x4*)&ep[row * 68 + rr * 4];
      float v0 = v.x + b4.x, v1 = v.y + b4.y, v2 = v.z + b4.z, v3 = v.w + b4.w;
      v0 = (v0 > 20.f) ? v0 : log1pf(expf(v0));
      v1 = (v1 > 20.f) ? v1 : log1pf(expf(v1));
      v2 = (v2 > 20.f) ? v2 : log1pf(expf(v2));
      v3 = (v3 > 20.f) ? v3 : log1pf(expf(v3));
      ushort4 o = {f2bf(v0), f2bf(v1), f2bf(v2), f2bf(v3)};
      *(ushort4*)&dt[(size_t)(r0g + row) * DINNER + cgb] = o;
    }
  }
}

// ---------------- x += P0 + P1, then RMSNorm(x)->bf16 (or plain cast) -------
__global__ __launch_bounds__(256) void add3_rms_kernel(
    const float* __restrict__ P0, const float* __restrict__ P1,
    float* __restrict__ x, ushort* __restrict__ dst, int donorm)
{
  size_t o = (size_t)blockIdx.x * (DMODEL / 4) + threadIdx.x;
  float4 a = ((const float4*)P0)[o];
  float4 b = ((const float4*)P1)[o];
  float4 c = ((float4*)x)[o];
  c.x += a.x + b.x; c.y += a.y + b.y; c.z += a.z + b.z; c.w += a.w + b.w;
  ((float4*)x)[o] = c;
  float sc = 1.f;
  if (donorm) {
    float s = c.x * c.x + c.y * c.y + c.z * c.z + c.w * c.w;
#pragma unroll
    for (int off = 32; off > 0; off >>= 1) s += __shfl_down(s, off);
    __shared__ float ws[4];
    if ((threadIdx.x & 63) == 0) ws[threadIdx.x >> 6] = s;
    __syncthreads();
    float tot = ws[0] + ws[1] + ws[2] + ws[3];
    sc = rsqrtf(tot * (1.0f / DMODEL) + 1e-6f);
  }
  ushort4 o4 = {f2bf(c.x * sc), f2bf(c.y * sc), f2bf(c.z * sc), f2bf(c.w * sc)};
  ((ushort4*)dst)[o] = o4;
}

// ---------------- embedding gather + RMSNorm -> x (f32) and xnb (bf16) ------
__global__ __launch_bounds__(256) void gather_rms_kernel(
    const int* __restrict__ ids, const float* __restrict__ embed,
    float* __restrict__ x, ushort* __restrict__ xnb)
{
  int row = blockIdx.x;
  int id = ids[row];
  float4 v = ((const float4*)(embed + (size_t)id * DMODEL))[threadIdx.x];
  size_t o = (size_t)row * (DMODEL / 4) + threadIdx.x;
  ((float4*)x)[o] = v;
  float s = v.x * v.x + v.y * v.y + v.z * v.z + v.w * v.w;
#pragma unroll
  for (int off = 32; off > 0; off >>= 1) s += __shfl_down(s, off);
  __shared__ float ws[4];
  if ((threadIdx.x & 63) == 0) ws[threadIdx.x >> 6] = s;
  __syncthreads();
  float tot = ws[0] + ws[1] + ws[2] + ws[3];
  float sc = rsqrtf(tot * (1.0f / DMODEL) + 1e-6f);
  ushort4 o4 = {f2bf(v.x * sc), f2bf(v.y * sc), f2bf(v.z * sc), f2bf(v.w * sc)};
  ((ushort4*)xnb)[o] = o4;
}

// ---- proj reduce: B/C -> bcdt f32 (cols 0..31), dt-in -> dtinb bf16 --------
__global__ __launch_bounds__(256) void proj_reduce(
    const float* __restrict__ Cp, float* __restrict__ bcdt,
    ushort* __restrict__ dtinb, int M)
{
  int idx = blockIdx.x * 256 + threadIdx.x;  // over M*96
  int row = idx / 96, col = idx - row * 96;
  float s = 0.f;
#pragma unroll
  for (int c = 0; c < PZ; ++c) s += Cp[(size_t)c * M * 128 + (size_t)row * 128 + col];
  if (col < 32) bcdt[(size_t)row * 96 + col] = s;
  else dtinb[(size_t)row * 64 + (col - 32)] = f2bf(s);
}

// ---------------- causal depthwise conv (K=4) + SiLU (bf16 in/out) ----------
__global__ __launch_bounds__(256) void conv_silu_kernel(
    const ushort* __restrict__ u0, int ld, const float* __restrict__ Wconv,
    ushort* __restrict__ u)
{
  int idx = blockIdx.x * 256 + threadIdx.x;
  int d4 = idx & (DINNER / 4 - 1);
  int l = idx >> 9;
  int d0 = d4 * 4;
  float wt[4][4];
#pragma unroll
  for (int j = 0; j < 4; ++j) {
    float4 tv = *(const float4*)&Wconv[(d0 + j) * 4];
    wt[j][0] = tv.x; wt[j][1] = tv.y; wt[j][2] = tv.z; wt[j][3] = tv.w;
  }
  float a[4] = {0.f, 0.f, 0.f, 0.f};
#pragma unroll
  for (int k = 0; k < 4; ++k) {
    int ls = l - 3 + k;
    if (ls >= 0) {
      ushort4 uv = *(const ushort4*)&u0[(size_t)ls * ld + d0];
      a[0] += bf2f(uv.x) * wt[0][k];
      a[1] += bf2f(uv.y) * wt[1][k];
      a[2] += bf2f(uv.z) * wt[2][k];
      a[3] += bf2f(uv.w) * wt[3][k];
    }
  }
  float s0 = a[0] / (1.f + expf(-a[0]));
  float s1 = a[1] / (1.f + expf(-a[1]));
  float s2 = a[2] / (1.f + expf(-a[2]));
  float s3 = a[3] / (1.f + expf(-a[3]));
  ushort4 o = {f2bf(s0), f2bf(s1), f2bf(s2), f2bf(s3)};
  *(ushort4*)&u[(size_t)l * DINNER + d0] = o;
}

// ---------------- chunk-parallel selective scan (bf16 dt/u inputs) ----------
__global__ __launch_bounds__(256) void scan_pass1(
    const ushort* __restrict__ dt, const ushort* __restrict__ u,
    const float* __restrict__ bcdt, const float* __restrict__ logA,
    float* __restrict__ P, float* __restrict__ S)
{
  const int tid = threadIdx.x;
  const int n = tid & 15, dl = tid >> 4;
  const int dbase = blockIdx.x * 16;
  const int c = blockIdx.y;
  const int t0 = c * CLEN;
  const int d = dbase + dl;
  const float Aval = -expf(logA[d * DSTATE + n]);
  __shared__ float sdt[CLEN][16], su[CLEN][16], sB[CLEN][16];
  {
    int tt = tid >> 2, j0 = (tid & 3) * 4;
    ushort4 rd = *(const ushort4*)&dt[(size_t)(t0 + tt) * DINNER + dbase + j0];
    ushort4 ru = *(const ushort4*)&u[(size_t)(t0 + tt) * DINNER + dbase + j0];
    sdt[tt][j0 + 0] = bf2f(rd.x); sdt[tt][j0 + 1] = bf2f(rd.y);
    sdt[tt][j0 + 2] = bf2f(rd.z); sdt[tt][j0 + 3] = bf2f(rd.w);
    su[tt][j0 + 0] = bf2f(ru.x); su[tt][j0 + 1] = bf2f(ru.y);
    su[tt][j0 + 2] = bf2f(ru.z); su[tt][j0 + 3] = bf2f(ru.w);
    *(float4*)&sB[tt][j0] = *(const float4*)&bcdt[(size_t)(t0 + tt) * 96 + j0];
  }
  __syncthreads();
  float h = 0.f, pr = 1.f;
#pragma unroll 8
  for (int i = 0; i < CLEN; ++i) {
    float dtv = sdt[i][dl], uv = su[i][dl], Bv = sB[i][n];
    float dtA = dtv * Aval;
    float rinv = __builtin_amdgcn_rcpf(1.f - 0.5f * dtA);
    float dA = (1.f + 0.5f * dtA) * rinv;
    float dBu = dtv * Bv * rinv * uv;
    h = dA * h + dBu;
    pr *= dA;
  }
  size_t idx = (size_t)c * (DINNER * DSTATE) + (size_t)d * DSTATE + n;
  P[idx] = pr;
  S[idx] = h;
}

__global__ __launch_bounds__(256) void scan_pass2(
    const ushort* __restrict__ dt, const ushort* __restrict__ u,
    const float* __restrict__ bcdt, const float* __restrict__ logA,
    const float* __restrict__ Dp, const float* __restrict__ P,
    const float* __restrict__ S, const ushort* __restrict__ resu0,
    ushort* __restrict__ y2b)
{
  const int tid = threadIdx.x;
  const int n = tid & 15, dl = tid >> 4;
  const int dbase = blockIdx.x * 16;
  const int c = blockIdx.y;
  const int t0 = c * CLEN;
  const int d = dbase + dl;
  const float Aval = -expf(logA[d * DSTATE + n]);
  const float Dpv = Dp[d];
  __shared__ float sdt[CLEN][16], su[CLEN][16], sB[CLEN][16], sC[CLEN][16], sres[CLEN][16];
  {
    int tt = tid >> 2, j0 = (tid & 3) * 4;
    ushort4 rd = *(const ushort4*)&dt[(size_t)(t0 + tt) * DINNER + dbase + j0];
    ushort4 ru = *(const ushort4*)&u[(size_t)(t0 + tt) * DINNER + dbase + j0];
    ushort4 rr4 = *(const ushort4*)&resu0[(size_t)(t0 + tt) * (2 * DINNER) + dbase + j0];
    sdt[tt][j0 + 0] = bf2f(rd.x); sdt[tt][j0 + 1] = bf2f(rd.y);
    sdt[tt][j0 + 2] = bf2f(rd.z); sdt[tt][j0 + 3] = bf2f(rd.w);
    su[tt][j0 + 0] = bf2f(ru.x); su[tt][j0 + 1] = bf2f(ru.y);
    su[tt][j0 + 2] = bf2f(ru.z); su[tt][j0 + 3] = bf2f(ru.w);
    sres[tt][j0 + 0] = bf2f(rr4.x); sres[tt][j0 + 1] = bf2f(rr4.y);
    sres[tt][j0 + 2] = bf2f(rr4.z); sres[tt][j0 + 3] = bf2f(rr4.w);
    *(float4*)&sB[tt][j0] = *(const float4*)&bcdt[(size_t)(t0 + tt) * 96 + j0];
    *(float4*)&sC[tt][j0] = *(const float4*)&bcdt[(size_t)(t0 + tt) * 96 + 16 + j0];
  }
  float h = 0.f;
  {
    const size_t base = (size_t)d * DSTATE + n;
#pragma unroll 4
    for (int cc = 0; cc < c; ++cc) {
      size_t o = (size_t)cc * (DINNER * DSTATE) + base;
      h = P[o] * h + S[o];
    }
  }
  __syncthreads();
#pragma unroll 4
  for (int i = 0; i < CLEN; ++i) {
    float dtv = sdt[i][dl], uv = su[i][dl];
    float dtA = dtv * Aval;
    float rinv = __builtin_amdgcn_rcpf(1.f - 0.5f * dtA);
    float dA = (1.f + 0.5f * dtA) * rinv;
    float dBu = dtv * sB[i][n] * rinv * uv;
    h = dA * h + dBu;
    float p = h * sC[i][n];
    p += __shfl_xor(p, 1);
    p += __shfl_xor(p, 2);
    p += __shfl_xor(p, 4);
    p += __shfl_xor(p, 8);
    if (n == 0) {
      float rv = sres[i][dl];
      float yv = (p + uv * Dpv) * (rv / (1.f + expf(-rv)));
      y2b[(size_t)(t0 + i) * DINNER + d] = f2bf(yv);
    }
  }
}

// ---------------- f32 -> bf16 cast ------------------------------------------
__global__ __launch_bounds__(256) void cast_bf16_kernel(
    const float* __restrict__ in, ushort* __restrict__ out, size_t n4)
{
  size_t i = (size_t)blockIdx.x * 256 + threadIdx.x;
  if (i >= n4) return;
  float4 v = ((const float4*)in)[i];
  ushort4 o = {f2bf(v.x), f2bf(v.y), f2bf(v.z), f2bf(v.w)};
  ((ushort4*)out)[i] = o;
}

// ---------------- concat-cast Wres|Win -> bf16 [L][2*DINNER][DMODEL] --------
__global__ __launch_bounds__(256) void cast_cat2_kernel(
    const float* __restrict__ Wres, const float* __restrict__ Win, ushort* __restrict__ out)
{
  size_t i4 = (size_t)blockIdx.x * 256 + threadIdx.x;
  size_t e0 = i4 * 4;
  int k = (int)(e0 & (DMODEL - 1));
  int r = (int)((e0 >> 10) & (2 * DINNER - 1));
  int l = (int)(e0 >> 22);
  const float* src = (r < DINNER)
      ? &Wres[(((size_t)l * DINNER + r) << 10) + k]
      : &Win[(((size_t)l * DINNER + (r - DINNER)) << 10) + k];
  float4 v = *(const float4*)src;
  ushort4 o = {f2bf(v.x), f2bf(v.y), f2bf(v.z), f2bf(v.w)};
  ((ushort4*)out)[i4] = o;
}

// ---------------- concat-cast WB|WC|Wdt1 -> bf16 [L][128][DINNER] (pad 0) ---
__global__ __launch_bounds__(256) void concat_wbcdt_bf16_kernel(
    const float* __restrict__ WB, const float* __restrict__ WC,
    const float* __restrict__ Wdt1, ushort* __restrict__ out)
{
  size_t i4 = (size_t)blockIdx.x * 256 + threadIdx.x;  // over L*128*DINNER/4
  int k4 = (int)(i4 & (DINNER / 4 - 1));
  int row = (int)((i4 >> 9) & 127);
  int l = (int)(i4 >> 16);
  int k = k4 * 4;
  float4 v = {0.f, 0.f, 0.f, 0.f};
  if (row < 16)       v = *(const float4*)&WB[((size_t)l * DSTATE + row) * DINNER + k];
  else if (row < 32)  v = *(const float4*)&WC[((size_t)l * DSTATE + (row - 16)) * DINNER + k];
  else if (row < 96)  v = *(const float4*)&Wdt1[((size_t)l * DTRANK + (row - 32)) * DINNER + k];
  ushort4 o = {f2bf(v.x), f2bf(v.y), f2bf(v.z), f2bf(v.w)};
  ((ushort4*)out)[i4] = o;
}

// ============================================================================
extern "C" void kernel_launch(void* const* d_in, const int* in_sizes, int n_in,
                              void* d_out, int out_size, void* d_ws, size_t ws_size,
                              hipStream_t stream) {
  (void)in_sizes; (void)n_in; (void)out_size;
  const int* token_ids = (const int*)d_in[0];
  const float* embed = (const float*)d_in[1];
  const float* Wres = (const float*)d_in[2];
  const float* Win = (const float*)d_in[3];
  const float* Wconv = (const float*)d_in[4];
  const float* WB = (const float*)d_in[5];
  const float* WC = (const float*)d_in[6];
  const float* Wdt1 = (const float*)d_in[7];
  const float* Wdt2 = (const float*)d_in[8];
  const float* bdt = (const float*)d_in[9];
  const float* logA = (const float*)d_in[10];
  const float* Dp = (const float*)d_in[11];
  const float* Wout = (const float*)d_in[12];
  float* out = (float*)d_out;

  char* w = (char*)d_ws;
  auto alloc = [&](size_t bytes) {
    char* p = w;
    w += (bytes + 255) & ~(size_t)255;
    return p;
  };
  ushort* eb     = (ushort*)alloc((size_t)VOCAB * DMODEL * 2);
  ushort* wcatb  = (ushort*)alloc((size_t)NLAYER * 2 * DINNER * DMODEL * 2);
  ushort* woutb  = (ushort*)alloc((size_t)NLAYER * DMODEL * DINNER * 2);
  ushort* wbcdtb = (ushort*)alloc((size_t)NLAYER * 128 * DINNER * 2);
  ushort* wdt2b  = (ushort*)alloc((size_t)NLAYER * DINNER * DTRANK * 2);
  float* x       = (float*)alloc((size_t)SEQ * DMODEL * 4);
  ushort* xnb    = (ushort*)alloc((size_t)SEQ * DMODEL * 2);
  ushort* resu0  = (ushort*)alloc((size_t)SEQ * 2 * DINNER * 2);
  ushort* u      = (ushort*)alloc((size_t)SEQ * DINNER * 2);
  float* bcdt    = (float*)alloc((size_t)SEQ * 96 * 4);
  ushort* dtinb  = (ushort*)alloc((size_t)SEQ * 64 * 2);
  ushort* dt     = (ushort*)alloc((size_t)SEQ * DINNER * 2);
  float* Cp      = (float*)alloc((size_t)PZ * SEQ * 128 * 4);
  float* Cp2     = (float*)alloc((size_t)2 * SEQ * DMODEL * 4);
  float* Pbuf    = (float*)alloc((size_t)NCHUNK * DINNER * DSTATE * 4);
  float* Sbuf    = (float*)alloc((size_t)NCHUNK * DINNER * DSTATE * 4);
  ushort* y2b    = (ushort*)alloc((size_t)SEQ * DINNER * 2);
  ushort* xb     = (ushort*)alloc((size_t)SEQ * DMODEL * 2);
  if ((size_t)(w - (char*)d_ws) > ws_size) return;

  // weight preprocessing
  cast_bf16_kernel<<<VOCAB * DMODEL / 4 / 256, 256, 0, stream>>>(embed, eb, (size_t)VOCAB * DMODEL / 4);
  cast_cat2_kernel<<<NLAYER * 2 * DINNER * DMODEL / 4 / 256, 256, 0, stream>>>(Wres, Win, wcatb);
  cast_bf16_kernel<<<NLAYER * DMODEL * DINNER / 4 / 256, 256, 0, stream>>>(Wout, woutb, (size_t)NLAYER * DMODEL * DINNER / 4);
  concat_wbcdt_bf16_kernel<<<NLAYER * 128 * DINNER / 4 / 256, 256, 0, stream>>>(WB, WC, Wdt1, wbcdtb);
  cast_bf16_kernel<<<NLAYER * DINNER * DTRANK / 4 / 256, 256, 0, stream>>>(Wdt2, wdt2b, (size_t)NLAYER * DINNER * DTRANK / 4);
  gather_rms_kernel<<<SEQ, 256, 0, stream>>>(token_ids, embed, x, xnb);

  for (int i = 0; i < NLAYER; ++i) {
    const ushort* wcati = wcatb + (size_t)i * 2 * DINNER * DMODEL;
    const ushort* wouti = woutb + (size_t)i * DMODEL * DINNER;
    const float* wconvi = Wconv + (size_t)i * DINNER * 4;
    const ushort* wbcdtbi = wbcdtb + (size_t)i * 128 * DINNER;
    const ushort* wdt2bi = wdt2b + (size_t)i * DINNER * DTRANK;
    const float* bdti = bdt + (size_t)i * DINNER;
    const float* logAi = logA + (size_t)i * DINNER * DSTATE;
    const float* Dpi = Dp + (size_t)i * DINNER;

    gemm2p_bt_bf16<true><<<dim3(SEQ / 128, 2 * DINNER / 128), 256, 0, stream>>>(
        xnb, wcati, resu0, 2 * DINNER, DMODEL);
    conv_silu_kernel<<<SEQ * DINNER / 4 / 256, 256, 0, stream>>>(resu0 + DINNER, 2 * DINNER, wconvi, u);
    gemm_btk_bf16<<<dim3(SEQ / 128, 1, PZ), 256, 0, stream>>>(
        u, wbcdtbi, Cp, SEQ, 128, DINNER);
    proj_reduce<<<SEQ * 96 / 256, 256, 0, stream>>>(Cp, bcdt, dtinb, SEQ);
    gemm_dt_bf16<<<dim3(SEQ / 128, DINNER / 128), 256, 0, stream>>>(
        dtinb, wdt2bi, bdti, dt);
    dim3 gs(DINNER / 16, NCHUNK);
    scan_pass1<<<gs, 256, 0, stream>>>(dt, u, bcdt, logAi, Pbuf, Sbuf);
    scan_pass2<<<gs, 256, 0, stream>>>(dt, u, bcdt, logAi, Dpi, Pbuf, Sbuf, resu0, y2b);
    gemm_btk_bf16<<<dim3(SEQ / 128, DMODEL / 128, 2), 256, 0, stream>>>(
        y2b, wouti, Cp2, SEQ, DMODEL, DINNER);
    add3_rms_kernel<<<SEQ, 256, 0, stream>>>(
        Cp2, Cp2 + (size_t)SEQ * DMODEL, x,
        (i < NLAYER - 1) ? xnb : xb, (i < NLAYER - 1) ? 1 : 0);
  }
  gemm8p_bt_bf16<256, true><<<dim3(SEQ / 256, VOCAB / 256), 512, 0, stream>>>(
      xb, eb, out, VOCAB, DMODEL);
}

// Round 16
// 1939.840 us; speedup vs baseline: 1.5528x; 1.0290x over previous
//
#include <hip/hip_runtime.h>

#define SEQ 2048
#define DMODEL 1024
#define DINNER 2048
#define DSTATE 16
#define DTRANK 64
#define NLAYER 8
#define VOCAB 32000
#define NCHUNK 32
#define CLEN 64   // SEQ / NCHUNK
#define PZ 16     // split-K chunks for the projection GEMM

typedef float f32x4 __attribute__((ext_vector_type(4)));
typedef short bf16x8 __attribute__((ext_vector_type(8)));

__device__ __forceinline__ ushort f2bf(float f) {
  union { float f; unsigned u; } v; v.f = f;
  unsigned r = v.u + 0x7fffu + ((v.u >> 16) & 1u);
  return (ushort)(r >> 16);
}
__device__ __forceinline__ float bf2f(ushort b) {
  union { unsigned u; float f; } v; v.u = ((unsigned)b) << 16;
  return v.f;
}

__device__ __forceinline__ void lds_load16(const void* g, void* l) {
  __builtin_amdgcn_global_load_lds(
      (const __attribute__((address_space(1))) void*)g,
      (__attribute__((address_space(3))) void*)l, 16, 0, 0);
}

// ---------------- 256x256 counted-vmcnt MFMA GEMM (proven ~197us logits) ----
template<int BM, bool NTS>
__global__ __launch_bounds__(512, 2) void gemm8p_bt_bf16(
    const ushort* __restrict__ A, const ushort* __restrict__ B,
    float* __restrict__ C, int N, int K)
{
  constexpr int MFR = BM / 32;
  constexpr int MPP = MFR / 4;
  constexpr int ALOADS = BM / 128;
  __shared__ __align__(16) ushort As[2 * BM * 64];
  __shared__ __align__(16) ushort Bs[2 * 256 * 64];
  const int tid = threadIdx.x;
  const int lane = tid & 63;
  const int wid = tid >> 6;
  const int wr = wid >> 2, wc = wid & 3;
  const int rr = lane & 15, kq = lane >> 4;

  unsigned nwg = gridDim.x * gridDim.y;
  unsigned lb = blockIdx.y * gridDim.x + blockIdx.x;
  if ((nwg & 7u) == 0u) { unsigned cpx = nwg >> 3; lb = (lb & 7u) * cpx + (lb >> 3); }
  const int bm = (int)(lb % gridDim.x) * BM;
  const int bn = (int)(lb / gridDim.x) * 256;

  const ushort* Abase = A + (size_t)bm * K;
  const ushort* Bbase = B + (size_t)bn * K;

  auto stageA = [&](int buf, int h, int kt) {
    constexpr int HR = BM / 2;
#pragma unroll
    for (int L = 0; L < ALOADS; ++L) {
      int f = L * 512 + tid;
      int rl = f >> 3, g = f & 7;
      int gg = g ^ (rl & 7);
      lds_load16(Abase + (size_t)(h * HR + rl) * K + kt * 64 + gg * 8,
                 (void*)(As + buf * (BM * 64) + (h * HR + rl) * 64 + g * 8));
    }
  };
  auto stageB = [&](int buf, int h, int kt) {
#pragma unroll
    for (int L = 0; L < 2; ++L) {
      int f = L * 512 + tid;
      int rl = f >> 3, g = f & 7;
      int gg = g ^ (rl & 7);
      lds_load16(Bbase + (size_t)(h * 128 + rl) * K + kt * 64 + gg * 8,
                 (void*)(Bs + buf * (256 * 64) + (h * 128 + rl) * 64 + g * 8));
    }
  };
  auto rdA = [&](int buf, int r, int kbyte) {
    int sw = kbyte ^ ((r & 7) << 4);
    return *(const bf16x8*)(As + buf * (BM * 64) + r * 64 + (sw >> 1));
  };
  auto rdB = [&](int buf, int r, int kbyte) {
    int sw = kbyte ^ ((r & 7) << 4);
    return *(const bf16x8*)(Bs + buf * (256 * 64) + r * 64 + (sw >> 1));
  };

  f32x4 acc[MFR][4];
#pragma unroll
  for (int m = 0; m < MFR; ++m)
#pragma unroll
    for (int n = 0; n < 4; ++n) acc[m][n] = (f32x4){0.f, 0.f, 0.f, 0.f};

  const int NT = K >> 6;
  stageA(0, 0, 0); stageA(0, 1, 0); stageB(0, 0, 0); stageB(0, 1, 0);

  for (int t = 0; t < NT; ++t) {
    const int cur = t & 1;
    const bool more = (t + 1 < NT);
    if (more) stageA(cur ^ 1, 0, t + 1);
    if (more) {
      if constexpr (BM == 256) asm volatile("s_waitcnt vmcnt(2)" ::: "memory");
      else                     asm volatile("s_waitcnt vmcnt(1)" ::: "memory");
    } else {
      asm volatile("s_waitcnt vmcnt(0)" ::: "memory");
    }
    __syncthreads();

    bf16x8 bfr[4][2];
#pragma unroll
    for (int n = 0; n < 4; ++n)
#pragma unroll
      for (int kk = 0; kk < 2; ++kk)
        bfr[n][kk] = rdB(cur, wc * 64 + n * 16 + rr, kk * 64 + kq * 16);

#pragma unroll
    for (int mq = 0; mq < 4; ++mq) {
      if (mq == 1 && more) stageA(cur ^ 1, 1, t + 1);
      if (mq == 2 && more) stageB(cur ^ 1, 0, t + 1);
      if (mq == 3 && more) stageB(cur ^ 1, 1, t + 1);
      bf16x8 af[MPP][2];
#pragma unroll
      for (int mf = 0; mf < MPP; ++mf)
#pragma unroll
        for (int kk = 0; kk < 2; ++kk)
          af[mf][kk] = rdA(cur, wr * (BM / 2) + (mq * MPP + mf) * 16 + rr, kk * 64 + kq * 16);
      __builtin_amdgcn_s_setprio(1);
#pragma unroll
      for (int kk = 0; kk < 2; ++kk)
#pragma unroll
        for (int mf = 0; mf < MPP; ++mf)
#pragma unroll
          for (int n = 0; n < 4; ++n)
            acc[mq * MPP + mf][n] = __builtin_amdgcn_mfma_f32_16x16x32_bf16(
                af[mf][kk], bfr[n][kk], acc[mq * MPP + mf][n], 0, 0, 0);
      __builtin_amdgcn_s_setprio(0);
    }
    __syncthreads();
  }

  float* ep = (float*)Bs + wid * (16 * 68);
  const int cg = bn + wc * 64;
#pragma unroll
  for (int m = 0; m < MFR; ++m) {
    const int r0g = bm + wr * (BM / 2) + m * 16;
#pragma unroll
    for (int n = 0; n < 4; ++n)
#pragma unroll
      for (int j = 0; j < 4; ++j)
        ep[(kq * 4 + j) * 68 + n * 16 + rr] = acc[m][n][j];
#pragma unroll
    for (int i = 0; i < 4; ++i) {
      int row = i * 4 + kq;
      f32x4 v = *(const f32x4*)&ep[row * 68 + rr * 4];
      f32x4* dst = (f32x4*)&C[(size_t)(r0g + row) * N + cg + rr * 4];
      if constexpr (NTS) __builtin_nontemporal_store(v, dst);
      else *dst = v;
    }
  }
}

// ---------------- 128x128 2-blocks/CU MFMA GEMM (layer gemm1) ---------------
template<bool OUTBF>
__global__ __launch_bounds__(256, 2) void gemm2p_bt_bf16(
    const ushort* __restrict__ A, const ushort* __restrict__ B,
    void* __restrict__ Cv, int N, int K)
{
  __shared__ __align__(16) ushort As[2 * 128 * 64];
  __shared__ __align__(16) ushort Bs[2 * 128 * 64];
  const int tid = threadIdx.x;
  const int lane = tid & 63;
  const int wave = tid >> 6;
  const int wr = wave >> 1, wc = wave & 1;
  const int rr = lane & 15, kq = lane >> 4;

  unsigned nwg = gridDim.x * gridDim.y;
  unsigned lb = blockIdx.y * gridDim.x + blockIdx.x;
  if ((nwg & 7u) == 0u) { unsigned cpx = nwg >> 3; lb = (lb & 7u) * cpx + (lb >> 3); }
  const int bm = (int)(lb % gridDim.x) * 128;
  const int bn = (int)(lb / gridDim.x) * 128;

  const ushort* Abase = A + (size_t)bm * K;
  const ushort* Bbase = B + (size_t)bn * K;

  auto stage = [&](int buf, int kt) {
#pragma unroll
    for (int i = 0; i < 4; ++i) {
      int f = i * 256 + tid;
      int rl = f >> 3, g = f & 7;
      int gg = g ^ (rl & 7);
      lds_load16(Abase + (size_t)rl * K + kt * 64 + gg * 8,
                 (void*)(As + buf * 8192 + rl * 64 + g * 8));
      lds_load16(Bbase + (size_t)rl * K + kt * 64 + gg * 8,
                 (void*)(Bs + buf * 8192 + rl * 64 + g * 8));
    }
  };
  auto rdA = [&](int buf, int r, int kbyte) {
    int sw = kbyte ^ ((r & 7) << 4);
    return *(const bf16x8*)(As + buf * 8192 + r * 64 + (sw >> 1));
  };
  auto rdB = [&](int buf, int r, int kbyte) {
    int sw = kbyte ^ ((r & 7) << 4);
    return *(const bf16x8*)(Bs + buf * 8192 + r * 64 + (sw >> 1));
  };

  f32x4 acc[4][4];
#pragma unroll
  for (int m = 0; m < 4; ++m)
#pragma unroll
    for (int n = 0; n < 4; ++n) acc[m][n] = (f32x4){0.f, 0.f, 0.f, 0.f};

  const int NT = K >> 6;
  stage(0, 0);

  for (int t = 0; t < NT; ++t) {
    const int cur = t & 1;
    if (t + 1 < NT) {
      stage(cur ^ 1, t + 1);
      asm volatile("s_waitcnt vmcnt(8)" ::: "memory");
    } else {
      asm volatile("s_waitcnt vmcnt(0)" ::: "memory");
    }
    __syncthreads();
#pragma unroll
    for (int ks = 0; ks < 2; ++ks) {
      const int kbyte = ks * 64 + kq * 16;
      bf16x8 af[4], bfr[4];
#pragma unroll
      for (int m = 0; m < 4; ++m)
        af[m] = rdA(cur, wr * 64 + m * 16 + rr, kbyte);
#pragma unroll
      for (int n = 0; n < 4; ++n)
        bfr[n] = rdB(cur, wc * 64 + n * 16 + rr, kbyte);
      __builtin_amdgcn_s_setprio(1);
#pragma unroll
      for (int m = 0; m < 4; ++m)
#pragma unroll
        for (int n = 0; n < 4; ++n)
          acc[m][n] = __builtin_amdgcn_mfma_f32_16x16x32_bf16(af[m], bfr[n], acc[m][n], 0, 0, 0);
      __builtin_amdgcn_s_setprio(0);
    }
    __syncthreads();
  }

  float* ep = (float*)Bs + wave * (16 * 68);
  const int cg = bn + wc * 64;
#pragma unroll
  for (int m = 0; m < 4; ++m) {
    const int r0g = bm + wr * 64 + m * 16;
#pragma unroll
    for (int n = 0; n < 4; ++n)
#pragma unroll
      for (int j = 0; j < 4; ++j)
        ep[(kq * 4 + j) * 68 + n * 16 + rr] = acc[m][n][j];
#pragma unroll
    for (int i = 0; i < 4; ++i) {
      int row = i * 4 + kq;
      f32x4 v = *(const f32x4*)&ep[row * 68 + rr * 4];
      if constexpr (OUTBF) {
        ushort* C = (ushort*)Cv;
        ushort4 o = {f2bf(v.x), f2bf(v.y), f2bf(v.z), f2bf(v.w)};
        *(ushort4*)&C[(size_t)(r0g + row) * N + cg + rr * 4] = o;
      } else {
        float* C = (float*)Cv;
        *(f32x4*)&C[(size_t)(r0g + row) * N + cg + rr * 4] = v;
      }
    }
  }
}

// ---------------- split-K bf16 MFMA GEMM (2-phase 128x128) ------------------
__global__ __launch_bounds__(256) void gemm_btk_bf16(
    const ushort* __restrict__ A, const ushort* __restrict__ B,
    float* __restrict__ Cp, int M, int N, int K)
{
  __shared__ __align__(16) ushort As[128 * 64];
  __shared__ __align__(16) ushort Bs[128 * 64];
  const int tid = threadIdx.x;
  const int lane = tid & 63;
  const int wave = tid >> 6;
  const int wr = wave >> 1, wc = wave & 1;
  const int KC = K / gridDim.z;
  const int k0 = blockIdx.z * KC;

  unsigned nwg = gridDim.x * gridDim.y;
  unsigned lb = blockIdx.y * gridDim.x + blockIdx.x;
  if ((nwg & 7u) == 0u) {
    unsigned cpx = nwg >> 3;
    lb = (lb & 7u) * cpx + (lb >> 3);
  }
  const int bm = (lb % gridDim.x) * 128;
  const int bn = (lb / gridDim.x) * 128;
  const int rr = lane & 15, kq = lane >> 4;

  f32x4 acc[4][4];
#pragma unroll
  for (int m = 0; m < 4; ++m)
#pragma unroll
    for (int n = 0; n < 4; ++n) acc[m][n] = (f32x4){0.f, 0.f, 0.f, 0.f};

  for (int kt = 0; kt < KC; kt += 64) {
#pragma unroll
    for (int i = 0; i < 4; ++i) {
      int fb = i * 256 + tid;
      int row = fb >> 3, cb = fb & 7;
      lds_load16(A + (size_t)(bm + row) * K + k0 + kt + cb * 8, (void*)(As + (size_t)fb * 8));
      lds_load16(B + (size_t)(bn + row) * K + k0 + kt + cb * 8, (void*)(Bs + (size_t)fb * 8));
    }
    __syncthreads();
#pragma unroll
    for (int ks = 0; ks < 2; ++ks) {
      bf16x8 af[4], bfr[4];
      const int koff = ks * 32 + kq * 8;
#pragma unroll
      for (int m = 0; m < 4; ++m)
        af[m] = *(const bf16x8*)&As[(wr * 64 + m * 16 + rr) * 64 + koff];
#pragma unroll
      for (int n = 0; n < 4; ++n)
        bfr[n] = *(const bf16x8*)&Bs[(wc * 64 + n * 16 + rr) * 64 + koff];
#pragma unroll
      for (int m = 0; m < 4; ++m)
#pragma unroll
        for (int n = 0; n < 4; ++n)
          acc[m][n] = __builtin_amdgcn_mfma_f32_16x16x32_bf16(af[m], bfr[n], acc[m][n], 0, 0, 0);
    }
    __syncthreads();
  }
  float* C = Cp + (size_t)blockIdx.z * M * N;
#pragma unroll
  for (int m = 0; m < 4; ++m) {
    const int r0 = bm + wr * 64 + m * 16 + kq * 4;
#pragma unroll
    for (int n = 0; n < 4; ++n) {
      const int cc = bn + wc * 64 + n * 16 + rr;
#pragma unroll
      for (int j = 0; j < 4; ++j)
        C[(size_t)(r0 + j) * N + cc] = acc[m][n][j];
    }
  }
}

// ---------------- fused conv+SiLU + split-K MFMA projection -----------------
// grid (SEQ/128, 1, PZ): block computes u[bm..bm+127][kc..kc+127] from resu0,
// writes u once, and accumulates Cp[z] = u_chunk @ W_chunk^T (N=128, K=128).
__global__ __launch_bounds__(256) void convproj_mfma(
    const ushort* __restrict__ resu0, const ushort* __restrict__ W,
    const float* __restrict__ Wconv, ushort* __restrict__ u,
    float* __restrict__ Cp, int M)
{
  __shared__ __align__(16) ushort u0s[131][128];
  __shared__ __align__(16) ushort As[2][128 * 64];
  __shared__ __align__(16) ushort Bs[2][128 * 64];
  const int tid = threadIdx.x;
  const int lane = tid & 63;
  const int wave = tid >> 6;
  const int wr = wave >> 1, wc = wave & 1;
  const int rr = lane & 15, kq = lane >> 4;
  const int bm = blockIdx.x * 128;
  const int kc = blockIdx.z * 128;

  // stage W rows [0..127] x cols [kc..kc+127] via global_load_lds (async)
#pragma unroll
  for (int h = 0; h < 2; ++h)
#pragma unroll
    for (int i = 0; i < 4; ++i) {
      int f = i * 256 + tid;
      int rl = f >> 3, g = f & 7;
      lds_load16(W + (size_t)rl * DINNER + kc + h * 64 + g * 8,
                 (void*)(&Bs[h][rl * 64 + g * 8]));
    }

  // stage u0 rows bm-3..bm+127 (131) x 128 cols (bf16)
  for (int i = tid; i < 131 * 32; i += 256) {
    int row = i >> 5, c4 = (i & 31) * 4;
    int gr = bm - 3 + row;
    ushort4 v = {0, 0, 0, 0};
    if (gr >= 0)
      v = *(const ushort4*)&resu0[(size_t)gr * (2 * DINNER) + DINNER + kc + c4];
    *(ushort4*)&u0s[row][c4] = v;
  }
  __syncthreads();

  // conv + silu: each thread 16 rows x 4 cols -> As (LDS) + u (global)
  {
    const int c0 = (tid & 31) * 4;
    const int r0 = (tid >> 5) * 16;
    float4 w0 = *(const float4*)&Wconv[(kc + c0 + 0) * 4];
    float4 w1 = *(const float4*)&Wconv[(kc + c0 + 1) * 4];
    float4 w2 = *(const float4*)&Wconv[(kc + c0 + 2) * 4];
    float4 w3 = *(const float4*)&Wconv[(kc + c0 + 3) * 4];
    const int ks = c0 >> 6;
    const int cl = c0 & 63;
    for (int r = r0; r < r0 + 16; ++r) {
      ushort4 a0 = *(const ushort4*)&u0s[r + 0][c0];
      ushort4 a1 = *(const ushort4*)&u0s[r + 1][c0];
      ushort4 a2 = *(const ushort4*)&u0s[r + 2][c0];
      ushort4 a3 = *(const ushort4*)&u0s[r + 3][c0];
      float o0 = bf2f(a0.x) * w0.x + bf2f(a1.x) * w0.y + bf2f(a2.x) * w0.z + bf2f(a3.x) * w0.w;
      float o1 = bf2f(a0.y) * w1.x + bf2f(a1.y) * w1.y + bf2f(a2.y) * w1.z + bf2f(a3.y) * w1.w;
      float o2 = bf2f(a0.z) * w2.x + bf2f(a1.z) * w2.y + bf2f(a2.z) * w2.z + bf2f(a3.z) * w2.w;
      float o3 = bf2f(a0.w) * w3.x + bf2f(a1.w) * w3.y + bf2f(a2.w) * w3.z + bf2f(a3.w) * w3.w;
      o0 = o0 / (1.f + expf(-o0));
      o1 = o1 / (1.f + expf(-o1));
      o2 = o2 / (1.f + expf(-o2));
      o3 = o3 / (1.f + expf(-o3));
      ushort4 o = {f2bf(o0), f2bf(o1), f2bf(o2), f2bf(o3)};
      *(ushort4*)&As[ks][r * 64 + cl] = o;
      *(ushort4*)&u[(size_t)(bm + r) * DINNER + kc + c0] = o;
    }
  }
  asm volatile("s_waitcnt vmcnt(0)" ::: "memory");  // W staged
  __syncthreads();

  f32x4 acc[4][4];
#pragma unroll
  for (int m = 0; m < 4; ++m)
#pragma unroll
    for (int n = 0; n < 4; ++n) acc[m][n] = (f32x4){0.f, 0.f, 0.f, 0.f};

#pragma unroll
  for (int ks = 0; ks < 2; ++ks) {
#pragma unroll
    for (int kk = 0; kk < 2; ++kk) {
      const int koff = kk * 32 + kq * 8;
      bf16x8 af[4], bfr[4];
#pragma unroll
      for (int m = 0; m < 4; ++m)
        af[m] = *(const bf16x8*)&As[ks][(wr * 64 + m * 16 + rr) * 64 + koff];
#pragma unroll
      for (int n = 0; n < 4; ++n)
        bfr[n] = *(const bf16x8*)&Bs[ks][(wc * 64 + n * 16 + rr) * 64 + koff];
      __builtin_amdgcn_s_setprio(1);
#pragma unroll
      for (int m = 0; m < 4; ++m)
#pragma unroll
        for (int n = 0; n < 4; ++n)
          acc[m][n] = __builtin_amdgcn_mfma_f32_16x16x32_bf16(af[m], bfr[n], acc[m][n], 0, 0, 0);
      __builtin_amdgcn_s_setprio(0);
    }
  }

  float* C = Cp + (size_t)blockIdx.z * M * 128;
#pragma unroll
  for (int m = 0; m < 4; ++m) {
    const int r0 = bm + wr * 64 + m * 16 + kq * 4;
#pragma unroll
    for (int n = 0; n < 4; ++n) {
      const int cc = wc * 64 + n * 16 + rr;
#pragma unroll
      for (int j = 0; j < 4; ++j)
        C[(size_t)(r0 + j) * 128 + cc] = acc[m][n][j];
    }
  }
}

// ---------------- dt GEMM: dt = softplus(dtin @ Wdt2^T + bdt) -> bf16 -------
__global__ __launch_bounds__(256) void gemm_dt_bf16(
    const ushort* __restrict__ A, const ushort* __restrict__ W,
    const float* __restrict__ bias, ushort* __restrict__ dt)
{
  __shared__ __align__(16) ushort As[128 * 64];
  __shared__ __align__(16) ushort Bs[128 * 64];
  __shared__ float eps[4 * 16 * 68];
  const int tid = threadIdx.x;
  const int lane = tid & 63;
  const int wave = tid >> 6;
  const int wr = wave >> 1, wc = wave & 1;
  const int rr = lane & 15, kq = lane >> 4;
  const int bm = blockIdx.x * 128;
  const int bn = blockIdx.y * 128;

#pragma unroll
  for (int i = 0; i < 4; ++i) {
    int f = i * 256 + tid;
    int rl = f >> 3, g = f & 7;
    lds_load16(A + (size_t)(bm + rl) * DTRANK + g * 8, (void*)(As + (size_t)f * 8));
    lds_load16(W + (size_t)(bn + rl) * DTRANK + g * 8, (void*)(Bs + (size_t)f * 8));
  }
  asm volatile("s_waitcnt vmcnt(0)" ::: "memory");
  __syncthreads();

  f32x4 acc[4][4];
#pragma unroll
  for (int m = 0; m < 4; ++m)
#pragma unroll
    for (int n = 0; n < 4; ++n) acc[m][n] = (f32x4){0.f, 0.f, 0.f, 0.f};

#pragma unroll
  for (int ks = 0; ks < 2; ++ks) {
    bf16x8 af[4], bfr[4];
    const int koff = ks * 32 + kq * 8;
#pragma unroll
    for (int m = 0; m < 4; ++m)
      af[m] = *(const bf16x8*)&As[(wr * 64 + m * 16 + rr) * 64 + koff];
#pragma unroll
    for (int n = 0; n < 4; ++n)
      bfr[n] = *(const bf16x8*)&Bs[(wc * 64 + n * 16 + rr) * 64 + koff];
#pragma unroll
    for (int m = 0; m < 4; ++m)
#pragma unroll
      for (int n = 0; n < 4; ++n)
        acc[m][n] = __builtin_amdgcn_mfma_f32_16x16x32_bf16(af[m], bfr[n], acc[m][n], 0, 0, 0);
  }
  __syncthreads();

  float* ep = eps + wave * (16 * 68);
  const int cgb = bn + wc * 64 + rr * 4;
  float4 b4 = *(const float4*)&bias[cgb];
#pragma unroll
  for (int m = 0; m < 4; ++m) {
    const int r0g = bm + wr * 64 + m * 16;
#pragma unroll
    for (int n = 0; n < 4; ++n)
#pragma unroll
      for (int j = 0; j < 4; ++j)
        ep[(kq * 4 + j) * 68 + n * 16 + rr] = acc[m][n][j];
#pragma unroll
    for (int i = 0; i < 4; ++i) {
      int row = i * 4 + kq;
      f32x4 v = *(const f32x4*)&ep[row * 68 + rr * 4];
      float v0 = v.x + b4.x, v1 = v.y + b4.y, v2 = v.z + b4.z, v3 = v.w + b4.w;
      v0 = (v0 > 20.f) ? v0 : log1pf(expf(v0));
      v1 = (v1 > 20.f) ? v1 : log1pf(expf(v1));
      v2 = (v2 > 20.f) ? v2 : log1pf(expf(v2));
      v3 = (v3 > 20.f) ? v3 : log1pf(expf(v3));
      ushort4 o = {f2bf(v0), f2bf(v1), f2bf(v2), f2bf(v3)};
      *(ushort4*)&dt[(size_t)(r0g + row) * DINNER + cgb] = o;
    }
  }
}

// ---------------- x += P0 + P1, then RMSNorm(x)->bf16 (or plain cast) -------
__global__ __launch_bounds__(256) void add3_rms_kernel(
    const float* __restrict__ P0, const float* __restrict__ P1,
    float* __restrict__ x, ushort* __restrict__ dst, int donorm)
{
  size_t o = (size_t)blockIdx.x * (DMODEL / 4) + threadIdx.x;
  float4 a = ((const float4*)P0)[o];
  float4 b = ((const float4*)P1)[o];
  float4 c = ((float4*)x)[o];
  c.x += a.x + b.x; c.y += a.y + b.y; c.z += a.z + b.z; c.w += a.w + b.w;
  ((float4*)x)[o] = c;
  float sc = 1.f;
  if (donorm) {
    float s = c.x * c.x + c.y * c.y + c.z * c.z + c.w * c.w;
#pragma unroll
    for (int off = 32; off > 0; off >>= 1) s += __shfl_down(s, off);
    __shared__ float ws[4];
    if ((threadIdx.x & 63) == 0) ws[threadIdx.x >> 6] = s;
    __syncthreads();
    float tot = ws[0] + ws[1] + ws[2] + ws[3];
    sc = rsqrtf(tot * (1.0f / DMODEL) + 1e-6f);
  }
  ushort4 o4 = {f2bf(c.x * sc), f2bf(c.y * sc), f2bf(c.z * sc), f2bf(c.w * sc)};
  ((ushort4*)dst)[o] = o4;
}

// ---------------- embedding gather + RMSNorm -> x (f32) and xnb (bf16) ------
__global__ __launch_bounds__(256) void gather_rms_kernel(
    const int* __restrict__ ids, const float* __restrict__ embed,
    float* __restrict__ x, ushort* __restrict__ xnb)
{
  int row = blockIdx.x;
  int id = ids[row];
  float4 v = ((const float4*)(embed + (size_t)id * DMODEL))[threadIdx.x];
  size_t o = (size_t)row * (DMODEL / 4) + threadIdx.x;
  ((float4*)x)[o] = v;
  float s = v.x * v.x + v.y * v.y + v.z * v.z + v.w * v.w;
#pragma unroll
  for (int off = 32; off > 0; off >>= 1) s += __shfl_down(s, off);
  __shared__ float ws[4];
  if ((threadIdx.x & 63) == 0) ws[threadIdx.x >> 6] = s;
  __syncthreads();
  float tot = ws[0] + ws[1] + ws[2] + ws[3];
  float sc = rsqrtf(tot * (1.0f / DMODEL) + 1e-6f);
  ushort4 o4 = {f2bf(v.x * sc), f2bf(v.y * sc), f2bf(v.z * sc), f2bf(v.w * sc)};
  ((ushort4*)xnb)[o] = o4;
}

// ---- proj reduce: B/C -> bcdt f32 (cols 0..31), dt-in -> dtinb bf16 --------
__global__ __launch_bounds__(256) void proj_reduce(
    const float* __restrict__ Cp, float* __restrict__ bcdt,
    ushort* __restrict__ dtinb, int M)
{
  int idx = blockIdx.x * 256 + threadIdx.x;  // over M*96
  int row = idx / 96, col = idx - row * 96;
  float s = 0.f;
#pragma unroll
  for (int c = 0; c < PZ; ++c) s += Cp[(size_t)c * M * 128 + (size_t)row * 128 + col];
  if (col < 32) bcdt[(size_t)row * 96 + col] = s;
  else dtinb[(size_t)row * 64 + (col - 32)] = f2bf(s);
}

// ---------------- chunk-parallel selective scan (bf16 dt/u inputs) ----------
__global__ __launch_bounds__(256) void scan_pass1(
    const ushort* __restrict__ dt, const ushort* __restrict__ u,
    const float* __restrict__ bcdt, const float* __restrict__ logA,
    float* __restrict__ P, float* __restrict__ S)
{
  const int tid = threadIdx.x;
  const int n = tid & 15, dl = tid >> 4;
  const int dbase = blockIdx.x * 16;
  const int c = blockIdx.y;
  const int t0 = c * CLEN;
  const int d = dbase + dl;
  const float Aval = -expf(logA[d * DSTATE + n]);
  __shared__ float sdt[CLEN][16], su[CLEN][16], sB[CLEN][16];
  {
    int tt = tid >> 2, j0 = (tid & 3) * 4;
    ushort4 rd = *(const ushort4*)&dt[(size_t)(t0 + tt) * DINNER + dbase + j0];
    ushort4 ru = *(const ushort4*)&u[(size_t)(t0 + tt) * DINNER + dbase + j0];
    sdt[tt][j0 + 0] = bf2f(rd.x); sdt[tt][j0 + 1] = bf2f(rd.y);
    sdt[tt][j0 + 2] = bf2f(rd.z); sdt[tt][j0 + 3] = bf2f(rd.w);
    su[tt][j0 + 0] = bf2f(ru.x); su[tt][j0 + 1] = bf2f(ru.y);
    su[tt][j0 + 2] = bf2f(ru.z); su[tt][j0 + 3] = bf2f(ru.w);
    *(float4*)&sB[tt][j0] = *(const float4*)&bcdt[(size_t)(t0 + tt) * 96 + j0];
  }
  __syncthreads();
  float h = 0.f, pr = 1.f;
#pragma unroll 8
  for (int i = 0; i < CLEN; ++i) {
    float dtv = sdt[i][dl], uv = su[i][dl], Bv = sB[i][n];
    float dtA = dtv * Aval;
    float rinv = __builtin_amdgcn_rcpf(1.f - 0.5f * dtA);
    float dA = (1.f + 0.5f * dtA) * rinv;
    float dBu = dtv * Bv * rinv * uv;
    h = dA * h + dBu;
    pr *= dA;
  }
  size_t idx = (size_t)c * (DINNER * DSTATE) + (size_t)d * DSTATE + n;
  P[idx] = pr;
  S[idx] = h;
}

__global__ __launch_bounds__(256) void scan_pass2(
    const ushort* __restrict__ dt, const ushort* __restrict__ u,
    const float* __restrict__ bcdt, const float* __restrict__ logA,
    const float* __restrict__ Dp, const float* __restrict__ P,
    const float* __restrict__ S, const ushort* __restrict__ resu0,
    ushort* __restrict__ y2b)
{
  const int tid = threadIdx.x;
  const int n = tid & 15, dl = tid >> 4;
  const int dbase = blockIdx.x * 16;
  const int c = blockIdx.y;
  const int t0 = c * CLEN;
  const int d = dbase + dl;
  const float Aval = -expf(logA[d * DSTATE + n]);
  const float Dpv = Dp[d];
  __shared__ float sdt[CLEN][16], su[CLEN][16], sB[CLEN][16], sC[CLEN][16], sres[CLEN][16];
  {
    int tt = tid >> 2, j0 = (tid & 3) * 4;
    ushort4 rd = *(const ushort4*)&dt[(size_t)(t0 + tt) * DINNER + dbase + j0];
    ushort4 ru = *(const ushort4*)&u[(size_t)(t0 + tt) * DINNER + dbase + j0];
    ushort4 rr4 = *(const ushort4*)&resu0[(size_t)(t0 + tt) * (2 * DINNER) + dbase + j0];
    sdt[tt][j0 + 0] = bf2f(rd.x); sdt[tt][j0 + 1] = bf2f(rd.y);
    sdt[tt][j0 + 2] = bf2f(rd.z); sdt[tt][j0 + 3] = bf2f(rd.w);
    su[tt][j0 + 0] = bf2f(ru.x); su[tt][j0 + 1] = bf2f(ru.y);
    su[tt][j0 + 2] = bf2f(ru.z); su[tt][j0 + 3] = bf2f(ru.w);
    sres[tt][j0 + 0] = bf2f(rr4.x); sres[tt][j0 + 1] = bf2f(rr4.y);
    sres[tt][j0 + 2] = bf2f(rr4.z); sres[tt][j0 + 3] = bf2f(rr4.w);
    *(float4*)&sB[tt][j0] = *(const float4*)&bcdt[(size_t)(t0 + tt) * 96 + j0];
    *(float4*)&sC[tt][j0] = *(const float4*)&bcdt[(size_t)(t0 + tt) * 96 + 16 + j0];
  }
  float h = 0.f;
  {
    const size_t base = (size_t)d * DSTATE + n;
#pragma unroll 4
    for (int cc = 0; cc < c; ++cc) {
      size_t o = (size_t)cc * (DINNER * DSTATE) + base;
      h = P[o] * h + S[o];
    }
  }
  __syncthreads();
#pragma unroll 4
  for (int i = 0; i < CLEN; ++i) {
    float dtv = sdt[i][dl], uv = su[i][dl];
    float dtA = dtv * Aval;
    float rinv = __builtin_amdgcn_rcpf(1.f - 0.5f * dtA);
    float dA = (1.f + 0.5f * dtA) * rinv;
    float dBu = dtv * sB[i][n] * rinv * uv;
    h = dA * h + dBu;
    float p = h * sC[i][n];
    p += __shfl_xor(p, 1);
    p += __shfl_xor(p, 2);
    p += __shfl_xor(p, 4);
    p += __shfl_xor(p, 8);
    if (n == 0) {
      float rv = sres[i][dl];
      float yv = (p + uv * Dpv) * (rv / (1.f + expf(-rv)));
      y2b[(size_t)(t0 + i) * DINNER + d] = f2bf(yv);
    }
  }
}

// ---------------- unified weight preprocessing (one launch) -----------------
// segments: [0,S0): embed cast; [S0,S0+S1): Wres|Win concat-cast;
// [.., +S2): Wout cast; [.., +S3): WB|WC|Wdt1 concat-cast (pad 128);
// [.., +S4): Wdt2 cast.  All indices in float4 units.
__global__ __launch_bounds__(256) void preproc_kernel(
    const float* __restrict__ embed, const float* __restrict__ Wres,
    const float* __restrict__ Win, const float* __restrict__ Wout,
    const float* __restrict__ WB, const float* __restrict__ WC,
    const float* __restrict__ Wdt1, const float* __restrict__ Wdt2,
    ushort* __restrict__ eb, ushort* __restrict__ wcatb,
    ushort* __restrict__ woutb, ushort* __restrict__ wbcdtb,
    ushort* __restrict__ wdt2b)
{
  const size_t S0 = (size_t)VOCAB * DMODEL / 4;
  const size_t S1 = (size_t)NLAYER * 2 * DINNER * DMODEL / 4;
  const size_t S2 = (size_t)NLAYER * DMODEL * DINNER / 4;
  const size_t S3 = (size_t)NLAYER * 128 * DINNER / 4;
  const size_t S4 = (size_t)NLAYER * DINNER * DTRANK / 4;
  size_t i4 = (size_t)blockIdx.x * 256 + threadIdx.x;
  float4 v;
  ushort* dst;
  size_t di;
  if (i4 < S0) {
    v = ((const float4*)embed)[i4];
    dst = eb; di = i4;
  } else if (i4 < S0 + S1) {
    size_t j4 = i4 - S0;
    size_t e0 = j4 * 4;
    int k = (int)(e0 & (DMODEL - 1));
    int r = (int)((e0 >> 10) & (2 * DINNER - 1));
    int l = (int)(e0 >> 22);
    const float* src = (r < DINNER)
        ? &Wres[(((size_t)l * DINNER + r) << 10) + k]
        : &Win[(((size_t)l * DINNER + (r - DINNER)) << 10) + k];
    v = *(const float4*)src;
    dst = wcatb; di = j4;
  } else if (i4 < S0 + S1 + S2) {
    size_t j4 = i4 - S0 - S1;
    v = ((const float4*)Wout)[j4];
    dst = woutb; di = j4;
  } else if (i4 < S0 + S1 + S2 + S3) {
    size_t j4 = i4 - S0 - S1 - S2;
    int k4 = (int)(j4 & (DINNER / 4 - 1));
    int row = (int)((j4 >> 9) & 127);
    int l = (int)(j4 >> 16);
    int k = k4 * 4;
    v = (float4){0.f, 0.f, 0.f, 0.f};
    if (row < 16)       v = *(const float4*)&WB[((size_t)l * DSTATE + row) * DINNER + k];
    else if (row < 32)  v = *(const float4*)&WC[((size_t)l * DSTATE + (row - 16)) * DINNER + k];
    else if (row < 96)  v = *(const float4*)&Wdt1[((size_t)l * DTRANK + (row - 32)) * DINNER + k];
    dst = wbcdtb; di = j4;
  } else if (i4 < S0 + S1 + S2 + S3 + S4) {
    size_t j4 = i4 - S0 - S1 - S2 - S3;
    v = ((const float4*)Wdt2)[j4];
    dst = wdt2b; di = j4;
  } else {
    return;
  }
  ushort4 o = {f2bf(v.x), f2bf(v.y), f2bf(v.z), f2bf(v.w)};
  ((ushort4*)dst)[di] = o;
}

// ============================================================================
extern "C" void kernel_launch(void* const* d_in, const int* in_sizes, int n_in,
                              void* d_out, int out_size, void* d_ws, size_t ws_size,
                              hipStream_t stream) {
  (void)in_sizes; (void)n_in; (void)out_size;
  const int* token_ids = (const int*)d_in[0];
  const float* embed = (const float*)d_in[1];
  const float* Wres = (const float*)d_in[2];
  const float* Win = (const float*)d_in[3];
  const float* Wconv = (const float*)d_in[4];
  const float* WB = (const float*)d_in[5];
  const float* WC = (const float*)d_in[6];
  const float* Wdt1 = (const float*)d_in[7];
  const float* Wdt2 = (const float*)d_in[8];
  const float* bdt = (const float*)d_in[9];
  const float* logA = (const float*)d_in[10];
  const float* Dp = (const float*)d_in[11];
  const float* Wout = (const float*)d_in[12];
  float* out = (float*)d_out;

  char* w = (char*)d_ws;
  auto alloc = [&](size_t bytes) {
    char* p = w;
    w += (bytes + 255) & ~(size_t)255;
    return p;
  };
  ushort* eb     = (ushort*)alloc((size_t)VOCAB * DMODEL * 2);
  ushort* wcatb  = (ushort*)alloc((size_t)NLAYER * 2 * DINNER * DMODEL * 2);
  ushort* woutb  = (ushort*)alloc((size_t)NLAYER * DMODEL * DINNER * 2);
  ushort* wbcdtb = (ushort*)alloc((size_t)NLAYER * 128 * DINNER * 2);
  ushort* wdt2b  = (ushort*)alloc((size_t)NLAYER * DINNER * DTRANK * 2);
  float* x       = (float*)alloc((size_t)SEQ * DMODEL * 4);
  ushort* xnb    = (ushort*)alloc((size_t)SEQ * DMODEL * 2);
  ushort* resu0  = (ushort*)alloc((size_t)SEQ * 2 * DINNER * 2);
  ushort* u      = (ushort*)alloc((size_t)SEQ * DINNER * 2);
  float* bcdt    = (float*)alloc((size_t)SEQ * 96 * 4);
  ushort* dtinb  = (ushort*)alloc((size_t)SEQ * 64 * 2);
  ushort* dt     = (ushort*)alloc((size_t)SEQ * DINNER * 2);
  float* Cp      = (float*)alloc((size_t)PZ * SEQ * 128 * 4);
  float* Cp2     = (float*)alloc((size_t)2 * SEQ * DMODEL * 4);
  float* Pbuf    = (float*)alloc((size_t)NCHUNK * DINNER * DSTATE * 4);
  float* Sbuf    = (float*)alloc((size_t)NCHUNK * DINNER * DSTATE * 4);
  ushort* y2b    = (ushort*)alloc((size_t)SEQ * DINNER * 2);
  ushort* xb     = (ushort*)alloc((size_t)SEQ * DMODEL * 2);
  if ((size_t)(w - (char*)d_ws) > ws_size) return;

  // unified weight preprocessing (one launch) + gather
  {
    size_t total4 = (size_t)VOCAB * DMODEL / 4
                  + (size_t)NLAYER * 2 * DINNER * DMODEL / 4
                  + (size_t)NLAYER * DMODEL * DINNER / 4
                  + (size_t)NLAYER * 128 * DINNER / 4
                  + (size_t)NLAYER * DINNER * DTRANK / 4;
    int nblk = (int)((total4 + 255) / 256);
    preproc_kernel<<<nblk, 256, 0, stream>>>(
        embed, Wres, Win, Wout, WB, WC, Wdt1, Wdt2,
        eb, wcatb, woutb, wbcdtb, wdt2b);
  }
  gather_rms_kernel<<<SEQ, 256, 0, stream>>>(token_ids, embed, x, xnb);

  for (int i = 0; i < NLAYER; ++i) {
    const ushort* wcati = wcatb + (size_t)i * 2 * DINNER * DMODEL;
    const ushort* wouti = woutb + (size_t)i * DMODEL * DINNER;
    const float* wconvi = Wconv + (size_t)i * DINNER * 4;
    const ushort* wbcdtbi = wbcdtb + (size_t)i * 128 * DINNER;
    const ushort* wdt2bi = wdt2b + (size_t)i * DINNER * DTRANK;
    const float* bdti = bdt + (size_t)i * DINNER;
    const float* logAi = logA + (size_t)i * DINNER * DSTATE;
    const float* Dpi = Dp + (size_t)i * DINNER;

    gemm2p_bt_bf16<true><<<dim3(SEQ / 128, 2 * DINNER / 128), 256, 0, stream>>>(
        xnb, wcati, resu0, 2 * DINNER, DMODEL);
    // fused conv+silu + projection partials (replaces conv_silu + gemm_btk)
    convproj_mfma<<<dim3(SEQ / 128, 1, PZ), 256, 0, stream>>>(
        resu0, wbcdtbi, wconvi, u, Cp, SEQ);
    proj_reduce<<<SEQ * 96 / 256, 256, 0, stream>>>(Cp, bcdt, dtinb, SEQ);
    gemm_dt_bf16<<<dim3(SEQ / 128, DINNER / 128), 256, 0, stream>>>(
        dtinb, wdt2bi, bdti, dt);
    dim3 gs(DINNER / 16, NCHUNK);
    scan_pass1<<<gs, 256, 0, stream>>>(dt, u, bcdt, logAi, Pbuf, Sbuf);
    scan_pass2<<<gs, 256, 0, stream>>>(dt, u, bcdt, logAi, Dpi, Pbuf, Sbuf, resu0, y2b);
    gemm_btk_bf16<<<dim3(SEQ / 128, DMODEL / 128, 2), 256, 0, stream>>>(
        y2b, wouti, Cp2, SEQ, DMODEL, DINNER);
    add3_rms_kernel<<<SEQ, 256, 0, stream>>>(
        Cp2, Cp2 + (size_t)SEQ * DMODEL, x,
        (i < NLAYER - 1) ? xnb : xb, (i < NLAYER - 1) ? 1 : 0);
  }
  gemm8p_bt_bf16<256, true><<<dim3(SEQ / 256, VOCAB / 256), 512, 0, stream>>>(
      xb, eb, out, VOCAB, DMODEL);
}

// Round 17
// 1928.596 us; speedup vs baseline: 1.5618x; 1.0058x over previous
//
#include <hip/hip_runtime.h>

#define SEQ 2048
#define DMODEL 1024
#define DINNER 2048
#define DSTATE 16
#define DTRANK 64
#define NLAYER 8
#define VOCAB 32000
#define NCHUNK 32
#define CLEN 64   // SEQ / NCHUNK
#define PZ 16     // split-K chunks for the projection GEMM

typedef float f32x4 __attribute__((ext_vector_type(4)));
typedef short bf16x8 __attribute__((ext_vector_type(8)));

__device__ __forceinline__ ushort f2bf(float f) {
  union { float f; unsigned u; } v; v.f = f;
  unsigned r = v.u + 0x7fffu + ((v.u >> 16) & 1u);
  return (ushort)(r >> 16);
}
__device__ __forceinline__ float bf2f(ushort b) {
  union { unsigned u; float f; } v; v.u = ((unsigned)b) << 16;
  return v.f;
}

__device__ __forceinline__ void lds_load16(const void* g, void* l) {
  __builtin_amdgcn_global_load_lds(
      (const __attribute__((address_space(1))) void*)g,
      (__attribute__((address_space(3))) void*)l, 16, 0, 0);
}

// ---------------- 256x256 counted-vmcnt MFMA GEMM (proven ~197us logits) ----
template<int BM, bool NTS>
__global__ __launch_bounds__(512, 2) void gemm8p_bt_bf16(
    const ushort* __restrict__ A, const ushort* __restrict__ B,
    float* __restrict__ C, int N, int K)
{
  constexpr int MFR = BM / 32;
  constexpr int MPP = MFR / 4;
  constexpr int ALOADS = BM / 128;
  __shared__ __align__(16) ushort As[2 * BM * 64];
  __shared__ __align__(16) ushort Bs[2 * 256 * 64];
  const int tid = threadIdx.x;
  const int lane = tid & 63;
  const int wid = tid >> 6;
  const int wr = wid >> 2, wc = wid & 3;
  const int rr = lane & 15, kq = lane >> 4;

  unsigned nwg = gridDim.x * gridDim.y;
  unsigned lb = blockIdx.y * gridDim.x + blockIdx.x;
  if ((nwg & 7u) == 0u) { unsigned cpx = nwg >> 3; lb = (lb & 7u) * cpx + (lb >> 3); }
  const int bm = (int)(lb % gridDim.x) * BM;
  const int bn = (int)(lb / gridDim.x) * 256;

  const ushort* Abase = A + (size_t)bm * K;
  const ushort* Bbase = B + (size_t)bn * K;

  auto stageA = [&](int buf, int h, int kt) {
    constexpr int HR = BM / 2;
#pragma unroll
    for (int L = 0; L < ALOADS; ++L) {
      int f = L * 512 + tid;
      int rl = f >> 3, g = f & 7;
      int gg = g ^ (rl & 7);
      lds_load16(Abase + (size_t)(h * HR + rl) * K + kt * 64 + gg * 8,
                 (void*)(As + buf * (BM * 64) + (h * HR + rl) * 64 + g * 8));
    }
  };
  auto stageB = [&](int buf, int h, int kt) {
#pragma unroll
    for (int L = 0; L < 2; ++L) {
      int f = L * 512 + tid;
      int rl = f >> 3, g = f & 7;
      int gg = g ^ (rl & 7);
      lds_load16(Bbase + (size_t)(h * 128 + rl) * K + kt * 64 + gg * 8,
                 (void*)(Bs + buf * (256 * 64) + (h * 128 + rl) * 64 + g * 8));
    }
  };
  auto rdA = [&](int buf, int r, int kbyte) {
    int sw = kbyte ^ ((r & 7) << 4);
    return *(const bf16x8*)(As + buf * (BM * 64) + r * 64 + (sw >> 1));
  };
  auto rdB = [&](int buf, int r, int kbyte) {
    int sw = kbyte ^ ((r & 7) << 4);
    return *(const bf16x8*)(Bs + buf * (256 * 64) + r * 64 + (sw >> 1));
  };

  f32x4 acc[MFR][4];
#pragma unroll
  for (int m = 0; m < MFR; ++m)
#pragma unroll
    for (int n = 0; n < 4; ++n) acc[m][n] = (f32x4){0.f, 0.f, 0.f, 0.f};

  const int NT = K >> 6;
  stageA(0, 0, 0); stageA(0, 1, 0); stageB(0, 0, 0); stageB(0, 1, 0);

  for (int t = 0; t < NT; ++t) {
    const int cur = t & 1;
    const bool more = (t + 1 < NT);
    if (more) stageA(cur ^ 1, 0, t + 1);
    if (more) {
      if constexpr (BM == 256) asm volatile("s_waitcnt vmcnt(2)" ::: "memory");
      else                     asm volatile("s_waitcnt vmcnt(1)" ::: "memory");
    } else {
      asm volatile("s_waitcnt vmcnt(0)" ::: "memory");
    }
    __syncthreads();

    bf16x8 bfr[4][2];
#pragma unroll
    for (int n = 0; n < 4; ++n)
#pragma unroll
      for (int kk = 0; kk < 2; ++kk)
        bfr[n][kk] = rdB(cur, wc * 64 + n * 16 + rr, kk * 64 + kq * 16);

#pragma unroll
    for (int mq = 0; mq < 4; ++mq) {
      if (mq == 1 && more) stageA(cur ^ 1, 1, t + 1);
      if (mq == 2 && more) stageB(cur ^ 1, 0, t + 1);
      if (mq == 3 && more) stageB(cur ^ 1, 1, t + 1);
      bf16x8 af[MPP][2];
#pragma unroll
      for (int mf = 0; mf < MPP; ++mf)
#pragma unroll
        for (int kk = 0; kk < 2; ++kk)
          af[mf][kk] = rdA(cur, wr * (BM / 2) + (mq * MPP + mf) * 16 + rr, kk * 64 + kq * 16);
      __builtin_amdgcn_s_setprio(1);
#pragma unroll
      for (int kk = 0; kk < 2; ++kk)
#pragma unroll
        for (int mf = 0; mf < MPP; ++mf)
#pragma unroll
          for (int n = 0; n < 4; ++n)
            acc[mq * MPP + mf][n] = __builtin_amdgcn_mfma_f32_16x16x32_bf16(
                af[mf][kk], bfr[n][kk], acc[mq * MPP + mf][n], 0, 0, 0);
      __builtin_amdgcn_s_setprio(0);
    }
    __syncthreads();
  }

  float* ep = (float*)Bs + wid * (16 * 68);
  const int cg = bn + wc * 64;
#pragma unroll
  for (int m = 0; m < MFR; ++m) {
    const int r0g = bm + wr * (BM / 2) + m * 16;
#pragma unroll
    for (int n = 0; n < 4; ++n)
#pragma unroll
      for (int j = 0; j < 4; ++j)
        ep[(kq * 4 + j) * 68 + n * 16 + rr] = acc[m][n][j];
#pragma unroll
    for (int i = 0; i < 4; ++i) {
      int row = i * 4 + kq;
      f32x4 v = *(const f32x4*)&ep[row * 68 + rr * 4];
      f32x4* dst = (f32x4*)&C[(size_t)(r0g + row) * N + cg + rr * 4];
      if constexpr (NTS) __builtin_nontemporal_store(v, dst);
      else *dst = v;
    }
  }
}

// ---------------- 128x128 2-blocks/CU MFMA GEMM (layer gemm1) ---------------
template<bool OUTBF>
__global__ __launch_bounds__(256, 2) void gemm2p_bt_bf16(
    const ushort* __restrict__ A, const ushort* __restrict__ B,
    void* __restrict__ Cv, int N, int K)
{
  __shared__ __align__(16) ushort As[2 * 128 * 64];
  __shared__ __align__(16) ushort Bs[2 * 128 * 64];
  const int tid = threadIdx.x;
  const int lane = tid & 63;
  const int wave = tid >> 6;
  const int wr = wave >> 1, wc = wave & 1;
  const int rr = lane & 15, kq = lane >> 4;

  unsigned nwg = gridDim.x * gridDim.y;
  unsigned lb = blockIdx.y * gridDim.x + blockIdx.x;
  if ((nwg & 7u) == 0u) { unsigned cpx = nwg >> 3; lb = (lb & 7u) * cpx + (lb >> 3); }
  const int bm = (int)(lb % gridDim.x) * 128;
  const int bn = (int)(lb / gridDim.x) * 128;

  const ushort* Abase = A + (size_t)bm * K;
  const ushort* Bbase = B + (size_t)bn * K;

  auto stage = [&](int buf, int kt) {
#pragma unroll
    for (int i = 0; i < 4; ++i) {
      int f = i * 256 + tid;
      int rl = f >> 3, g = f & 7;
      int gg = g ^ (rl & 7);
      lds_load16(Abase + (size_t)rl * K + kt * 64 + gg * 8,
                 (void*)(As + buf * 8192 + rl * 64 + g * 8));
      lds_load16(Bbase + (size_t)rl * K + kt * 64 + gg * 8,
                 (void*)(Bs + buf * 8192 + rl * 64 + g * 8));
    }
  };
  auto rdA = [&](int buf, int r, int kbyte) {
    int sw = kbyte ^ ((r & 7) << 4);
    return *(const bf16x8*)(As + buf * 8192 + r * 64 + (sw >> 1));
  };
  auto rdB = [&](int buf, int r, int kbyte) {
    int sw = kbyte ^ ((r & 7) << 4);
    return *(const bf16x8*)(Bs + buf * 8192 + r * 64 + (sw >> 1));
  };

  f32x4 acc[4][4];
#pragma unroll
  for (int m = 0; m < 4; ++m)
#pragma unroll
    for (int n = 0; n < 4; ++n) acc[m][n] = (f32x4){0.f, 0.f, 0.f, 0.f};

  const int NT = K >> 6;
  stage(0, 0);

  for (int t = 0; t < NT; ++t) {
    const int cur = t & 1;
    if (t + 1 < NT) {
      stage(cur ^ 1, t + 1);
      asm volatile("s_waitcnt vmcnt(8)" ::: "memory");
    } else {
      asm volatile("s_waitcnt vmcnt(0)" ::: "memory");
    }
    __syncthreads();
#pragma unroll
    for (int ks = 0; ks < 2; ++ks) {
      const int kbyte = ks * 64 + kq * 16;
      bf16x8 af[4], bfr[4];
#pragma unroll
      for (int m = 0; m < 4; ++m)
        af[m] = rdA(cur, wr * 64 + m * 16 + rr, kbyte);
#pragma unroll
      for (int n = 0; n < 4; ++n)
        bfr[n] = rdB(cur, wc * 64 + n * 16 + rr, kbyte);
      __builtin_amdgcn_s_setprio(1);
#pragma unroll
      for (int m = 0; m < 4; ++m)
#pragma unroll
        for (int n = 0; n < 4; ++n)
          acc[m][n] = __builtin_amdgcn_mfma_f32_16x16x32_bf16(af[m], bfr[n], acc[m][n], 0, 0, 0);
      __builtin_amdgcn_s_setprio(0);
    }
    __syncthreads();
  }

  float* ep = (float*)Bs + wave * (16 * 68);
  const int cg = bn + wc * 64;
#pragma unroll
  for (int m = 0; m < 4; ++m) {
    const int r0g = bm + wr * 64 + m * 16;
#pragma unroll
    for (int n = 0; n < 4; ++n)
#pragma unroll
      for (int j = 0; j < 4; ++j)
        ep[(kq * 4 + j) * 68 + n * 16 + rr] = acc[m][n][j];
#pragma unroll
    for (int i = 0; i < 4; ++i) {
      int row = i * 4 + kq;
      f32x4 v = *(const f32x4*)&ep[row * 68 + rr * 4];
      if constexpr (OUTBF) {
        ushort* C = (ushort*)Cv;
        ushort4 o = {f2bf(v.x), f2bf(v.y), f2bf(v.z), f2bf(v.w)};
        *(ushort4*)&C[(size_t)(r0g + row) * N + cg + rr * 4] = o;
      } else {
        float* C = (float*)Cv;
        *(f32x4*)&C[(size_t)(r0g + row) * N + cg + rr * 4] = v;
      }
    }
  }
}

// ---------------- split-K bf16 MFMA GEMM (2-phase 128x128, T2 swizzle) ------
__global__ __launch_bounds__(256) void gemm_btk_bf16(
    const ushort* __restrict__ A, const ushort* __restrict__ B,
    float* __restrict__ Cp, int M, int N, int K)
{
  __shared__ __align__(16) ushort As[128 * 64];
  __shared__ __align__(16) ushort Bs[128 * 64];
  const int tid = threadIdx.x;
  const int lane = tid & 63;
  const int wave = tid >> 6;
  const int wr = wave >> 1, wc = wave & 1;
  const int KC = K / gridDim.z;
  const int k0 = blockIdx.z * KC;

  unsigned nwg = gridDim.x * gridDim.y;
  unsigned lb = blockIdx.y * gridDim.x + blockIdx.x;
  if ((nwg & 7u) == 0u) {
    unsigned cpx = nwg >> 3;
    lb = (lb & 7u) * cpx + (lb >> 3);
  }
  const int bm = (lb % gridDim.x) * 128;
  const int bn = (lb / gridDim.x) * 128;
  const int rr = lane & 15, kq = lane >> 4;

  auto rdA = [&](int r, int kbyte) {
    int sw = kbyte ^ ((r & 7) << 4);
    return *(const bf16x8*)(As + r * 64 + (sw >> 1));
  };
  auto rdB = [&](int r, int kbyte) {
    int sw = kbyte ^ ((r & 7) << 4);
    return *(const bf16x8*)(Bs + r * 64 + (sw >> 1));
  };

  f32x4 acc[4][4];
#pragma unroll
  for (int m = 0; m < 4; ++m)
#pragma unroll
    for (int n = 0; n < 4; ++n) acc[m][n] = (f32x4){0.f, 0.f, 0.f, 0.f};

  for (int kt = 0; kt < KC; kt += 64) {
#pragma unroll
    for (int i = 0; i < 4; ++i) {
      int fb = i * 256 + tid;
      int row = fb >> 3, g = fb & 7;
      int gg = g ^ (row & 7);  // pre-swizzled source granule
      lds_load16(A + (size_t)(bm + row) * K + k0 + kt + gg * 8, (void*)(As + (size_t)fb * 8));
      lds_load16(B + (size_t)(bn + row) * K + k0 + kt + gg * 8, (void*)(Bs + (size_t)fb * 8));
    }
    asm volatile("s_waitcnt vmcnt(0)" ::: "memory");
    __syncthreads();
#pragma unroll
    for (int ks = 0; ks < 2; ++ks) {
      const int kbyte = ks * 64 + kq * 16;
      bf16x8 af[4], bfr[4];
#pragma unroll
      for (int m = 0; m < 4; ++m)
        af[m] = rdA(wr * 64 + m * 16 + rr, kbyte);
#pragma unroll
      for (int n = 0; n < 4; ++n)
        bfr[n] = rdB(wc * 64 + n * 16 + rr, kbyte);
#pragma unroll
      for (int m = 0; m < 4; ++m)
#pragma unroll
        for (int n = 0; n < 4; ++n)
          acc[m][n] = __builtin_amdgcn_mfma_f32_16x16x32_bf16(af[m], bfr[n], acc[m][n], 0, 0, 0);
    }
    __syncthreads();
  }
  float* C = Cp + (size_t)blockIdx.z * M * N;
#pragma unroll
  for (int m = 0; m < 4; ++m) {
    const int r0 = bm + wr * 64 + m * 16 + kq * 4;
#pragma unroll
    for (int n = 0; n < 4; ++n) {
      const int cc = bn + wc * 64 + n * 16 + rr;
#pragma unroll
      for (int j = 0; j < 4; ++j)
        C[(size_t)(r0 + j) * N + cc] = acc[m][n][j];
    }
  }
}

// ---------------- fused conv+SiLU + split-K MFMA projection (T2 swizzle) ----
__global__ __launch_bounds__(256) void convproj_mfma(
    const ushort* __restrict__ resu0, const ushort* __restrict__ W,
    const float* __restrict__ Wconv, ushort* __restrict__ u,
    float* __restrict__ Cp, int M)
{
  __shared__ __align__(16) ushort u0s[131][128];
  __shared__ __align__(16) ushort As[2][128 * 64];
  __shared__ __align__(16) ushort Bs[2][128 * 64];
  const int tid = threadIdx.x;
  const int lane = tid & 63;
  const int wave = tid >> 6;
  const int wr = wave >> 1, wc = wave & 1;
  const int rr = lane & 15, kq = lane >> 4;
  const int bm = blockIdx.x * 128;
  const int kc = blockIdx.z * 128;

  // stage W rows [0..127] x cols [kc..kc+127] via global_load_lds (swizzled src)
#pragma unroll
  for (int h = 0; h < 2; ++h)
#pragma unroll
    for (int i = 0; i < 4; ++i) {
      int f = i * 256 + tid;
      int rl = f >> 3, g = f & 7;
      int gg = g ^ (rl & 7);
      lds_load16(W + (size_t)rl * DINNER + kc + h * 64 + gg * 8,
                 (void*)(&Bs[h][rl * 64 + g * 8]));
    }

  // stage u0 rows bm-3..bm+127 (131) x 128 cols (bf16)
  for (int i = tid; i < 131 * 32; i += 256) {
    int row = i >> 5, c4 = (i & 31) * 4;
    int gr = bm - 3 + row;
    ushort4 v = {0, 0, 0, 0};
    if (gr >= 0)
      v = *(const ushort4*)&resu0[(size_t)gr * (2 * DINNER) + DINNER + kc + c4];
    *(ushort4*)&u0s[row][c4] = v;
  }
  __syncthreads();

  // conv + silu: each thread 16 rows x 4 cols -> As (swizzled LDS) + u (global)
  {
    const int c0 = (tid & 31) * 4;
    const int r0 = (tid >> 5) * 16;
    float4 w0 = *(const float4*)&Wconv[(kc + c0 + 0) * 4];
    float4 w1 = *(const float4*)&Wconv[(kc + c0 + 1) * 4];
    float4 w2 = *(const float4*)&Wconv[(kc + c0 + 2) * 4];
    float4 w3 = *(const float4*)&Wconv[(kc + c0 + 3) * 4];
    const int ks = c0 >> 6;
    const int cl = c0 & 63;
    for (int r = r0; r < r0 + 16; ++r) {
      ushort4 a0 = *(const ushort4*)&u0s[r + 0][c0];
      ushort4 a1 = *(const ushort4*)&u0s[r + 1][c0];
      ushort4 a2 = *(const ushort4*)&u0s[r + 2][c0];
      ushort4 a3 = *(const ushort4*)&u0s[r + 3][c0];
      float o0 = bf2f(a0.x) * w0.x + bf2f(a1.x) * w0.y + bf2f(a2.x) * w0.z + bf2f(a3.x) * w0.w;
      float o1 = bf2f(a0.y) * w1.x + bf2f(a1.y) * w1.y + bf2f(a2.y) * w1.z + bf2f(a3.y) * w1.w;
      float o2 = bf2f(a0.z) * w2.x + bf2f(a1.z) * w2.y + bf2f(a2.z) * w2.z + bf2f(a3.z) * w2.w;
      float o3 = bf2f(a0.w) * w3.x + bf2f(a1.w) * w3.y + bf2f(a2.w) * w3.z + bf2f(a3.w) * w3.w;
      o0 = o0 / (1.f + expf(-o0));
      o1 = o1 / (1.f + expf(-o1));
      o2 = o2 / (1.f + expf(-o2));
      o3 = o3 / (1.f + expf(-o3));
      ushort4 o = {f2bf(o0), f2bf(o1), f2bf(o2), f2bf(o3)};
      // swizzled LDS write: granule (cl>>3) ^ (r&7), keep low 3 bits
      int sg = ((cl >> 3) ^ (r & 7)) * 8 + (cl & 7);
      *(ushort4*)&As[ks][r * 64 + sg] = o;
      *(ushort4*)&u[(size_t)(bm + r) * DINNER + kc + c0] = o;
    }
  }
  asm volatile("s_waitcnt vmcnt(0)" ::: "memory");  // W staged
  __syncthreads();

  f32x4 acc[4][4];
#pragma unroll
  for (int m = 0; m < 4; ++m)
#pragma unroll
    for (int n = 0; n < 4; ++n) acc[m][n] = (f32x4){0.f, 0.f, 0.f, 0.f};

#pragma unroll
  for (int ks = 0; ks < 2; ++ks) {
#pragma unroll
    for (int kk = 0; kk < 2; ++kk) {
      const int kbyte = kk * 64 + kq * 16;
      bf16x8 af[4], bfr[4];
#pragma unroll
      for (int m = 0; m < 4; ++m) {
        int r = wr * 64 + m * 16 + rr;
        int sw = kbyte ^ ((r & 7) << 4);
        af[m] = *(const bf16x8*)&As[ks][r * 64 + (sw >> 1)];
      }
#pragma unroll
      for (int n = 0; n < 4; ++n) {
        int r = wc * 64 + n * 16 + rr;
        int sw = kbyte ^ ((r & 7) << 4);
        bfr[n] = *(const bf16x8*)&Bs[ks][r * 64 + (sw >> 1)];
      }
      __builtin_amdgcn_s_setprio(1);
#pragma unroll
      for (int m = 0; m < 4; ++m)
#pragma unroll
        for (int n = 0; n < 4; ++n)
          acc[m][n] = __builtin_amdgcn_mfma_f32_16x16x32_bf16(af[m], bfr[n], acc[m][n], 0, 0, 0);
      __builtin_amdgcn_s_setprio(0);
    }
  }

  float* C = Cp + (size_t)blockIdx.z * M * 128;
#pragma unroll
  for (int m = 0; m < 4; ++m) {
    const int r0 = bm + wr * 64 + m * 16 + kq * 4;
#pragma unroll
    for (int n = 0; n < 4; ++n) {
      const int cc = wc * 64 + n * 16 + rr;
#pragma unroll
      for (int j = 0; j < 4; ++j)
        C[(size_t)(r0 + j) * 128 + cc] = acc[m][n][j];
    }
  }
}

// ---------------- dt GEMM (K=64, T2 swizzle): softplus epilogue -> bf16 -----
__global__ __launch_bounds__(256) void gemm_dt_bf16(
    const ushort* __restrict__ A, const ushort* __restrict__ W,
    const float* __restrict__ bias, ushort* __restrict__ dt)
{
  __shared__ __align__(16) ushort As[128 * 64];
  __shared__ __align__(16) ushort Bs[128 * 64];
  __shared__ float eps[4 * 16 * 68];
  const int tid = threadIdx.x;
  const int lane = tid & 63;
  const int wave = tid >> 6;
  const int wr = wave >> 1, wc = wave & 1;
  const int rr = lane & 15, kq = lane >> 4;
  const int bm = blockIdx.x * 128;
  const int bn = blockIdx.y * 128;

#pragma unroll
  for (int i = 0; i < 4; ++i) {
    int f = i * 256 + tid;
    int rl = f >> 3, g = f & 7;
    int gg = g ^ (rl & 7);
    lds_load16(A + (size_t)(bm + rl) * DTRANK + gg * 8, (void*)(As + (size_t)f * 8));
    lds_load16(W + (size_t)(bn + rl) * DTRANK + gg * 8, (void*)(Bs + (size_t)f * 8));
  }
  asm volatile("s_waitcnt vmcnt(0)" ::: "memory");
  __syncthreads();

  f32x4 acc[4][4];
#pragma unroll
  for (int m = 0; m < 4; ++m)
#pragma unroll
    for (int n = 0; n < 4; ++n) acc[m][n] = (f32x4){0.f, 0.f, 0.f, 0.f};

#pragma unroll
  for (int ks = 0; ks < 2; ++ks) {
    const int kbyte = ks * 64 + kq * 16;
    bf16x8 af[4], bfr[4];
#pragma unroll
    for (int m = 0; m < 4; ++m) {
      int r = wr * 64 + m * 16 + rr;
      int sw = kbyte ^ ((r & 7) << 4);
      af[m] = *(const bf16x8*)&As[r * 64 + (sw >> 1)];
    }
#pragma unroll
    for (int n = 0; n < 4; ++n) {
      int r = wc * 64 + n * 16 + rr;
      int sw = kbyte ^ ((r & 7) << 4);
      bfr[n] = *(const bf16x8*)&Bs[r * 64 + (sw >> 1)];
    }
#pragma unroll
    for (int m = 0; m < 4; ++m)
#pragma unroll
      for (int n = 0; n < 4; ++n)
        acc[m][n] = __builtin_amdgcn_mfma_f32_16x16x32_bf16(af[m], bfr[n], acc[m][n], 0, 0, 0);
  }
  __syncthreads();

  float* ep = eps + wave * (16 * 68);
  const int cgb = bn + wc * 64 + rr * 4;
  float4 b4 = *(const float4*)&bias[cgb];
#pragma unroll
  for (int m = 0; m < 4; ++m) {
    const int r0g = bm + wr * 64 + m * 16;
#pragma unroll
    for (int n = 0; n < 4; ++n)
#pragma unroll
      for (int j = 0; j < 4; ++j)
        ep[(kq * 4 + j) * 68 + n * 16 + rr] = acc[m][n][j];
#pragma unroll
    for (int i = 0; i < 4; ++i) {
      int row = i * 4 + kq;
      f32x4 v = *(const f32x4*)&ep[row * 68 + rr * 4];
      float v0 = v.x + b4.x, v1 = v.y + b4.y, v2 = v.z + b4.z, v3 = v.w + b4.w;
      v0 = (v0 > 20.f) ? v0 : log1pf(expf(v0));
      v1 = (v1 > 20.f) ? v1 : log1pf(expf(v1));
      v2 = (v2 > 20.f) ? v2 : log1pf(expf(v2));
      v3 = (v3 > 20.f) ? v3 : log1pf(expf(v3));
      ushort4 o = {f2bf(v0), f2bf(v1), f2bf(v2), f2bf(v3)};
      *(ushort4*)&dt[(size_t)(r0g + row) * DINNER + cgb] = o;
    }
  }
}

// ---------------- x += P0 + P1, then RMSNorm(x)->bf16 (or plain cast) -------
__global__ __launch_bounds__(256) void add3_rms_kernel(
    const float* __restrict__ P0, const float* __restrict__ P1,
    float* __restrict__ x, ushort* __restrict__ dst, int donorm)
{
  size_t o = (size_t)blockIdx.x * (DMODEL / 4) + threadIdx.x;
  float4 a = ((const float4*)P0)[o];
  float4 b = ((const float4*)P1)[o];
  float4 c = ((float4*)x)[o];
  c.x += a.x + b.x; c.y += a.y + b.y; c.z += a.z + b.z; c.w += a.w + b.w;
  ((float4*)x)[o] = c;
  float sc = 1.f;
  if (donorm) {
    float s = c.x * c.x + c.y * c.y + c.z * c.z + c.w * c.w;
#pragma unroll
    for (int off = 32; off > 0; off >>= 1) s += __shfl_down(s, off);
    __shared__ float ws[4];
    if ((threadIdx.x & 63) == 0) ws[threadIdx.x >> 6] = s;
    __syncthreads();
    float tot = ws[0] + ws[1] + ws[2] + ws[3];
    sc = rsqrtf(tot * (1.0f / DMODEL) + 1e-6f);
  }
  ushort4 o4 = {f2bf(c.x * sc), f2bf(c.y * sc), f2bf(c.z * sc), f2bf(c.w * sc)};
  ((ushort4*)dst)[o] = o4;
}

// ---------------- embedding gather + RMSNorm -> x (f32) and xnb (bf16) ------
__global__ __launch_bounds__(256) void gather_rms_kernel(
    const int* __restrict__ ids, const float* __restrict__ embed,
    float* __restrict__ x, ushort* __restrict__ xnb)
{
  int row = blockIdx.x;
  int id = ids[row];
  float4 v = ((const float4*)(embed + (size_t)id * DMODEL))[threadIdx.x];
  size_t o = (size_t)row * (DMODEL / 4) + threadIdx.x;
  ((float4*)x)[o] = v;
  float s = v.x * v.x + v.y * v.y + v.z * v.z + v.w * v.w;
#pragma unroll
  for (int off = 32; off > 0; off >>= 1) s += __shfl_down(s, off);
  __shared__ float ws[4];
  if ((threadIdx.x & 63) == 0) ws[threadIdx.x >> 6] = s;
  __syncthreads();
  float tot = ws[0] + ws[1] + ws[2] + ws[3];
  float sc = rsqrtf(tot * (1.0f / DMODEL) + 1e-6f);
  ushort4 o4 = {f2bf(v.x * sc), f2bf(v.y * sc), f2bf(v.z * sc), f2bf(v.w * sc)};
  ((ushort4*)xnb)[o] = o4;
}

// ---- proj reduce: B/C -> bcdt f32 (cols 0..31), dt-in -> dtinb bf16 --------
__global__ __launch_bounds__(256) void proj_reduce(
    const float* __restrict__ Cp, float* __restrict__ bcdt,
    ushort* __restrict__ dtinb, int M)
{
  int idx = blockIdx.x * 256 + threadIdx.x;  // over M*96
  int row = idx / 96, col = idx - row * 96;
  float s = 0.f;
#pragma unroll
  for (int c = 0; c < PZ; ++c) s += Cp[(size_t)c * M * 128 + (size_t)row * 128 + col];
  if (col < 32) bcdt[(size_t)row * 96 + col] = s;
  else dtinb[(size_t)row * 64 + (col - 32)] = f2bf(s);
}

// ---------------- chunk-parallel selective scan (bf16 dt/u inputs) ----------
__global__ __launch_bounds__(256) void scan_pass1(
    const ushort* __restrict__ dt, const ushort* __restrict__ u,
    const float* __restrict__ bcdt, const float* __restrict__ logA,
    float* __restrict__ P, float* __restrict__ S)
{
  const int tid = threadIdx.x;
  const int n = tid & 15, dl = tid >> 4;
  const int dbase = blockIdx.x * 16;
  const int c = blockIdx.y;
  const int t0 = c * CLEN;
  const int d = dbase + dl;
  const float Aval = -expf(logA[d * DSTATE + n]);
  __shared__ float sdt[CLEN][16], su[CLEN][16], sB[CLEN][16];
  {
    int tt = tid >> 2, j0 = (tid & 3) * 4;
    ushort4 rd = *(const ushort4*)&dt[(size_t)(t0 + tt) * DINNER + dbase + j0];
    ushort4 ru = *(const ushort4*)&u[(size_t)(t0 + tt) * DINNER + dbase + j0];
    sdt[tt][j0 + 0] = bf2f(rd.x); sdt[tt][j0 + 1] = bf2f(rd.y);
    sdt[tt][j0 + 2] = bf2f(rd.z); sdt[tt][j0 + 3] = bf2f(rd.w);
    su[tt][j0 + 0] = bf2f(ru.x); su[tt][j0 + 1] = bf2f(ru.y);
    su[tt][j0 + 2] = bf2f(ru.z); su[tt][j0 + 3] = bf2f(ru.w);
    *(float4*)&sB[tt][j0] = *(const float4*)&bcdt[(size_t)(t0 + tt) * 96 + j0];
  }
  __syncthreads();
  float h = 0.f, pr = 1.f;
#pragma unroll 8
  for (int i = 0; i < CLEN; ++i) {
    float dtv = sdt[i][dl], uv = su[i][dl], Bv = sB[i][n];
    float dtA = dtv * Aval;
    float rinv = __builtin_amdgcn_rcpf(1.f - 0.5f * dtA);
    float dA = (1.f + 0.5f * dtA) * rinv;
    float dBu = dtv * Bv * rinv * uv;
    h = dA * h + dBu;
    pr *= dA;
  }
  size_t idx = (size_t)c * (DINNER * DSTATE) + (size_t)d * DSTATE + n;
  P[idx] = pr;
  S[idx] = h;
}

__global__ __launch_bounds__(256) void scan_pass2(
    const ushort* __restrict__ dt, const ushort* __restrict__ u,
    const float* __restrict__ bcdt, const float* __restrict__ logA,
    const float* __restrict__ Dp, const float* __restrict__ P,
    const float* __restrict__ S, const ushort* __restrict__ resu0,
    ushort* __restrict__ y2b)
{
  const int tid = threadIdx.x;
  const int n = tid & 15, dl = tid >> 4;
  const int dbase = blockIdx.x * 16;
  const int c = blockIdx.y;
  const int t0 = c * CLEN;
  const int d = dbase + dl;
  const float Aval = -expf(logA[d * DSTATE + n]);
  const float Dpv = Dp[d];
  __shared__ float sdt[CLEN][16], su[CLEN][16], sB[CLEN][16], sC[CLEN][16], sres[CLEN][16];
  {
    int tt = tid >> 2, j0 = (tid & 3) * 4;
    ushort4 rd = *(const ushort4*)&dt[(size_t)(t0 + tt) * DINNER + dbase + j0];
    ushort4 ru = *(const ushort4*)&u[(size_t)(t0 + tt) * DINNER + dbase + j0];
    ushort4 rr4 = *(const ushort4*)&resu0[(size_t)(t0 + tt) * (2 * DINNER) + dbase + j0];
    sdt[tt][j0 + 0] = bf2f(rd.x); sdt[tt][j0 + 1] = bf2f(rd.y);
    sdt[tt][j0 + 2] = bf2f(rd.z); sdt[tt][j0 + 3] = bf2f(rd.w);
    su[tt][j0 + 0] = bf2f(ru.x); su[tt][j0 + 1] = bf2f(ru.y);
    su[tt][j0 + 2] = bf2f(ru.z); su[tt][j0 + 3] = bf2f(ru.w);
    sres[tt][j0 + 0] = bf2f(rr4.x); sres[tt][j0 + 1] = bf2f(rr4.y);
    sres[tt][j0 + 2] = bf2f(rr4.z); sres[tt][j0 + 3] = bf2f(rr4.w);
    *(float4*)&sB[tt][j0] = *(const float4*)&bcdt[(size_t)(t0 + tt) * 96 + j0];
    *(float4*)&sC[tt][j0] = *(const float4*)&bcdt[(size_t)(t0 + tt) * 96 + 16 + j0];
  }
  float h = 0.f;
  {
    const size_t base = (size_t)d * DSTATE + n;
#pragma unroll 4
    for (int cc = 0; cc < c; ++cc) {
      size_t o = (size_t)cc * (DINNER * DSTATE) + base;
      h = P[o] * h + S[o];
    }
  }
  __syncthreads();
#pragma unroll 4
  for (int i = 0; i < CLEN; ++i) {
    float dtv = sdt[i][dl], uv = su[i][dl];
    float dtA = dtv * Aval;
    float rinv = __builtin_amdgcn_rcpf(1.f - 0.5f * dtA);
    float dA = (1.f + 0.5f * dtA) * rinv;
    float dBu = dtv * sB[i][n] * rinv * uv;
    h = dA * h + dBu;
    float p = h * sC[i][n];
    p += __shfl_xor(p, 1);
    p += __shfl_xor(p, 2);
    p += __shfl_xor(p, 4);
    p += __shfl_xor(p, 8);
    if (n == 0) {
      float rv = sres[i][dl];
      float yv = (p + uv * Dpv) * (rv / (1.f + expf(-rv)));
      y2b[(size_t)(t0 + i) * DINNER + d] = f2bf(yv);
    }
  }
}

// ---------------- unified weight preprocessing (one launch) -----------------
__global__ __launch_bounds__(256) void preproc_kernel(
    const float* __restrict__ embed, const float* __restrict__ Wres,
    const float* __restrict__ Win, const float* __restrict__ Wout,
    const float* __restrict__ WB, const float* __restrict__ WC,
    const float* __restrict__ Wdt1, const float* __restrict__ Wdt2,
    ushort* __restrict__ eb, ushort* __restrict__ wcatb,
    ushort* __restrict__ woutb, ushort* __restrict__ wbcdtb,
    ushort* __restrict__ wdt2b)
{
  const size_t S0 = (size_t)VOCAB * DMODEL / 4;
  const size_t S1 = (size_t)NLAYER * 2 * DINNER * DMODEL / 4;
  const size_t S2 = (size_t)NLAYER * DMODEL * DINNER / 4;
  const size_t S3 = (size_t)NLAYER * 128 * DINNER / 4;
  const size_t S4 = (size_t)NLAYER * DINNER * DTRANK / 4;
  size_t i4 = (size_t)blockIdx.x * 256 + threadIdx.x;
  float4 v;
  ushort* dst;
  size_t di;
  if (i4 < S0) {
    v = ((const float4*)embed)[i4];
    dst = eb; di = i4;
  } else if (i4 < S0 + S1) {
    size_t j4 = i4 - S0;
    size_t e0 = j4 * 4;
    int k = (int)(e0 & (DMODEL - 1));
    int r = (int)((e0 >> 10) & (2 * DINNER - 1));
    int l = (int)(e0 >> 22);
    const float* src = (r < DINNER)
        ? &Wres[(((size_t)l * DINNER + r) << 10) + k]
        : &Win[(((size_t)l * DINNER + (r - DINNER)) << 10) + k];
    v = *(const float4*)src;
    dst = wcatb; di = j4;
  } else if (i4 < S0 + S1 + S2) {
    size_t j4 = i4 - S0 - S1;
    v = ((const float4*)Wout)[j4];
    dst = woutb; di = j4;
  } else if (i4 < S0 + S1 + S2 + S3) {
    size_t j4 = i4 - S0 - S1 - S2;
    int k4 = (int)(j4 & (DINNER / 4 - 1));
    int row = (int)((j4 >> 9) & 127);
    int l = (int)(j4 >> 16);
    int k = k4 * 4;
    v = (float4){0.f, 0.f, 0.f, 0.f};
    if (row < 16)       v = *(const float4*)&WB[((size_t)l * DSTATE + row) * DINNER + k];
    else if (row < 32)  v = *(const float4*)&WC[((size_t)l * DSTATE + (row - 16)) * DINNER + k];
    else if (row < 96)  v = *(const float4*)&Wdt1[((size_t)l * DTRANK + (row - 32)) * DINNER + k];
    dst = wbcdtb; di = j4;
  } else if (i4 < S0 + S1 + S2 + S3 + S4) {
    size_t j4 = i4 - S0 - S1 - S2 - S3;
    v = ((const float4*)Wdt2)[j4];
    dst = wdt2b; di = j4;
  } else {
    return;
  }
  ushort4 o = {f2bf(v.x), f2bf(v.y), f2bf(v.z), f2bf(v.w)};
  ((ushort4*)dst)[di] = o;
}

// ============================================================================
extern "C" void kernel_launch(void* const* d_in, const int* in_sizes, int n_in,
                              void* d_out, int out_size, void* d_ws, size_t ws_size,
                              hipStream_t stream) {
  (void)in_sizes; (void)n_in; (void)out_size;
  const int* token_ids = (const int*)d_in[0];
  const float* embed = (const float*)d_in[1];
  const float* Wres = (const float*)d_in[2];
  const float* Win = (const float*)d_in[3];
  const float* Wconv = (const float*)d_in[4];
  const float* WB = (const float*)d_in[5];
  const float* WC = (const float*)d_in[6];
  const float* Wdt1 = (const float*)d_in[7];
  const float* Wdt2 = (const float*)d_in[8];
  const float* bdt = (const float*)d_in[9];
  const float* logA = (const float*)d_in[10];
  const float* Dp = (const float*)d_in[11];
  const float* Wout = (const float*)d_in[12];
  float* out = (float*)d_out;

  char* w = (char*)d_ws;
  auto alloc = [&](size_t bytes) {
    char* p = w;
    w += (bytes + 255) & ~(size_t)255;
    return p;
  };
  ushort* eb     = (ushort*)alloc((size_t)VOCAB * DMODEL * 2);
  ushort* wcatb  = (ushort*)alloc((size_t)NLAYER * 2 * DINNER * DMODEL * 2);
  ushort* woutb  = (ushort*)alloc((size_t)NLAYER * DMODEL * DINNER * 2);
  ushort* wbcdtb = (ushort*)alloc((size_t)NLAYER * 128 * DINNER * 2);
  ushort* wdt2b  = (ushort*)alloc((size_t)NLAYER * DINNER * DTRANK * 2);
  float* x       = (float*)alloc((size_t)SEQ * DMODEL * 4);
  ushort* xnb    = (ushort*)alloc((size_t)SEQ * DMODEL * 2);
  ushort* resu0  = (ushort*)alloc((size_t)SEQ * 2 * DINNER * 2);
  ushort* u      = (ushort*)alloc((size_t)SEQ * DINNER * 2);
  float* bcdt    = (float*)alloc((size_t)SEQ * 96 * 4);
  ushort* dtinb  = (ushort*)alloc((size_t)SEQ * 64 * 2);
  ushort* dt     = (ushort*)alloc((size_t)SEQ * DINNER * 2);
  float* Cp      = (float*)alloc((size_t)PZ * SEQ * 128 * 4);
  float* Cp2     = (float*)alloc((size_t)2 * SEQ * DMODEL * 4);
  float* Pbuf    = (float*)alloc((size_t)NCHUNK * DINNER * DSTATE * 4);
  float* Sbuf    = (float*)alloc((size_t)NCHUNK * DINNER * DSTATE * 4);
  ushort* y2b    = (ushort*)alloc((size_t)SEQ * DINNER * 2);
  ushort* xb     = (ushort*)alloc((size_t)SEQ * DMODEL * 2);
  if ((size_t)(w - (char*)d_ws) > ws_size) return;

  {
    size_t total4 = (size_t)VOCAB * DMODEL / 4
                  + (size_t)NLAYER * 2 * DINNER * DMODEL / 4
                  + (size_t)NLAYER * DMODEL * DINNER / 4
                  + (size_t)NLAYER * 128 * DINNER / 4
                  + (size_t)NLAYER * DINNER * DTRANK / 4;
    int nblk = (int)((total4 + 255) / 256);
    preproc_kernel<<<nblk, 256, 0, stream>>>(
        embed, Wres, Win, Wout, WB, WC, Wdt1, Wdt2,
        eb, wcatb, woutb, wbcdtb, wdt2b);
  }
  gather_rms_kernel<<<SEQ, 256, 0, stream>>>(token_ids, embed, x, xnb);

  for (int i = 0; i < NLAYER; ++i) {
    const ushort* wcati = wcatb + (size_t)i * 2 * DINNER * DMODEL;
    const ushort* wouti = woutb + (size_t)i * DMODEL * DINNER;
    const float* wconvi = Wconv + (size_t)i * DINNER * 4;
    const ushort* wbcdtbi = wbcdtb + (size_t)i * 128 * DINNER;
    const ushort* wdt2bi = wdt2b + (size_t)i * DINNER * DTRANK;
    const float* bdti = bdt + (size_t)i * DINNER;
    const float* logAi = logA + (size_t)i * DINNER * DSTATE;
    const float* Dpi = Dp + (size_t)i * DINNER;

    gemm2p_bt_bf16<true><<<dim3(SEQ / 128, 2 * DINNER / 128), 256, 0, stream>>>(
        xnb, wcati, resu0, 2 * DINNER, DMODEL);
    convproj_mfma<<<dim3(SEQ / 128, 1, PZ), 256, 0, stream>>>(
        resu0, wbcdtbi, wconvi, u, Cp, SEQ);
    proj_reduce<<<SEQ * 96 / 256, 256, 0, stream>>>(Cp, bcdt, dtinb, SEQ);
    gemm_dt_bf16<<<dim3(SEQ / 128, DINNER / 128), 256, 0, stream>>>(
        dtinb, wdt2bi, bdti, dt);
    dim3 gs(DINNER / 16, NCHUNK);
    scan_pass1<<<gs, 256, 0, stream>>>(dt, u, bcdt, logAi, Pbuf, Sbuf);
    scan_pass2<<<gs, 256, 0, stream>>>(dt, u, bcdt, logAi, Dpi, Pbuf, Sbuf, resu0, y2b);
    gemm_btk_bf16<<<dim3(SEQ / 128, DMODEL / 128, 2), 256, 0, stream>>>(
        y2b, wouti, Cp2, SEQ, DMODEL, DINNER);
    add3_rms_kernel<<<SEQ, 256, 0, stream>>>(
        Cp2, Cp2 + (size_t)SEQ * DMODEL, x,
        (i < NLAYER - 1) ? xnb : xb, (i < NLAYER - 1) ? 1 : 0);
  }
  gemm8p_bt_bf16<256, true><<<dim3(SEQ / 256, VOCAB / 256), 512, 0, stream>>>(
      xb, eb, out, VOCAB, DMODEL);
}